// Round 1
// 6286.244 us; speedup vs baseline: 1.1447x; 1.1447x over previous
//
#include <hip/hip_runtime.h>
#include <hip/hip_bf16.h>

typedef unsigned short u16;
typedef unsigned int   u32;

constexpr int H     = 256;
constexpr int HH    = 128;
constexpr int MELD  = 80;
constexpr int RF    = 5;
constexpr int BS    = 128;
constexpr int TENC  = 512;
constexpr int TDEC  = 1000;
constexpr int STEPS = 200;
constexpr int OD    = 400;
constexpr int M_ALL = STEPS * BS;   // 25600

// ================= fast-path workspace layout (bytes) =================
constexpr size_t XS_B   = 0;                                  // xs f32 [s][b][128]
constexpr size_t W1ET_B = XS_B + (size_t)M_ALL*HH*4;          // w1eT bf16 [b][h][t] (PRE-SCALED by 2/ln2... see k_w1encT)
constexpr size_t DD_B   = W1ET_B + (size_t)BS*H*TENC*2;       // ddcat f32 [m][512] (d|ddot); later in2 [m][256]
constexpr size_t GI_B   = DD_B + (size_t)M_ALL*512*4;         // gi f32 [m][768]; also Q [m][256]
constexpr size_t P_B    = GI_B + (size_t)M_ALL*768*4;         // P f32 [m][256]; later st
constexpr size_t WPK_B  = P_B + (size_t)M_ALL*H*4;            // 3 packed whh, 393216 B each
constexpr size_t NEED_FAST = WPK_B + 3*(size_t)393216;

// ================= fallback (R4) workspace layout =====================
constexpr size_t FBW1E_B  = 65536;
constexpr size_t FBXST_B  = FBW1E_B + (size_t)BS*TENC*H*2;
constexpr size_t FBF32_B  = FBXST_B + (size_t)STEPS*HH*BS*2;
constexpr size_t FBDT_F   = 0;
constexpr size_t FBO1_F   = FBDT_F + 2*(size_t)H*BS;
constexpr size_t FBO2_F   = FBO1_F + 2*(size_t)H*BS;
constexpr size_t FBPT_F   = FBO2_F + 2*(size_t)H*BS;
constexpr size_t FBIN2_F  = FBPT_F + (size_t)H*BS;
constexpr size_t FBST_F   = FBIN2_F + (size_t)H*BS;
constexpr size_t FB_NEED_B = FBF32_B + (FBST_F + 2*(size_t)H*BS) * 4;

// ================= helpers =================
__device__ __forceinline__ float bf2f(u16 v) {
  union { u32 x; float f; } c; c.x = ((u32)v) << 16; return c.f;
}
__device__ __forceinline__ float bfu_lo(u32 u) { union { u32 x; float f; } c; c.x = u << 16;        return c.f; }
__device__ __forceinline__ float bfu_hi(u32 u) { union { u32 x; float f; } c; c.x = u & 0xffff0000u; return c.f; }
__device__ __forceinline__ u16 f2bf(float f) {
  union { float f; u32 u; } c; c.f = f;
  u32 u = c.u;
  u32 r = (u + 0x7fffu + ((u >> 16) & 1u)) >> 16;  // RNE
  return (u16)r;
}
__device__ __forceinline__ float fexp(float x) {
  return __builtin_amdgcn_exp2f(1.4426950408889634f * x);
}
__device__ __forceinline__ float sigm_f(float x) {
  return __builtin_amdgcn_rcpf(1.0f + __builtin_amdgcn_exp2f(-1.4426950408889634f * x));
}
__device__ __forceinline__ float tanh_f(float x) {
  x = fminf(fmaxf(x, -15.f), 15.f);
  float e = __builtin_amdgcn_exp2f(2.8853900817779268f * x);   // e^(2x)
  return (e - 1.0f) * __builtin_amdgcn_rcpf(e + 1.0f);
}

__global__ __launch_bounds__(256) void k_zero(float* __restrict__ out, int n) {
  int i = blockIdx.x * 256 + threadIdx.x;
  if (i < n) out[i] = 0.f;
}

// =====================================================================
//                           FAST PATH
// =====================================================================

// ---- prenet (2 fused layers) -> xs f32 [s][b][128] ----
__global__ __launch_bounds__(256) void k_prenet_f(
    const float* __restrict__ dec, const float* __restrict__ w1, const float* __restrict__ b1,
    const float* __restrict__ w2, const float* __restrict__ b2, float* __restrict__ xs)
{
  const int s = blockIdx.x, tid = threadIdx.x;
  __shared__ float X0[32][80];
  __shared__ float P1t[32][256];
  for (int bt = 0; bt < 4; ++bt) {
    const int b0 = bt * 32;
    __syncthreads();
    for (int i = tid; i < 32 * 80; i += 256) {
      int bb = i / 80, m = i - bb * 80;
      X0[bb][m] = dec[((size_t)(b0 + bb) * TDEC + (size_t)s * RF) * MELD + m];
    }
    __syncthreads();
    {
      const int h = tid;
      float acc[32];
      const float bias = b1[h];
      #pragma unroll
      for (int r = 0; r < 32; ++r) acc[r] = bias;
      const float* wr = w1 + (size_t)h * MELD;
      for (int m = 0; m < 80; m += 4) {
        float4 wv = *(const float4*)(wr + m);
        #pragma unroll
        for (int r = 0; r < 32; ++r) {
          float4 x = *(const float4*)&X0[r][m];
          acc[r] += x.x * wv.x + x.y * wv.y + x.z * wv.z + x.w * wv.w;
        }
      }
      #pragma unroll
      for (int r = 0; r < 32; ++r) P1t[r][h] = fmaxf(acc[r], 0.f);
    }
    __syncthreads();
    {
      const int k = tid & 127, bh = tid >> 7;
      float acc[16];
      const float bias = b2[k];
      #pragma unroll
      for (int r = 0; r < 16; ++r) acc[r] = bias;
      const float* wr = w2 + (size_t)k * H;
      for (int h = 0; h < H; h += 4) {
        float4 wv = *(const float4*)(wr + h);
        #pragma unroll
        for (int r = 0; r < 16; ++r) {
          float4 x = *(const float4*)&P1t[bh * 16 + r][h];
          acc[r] += x.x * wv.x + x.y * wv.y + x.z * wv.z + x.w * wv.w;
        }
      }
      #pragma unroll
      for (int r = 0; r < 16; ++r)
        xs[((size_t)s * BS + b0 + bh * 16 + r) * HH + k] = fmaxf(acc[r], 0.f);
    }
  }
}

// ---- w1enc transposed: w1eT[b][h][t] bf16, PRE-SCALED by 2/ln2-equivalent ----
// Stores 2.8853900817779268 * (enc@w1^T + b1) so that k_att's inner loop can
// evaluate tanh(x) = 1 - 2*rcp(1 + exp2(sx)) with sx = w_scaled + q_scaled.
__global__ __launch_bounds__(256) void k_w1encT(
    const float* __restrict__ enc, const float* __restrict__ w1, const float* __restrict__ b1,
    u16* __restrict__ w1eT)
{
  const int row0 = blockIdx.x * 32;   // row = b*TENC + t
  const int tid = threadIdx.x;
  __shared__ float A[32 * 256];
  for (int i = tid * 4; i < 32 * 256; i += 256 * 4) {
    float4 v = *(const float4*)(enc + (size_t)row0 * H + i);
    A[i] = v.x; A[i + 1] = v.y; A[i + 2] = v.z; A[i + 3] = v.w;
  }
  __syncthreads();
  const int h = tid;
  float acc[32];
  const float bias = b1[h];
  #pragma unroll
  for (int r = 0; r < 32; ++r) acc[r] = bias;
  const float* wr = w1 + (size_t)h * H;
  for (int k = 0; k < H; k += 4) {
    float4 wv = *(const float4*)(wr + k);
    #pragma unroll
    for (int r = 0; r < 32; ++r) {
      float4 a = *(const float4*)&A[r * 256 + k];
      acc[r] += a.x * wv.x + a.y * wv.y + a.z * wv.z + a.w * wv.w;
    }
  }
  const int b = row0 / TENC, t0 = row0 % TENC;
  #pragma unroll
  for (int r = 0; r < 32; ++r)
    w1eT[((size_t)b * H + h) * TENC + t0 + r] = f2bf(2.8853900817779268f * acc[r]);
}

// ---- pack whh f32[768][256] -> u32 planes [3][128][256] (bf16 k-pairs) ----
__global__ __launch_bounds__(256) void k_pack(const float* __restrict__ w, u32* __restrict__ o) {
  int idx = blockIdx.x * 256 + threadIdx.x;
  if (idx >= 3 * 128 * 256) return;
  int g = idx / 32768, rem = idx - g * 32768;
  int k2 = rem / 256, j = rem & 255;
  u32 lo = f2bf(w[((size_t)g * 256 + j) * 256 + 2 * k2]);
  u32 hi = f2bf(w[((size_t)g * 256 + j) * 256 + 2 * k2 + 1]);
  o[idx] = lo | (hi << 16);
}

// ---- tiled GEMM: C[M][N] = A[M][K] @ W[N][K]^T + bias ----
// if outmap != nullptr: write to mel-output layout instead of C.
__global__ __launch_bounds__(256) void k_gemm(
    const float* __restrict__ A, int lda, const float* __restrict__ W, int K,
    const float* __restrict__ bias, float* __restrict__ C, int ldc, int N,
    float* __restrict__ outmap)
{
  __shared__ float As[64][65];
  __shared__ float Ws[64][65];
  const int m0 = blockIdx.y * 64, n0 = blockIdx.x * 64;
  const int tid = threadIdx.x, tx = tid & 15, ty = tid >> 4;
  float acc[4][4] = {};
  for (int k0 = 0; k0 < K; k0 += 64) {
    #pragma unroll
    for (int it = 0; it < 4; ++it) {
      int flat = tid + it * 256;
      int r = flat >> 4, c4 = (flat & 15) * 4;
      *(float4*)&As[r][c4] = *(const float4*)(A + (size_t)(m0 + r) * lda + k0 + c4);
      float4 wv;
      if (n0 + r < N) wv = *(const float4*)(W + (size_t)(n0 + r) * K + k0 + c4);
      else { wv.x = wv.y = wv.z = wv.w = 0.f; }
      *(float4*)&Ws[r][c4] = wv;
    }
    __syncthreads();
    for (int kk = 0; kk < 64; ++kk) {
      float a0 = As[ty*4+0][kk], a1 = As[ty*4+1][kk], a2 = As[ty*4+2][kk], a3 = As[ty*4+3][kk];
      float b0 = Ws[tx*4+0][kk], b1 = Ws[tx*4+1][kk], b2 = Ws[tx*4+2][kk], b3 = Ws[tx*4+3][kk];
      acc[0][0]+=a0*b0; acc[0][1]+=a0*b1; acc[0][2]+=a0*b2; acc[0][3]+=a0*b3;
      acc[1][0]+=a1*b0; acc[1][1]+=a1*b1; acc[1][2]+=a1*b2; acc[1][3]+=a1*b3;
      acc[2][0]+=a2*b0; acc[2][1]+=a2*b1; acc[2][2]+=a2*b2; acc[2][3]+=a2*b3;
      acc[3][0]+=a3*b0; acc[3][1]+=a3*b1; acc[3][2]+=a3*b2; acc[3][3]+=a3*b3;
    }
    __syncthreads();
  }
  #pragma unroll
  for (int i = 0; i < 4; ++i) {
    const int m = m0 + ty * 4 + i;
    #pragma unroll
    for (int jj = 0; jj < 4; ++jj) {
      const int n = n0 + tx * 4 + jj;
      if (n < N) {
        float v = acc[i][jj] + bias[n];
        if (outmap == nullptr) {
          C[(size_t)m * ldc + n] = v;
        } else {
          int s = m >> 7, b = m & 127;
          int fr = s * RF + n / MELD, mel = n - (n / MELD) * MELD;
          outmap[((size_t)b * TDEC + fr) * MELD + mel] = v;
        }
      }
    }
  }
}

// ---- per-row sequential GRU chain (state in LDS, no grid sync) ----
constexpr int KC = 40;  // k-pairs of whh cached in LDS (of 128)
__global__ __launch_bounds__(256) void k_chain(
    const float* __restrict__ gi,      // [25600][768] includes bih
    const u32* __restrict__ wpk,       // [3][128][256]
    const float* __restrict__ bhh,     // [768]
    const float* __restrict__ addsrc,  // nullptr or [25600][astride]
    int astride,
    float* __restrict__ outp, int ostride)
{
  const int b = blockIdx.x, tid = threadIdx.x, j = tid;
  __shared__ float hsh[256];
  __shared__ u32 wl[3][KC * 256];
  for (int i = tid; i < 3 * KC * 256; i += 256) {
    int g = i / (KC * 256), rem = i - g * (KC * 256);
    wl[g][rem] = wpk[(size_t)g * 32768 + rem];
  }
  hsh[tid] = 0.f;
  const float br = bhh[j], bz = bhh[256 + j], bn = bhh[512 + j];
  const u32* pr_ = wpk;
  const u32* pz_ = wpk + 32768;
  const u32* pn_ = wpk + 65536;
  __syncthreads();
  for (int s = 0; s < STEPS; ++s) {
    const size_t m = (size_t)s * BS + b;
    const float* gim = gi + m * 768;
    float gr = gim[j], gz = gim[256 + j], gn = gim[512 + j];
    float ar = 0.f, az = 0.f, an = 0.f;
    #pragma unroll 4
    for (int k2 = 0; k2 < KC; ++k2) {
      float d0 = hsh[2 * k2], d1 = hsh[2 * k2 + 1];
      u32 wr = wl[0][k2 * 256 + j], wz = wl[1][k2 * 256 + j], wn = wl[2][k2 * 256 + j];
      ar += d0 * bfu_lo(wr) + d1 * bfu_hi(wr);
      az += d0 * bfu_lo(wz) + d1 * bfu_hi(wz);
      an += d0 * bfu_lo(wn) + d1 * bfu_hi(wn);
    }
    #pragma unroll 4
    for (int k2 = KC; k2 < 128; ++k2) {
      float d0 = hsh[2 * k2], d1 = hsh[2 * k2 + 1];
      u32 wr = pr_[k2 * 256 + j], wz = pz_[k2 * 256 + j], wn = pn_[k2 * 256 + j];
      ar += d0 * bfu_lo(wr) + d1 * bfu_hi(wr);
      az += d0 * bfu_lo(wz) + d1 * bfu_hi(wz);
      an += d0 * bfu_lo(wn) + d1 * bfu_hi(wn);
    }
    float r = sigm_f(gr + ar + br);
    float z = sigm_f(gz + az + bz);
    float n = tanh_f(gn + r * (an + bn));
    float hp = hsh[j];
    float hn_ = (1.f - z) * n + z * hp;
    __syncthreads();
    hsh[j] = hn_;
    float ov = hn_;
    if (addsrc) ov += addsrc[m * astride + j];
    outp[m * ostride + j] = ov;
    __syncthreads();
  }
}

// ---- fused scores + softmax + d_dot: block = (b, 10-step tile) ----
// Rewritten for occupancy + cheaper tanh:
//  * step tile 25 -> 10, esh staging dropped (enc read direct from L2/L3):
//    LDS 141KB -> ~32KB  => 4-5 blocks/CU instead of 1.
//  * v*tanh(x) = v - 2v*rcp(1+exp2(s*x)); s baked into w1eT + qt load,
//    -2v baked into vw table, sum(v) constant dropped (softmax shift-inv).
constexpr int ATT_ST = 10;
__global__ __launch_bounds__(256) void k_att(
    const u16* __restrict__ w1eT, const float* __restrict__ Q,
    const float* __restrict__ vw_, const float* __restrict__ enc,
    float* __restrict__ DD)
{
  const int b = blockIdx.x, s0 = blockIdx.y * ATT_ST, tid = threadIdx.x;
  __shared__ float qt[ATT_ST][260];
  __shared__ float vws[256];
  __shared__ float us[ATT_ST][516];
  __shared__ float redw[ATT_ST][4];
  vws[tid] = -2.0f * vw_[tid];
  #pragma unroll
  for (int si = 0; si < ATT_ST; ++si)
    qt[si][tid] = 2.8853900817779268f * Q[((size_t)(s0 + si) * BS + b) * H + tid];
  __syncthreads();

  // ---- scores: sc = sum_h (-2 v_h) * rcp(1 + exp2(w_sc + q_sc)) ----
  float sc0[ATT_ST], sc1[ATT_ST];
  #pragma unroll
  for (int si = 0; si < ATT_ST; ++si) { sc0[si] = 0.f; sc1[si] = 0.f; }
  const u32* wrow = (const u32*)w1eT + (size_t)b * H * (TENC / 2);
  for (int h = 0; h < H; h += 2) {
    u32 wa = wrow[(size_t)h * 256 + tid];          // t = 2*tid, 2*tid+1
    u32 wb = wrow[(size_t)(h + 1) * 256 + tid];
    float wa0 = bfu_lo(wa), wa1 = bfu_hi(wa);
    float wb0 = bfu_lo(wb), wb1 = bfu_hi(wb);
    float va = vws[h], vb = vws[h + 1];
    #pragma unroll
    for (int si = 0; si < ATT_ST; ++si) {
      float2 q2 = *(const float2*)&qt[si][h];
      sc0[si] += va * __builtin_amdgcn_rcpf(1.f + __builtin_amdgcn_exp2f(wa0 + q2.x))
               + vb * __builtin_amdgcn_rcpf(1.f + __builtin_amdgcn_exp2f(wb0 + q2.y));
      sc1[si] += va * __builtin_amdgcn_rcpf(1.f + __builtin_amdgcn_exp2f(wa1 + q2.x))
               + vb * __builtin_amdgcn_rcpf(1.f + __builtin_amdgcn_exp2f(wb1 + q2.y));
    }
  }
  // softmax over 512 t (2 per thread x 256 threads, 4 waves)
  const int lane = tid & 63, wvi = tid >> 6;
  #pragma unroll
  for (int si = 0; si < ATT_ST; ++si) {
    float mw = fmaxf(sc0[si], sc1[si]);
    for (int off = 1; off < 64; off <<= 1) mw = fmaxf(mw, __shfl_xor(mw, off));
    if (lane == 0) redw[si][wvi] = mw;
  }
  __syncthreads();
  #pragma unroll
  for (int si = 0; si < ATT_ST; ++si) {
    float mx = fmaxf(fmaxf(redw[si][0], redw[si][1]), fmaxf(redw[si][2], redw[si][3]));
    sc0[si] = fexp(sc0[si] - mx);
    sc1[si] = fexp(sc1[si] - mx);
  }
  __syncthreads();
  #pragma unroll
  for (int si = 0; si < ATT_ST; ++si) {
    float sm = sc0[si] + sc1[si];
    for (int off = 1; off < 64; off <<= 1) sm += __shfl_xor(sm, off);
    if (lane == 0) redw[si][wvi] = sm;
  }
  __syncthreads();
  #pragma unroll
  for (int si = 0; si < ATT_ST; ++si) {
    float tot = redw[si][0] + redw[si][1] + redw[si][2] + redw[si][3];
    float li = __builtin_amdgcn_rcpf(tot);
    float2 uv; uv.x = sc0[si] * li; uv.y = sc1[si] * li;
    *(float2*)&us[si][2 * tid] = uv;
  }
  __syncthreads();
  // ---- d_dot[si][h=tid] = sum_t us[si][t] * enc[b][t][h]  (enc direct) ----
  float dd[ATT_ST];
  #pragma unroll
  for (int si = 0; si < ATT_ST; ++si) dd[si] = 0.f;
  const float* ep = enc + (size_t)b * TENC * H + tid;
  for (int t = 0; t < TENC; t += 4) {
    float e0 = ep[(size_t)(t + 0) * H];
    float e1 = ep[(size_t)(t + 1) * H];
    float e2 = ep[(size_t)(t + 2) * H];
    float e3 = ep[(size_t)(t + 3) * H];
    #pragma unroll
    for (int si = 0; si < ATT_ST; ++si) {
      float4 u4 = *(const float4*)&us[si][t];
      dd[si] += e0 * u4.x + e1 * u4.y + e2 * u4.z + e3 * u4.w;
    }
  }
  #pragma unroll
  for (int si = 0; si < ATT_ST; ++si)
    DD[((size_t)(s0 + si) * BS + b) * 512 + 256 + tid] = dd[si];
}

// =====================================================================
//                      FALLBACK PATH (R4, verified)
// =====================================================================
__global__ __launch_bounds__(256) void fbk_zeroinit(float* __restrict__ fst) {
  int i = blockIdx.x * 256 + threadIdx.x;
  if (i < H * BS)              fst[FBDT_F + i] = 0.f;
  else if (i < 2 * H * BS)     fst[FBO1_F + (i - H * BS)] = 0.f;
  else if (i < 3 * H * BS)     fst[FBO2_F + (i - 2 * H * BS)] = 0.f;
}

__global__ __launch_bounds__(256) void fbk_prenet(
    const float* __restrict__ dec, const float* __restrict__ w1, const float* __restrict__ b1,
    const float* __restrict__ w2, const float* __restrict__ b2, u16* __restrict__ xsT)
{
  const int s = blockIdx.x, tid = threadIdx.x;
  __shared__ float X0[32][80];
  __shared__ float P1t[32][256];
  for (int bt = 0; bt < 4; ++bt) {
    const int b0 = bt * 32;
    __syncthreads();
    for (int i = tid; i < 32 * 80; i += 256) {
      int bb = i / 80, m = i - bb * 80;
      X0[bb][m] = dec[((size_t)(b0 + bb) * TDEC + (size_t)s * RF) * MELD + m];
    }
    __syncthreads();
    {
      const int h = tid;
      float acc[32];
      const float bias = b1[h];
      #pragma unroll
      for (int r = 0; r < 32; ++r) acc[r] = bias;
      const float* wr = w1 + (size_t)h * MELD;
      for (int m = 0; m < 80; m += 4) {
        float4 wv = *(const float4*)(wr + m);
        #pragma unroll
        for (int r = 0; r < 32; ++r) {
          float4 x = *(const float4*)&X0[r][m];
          acc[r] += x.x * wv.x + x.y * wv.y + x.z * wv.z + x.w * wv.w;
        }
      }
      #pragma unroll
      for (int r = 0; r < 32; ++r) P1t[r][h] = fmaxf(acc[r], 0.f);
    }
    __syncthreads();
    {
      const int k = tid & 127, bh = tid >> 7;
      float acc[16];
      const float bias = b2[k];
      #pragma unroll
      for (int r = 0; r < 16; ++r) acc[r] = bias;
      const float* wr = w2 + (size_t)k * H;
      for (int h = 0; h < H; h += 4) {
        float4 wv = *(const float4*)(wr + h);
        #pragma unroll
        for (int r = 0; r < 16; ++r) {
          float4 x = *(const float4*)&P1t[bh * 16 + r][h];
          acc[r] += x.x * wv.x + x.y * wv.y + x.z * wv.z + x.w * wv.w;
        }
      }
      #pragma unroll
      for (int r = 0; r < 16; ++r)
        xsT[((size_t)s * HH + k) * BS + b0 + bh * 16 + r] = f2bf(fmaxf(acc[r], 0.f));
    }
  }
}

__global__ __launch_bounds__(256) void fbk_w1enc(
    const float* __restrict__ enc, const float* __restrict__ w1, const float* __restrict__ b1,
    u16* __restrict__ w1e)
{
  const int row0 = blockIdx.x * 32;
  const int tid = threadIdx.x;
  __shared__ float A[32 * 256];
  for (int i = tid * 4; i < 32 * 256; i += 256 * 4) {
    float4 v = *(const float4*)(enc + (size_t)row0 * H + i);
    A[i] = v.x; A[i + 1] = v.y; A[i + 2] = v.z; A[i + 3] = v.w;
  }
  __syncthreads();
  const int h = tid;
  float acc[32];
  const float bias = b1[h];
  #pragma unroll
  for (int r = 0; r < 32; ++r) acc[r] = bias;
  const float* wr = w1 + (size_t)h * H;
  for (int k = 0; k < H; k += 4) {
    float4 wv = *(const float4*)(wr + k);
    #pragma unroll
    for (int r = 0; r < 32; ++r) {
      float4 a = *(const float4*)&A[r * 256 + k];
      acc[r] += a.x * wv.x + a.y * wv.y + a.z * wv.z + a.w * wv.w;
    }
  }
  #pragma unroll
  for (int r = 0; r < 32; ++r) w1e[((size_t)row0 + r) * H + h] = f2bf(acc[r]);
}

__device__ __forceinline__ void fb_gru_body(
    float (*w6)[260], float (*pA)[128], float (*pB)[128], int j, int tid,
    const float* __restrict__ gi_src, const float* __restrict__ h_src,
    const float* __restrict__ wih, const float* __restrict__ whh,
    const float* __restrict__ bih, const float* __restrict__ bhh,
    float* __restrict__ h_out, float* __restrict__ sum_out)
{
  for (int i = tid; i < 3 * H; i += 256) {
    int gg = i >> 8, k = i & 255;
    w6[gg][k]     = wih[((size_t)gg * H + j) * H + k];
    w6[3 + gg][k] = whh[((size_t)gg * H + j) * H + k];
  }
  __syncthreads();
  const int b = tid & 127, kh = tid >> 7;
  float pr = 0, pz = 0, pn = 0, hr = 0, hz = 0, hn = 0;
  for (int k = kh * 128; k < kh * 128 + 128; k += 4) {
    float4 wia = *(const float4*)&w6[0][k];
    float4 wib = *(const float4*)&w6[1][k];
    float4 wic = *(const float4*)&w6[2][k];
    float4 wha = *(const float4*)&w6[3][k];
    float4 whb = *(const float4*)&w6[4][k];
    float4 whc = *(const float4*)&w6[5][k];
    float x0 = gi_src[(size_t)(k + 0) * BS + b], x1 = gi_src[(size_t)(k + 1) * BS + b];
    float x2 = gi_src[(size_t)(k + 2) * BS + b], x3 = gi_src[(size_t)(k + 3) * BS + b];
    float h0 = h_src[(size_t)(k + 0) * BS + b],  h1 = h_src[(size_t)(k + 1) * BS + b];
    float h2 = h_src[(size_t)(k + 2) * BS + b],  h3 = h_src[(size_t)(k + 3) * BS + b];
    pr += x0 * wia.x + x1 * wia.y + x2 * wia.z + x3 * wia.w;
    pz += x0 * wib.x + x1 * wib.y + x2 * wib.z + x3 * wib.w;
    pn += x0 * wic.x + x1 * wic.y + x2 * wic.z + x3 * wic.w;
    hr += h0 * wha.x + h1 * wha.y + h2 * wha.z + h3 * wha.w;
    hz += h0 * whb.x + h1 * whb.y + h2 * whb.z + h3 * whb.w;
    hn += h0 * whc.x + h1 * whc.y + h2 * whc.z + h3 * whc.w;
  }
  if (kh) {
    pA[0][b] = pr; pA[1][b] = pz; pA[2][b] = pn;
    pB[0][b] = hr; pB[1][b] = hz; pB[2][b] = hn;
  }
  __syncthreads();
  if (!kh) {
    float gir = pr + pA[0][b] + bih[j];
    float giz = pz + pA[1][b] + bih[H + j];
    float gin = pn + pA[2][b] + bih[2 * H + j];
    float ghr = hr + pB[0][b] + bhh[j];
    float ghz = hz + pB[1][b] + bhh[H + j];
    float ghn = hn + pB[2][b] + bhh[2 * H + j];
    float r = sigm_f(gir + ghr);
    float z = sigm_f(giz + ghz);
    float n = tanh_f(gin + r * ghn);
    float hp = h_src[(size_t)j * BS + b];
    float o = (1.f - z) * n + z * hp;
    h_out[(size_t)j * BS + b] = o;
    if (sum_out) sum_out[(size_t)j * BS + b] = o + gi_src[(size_t)j * BS + b];
  }
}

__global__ __launch_bounds__(256) void fbk_attgru(
    const u16* __restrict__ xstu, float* __restrict__ fst,
    const float* __restrict__ awih, const float* __restrict__ awhh,
    const float* __restrict__ abih, const float* __restrict__ abhh, int s)
{
  const int j = blockIdx.x, tid = threadIdx.x;
  __shared__ float w6[6][260];
  __shared__ float pA[3][128];
  __shared__ float pB[3][128];
  const float* dprev = fst + FBDT_F + (size_t)(s & 1) * H * BS;
  float*       dcur  = fst + FBDT_F + (size_t)((s + 1) & 1) * H * BS;
  for (int i = tid; i < 3 * HH; i += 256) {
    int gg = i >> 7, k = i & (HH - 1);
    w6[gg][k] = awih[((size_t)gg * H + j) * HH + k];
  }
  for (int i = tid; i < 3 * H; i += 256) {
    int gg = i >> 8, k = i & (H - 1);
    w6[3 + gg][k] = awhh[((size_t)gg * H + j) * H + k];
  }
  __syncthreads();
  const u16* xcol = xstu + (size_t)s * HH * BS;
  const int b = tid & 127, kh = tid >> 7;
  float pr = 0, pz = 0, pn = 0, hr = 0, hz = 0, hn = 0;
  for (int k = kh * 64; k < kh * 64 + 64; k += 4) {
    float4 wa = *(const float4*)&w6[0][k];
    float4 wb = *(const float4*)&w6[1][k];
    float4 wc = *(const float4*)&w6[2][k];
    float x0 = bf2f(xcol[(size_t)(k + 0) * BS + b]), x1 = bf2f(xcol[(size_t)(k + 1) * BS + b]);
    float x2 = bf2f(xcol[(size_t)(k + 2) * BS + b]), x3 = bf2f(xcol[(size_t)(k + 3) * BS + b]);
    pr += x0 * wa.x + x1 * wa.y + x2 * wa.z + x3 * wa.w;
    pz += x0 * wb.x + x1 * wb.y + x2 * wb.z + x3 * wb.w;
    pn += x0 * wc.x + x1 * wc.y + x2 * wc.z + x3 * wc.w;
  }
  for (int k = kh * 128; k < kh * 128 + 128; k += 4) {
    float4 wa = *(const float4*)&w6[3][k];
    float4 wb = *(const float4*)&w6[4][k];
    float4 wc = *(const float4*)&w6[5][k];
    float h0 = dprev[(size_t)(k + 0) * BS + b], h1 = dprev[(size_t)(k + 1) * BS + b];
    float h2 = dprev[(size_t)(k + 2) * BS + b], h3 = dprev[(size_t)(k + 3) * BS + b];
    hr += h0 * wa.x + h1 * wa.y + h2 * wa.z + h3 * wa.w;
    hz += h0 * wb.x + h1 * wb.y + h2 * wb.z + h3 * wb.w;
    hn += h0 * wc.x + h1 * wc.y + h2 * wc.z + h3 * wc.w;
  }
  if (kh) {
    pA[0][b] = pr; pA[1][b] = pz; pA[2][b] = pn;
    pB[0][b] = hr; pB[1][b] = hz; pB[2][b] = hn;
  }
  __syncthreads();
  if (!kh) {
    float gir = pr + pA[0][b] + abih[j];
    float giz = pz + pA[1][b] + abih[H + j];
    float gin = pn + pA[2][b] + abih[2 * H + j];
    float ghr = hr + pB[0][b] + abhh[j];
    float ghz = hz + pB[1][b] + abhh[H + j];
    float ghn = hn + pB[2][b] + abhh[2 * H + j];
    float r = sigm_f(gir + ghr);
    float z = sigm_f(giz + ghz);
    float n = tanh_f(gin + r * ghn);
    float hp = dprev[(size_t)j * BS + b];
    dcur[(size_t)j * BS + b] = (1.f - z) * n + z * hp;
  }
}

__global__ __launch_bounds__(256) void fbk_attn(
    const float* __restrict__ enc, const u16* __restrict__ w1eu,
    const float* __restrict__ w2w, const float* __restrict__ b2w,
    const float* __restrict__ vww, const float* __restrict__ vbw,
    const float* __restrict__ pjw, const float* __restrict__ pjb,
    float* __restrict__ fst, int s)
{
  const int b3 = blockIdx.x, tid = threadIdx.x;
  __shared__ float dsh[256], qs[256], ddh[256], vwsh[256], ev[512], red[256];
  const float* dcur = fst + FBDT_F + (size_t)((s + 1) & 1) * H * BS;
  float* pT = fst + FBPT_F;
  dsh[tid]  = dcur[(size_t)tid * BS + b3];
  vwsh[tid] = vww[tid];
  __syncthreads();
  {
    const int jj = tid;
    const float* wr = w2w + (size_t)jj * H;
    float acc = b2w[jj];
    for (int k = 0; k < H; k += 8) {
      float4 wA = *(const float4*)(wr + k);
      float4 wB = *(const float4*)(wr + k + 4);
      float4 dA = *(const float4*)&dsh[k];
      float4 dB = *(const float4*)&dsh[k + 4];
      acc += dA.x * wA.x + dA.y * wA.y + dA.z * wA.z + dA.w * wA.w
           + dB.x * wB.x + dB.y * wB.y + dB.z * wB.z + dB.w * wB.w;
    }
    qs[jj] = acc;
  }
  __syncthreads();
  const float vbf = vbw[0];
  const u16* wr0 = w1eu + ((size_t)b3 * TENC + tid) * H;
  const u16* wr1 = wr0 + (size_t)256 * H;
  float sc0 = vbf, sc1 = vbf;
  for (int h = 0; h < H; h += 8) {
    uint4 ua = *(const uint4*)(wr0 + h);
    uint4 uc = *(const uint4*)(wr1 + h);
    float4 qA = *(const float4*)&qs[h];
    float4 qB = *(const float4*)&qs[h + 4];
    float4 vA = *(const float4*)&vwsh[h];
    float4 vB = *(const float4*)&vwsh[h + 4];
    sc0 += vA.x * tanh_f(bfu_lo(ua.x) + qA.x) + vA.y * tanh_f(bfu_hi(ua.x) + qA.y)
         + vA.z * tanh_f(bfu_lo(ua.y) + qA.z) + vA.w * tanh_f(bfu_hi(ua.y) + qA.w)
         + vB.x * tanh_f(bfu_lo(ua.z) + qB.x) + vB.y * tanh_f(bfu_hi(ua.z) + qB.y)
         + vB.z * tanh_f(bfu_lo(ua.w) + qB.z) + vB.w * tanh_f(bfu_hi(ua.w) + qB.w);
    sc1 += vA.x * tanh_f(bfu_lo(uc.x) + qA.x) + vA.y * tanh_f(bfu_hi(uc.x) + qA.y)
         + vA.z * tanh_f(bfu_lo(uc.y) + qA.z) + vA.w * tanh_f(bfu_hi(uc.y) + qA.w)
         + vB.x * tanh_f(bfu_lo(uc.z) + qB.x) + vB.y * tanh_f(bfu_hi(uc.z) + qB.y)
         + vB.z * tanh_f(bfu_lo(uc.w) + qB.z) + vB.w * tanh_f(bfu_hi(uc.w) + qB.w);
  }
  red[tid] = fmaxf(sc0, sc1);
  __syncthreads();
  for (int off = 128; off > 0; off >>= 1) {
    if (tid < off) red[tid] = fmaxf(red[tid], red[tid + off]);
    __syncthreads();
  }
  float mx = red[0];
  __syncthreads();
  float e0 = fexp(sc0 - mx), e1 = fexp(sc1 - mx);
  ev[tid] = e0; ev[256 + tid] = e1;
  red[tid] = e0 + e1;
  __syncthreads();
  for (int off = 128; off > 0; off >>= 1) {
    if (tid < off) red[tid] += red[tid + off];
    __syncthreads();
  }
  float linv = __builtin_amdgcn_rcpf(red[0]);
  __syncthreads();
  {
    float vacc = 0.f;
    const float* ep = enc + (size_t)b3 * TENC * H + tid;
    for (int tt = 0; tt < TENC; tt += 4) {
      float4 e4 = *(const float4*)&ev[tt];
      vacc += e4.x * ep[(size_t)(tt + 0) * H] + e4.y * ep[(size_t)(tt + 1) * H]
            + e4.z * ep[(size_t)(tt + 2) * H] + e4.w * ep[(size_t)(tt + 3) * H];
    }
    ddh[tid] = vacc * linv;
  }
  __syncthreads();
  {
    const int jj = tid;
    const float* wr = pjw + (size_t)jj * (2 * H);
    float acc = pjb[jj];
    for (int k = 0; k < H; k += 8) {
      float4 wA = *(const float4*)(wr + k);
      float4 wB = *(const float4*)(wr + k + 4);
      float4 dA = *(const float4*)&dsh[k];
      float4 dB = *(const float4*)&dsh[k + 4];
      acc += dA.x * wA.x + dA.y * wA.y + dA.z * wA.z + dA.w * wA.w
           + dB.x * wB.x + dB.y * wB.y + dB.z * wB.z + dB.w * wB.w;
    }
    for (int k = 0; k < H; k += 8) {
      float4 wA = *(const float4*)(wr + H + k);
      float4 wB = *(const float4*)(wr + H + k + 4);
      float4 dA = *(const float4*)&ddh[k];
      float4 dB = *(const float4*)&ddh[k + 4];
      acc += dA.x * wA.x + dA.y * wA.y + dA.z * wA.z + dA.w * wA.w
           + dB.x * wB.x + dB.y * wB.y + dB.z * wB.z + dB.w * wB.w;
    }
    pT[(size_t)jj * BS + b3] = acc;
  }
}

__global__ __launch_bounds__(256) void fbk_gru1(
    float* __restrict__ fst,
    const float* __restrict__ wih, const float* __restrict__ whh,
    const float* __restrict__ bih, const float* __restrict__ bhh, int s)
{
  __shared__ float w6[6][260];
  __shared__ float pA[3][128];
  __shared__ float pB[3][128];
  const float* pT     = fst + FBPT_F;
  const float* o1prev = fst + FBO1_F + (size_t)(s & 1) * H * BS;
  float*       o1cur  = fst + FBO1_F + (size_t)((s + 1) & 1) * H * BS;
  float*       in2T   = fst + FBIN2_F;
  fb_gru_body(w6, pA, pB, blockIdx.x, threadIdx.x, pT, o1prev, wih, whh, bih, bhh, o1cur, in2T);
}

__device__ __forceinline__ void fb_out_body(
    float (*pA)[128], int bb, int tid, int s,
    const float* __restrict__ sT, const float* __restrict__ ow,
    const float* __restrict__ ob, float* __restrict__ out)
{
  const int b = tid & 127, kh = tid >> 7;
  for (int r = bb; r < OD; r += 128) {
    const float* wr = ow + (size_t)r * H + kh * 128;
    float acc = 0.f;
    for (int kk = 0; kk < 128; kk += 4) {
      float4 wv = *(const float4*)(wr + kk);
      const float* sp = sT + (size_t)(kh * 128 + kk) * BS + b;
      acc += sp[0] * wv.x + sp[BS] * wv.y + sp[2 * BS] * wv.z + sp[3 * BS] * wv.w;
    }
    __syncthreads();
    if (kh) pA[0][b] = acc;
    __syncthreads();
    if (!kh) {
      float y = acc + pA[0][b] + ob[r];
      int frame = s * RF + r / MELD;
      int m = r - (r / MELD) * MELD;
      out[((size_t)b * TDEC + frame) * MELD + m] = y;
    }
  }
}

__global__ __launch_bounds__(256) void fbk_gru2out(
    float* __restrict__ fst,
    const float* __restrict__ wih, const float* __restrict__ whh,
    const float* __restrict__ bih, const float* __restrict__ bhh,
    const float* __restrict__ ow, const float* __restrict__ ob,
    float* __restrict__ out, int s)
{
  const int bid = blockIdx.x, tid = threadIdx.x;
  __shared__ float w6[6][260];
  __shared__ float pA[3][128];
  __shared__ float pB[3][128];
  if (bid < 256) {
    const float* in2T   = fst + FBIN2_F;
    const float* o2prev = fst + FBO2_F + (size_t)(s & 1) * H * BS;
    float*       o2cur  = fst + FBO2_F + (size_t)((s + 1) & 1) * H * BS;
    float*       stp    = fst + FBST_F + (size_t)(s & 1) * H * BS;
    fb_gru_body(w6, pA, pB, bid, tid, in2T, o2prev, wih, whh, bih, bhh, o2cur, stp);
  } else if (s > 0) {
    const float* sT = fst + FBST_F + (size_t)((s - 1) & 1) * H * BS;
    fb_out_body(pA, bid - 256, tid, s - 1, sT, ow, ob, out);
  }
}

__global__ __launch_bounds__(256) void fbk_outlast(
    const float* __restrict__ fst, const float* __restrict__ ow,
    const float* __restrict__ ob, float* __restrict__ out)
{
  __shared__ float pA[3][128];
  const float* sT = fst + FBST_F + (size_t)((STEPS - 1) & 1) * H * BS;
  fb_out_body(pA, blockIdx.x, threadIdx.x, STEPS - 1, sT, ow, ob, out);
}

// =====================================================================
//                              LAUNCH
// =====================================================================
extern "C" void kernel_launch(void* const* d_in, const int* in_sizes, int n_in,
                              void* d_out, int out_size, void* d_ws, size_t ws_size,
                              hipStream_t stream) {
  const float* enc   = (const float*)d_in[0];
  const float* dec   = (const float*)d_in[1];
  const float* pw1   = (const float*)d_in[2];
  const float* pb1   = (const float*)d_in[3];
  const float* pw2   = (const float*)d_in[4];
  const float* pb2   = (const float*)d_in[5];
  const float* w1w   = (const float*)d_in[6];
  const float* b1w   = (const float*)d_in[7];
  const float* w2w   = (const float*)d_in[8];
  const float* b2w   = (const float*)d_in[9];
  const float* vww   = (const float*)d_in[10];
  const float* vbw   = (const float*)d_in[11];
  const float* pjw   = (const float*)d_in[12];
  const float* pjb   = (const float*)d_in[13];
  const float* ow    = (const float*)d_in[14];
  const float* ob    = (const float*)d_in[15];
  const float* awih  = (const float*)d_in[16];
  const float* awhh  = (const float*)d_in[17];
  const float* abih  = (const float*)d_in[18];
  const float* abhh  = (const float*)d_in[19];
  const float* g1wih = (const float*)d_in[20];
  const float* g1whh = (const float*)d_in[21];
  const float* g1bih = (const float*)d_in[22];
  const float* g1bhh = (const float*)d_in[23];
  const float* g2wih = (const float*)d_in[24];
  const float* g2whh = (const float*)d_in[25];
  const float* g2bih = (const float*)d_in[26];
  const float* g2bhh = (const float*)d_in[27];
  float* out = (float*)d_out;
  char* wsb = (char*)d_ws;

  if (ws_size >= NEED_FAST) {
    float* xs   = (float*)(wsb + XS_B);
    u16*   w1eT = (u16*)(wsb + W1ET_B);
    float* DD   = (float*)(wsb + DD_B);
    float* GI   = (float*)(wsb + GI_B);
    float* P    = (float*)(wsb + P_B);
    u32*   wpkA = (u32*)(wsb + WPK_B);
    u32*   wpk1 = wpkA + 98304;
    u32*   wpk2 = wpk1 + 98304;

    k_prenet_f<<<STEPS, 256, 0, stream>>>(dec, pw1, pb1, pw2, pb2, xs);
    k_w1encT<<<(BS * TENC) / 32, 256, 0, stream>>>(enc, w1w, b1w, w1eT);
    k_pack<<<384, 256, 0, stream>>>(awhh, wpkA);
    k_pack<<<384, 256, 0, stream>>>(g1whh, wpk1);
    k_pack<<<384, 256, 0, stream>>>(g2whh, wpk2);
    // gi_x = xs @ awih^T + abih  -> GI [m][768]
    k_gemm<<<dim3(12, M_ALL / 64), 256, 0, stream>>>(xs, HH, awih, HH, abih, GI, 768, 768, nullptr);
    // attention-GRU chain -> d into DD[m][0:256] (row stride 512)
    k_chain<<<BS, 256, 0, stream>>>(GI, wpkA, abhh, nullptr, 0, DD, 512);
    // Q = d @ w2^T + b2 -> GI (reused) [m][256]
    k_gemm<<<dim3(4, M_ALL / 64), 256, 0, stream>>>(DD, 512, w2w, H, b2w, GI, 256, 256, nullptr);
    // scores+softmax+d_dot -> DD[m][256:512]
    k_att<<<dim3(BS, STEPS / ATT_ST), 256, 0, stream>>>(w1eT, GI, vww, enc, DD);
    // P = [d|ddot] @ pjw^T + pjb
    k_gemm<<<dim3(4, M_ALL / 64), 256, 0, stream>>>(DD, 512, pjw, 2 * H, pjb, P, 256, 256, nullptr);
    // gi1 = P @ g1wih^T + g1bih -> GI
    k_gemm<<<dim3(12, M_ALL / 64), 256, 0, stream>>>(P, H, g1wih, H, g1bih, GI, 768, 768, nullptr);
    // GRU1 chain; in2 = o1 + P -> DD (reused as [m][256])
    k_chain<<<BS, 256, 0, stream>>>(GI, wpk1, g1bhh, P, 256, DD, 256);
    // gi2 = in2 @ g2wih^T + g2bih -> GI
    k_gemm<<<dim3(12, M_ALL / 64), 256, 0, stream>>>(DD, H, g2wih, H, g2bih, GI, 768, 768, nullptr);
    // GRU2 chain; st = in2 + o2 -> P (reused)
    k_chain<<<BS, 256, 0, stream>>>(GI, wpk2, g2bhh, DD, 256, P, 256);
    // out = st @ ow^T + ob, mapped to [b][frame][mel]
    k_gemm<<<dim3(7, M_ALL / 64), 256, 0, stream>>>(P, H, ow, H, ob, nullptr, 0, OD, out);
    return;
  }

  if (ws_size < FB_NEED_B) {
    k_zero<<<(out_size + 255) / 256, 256, 0, stream>>>(out, out_size);
    return;
  }

  // -------- fallback: verified R4 multi-kernel path --------
  u16*  w1eu = (u16*)(wsb + FBW1E_B);
  u16*  xstu = (u16*)(wsb + FBXST_B);
  float* fst = (float*)(wsb + FBF32_B);

  fbk_zeroinit<<<384, 256, 0, stream>>>(fst);
  fbk_prenet<<<STEPS, 256, 0, stream>>>(dec, pw1, pb1, pw2, pb2, xstu);
  fbk_w1enc<<<(BS * TENC) / 32, 256, 0, stream>>>(enc, w1w, b1w, w1eu);
  for (int s = 0; s < STEPS; ++s) {
    fbk_attgru<<<256, 256, 0, stream>>>(xstu, fst, awih, awhh, abih, abhh, s);
    fbk_attn<<<BS, 256, 0, stream>>>(enc, w1eu, w2w, b2w, vww, vbw, pjw, pjb, fst, s);
    fbk_gru1<<<256, 256, 0, stream>>>(fst, g1wih, g1whh, g1bih, g1bhh, s);
    fbk_gru2out<<<384, 256, 0, stream>>>(fst, g2wih, g2whh, g2bih, g2bhh, ow, ob, out, s);
  }
  fbk_outlast<<<BS, 256, 0, stream>>>(fst, ow, ob, out);
}

// Round 2
// 4426.734 us; speedup vs baseline: 1.6255x; 1.4201x over previous
//
#include <hip/hip_runtime.h>
#include <hip/hip_bf16.h>

typedef unsigned short u16;
typedef unsigned int   u32;

constexpr int H     = 256;
constexpr int HH    = 128;
constexpr int MELD  = 80;
constexpr int RF    = 5;
constexpr int BS    = 128;
constexpr int TENC  = 512;
constexpr int TDEC  = 1000;
constexpr int STEPS = 200;
constexpr int OD    = 400;
constexpr int M_ALL = STEPS * BS;   // 25600

// ================= fast-path workspace layout (bytes) =================
constexpr size_t XS_B   = 0;                                  // xs f32 [s][b][128]
constexpr size_t W1ET_B = XS_B + (size_t)M_ALL*HH*4;          // w1eT bf16 [b][h][t] (pre-scaled, see k_w1encT)
constexpr size_t DD_B   = W1ET_B + (size_t)BS*H*TENC*2;       // ddcat f32 [m][512] (d|ddot); later in2 [m][256]
constexpr size_t GI_B   = DD_B + (size_t)M_ALL*512*4;         // gi f32 [m][768]; also Q [m][256]
constexpr size_t P_B    = GI_B + (size_t)M_ALL*768*4;         // P f32 [m][256]; later st
constexpr size_t WPK_B  = P_B + (size_t)M_ALL*H*4;            // 3 packed whh, 393216 B each
constexpr size_t NEED_FAST = WPK_B + 3*(size_t)393216;

// ================= fallback (R4) workspace layout =====================
constexpr size_t FBW1E_B  = 65536;
constexpr size_t FBXST_B  = FBW1E_B + (size_t)BS*TENC*H*2;
constexpr size_t FBF32_B  = FBXST_B + (size_t)STEPS*HH*BS*2;
constexpr size_t FBDT_F   = 0;
constexpr size_t FBO1_F   = FBDT_F + 2*(size_t)H*BS;
constexpr size_t FBO2_F   = FBO1_F + 2*(size_t)H*BS;
constexpr size_t FBPT_F   = FBO2_F + 2*(size_t)H*BS;
constexpr size_t FBIN2_F  = FBPT_F + (size_t)H*BS;
constexpr size_t FBST_F   = FBIN2_F + (size_t)H*BS;
constexpr size_t FB_NEED_B = FBF32_B + (FBST_F + 2*(size_t)H*BS) * 4;

// ================= helpers =================
__device__ __forceinline__ float bf2f(u16 v) {
  union { u32 x; float f; } c; c.x = ((u32)v) << 16; return c.f;
}
__device__ __forceinline__ float bfu_lo(u32 u) { union { u32 x; float f; } c; c.x = u << 16;        return c.f; }
__device__ __forceinline__ float bfu_hi(u32 u) { union { u32 x; float f; } c; c.x = u & 0xffff0000u; return c.f; }
__device__ __forceinline__ u16 f2bf(float f) {
  union { float f; u32 u; } c; c.f = f;
  u32 u = c.u;
  u32 r = (u + 0x7fffu + ((u >> 16) & 1u)) >> 16;  // RNE
  return (u16)r;
}
__device__ __forceinline__ float fexp(float x) {
  return __builtin_amdgcn_exp2f(1.4426950408889634f * x);
}
__device__ __forceinline__ float sigm_f(float x) {
  return __builtin_amdgcn_rcpf(1.0f + __builtin_amdgcn_exp2f(-1.4426950408889634f * x));
}
__device__ __forceinline__ float tanh_f(float x) {
  x = fminf(fmaxf(x, -15.f), 15.f);
  float e = __builtin_amdgcn_exp2f(2.8853900817779268f * x);   // e^(2x)
  return (e - 1.0f) * __builtin_amdgcn_rcpf(e + 1.0f);
}

__global__ __launch_bounds__(256) void k_zero(float* __restrict__ out, int n) {
  int i = blockIdx.x * 256 + threadIdx.x;
  if (i < n) out[i] = 0.f;
}

// =====================================================================
//                           FAST PATH
// =====================================================================

// ---- prenet (2 fused layers) -> xs f32 [s][b][128] ----
__global__ __launch_bounds__(256) void k_prenet_f(
    const float* __restrict__ dec, const float* __restrict__ w1, const float* __restrict__ b1,
    const float* __restrict__ w2, const float* __restrict__ b2, float* __restrict__ xs)
{
  const int s = blockIdx.x, tid = threadIdx.x;
  __shared__ float X0[32][80];
  __shared__ float P1t[32][256];
  for (int bt = 0; bt < 4; ++bt) {
    const int b0 = bt * 32;
    __syncthreads();
    for (int i = tid; i < 32 * 80; i += 256) {
      int bb = i / 80, m = i - bb * 80;
      X0[bb][m] = dec[((size_t)(b0 + bb) * TDEC + (size_t)s * RF) * MELD + m];
    }
    __syncthreads();
    {
      const int h = tid;
      float acc[32];
      const float bias = b1[h];
      #pragma unroll
      for (int r = 0; r < 32; ++r) acc[r] = bias;
      const float* wr = w1 + (size_t)h * MELD;
      for (int m = 0; m < 80; m += 4) {
        float4 wv = *(const float4*)(wr + m);
        #pragma unroll
        for (int r = 0; r < 32; ++r) {
          float4 x = *(const float4*)&X0[r][m];
          acc[r] += x.x * wv.x + x.y * wv.y + x.z * wv.z + x.w * wv.w;
        }
      }
      #pragma unroll
      for (int r = 0; r < 32; ++r) P1t[r][h] = fmaxf(acc[r], 0.f);
    }
    __syncthreads();
    {
      const int k = tid & 127, bh = tid >> 7;
      float acc[16];
      const float bias = b2[k];
      #pragma unroll
      for (int r = 0; r < 16; ++r) acc[r] = bias;
      const float* wr = w2 + (size_t)k * H;
      for (int h = 0; h < H; h += 4) {
        float4 wv = *(const float4*)(wr + h);
        #pragma unroll
        for (int r = 0; r < 16; ++r) {
          float4 x = *(const float4*)&P1t[bh * 16 + r][h];
          acc[r] += x.x * wv.x + x.y * wv.y + x.z * wv.z + x.w * wv.w;
        }
      }
      #pragma unroll
      for (int r = 0; r < 16; ++r)
        xs[((size_t)s * BS + b0 + bh * 16 + r) * HH + k] = fmaxf(acc[r], 0.f);
    }
  }
}

// ---- w1enc transposed: w1eT[b][h][t] bf16, PRE-SCALED by 2/ln2-equivalent ----
__global__ __launch_bounds__(256) void k_w1encT(
    const float* __restrict__ enc, const float* __restrict__ w1, const float* __restrict__ b1,
    u16* __restrict__ w1eT)
{
  const int row0 = blockIdx.x * 32;   // row = b*TENC + t
  const int tid = threadIdx.x;
  __shared__ float A[32 * 256];
  for (int i = tid * 4; i < 32 * 256; i += 256 * 4) {
    float4 v = *(const float4*)(enc + (size_t)row0 * H + i);
    A[i] = v.x; A[i + 1] = v.y; A[i + 2] = v.z; A[i + 3] = v.w;
  }
  __syncthreads();
  const int h = tid;
  float acc[32];
  const float bias = b1[h];
  #pragma unroll
  for (int r = 0; r < 32; ++r) acc[r] = bias;
  const float* wr = w1 + (size_t)h * H;
  for (int k = 0; k < H; k += 4) {
    float4 wv = *(const float4*)(wr + k);
    #pragma unroll
    for (int r = 0; r < 32; ++r) {
      float4 a = *(const float4*)&A[r * 256 + k];
      acc[r] += a.x * wv.x + a.y * wv.y + a.z * wv.z + a.w * wv.w;
    }
  }
  const int b = row0 / TENC, t0 = row0 % TENC;
  #pragma unroll
  for (int r = 0; r < 32; ++r)
    w1eT[((size_t)b * H + h) * TENC + t0 + r] = f2bf(2.8853900817779268f * acc[r]);
}

// ---- pack whh f32[768][256] -> uint4 groups: [3][32][256] of 4 bf16-pairs ----
// u32 flat index: ((g*32 + k4)*256 + j)*4 + i   where k2 = 4*k4 + i,
// value = bf16(w[g*256+j][2*k2]) | bf16(w[g*256+j][2*k2+1]) << 16.
__global__ __launch_bounds__(256) void k_pack(const float* __restrict__ w, u32* __restrict__ o) {
  int idx = blockIdx.x * 256 + threadIdx.x;
  if (idx >= 3 * 32 * 256 * 4) return;
  int i  = idx & 3;
  int j  = (idx >> 2) & 255;
  int k4 = (idx >> 10) & 31;
  int g  = idx >> 15;
  int k2 = 4 * k4 + i;
  u32 lo = f2bf(w[((size_t)g * 256 + j) * 256 + 2 * k2]);
  u32 hi = f2bf(w[((size_t)g * 256 + j) * 256 + 2 * k2 + 1]);
  o[idx] = lo | (hi << 16);
}

// ---- tiled GEMM: C[M][N] = A[M][K] @ W[N][K]^T + bias ----
// if outmap != nullptr: write to mel-output layout instead of C.
__global__ __launch_bounds__(256) void k_gemm(
    const float* __restrict__ A, int lda, const float* __restrict__ W, int K,
    const float* __restrict__ bias, float* __restrict__ C, int ldc, int N,
    float* __restrict__ outmap)
{
  __shared__ float As[64][65];
  __shared__ float Ws[64][65];
  const int m0 = blockIdx.y * 64, n0 = blockIdx.x * 64;
  const int tid = threadIdx.x, tx = tid & 15, ty = tid >> 4;
  float acc[4][4] = {};
  for (int k0 = 0; k0 < K; k0 += 64) {
    #pragma unroll
    for (int it = 0; it < 4; ++it) {
      int flat = tid + it * 256;
      int r = flat >> 4, c4 = (flat & 15) * 4;
      *(float4*)&As[r][c4] = *(const float4*)(A + (size_t)(m0 + r) * lda + k0 + c4);
      float4 wv;
      if (n0 + r < N) wv = *(const float4*)(W + (size_t)(n0 + r) * K + k0 + c4);
      else { wv.x = wv.y = wv.z = wv.w = 0.f; }
      *(float4*)&Ws[r][c4] = wv;
    }
    __syncthreads();
    for (int kk = 0; kk < 64; ++kk) {
      float a0 = As[ty*4+0][kk], a1 = As[ty*4+1][kk], a2 = As[ty*4+2][kk], a3 = As[ty*4+3][kk];
      float b0 = Ws[tx*4+0][kk], b1 = Ws[tx*4+1][kk], b2 = Ws[tx*4+2][kk], b3 = Ws[tx*4+3][kk];
      acc[0][0]+=a0*b0; acc[0][1]+=a0*b1; acc[0][2]+=a0*b2; acc[0][3]+=a0*b3;
      acc[1][0]+=a1*b0; acc[1][1]+=a1*b1; acc[1][2]+=a1*b2; acc[1][3]+=a1*b3;
      acc[2][0]+=a2*b0; acc[2][1]+=a2*b1; acc[2][2]+=a2*b2; acc[2][3]+=a2*b3;
      acc[3][0]+=a3*b0; acc[3][1]+=a3*b1; acc[3][2]+=a3*b2; acc[3][3]+=a3*b3;
    }
    __syncthreads();
  }
  #pragma unroll
  for (int i = 0; i < 4; ++i) {
    const int m = m0 + ty * 4 + i;
    #pragma unroll
    for (int jj = 0; jj < 4; ++jj) {
      const int n = n0 + tx * 4 + jj;
      if (n < N) {
        float v = acc[i][jj] + bias[n];
        if (outmap == nullptr) {
          C[(size_t)m * ldc + n] = v;
        } else {
          int s = m >> 7, b = m & 127;
          int fr = s * RF + n / MELD, mel = n - (n / MELD) * MELD;
          outmap[((size_t)b * TDEC + fr) * MELD + mel] = v;
        }
      }
    }
  }
}

// ---- per-row sequential GRU chain, v2 -------------------------------
// 512 threads: tid = (kh<<8)|j ; kh selects the k-half (h[0:128] / h[128:256]).
// Weights loaded as uint4 (4 bf16 k-pairs) from the k4-grouped pack layout;
// 6 of 16 k4-groups per half cached in LDS.  Partial gate sums from kh=1
// are reduced through psum; gate math + h update done by kh=0 threads.
constexpr int KC4H = 6;   // cached k4-groups per half
__device__ __forceinline__ void dot8(float& acc, const uint4 w, const float4 h0, const float4 h1) {
  acc += h0.x * bfu_lo(w.x) + h0.y * bfu_hi(w.x)
       + h0.z * bfu_lo(w.y) + h0.w * bfu_hi(w.y)
       + h1.x * bfu_lo(w.z) + h1.y * bfu_hi(w.z)
       + h1.z * bfu_lo(w.w) + h1.w * bfu_hi(w.w);
}
__global__ __launch_bounds__(512) void k_chain(
    const float* __restrict__ gi,      // [25600][768] includes bih
    const uint4* __restrict__ wpk4,    // [3][32][256] uint4
    const float* __restrict__ bhh,     // [768]
    const float* __restrict__ addsrc,  // nullptr or [25600][astride]
    int astride,
    float* __restrict__ outp, int ostride)
{
  const int b = blockIdx.x, tid = threadIdx.x;
  const int j = tid & 255, kh = tid >> 8;
  __shared__ __align__(16) float hsh[256];
  __shared__ float psum[3][256];
  __shared__ uint4 wl4[3][2 * KC4H][256];
  // fill LDS weight cache: slot s -> k4 = (s>=KC4H ? 16 : 0) + s%KC4H
  for (int i = tid; i < 3 * 2 * KC4H * 256; i += 512) {
    int g = i / (2 * KC4H * 256), rem = i - g * (2 * KC4H * 256);
    int slot = rem >> 8, jj = rem & 255;
    int c = slot < KC4H ? slot : slot - KC4H;
    int k4 = (slot < KC4H ? 0 : 16) + c;
    wl4[g][slot][jj] = wpk4[((size_t)g * 32 + k4) * 256 + jj];
  }
  if (tid < 256) hsh[tid] = 0.f;
  const float br = bhh[j], bz = bhh[256 + j], bn = bhh[512 + j];
  __syncthreads();
  for (int s = 0; s < STEPS; ++s) {
    const size_t m = (size_t)s * BS + b;
    float gr = 0.f, gz = 0.f, gn = 0.f, av = 0.f;
    if (kh == 0) {                       // wave-uniform branch
      const float* gim = gi + m * 768;
      gr = gim[j]; gz = gim[256 + j]; gn = gim[512 + j];
      if (addsrc) av = addsrc[m * astride + j];
    }
    float ar = 0.f, az = 0.f, an = 0.f;
    const int k4b = kh * 16;
    // global-resident k4 groups (issue loads early, pipeline over unroll)
    #pragma unroll 5
    for (int t = KC4H; t < 16; ++t) {
      const int k4 = k4b + t;
      uint4 wr = wpk4[(size_t)(0 * 32 + k4) * 256 + j];
      uint4 wz = wpk4[(size_t)(1 * 32 + k4) * 256 + j];
      uint4 wn = wpk4[(size_t)(2 * 32 + k4) * 256 + j];
      float4 h0 = *(const float4*)&hsh[8 * k4];
      float4 h1 = *(const float4*)&hsh[8 * k4 + 4];
      dot8(ar, wr, h0, h1); dot8(az, wz, h0, h1); dot8(an, wn, h0, h1);
    }
    // LDS-cached k4 groups
    #pragma unroll
    for (int c = 0; c < KC4H; ++c) {
      const int k4 = k4b + c;
      const int slot = kh * KC4H + c;
      uint4 wr = wl4[0][slot][j];
      uint4 wz = wl4[1][slot][j];
      uint4 wn = wl4[2][slot][j];
      float4 h0 = *(const float4*)&hsh[8 * k4];
      float4 h1 = *(const float4*)&hsh[8 * k4 + 4];
      dot8(ar, wr, h0, h1); dot8(az, wz, h0, h1); dot8(an, wn, h0, h1);
    }
    if (kh == 1) { psum[0][j] = ar; psum[1][j] = az; psum[2][j] = an; }
    __syncthreads();
    if (kh == 0) {
      ar += psum[0][j]; az += psum[1][j]; an += psum[2][j];
      float r = sigm_f(gr + ar + br);
      float z = sigm_f(gz + az + bz);
      float n = tanh_f(gn + r * (an + bn));
      float hp = hsh[j];
      float hn_ = (1.f - z) * n + z * hp;
      hsh[j] = hn_;
      outp[m * ostride + j] = hn_ + av;
    }
    __syncthreads();
  }
}

// ---- fused scores + softmax + d_dot: block = (b, 10-step tile) ----
constexpr int ATT_ST = 10;
__global__ __launch_bounds__(256) void k_att(
    const u16* __restrict__ w1eT, const float* __restrict__ Q,
    const float* __restrict__ vw_, const float* __restrict__ enc,
    float* __restrict__ DD)
{
  const int b = blockIdx.x, s0 = blockIdx.y * ATT_ST, tid = threadIdx.x;
  __shared__ float qt[ATT_ST][260];
  __shared__ float vws[256];
  __shared__ float us[ATT_ST][516];
  __shared__ float redw[ATT_ST][4];
  vws[tid] = -2.0f * vw_[tid];
  #pragma unroll
  for (int si = 0; si < ATT_ST; ++si)
    qt[si][tid] = 2.8853900817779268f * Q[((size_t)(s0 + si) * BS + b) * H + tid];
  __syncthreads();

  // ---- scores: sc = sum_h (-2 v_h) * rcp(1 + exp2(w_sc + q_sc)) ----
  float sc0[ATT_ST], sc1[ATT_ST];
  #pragma unroll
  for (int si = 0; si < ATT_ST; ++si) { sc0[si] = 0.f; sc1[si] = 0.f; }
  const u32* wrow = (const u32*)w1eT + (size_t)b * H * (TENC / 2);
  for (int h = 0; h < H; h += 2) {
    u32 wa = wrow[(size_t)h * 256 + tid];          // t = 2*tid, 2*tid+1
    u32 wb = wrow[(size_t)(h + 1) * 256 + tid];
    float wa0 = bfu_lo(wa), wa1 = bfu_hi(wa);
    float wb0 = bfu_lo(wb), wb1 = bfu_hi(wb);
    float va = vws[h], vb = vws[h + 1];
    #pragma unroll
    for (int si = 0; si < ATT_ST; ++si) {
      float2 q2 = *(const float2*)&qt[si][h];
      sc0[si] += va * __builtin_amdgcn_rcpf(1.f + __builtin_amdgcn_exp2f(wa0 + q2.x))
               + vb * __builtin_amdgcn_rcpf(1.f + __builtin_amdgcn_exp2f(wb0 + q2.y));
      sc1[si] += va * __builtin_amdgcn_rcpf(1.f + __builtin_amdgcn_exp2f(wa1 + q2.x))
               + vb * __builtin_amdgcn_rcpf(1.f + __builtin_amdgcn_exp2f(wb1 + q2.y));
    }
  }
  // softmax over 512 t (2 per thread x 256 threads, 4 waves)
  const int lane = tid & 63, wvi = tid >> 6;
  #pragma unroll
  for (int si = 0; si < ATT_ST; ++si) {
    float mw = fmaxf(sc0[si], sc1[si]);
    for (int off = 1; off < 64; off <<= 1) mw = fmaxf(mw, __shfl_xor(mw, off));
    if (lane == 0) redw[si][wvi] = mw;
  }
  __syncthreads();
  #pragma unroll
  for (int si = 0; si < ATT_ST; ++si) {
    float mx = fmaxf(fmaxf(redw[si][0], redw[si][1]), fmaxf(redw[si][2], redw[si][3]));
    sc0[si] = fexp(sc0[si] - mx);
    sc1[si] = fexp(sc1[si] - mx);
  }
  __syncthreads();
  #pragma unroll
  for (int si = 0; si < ATT_ST; ++si) {
    float sm = sc0[si] + sc1[si];
    for (int off = 1; off < 64; off <<= 1) sm += __shfl_xor(sm, off);
    if (lane == 0) redw[si][wvi] = sm;
  }
  __syncthreads();
  #pragma unroll
  for (int si = 0; si < ATT_ST; ++si) {
    float tot = redw[si][0] + redw[si][1] + redw[si][2] + redw[si][3];
    float li = __builtin_amdgcn_rcpf(tot);
    float2 uv; uv.x = sc0[si] * li; uv.y = sc1[si] * li;
    *(float2*)&us[si][2 * tid] = uv;
  }
  __syncthreads();
  // ---- d_dot[si][h=tid] = sum_t us[si][t] * enc[b][t][h]  (enc direct) ----
  float dd[ATT_ST];
  #pragma unroll
  for (int si = 0; si < ATT_ST; ++si) dd[si] = 0.f;
  const float* ep = enc + (size_t)b * TENC * H + tid;
  for (int t = 0; t < TENC; t += 4) {
    float e0 = ep[(size_t)(t + 0) * H];
    float e1 = ep[(size_t)(t + 1) * H];
    float e2 = ep[(size_t)(t + 2) * H];
    float e3 = ep[(size_t)(t + 3) * H];
    #pragma unroll
    for (int si = 0; si < ATT_ST; ++si) {
      float4 u4 = *(const float4*)&us[si][t];
      dd[si] += e0 * u4.x + e1 * u4.y + e2 * u4.z + e3 * u4.w;
    }
  }
  #pragma unroll
  for (int si = 0; si < ATT_ST; ++si)
    DD[((size_t)(s0 + si) * BS + b) * 512 + 256 + tid] = dd[si];
}

// =====================================================================
//                      FALLBACK PATH (R4, verified)
// =====================================================================
__global__ __launch_bounds__(256) void fbk_zeroinit(float* __restrict__ fst) {
  int i = blockIdx.x * 256 + threadIdx.x;
  if (i < H * BS)              fst[FBDT_F + i] = 0.f;
  else if (i < 2 * H * BS)     fst[FBO1_F + (i - H * BS)] = 0.f;
  else if (i < 3 * H * BS)     fst[FBO2_F + (i - 2 * H * BS)] = 0.f;
}

__global__ __launch_bounds__(256) void fbk_prenet(
    const float* __restrict__ dec, const float* __restrict__ w1, const float* __restrict__ b1,
    const float* __restrict__ w2, const float* __restrict__ b2, u16* __restrict__ xsT)
{
  const int s = blockIdx.x, tid = threadIdx.x;
  __shared__ float X0[32][80];
  __shared__ float P1t[32][256];
  for (int bt = 0; bt < 4; ++bt) {
    const int b0 = bt * 32;
    __syncthreads();
    for (int i = tid; i < 32 * 80; i += 256) {
      int bb = i / 80, m = i - bb * 80;
      X0[bb][m] = dec[((size_t)(b0 + bb) * TDEC + (size_t)s * RF) * MELD + m];
    }
    __syncthreads();
    {
      const int h = tid;
      float acc[32];
      const float bias = b1[h];
      #pragma unroll
      for (int r = 0; r < 32; ++r) acc[r] = bias;
      const float* wr = w1 + (size_t)h * MELD;
      for (int m = 0; m < 80; m += 4) {
        float4 wv = *(const float4*)(wr + m);
        #pragma unroll
        for (int r = 0; r < 32; ++r) {
          float4 x = *(const float4*)&X0[r][m];
          acc[r] += x.x * wv.x + x.y * wv.y + x.z * wv.z + x.w * wv.w;
        }
      }
      #pragma unroll
      for (int r = 0; r < 32; ++r) P1t[r][h] = fmaxf(acc[r], 0.f);
    }
    __syncthreads();
    {
      const int k = tid & 127, bh = tid >> 7;
      float acc[16];
      const float bias = b2[k];
      #pragma unroll
      for (int r = 0; r < 16; ++r) acc[r] = bias;
      const float* wr = w2 + (size_t)k * H;
      for (int h = 0; h < H; h += 4) {
        float4 wv = *(const float4*)(wr + h);
        #pragma unroll
        for (int r = 0; r < 16; ++r) {
          float4 x = *(const float4*)&P1t[bh * 16 + r][h];
          acc[r] += x.x * wv.x + x.y * wv.y + x.z * wv.z + x.w * wv.w;
        }
      }
      #pragma unroll
      for (int r = 0; r < 16; ++r)
        xsT[((size_t)s * HH + k) * BS + b0 + bh * 16 + r] = f2bf(fmaxf(acc[r], 0.f));
    }
  }
}

__global__ __launch_bounds__(256) void fbk_w1enc(
    const float* __restrict__ enc, const float* __restrict__ w1, const float* __restrict__ b1,
    u16* __restrict__ w1e)
{
  const int row0 = blockIdx.x * 32;
  const int tid = threadIdx.x;
  __shared__ float A[32 * 256];
  for (int i = tid * 4; i < 32 * 256; i += 256 * 4) {
    float4 v = *(const float4*)(enc + (size_t)row0 * H + i);
    A[i] = v.x; A[i + 1] = v.y; A[i + 2] = v.z; A[i + 3] = v.w;
  }
  __syncthreads();
  const int h = tid;
  float acc[32];
  const float bias = b1[h];
  #pragma unroll
  for (int r = 0; r < 32; ++r) acc[r] = bias;
  const float* wr = w1 + (size_t)h * H;
  for (int k = 0; k < H; k += 4) {
    float4 wv = *(const float4*)(wr + k);
    #pragma unroll
    for (int r = 0; r < 32; ++r) {
      float4 a = *(const float4*)&A[r * 256 + k];
      acc[r] += a.x * wv.x + a.y * wv.y + a.z * wv.z + a.w * wv.w;
    }
  }
  #pragma unroll
  for (int r = 0; r < 32; ++r) w1e[((size_t)row0 + r) * H + h] = f2bf(acc[r]);
}

__device__ __forceinline__ void fb_gru_body(
    float (*w6)[260], float (*pA)[128], float (*pB)[128], int j, int tid,
    const float* __restrict__ gi_src, const float* __restrict__ h_src,
    const float* __restrict__ wih, const float* __restrict__ whh,
    const float* __restrict__ bih, const float* __restrict__ bhh,
    float* __restrict__ h_out, float* __restrict__ sum_out)
{
  for (int i = tid; i < 3 * H; i += 256) {
    int gg = i >> 8, k = i & 255;
    w6[gg][k]     = wih[((size_t)gg * H + j) * H + k];
    w6[3 + gg][k] = whh[((size_t)gg * H + j) * H + k];
  }
  __syncthreads();
  const int b = tid & 127, kh = tid >> 7;
  float pr = 0, pz = 0, pn = 0, hr = 0, hz = 0, hn = 0;
  for (int k = kh * 128; k < kh * 128 + 128; k += 4) {
    float4 wia = *(const float4*)&w6[0][k];
    float4 wib = *(const float4*)&w6[1][k];
    float4 wic = *(const float4*)&w6[2][k];
    float4 wha = *(const float4*)&w6[3][k];
    float4 whb = *(const float4*)&w6[4][k];
    float4 whc = *(const float4*)&w6[5][k];
    float x0 = gi_src[(size_t)(k + 0) * BS + b], x1 = gi_src[(size_t)(k + 1) * BS + b];
    float x2 = gi_src[(size_t)(k + 2) * BS + b], x3 = gi_src[(size_t)(k + 3) * BS + b];
    float h0 = h_src[(size_t)(k + 0) * BS + b],  h1 = h_src[(size_t)(k + 1) * BS + b];
    float h2 = h_src[(size_t)(k + 2) * BS + b],  h3 = h_src[(size_t)(k + 3) * BS + b];
    pr += x0 * wia.x + x1 * wia.y + x2 * wia.z + x3 * wia.w;
    pz += x0 * wib.x + x1 * wib.y + x2 * wib.z + x3 * wib.w;
    pn += x0 * wic.x + x1 * wic.y + x2 * wic.z + x3 * wic.w;
    hr += h0 * wha.x + h1 * wha.y + h2 * wha.z + h3 * wha.w;
    hz += h0 * whb.x + h1 * whb.y + h2 * whb.z + h3 * whb.w;
    hn += h0 * whc.x + h1 * whc.y + h2 * whc.z + h3 * whc.w;
  }
  if (kh) {
    pA[0][b] = pr; pA[1][b] = pz; pA[2][b] = pn;
    pB[0][b] = hr; pB[1][b] = hz; pB[2][b] = hn;
  }
  __syncthreads();
  if (!kh) {
    float gir = pr + pA[0][b] + bih[j];
    float giz = pz + pA[1][b] + bih[H + j];
    float gin = pn + pA[2][b] + bih[2 * H + j];
    float ghr = hr + pB[0][b] + bhh[j];
    float ghz = hz + pB[1][b] + bhh[H + j];
    float ghn = hn + pB[2][b] + bhh[2 * H + j];
    float r = sigm_f(gir + ghr);
    float z = sigm_f(giz + ghz);
    float n = tanh_f(gin + r * ghn);
    float hp = h_src[(size_t)j * BS + b];
    float o = (1.f - z) * n + z * hp;
    h_out[(size_t)j * BS + b] = o;
    if (sum_out) sum_out[(size_t)j * BS + b] = o + gi_src[(size_t)j * BS + b];
  }
}

__global__ __launch_bounds__(256) void fbk_attgru(
    const u16* __restrict__ xstu, float* __restrict__ fst,
    const float* __restrict__ awih, const float* __restrict__ awhh,
    const float* __restrict__ abih, const float* __restrict__ abhh, int s)
{
  const int j = blockIdx.x, tid = threadIdx.x;
  __shared__ float w6[6][260];
  __shared__ float pA[3][128];
  __shared__ float pB[3][128];
  const float* dprev = fst + FBDT_F + (size_t)(s & 1) * H * BS;
  float*       dcur  = fst + FBDT_F + (size_t)((s + 1) & 1) * H * BS;
  for (int i = tid; i < 3 * HH; i += 256) {
    int gg = i >> 7, k = i & (HH - 1);
    w6[gg][k] = awih[((size_t)gg * H + j) * HH + k];
  }
  for (int i = tid; i < 3 * H; i += 256) {
    int gg = i >> 8, k = i & (H - 1);
    w6[3 + gg][k] = awhh[((size_t)gg * H + j) * H + k];
  }
  __syncthreads();
  const u16* xcol = xstu + (size_t)s * HH * BS;
  const int b = tid & 127, kh = tid >> 7;
  float pr = 0, pz = 0, pn = 0, hr = 0, hz = 0, hn = 0;
  for (int k = kh * 64; k < kh * 64 + 64; k += 4) {
    float4 wa = *(const float4*)&w6[0][k];
    float4 wb = *(const float4*)&w6[1][k];
    float4 wc = *(const float4*)&w6[2][k];
    float x0 = bf2f(xcol[(size_t)(k + 0) * BS + b]), x1 = bf2f(xcol[(size_t)(k + 1) * BS + b]);
    float x2 = bf2f(xcol[(size_t)(k + 2) * BS + b]), x3 = bf2f(xcol[(size_t)(k + 3) * BS + b]);
    pr += x0 * wa.x + x1 * wa.y + x2 * wa.z + x3 * wa.w;
    pz += x0 * wb.x + x1 * wb.y + x2 * wb.z + x3 * wb.w;
    pn += x0 * wc.x + x1 * wc.y + x2 * wc.z + x3 * wc.w;
  }
  for (int k = kh * 128; k < kh * 128 + 128; k += 4) {
    float4 wa = *(const float4*)&w6[3][k];
    float4 wb = *(const float4*)&w6[4][k];
    float4 wc = *(const float4*)&w6[5][k];
    float h0 = dprev[(size_t)(k + 0) * BS + b], h1 = dprev[(size_t)(k + 1) * BS + b];
    float h2 = dprev[(size_t)(k + 2) * BS + b], h3 = dprev[(size_t)(k + 3) * BS + b];
    hr += h0 * wa.x + h1 * wa.y + h2 * wa.z + h3 * wa.w;
    hz += h0 * wb.x + h1 * wb.y + h2 * wb.z + h3 * wb.w;
    hn += h0 * wc.x + h1 * wc.y + h2 * wc.z + h3 * wc.w;
  }
  if (kh) {
    pA[0][b] = pr; pA[1][b] = pz; pA[2][b] = pn;
    pB[0][b] = hr; pB[1][b] = hz; pB[2][b] = hn;
  }
  __syncthreads();
  if (!kh) {
    float gir = pr + pA[0][b] + abih[j];
    float giz = pz + pA[1][b] + abih[H + j];
    float gin = pn + pA[2][b] + abih[2 * H + j];
    float ghr = hr + pB[0][b] + abhh[j];
    float ghz = hz + pB[1][b] + abhh[H + j];
    float ghn = hn + pB[2][b] + abhh[2 * H + j];
    float r = sigm_f(gir + ghr);
    float z = sigm_f(giz + ghz);
    float n = tanh_f(gin + r * ghn);
    float hp = dprev[(size_t)j * BS + b];
    dcur[(size_t)j * BS + b] = (1.f - z) * n + z * hp;
  }
}

__global__ __launch_bounds__(256) void fbk_attn(
    const float* __restrict__ enc, const u16* __restrict__ w1eu,
    const float* __restrict__ w2w, const float* __restrict__ b2w,
    const float* __restrict__ vww, const float* __restrict__ vbw,
    const float* __restrict__ pjw, const float* __restrict__ pjb,
    float* __restrict__ fst, int s)
{
  const int b3 = blockIdx.x, tid = threadIdx.x;
  __shared__ float dsh[256], qs[256], ddh[256], vwsh[256], ev[512], red[256];
  const float* dcur = fst + FBDT_F + (size_t)((s + 1) & 1) * H * BS;
  float* pT = fst + FBPT_F;
  dsh[tid]  = dcur[(size_t)tid * BS + b3];
  vwsh[tid] = vww[tid];
  __syncthreads();
  {
    const int jj = tid;
    const float* wr = w2w + (size_t)jj * H;
    float acc = b2w[jj];
    for (int k = 0; k < H; k += 8) {
      float4 wA = *(const float4*)(wr + k);
      float4 wB = *(const float4*)(wr + k + 4);
      float4 dA = *(const float4*)&dsh[k];
      float4 dB = *(const float4*)&dsh[k + 4];
      acc += dA.x * wA.x + dA.y * wA.y + dA.z * wA.z + dA.w * wA.w
           + dB.x * wB.x + dB.y * wB.y + dB.z * wB.z + dB.w * wB.w;
    }
    qs[jj] = acc;
  }
  __syncthreads();
  const float vbf = vbw[0];
  const u16* wr0 = w1eu + ((size_t)b3 * TENC + tid) * H;
  const u16* wr1 = wr0 + (size_t)256 * H;
  float sc0 = vbf, sc1 = vbf;
  for (int h = 0; h < H; h += 8) {
    uint4 ua = *(const uint4*)(wr0 + h);
    uint4 uc = *(const uint4*)(wr1 + h);
    float4 qA = *(const float4*)&qs[h];
    float4 qB = *(const float4*)&qs[h + 4];
    float4 vA = *(const float4*)&vwsh[h];
    float4 vB = *(const float4*)&vwsh[h + 4];
    sc0 += vA.x * tanh_f(bfu_lo(ua.x) + qA.x) + vA.y * tanh_f(bfu_hi(ua.x) + qA.y)
         + vA.z * tanh_f(bfu_lo(ua.y) + qA.z) + vA.w * tanh_f(bfu_hi(ua.y) + qA.w)
         + vB.x * tanh_f(bfu_lo(ua.z) + qB.x) + vB.y * tanh_f(bfu_hi(ua.z) + qB.y)
         + vB.z * tanh_f(bfu_lo(ua.w) + qB.z) + vB.w * tanh_f(bfu_hi(ua.w) + qB.w);
    sc1 += vA.x * tanh_f(bfu_lo(uc.x) + qA.x) + vA.y * tanh_f(bfu_hi(uc.x) + qA.y)
         + vA.z * tanh_f(bfu_lo(uc.y) + qA.z) + vA.w * tanh_f(bfu_hi(uc.y) + qA.w)
         + vB.x * tanh_f(bfu_lo(uc.z) + qB.x) + vB.y * tanh_f(bfu_hi(uc.z) + qB.y)
         + vB.z * tanh_f(bfu_lo(uc.w) + qB.z) + vB.w * tanh_f(bfu_hi(uc.w) + qB.w);
  }
  red[tid] = fmaxf(sc0, sc1);
  __syncthreads();
  for (int off = 128; off > 0; off >>= 1) {
    if (tid < off) red[tid] = fmaxf(red[tid], red[tid + off]);
    __syncthreads();
  }
  float mx = red[0];
  __syncthreads();
  float e0 = fexp(sc0 - mx), e1 = fexp(sc1 - mx);
  ev[tid] = e0; ev[256 + tid] = e1;
  red[tid] = e0 + e1;
  __syncthreads();
  for (int off = 128; off > 0; off >>= 1) {
    if (tid < off) red[tid] += red[tid + off];
    __syncthreads();
  }
  float linv = __builtin_amdgcn_rcpf(red[0]);
  __syncthreads();
  {
    float vacc = 0.f;
    const float* ep = enc + (size_t)b3 * TENC * H + tid;
    for (int tt = 0; tt < TENC; tt += 4) {
      float4 e4 = *(const float4*)&ev[tt];
      vacc += e4.x * ep[(size_t)(tt + 0) * H] + e4.y * ep[(size_t)(tt + 1) * H]
            + e4.z * ep[(size_t)(tt + 2) * H] + e4.w * ep[(size_t)(tt + 3) * H];
    }
    ddh[tid] = vacc * linv;
  }
  __syncthreads();
  {
    const int jj = tid;
    const float* wr = pjw + (size_t)jj * (2 * H);
    float acc = pjb[jj];
    for (int k = 0; k < H; k += 8) {
      float4 wA = *(const float4*)(wr + k);
      float4 wB = *(const float4*)(wr + k + 4);
      float4 dA = *(const float4*)&dsh[k];
      float4 dB = *(const float4*)&dsh[k + 4];
      acc += dA.x * wA.x + dA.y * wA.y + dA.z * wA.z + dA.w * wA.w
           + dB.x * wB.x + dB.y * wB.y + dB.z * wB.z + dB.w * wB.w;
    }
    for (int k = 0; k < H; k += 8) {
      float4 wA = *(const float4*)(wr + H + k);
      float4 wB = *(const float4*)(wr + H + k + 4);
      float4 dA = *(const float4*)&ddh[k];
      float4 dB = *(const float4*)&ddh[k + 4];
      acc += dA.x * wA.x + dA.y * wA.y + dA.z * wA.z + dA.w * wA.w
           + dB.x * wB.x + dB.y * wB.y + dB.z * wB.z + dB.w * wB.w;
    }
    pT[(size_t)jj * BS + b3] = acc;
  }
}

__global__ __launch_bounds__(256) void fbk_gru1(
    float* __restrict__ fst,
    const float* __restrict__ wih, const float* __restrict__ whh,
    const float* __restrict__ bih, const float* __restrict__ bhh, int s)
{
  __shared__ float w6[6][260];
  __shared__ float pA[3][128];
  __shared__ float pB[3][128];
  const float* pT     = fst + FBPT_F;
  const float* o1prev = fst + FBO1_F + (size_t)(s & 1) * H * BS;
  float*       o1cur  = fst + FBO1_F + (size_t)((s + 1) & 1) * H * BS;
  float*       in2T   = fst + FBIN2_F;
  fb_gru_body(w6, pA, pB, blockIdx.x, threadIdx.x, pT, o1prev, wih, whh, bih, bhh, o1cur, in2T);
}

__device__ __forceinline__ void fb_out_body(
    float (*pA)[128], int bb, int tid, int s,
    const float* __restrict__ sT, const float* __restrict__ ow,
    const float* __restrict__ ob, float* __restrict__ out)
{
  const int b = tid & 127, kh = tid >> 7;
  for (int r = bb; r < OD; r += 128) {
    const float* wr = ow + (size_t)r * H + kh * 128;
    float acc = 0.f;
    for (int kk = 0; kk < 128; kk += 4) {
      float4 wv = *(const float4*)(wr + kk);
      const float* sp = sT + (size_t)(kh * 128 + kk) * BS + b;
      acc += sp[0] * wv.x + sp[BS] * wv.y + sp[2 * BS] * wv.z + sp[3 * BS] * wv.w;
    }
    __syncthreads();
    if (kh) pA[0][b] = acc;
    __syncthreads();
    if (!kh) {
      float y = acc + pA[0][b] + ob[r];
      int frame = s * RF + r / MELD;
      int m = r - (r / MELD) * MELD;
      out[((size_t)b * TDEC + frame) * MELD + m] = y;
    }
  }
}

__global__ __launch_bounds__(256) void fbk_gru2out(
    float* __restrict__ fst,
    const float* __restrict__ wih, const float* __restrict__ whh,
    const float* __restrict__ bih, const float* __restrict__ bhh,
    const float* __restrict__ ow, const float* __restrict__ ob,
    float* __restrict__ out, int s)
{
  const int bid = blockIdx.x, tid = threadIdx.x;
  __shared__ float w6[6][260];
  __shared__ float pA[3][128];
  __shared__ float pB[3][128];
  if (bid < 256) {
    const float* in2T   = fst + FBIN2_F;
    const float* o2prev = fst + FBO2_F + (size_t)(s & 1) * H * BS;
    float*       o2cur  = fst + FBO2_F + (size_t)((s + 1) & 1) * H * BS;
    float*       stp    = fst + FBST_F + (size_t)(s & 1) * H * BS;
    fb_gru_body(w6, pA, pB, bid, tid, in2T, o2prev, wih, whh, bih, bhh, o2cur, stp);
  } else if (s > 0) {
    const float* sT = fst + FBST_F + (size_t)((s - 1) & 1) * H * BS;
    fb_out_body(pA, bid - 256, tid, s - 1, sT, ow, ob, out);
  }
}

__global__ __launch_bounds__(256) void fbk_outlast(
    const float* __restrict__ fst, const float* __restrict__ ow,
    const float* __restrict__ ob, float* __restrict__ out)
{
  __shared__ float pA[3][128];
  const float* sT = fst + FBST_F + (size_t)((STEPS - 1) & 1) * H * BS;
  fb_out_body(pA, blockIdx.x, threadIdx.x, STEPS - 1, sT, ow, ob, out);
}

// =====================================================================
//                              LAUNCH
// =====================================================================
extern "C" void kernel_launch(void* const* d_in, const int* in_sizes, int n_in,
                              void* d_out, int out_size, void* d_ws, size_t ws_size,
                              hipStream_t stream) {
  const float* enc   = (const float*)d_in[0];
  const float* dec   = (const float*)d_in[1];
  const float* pw1   = (const float*)d_in[2];
  const float* pb1   = (const float*)d_in[3];
  const float* pw2   = (const float*)d_in[4];
  const float* pb2   = (const float*)d_in[5];
  const float* w1w   = (const float*)d_in[6];
  const float* b1w   = (const float*)d_in[7];
  const float* w2w   = (const float*)d_in[8];
  const float* b2w   = (const float*)d_in[9];
  const float* vww   = (const float*)d_in[10];
  const float* vbw   = (const float*)d_in[11];
  const float* pjw   = (const float*)d_in[12];
  const float* pjb   = (const float*)d_in[13];
  const float* ow    = (const float*)d_in[14];
  const float* ob    = (const float*)d_in[15];
  const float* awih  = (const float*)d_in[16];
  const float* awhh  = (const float*)d_in[17];
  const float* abih  = (const float*)d_in[18];
  const float* abhh  = (const float*)d_in[19];
  const float* g1wih = (const float*)d_in[20];
  const float* g1whh = (const float*)d_in[21];
  const float* g1bih = (const float*)d_in[22];
  const float* g1bhh = (const float*)d_in[23];
  const float* g2wih = (const float*)d_in[24];
  const float* g2whh = (const float*)d_in[25];
  const float* g2bih = (const float*)d_in[26];
  const float* g2bhh = (const float*)d_in[27];
  float* out = (float*)d_out;
  char* wsb = (char*)d_ws;

  if (ws_size >= NEED_FAST) {
    float* xs   = (float*)(wsb + XS_B);
    u16*   w1eT = (u16*)(wsb + W1ET_B);
    float* DD   = (float*)(wsb + DD_B);
    float* GI   = (float*)(wsb + GI_B);
    float* P    = (float*)(wsb + P_B);
    u32*   wpkA = (u32*)(wsb + WPK_B);
    u32*   wpk1 = wpkA + 98304;
    u32*   wpk2 = wpk1 + 98304;

    k_prenet_f<<<STEPS, 256, 0, stream>>>(dec, pw1, pb1, pw2, pb2, xs);
    k_w1encT<<<(BS * TENC) / 32, 256, 0, stream>>>(enc, w1w, b1w, w1eT);
    k_pack<<<384, 256, 0, stream>>>(awhh, wpkA);
    k_pack<<<384, 256, 0, stream>>>(g1whh, wpk1);
    k_pack<<<384, 256, 0, stream>>>(g2whh, wpk2);
    // gi_x = xs @ awih^T + abih  -> GI [m][768]
    k_gemm<<<dim3(12, M_ALL / 64), 256, 0, stream>>>(xs, HH, awih, HH, abih, GI, 768, 768, nullptr);
    // attention-GRU chain -> d into DD[m][0:256] (row stride 512)
    k_chain<<<BS, 512, 0, stream>>>(GI, (const uint4*)wpkA, abhh, nullptr, 0, DD, 512);
    // Q = d @ w2^T + b2 -> GI (reused) [m][256]
    k_gemm<<<dim3(4, M_ALL / 64), 256, 0, stream>>>(DD, 512, w2w, H, b2w, GI, 256, 256, nullptr);
    // scores+softmax+d_dot -> DD[m][256:512]
    k_att<<<dim3(BS, STEPS / ATT_ST), 256, 0, stream>>>(w1eT, GI, vww, enc, DD);
    // P = [d|ddot] @ pjw^T + pjb
    k_gemm<<<dim3(4, M_ALL / 64), 256, 0, stream>>>(DD, 512, pjw, 2 * H, pjb, P, 256, 256, nullptr);
    // gi1 = P @ g1wih^T + g1bih -> GI
    k_gemm<<<dim3(12, M_ALL / 64), 256, 0, stream>>>(P, H, g1wih, H, g1bih, GI, 768, 768, nullptr);
    // GRU1 chain; in2 = o1 + P -> DD (reused as [m][256])
    k_chain<<<BS, 512, 0, stream>>>(GI, (const uint4*)wpk1, g1bhh, P, 256, DD, 256);
    // gi2 = in2 @ g2wih^T + g2bih -> GI
    k_gemm<<<dim3(12, M_ALL / 64), 256, 0, stream>>>(DD, H, g2wih, H, g2bih, GI, 768, 768, nullptr);
    // GRU2 chain; st = in2 + o2 -> P (reused)
    k_chain<<<BS, 512, 0, stream>>>(GI, (const uint4*)wpk2, g2bhh, DD, 256, P, 256);
    // out = st @ ow^T + ob, mapped to [b][frame][mel]
    k_gemm<<<dim3(7, M_ALL / 64), 256, 0, stream>>>(P, H, ow, H, ob, nullptr, 0, OD, out);
    return;
  }

  if (ws_size < FB_NEED_B) {
    k_zero<<<(out_size + 255) / 256, 256, 0, stream>>>(out, out_size);
    return;
  }

  // -------- fallback: verified R4 multi-kernel path --------
  u16*  w1eu = (u16*)(wsb + FBW1E_B);
  u16*  xstu = (u16*)(wsb + FBXST_B);
  float* fst = (float*)(wsb + FBF32_B);

  fbk_zeroinit<<<384, 256, 0, stream>>>(fst);
  fbk_prenet<<<STEPS, 256, 0, stream>>>(dec, pw1, pb1, pw2, pb2, xstu);
  fbk_w1enc<<<(BS * TENC) / 32, 256, 0, stream>>>(enc, w1w, b1w, w1eu);
  for (int s = 0; s < STEPS; ++s) {
    fbk_attgru<<<256, 256, 0, stream>>>(xstu, fst, awih, awhh, abih, abhh, s);
    fbk_attn<<<BS, 256, 0, stream>>>(enc, w1eu, w2w, b2w, vww, vbw, pjw, pjb, fst, s);
    fbk_gru1<<<256, 256, 0, stream>>>(fst, g1wih, g1whh, g1bih, g1bhh, s);
    fbk_gru2out<<<384, 256, 0, stream>>>(fst, g2wih, g2whh, g2bih, g2bhh, ow, ob, out, s);
  }
  fbk_outlast<<<BS, 256, 0, stream>>>(fst, ow, ob, out);
}

// Round 3
// 2843.655 us; speedup vs baseline: 2.5305x; 1.5567x over previous
//
#include <hip/hip_runtime.h>
#include <hip/hip_bf16.h>

typedef unsigned short u16;
typedef unsigned int   u32;

constexpr int H     = 256;
constexpr int HH    = 128;
constexpr int MELD  = 80;
constexpr int RF    = 5;
constexpr int BS    = 128;
constexpr int TENC  = 512;
constexpr int TDEC  = 1000;
constexpr int STEPS = 200;
constexpr int OD    = 400;
constexpr int M_ALL = STEPS * BS;   // 25600

// ================= fast-path workspace layout (bytes) =================
constexpr size_t XS_B   = 0;                                  // xs f32 [s][b][128]
constexpr size_t W1ET_B = XS_B + (size_t)M_ALL*HH*4;          // w1eT bf16 [b][h][t] (pre-scaled, see k_w1encT)
constexpr size_t DD_B   = W1ET_B + (size_t)BS*H*TENC*2;       // ddcat f32 [m][512] (d|ddot); later in2 [m][256]
constexpr size_t GI_B   = DD_B + (size_t)M_ALL*512*4;         // gi f32 [m][768]; also Q [m][256]
constexpr size_t P_B    = GI_B + (size_t)M_ALL*768*4;         // P f32 [m][256]; later st
constexpr size_t WPK_B  = P_B + (size_t)M_ALL*H*4;            // 3 packed whh (f16 pairs), 393216 B each
constexpr size_t NEED_FAST = WPK_B + 3*(size_t)393216;

// ================= fallback (R4) workspace layout =====================
constexpr size_t FBW1E_B  = 65536;
constexpr size_t FBXST_B  = FBW1E_B + (size_t)BS*TENC*H*2;
constexpr size_t FBF32_B  = FBXST_B + (size_t)STEPS*HH*BS*2;
constexpr size_t FBDT_F   = 0;
constexpr size_t FBO1_F   = FBDT_F + 2*(size_t)H*BS;
constexpr size_t FBO2_F   = FBO1_F + 2*(size_t)H*BS;
constexpr size_t FBPT_F   = FBO2_F + 2*(size_t)H*BS;
constexpr size_t FBIN2_F  = FBPT_F + (size_t)H*BS;
constexpr size_t FBST_F   = FBIN2_F + (size_t)H*BS;
constexpr size_t FB_NEED_B = FBF32_B + (FBST_F + 2*(size_t)H*BS) * 4;

// ================= helpers =================
__device__ __forceinline__ float bf2f(u16 v) {
  union { u32 x; float f; } c; c.x = ((u32)v) << 16; return c.f;
}
__device__ __forceinline__ float bfu_lo(u32 u) { union { u32 x; float f; } c; c.x = u << 16;        return c.f; }
__device__ __forceinline__ float bfu_hi(u32 u) { union { u32 x; float f; } c; c.x = u & 0xffff0000u; return c.f; }
__device__ __forceinline__ u16 f2bf(float f) {
  union { float f; u32 u; } c; c.f = f;
  u32 u = c.u;
  u32 r = (u + 0x7fffu + ((u >> 16) & 1u)) >> 16;  // RNE
  return (u16)r;
}
__device__ __forceinline__ float fexp(float x) {
  return __builtin_amdgcn_exp2f(1.4426950408889634f * x);
}
__device__ __forceinline__ float sigm_f(float x) {
  return __builtin_amdgcn_rcpf(1.0f + __builtin_amdgcn_exp2f(-1.4426950408889634f * x));
}
__device__ __forceinline__ float tanh_f(float x) {
  x = fminf(fmaxf(x, -15.f), 15.f);
  float e = __builtin_amdgcn_exp2f(2.8853900817779268f * x);   // e^(2x)
  return (e - 1.0f) * __builtin_amdgcn_rcpf(e + 1.0f);
}

// f16 pair dot: acc += w.lo*h.lo + w.hi*h.hi  (V_DOT2_F32_F16 when available)
typedef _Float16 hlf2 __attribute__((ext_vector_type(2)));
#if __has_builtin(__builtin_amdgcn_fdot2)
__device__ __forceinline__ float dot2h(float acc, u32 w, u32 h) {
  union { u32 u; hlf2 v; } cw, ch; cw.u = w; ch.u = h;
  return __builtin_amdgcn_fdot2(cw.v, ch.v, acc, false);
}
#else
__device__ __forceinline__ float dot2h(float acc, u32 w, u32 h) {
  union { u32 u; _Float16 f[2]; } cw, ch; cw.u = w; ch.u = h;
  return acc + (float)cw.f[0] * (float)ch.f[0] + (float)cw.f[1] * (float)ch.f[1];
}
#endif
__device__ __forceinline__ void dot8h(float& acc, const uint4 w, const uint4 hp) {
  acc = dot2h(acc, w.x, hp.x);
  acc = dot2h(acc, w.y, hp.y);
  acc = dot2h(acc, w.z, hp.z);
  acc = dot2h(acc, w.w, hp.w);
}

__global__ __launch_bounds__(256) void k_zero(float* __restrict__ out, int n) {
  int i = blockIdx.x * 256 + threadIdx.x;
  if (i < n) out[i] = 0.f;
}

// =====================================================================
//                           FAST PATH
// =====================================================================

// ---- prenet (2 fused layers) -> xs f32 [s][b][128] ----
__global__ __launch_bounds__(256) void k_prenet_f(
    const float* __restrict__ dec, const float* __restrict__ w1, const float* __restrict__ b1,
    const float* __restrict__ w2, const float* __restrict__ b2, float* __restrict__ xs)
{
  const int s = blockIdx.x, tid = threadIdx.x;
  __shared__ float X0[32][80];
  __shared__ float P1t[32][256];
  for (int bt = 0; bt < 4; ++bt) {
    const int b0 = bt * 32;
    __syncthreads();
    for (int i = tid; i < 32 * 80; i += 256) {
      int bb = i / 80, m = i - bb * 80;
      X0[bb][m] = dec[((size_t)(b0 + bb) * TDEC + (size_t)s * RF) * MELD + m];
    }
    __syncthreads();
    {
      const int h = tid;
      float acc[32];
      const float bias = b1[h];
      #pragma unroll
      for (int r = 0; r < 32; ++r) acc[r] = bias;
      const float* wr = w1 + (size_t)h * MELD;
      for (int m = 0; m < 80; m += 4) {
        float4 wv = *(const float4*)(wr + m);
        #pragma unroll
        for (int r = 0; r < 32; ++r) {
          float4 x = *(const float4*)&X0[r][m];
          acc[r] += x.x * wv.x + x.y * wv.y + x.z * wv.z + x.w * wv.w;
        }
      }
      #pragma unroll
      for (int r = 0; r < 32; ++r) P1t[r][h] = fmaxf(acc[r], 0.f);
    }
    __syncthreads();
    {
      const int k = tid & 127, bh = tid >> 7;
      float acc[16];
      const float bias = b2[k];
      #pragma unroll
      for (int r = 0; r < 16; ++r) acc[r] = bias;
      const float* wr = w2 + (size_t)k * H;
      for (int h = 0; h < H; h += 4) {
        float4 wv = *(const float4*)(wr + h);
        #pragma unroll
        for (int r = 0; r < 16; ++r) {
          float4 x = *(const float4*)&P1t[bh * 16 + r][h];
          acc[r] += x.x * wv.x + x.y * wv.y + x.z * wv.z + x.w * wv.w;
        }
      }
      #pragma unroll
      for (int r = 0; r < 16; ++r)
        xs[((size_t)s * BS + b0 + bh * 16 + r) * HH + k] = fmaxf(acc[r], 0.f);
    }
  }
}

// ---- w1enc transposed: w1eT[b][h][t] bf16, PRE-SCALED by 2/ln2-equivalent ----
__global__ __launch_bounds__(256) void k_w1encT(
    const float* __restrict__ enc, const float* __restrict__ w1, const float* __restrict__ b1,
    u16* __restrict__ w1eT)
{
  const int row0 = blockIdx.x * 32;   // row = b*TENC + t
  const int tid = threadIdx.x;
  __shared__ float A[32 * 256];
  for (int i = tid * 4; i < 32 * 256; i += 256 * 4) {
    float4 v = *(const float4*)(enc + (size_t)row0 * H + i);
    A[i] = v.x; A[i + 1] = v.y; A[i + 2] = v.z; A[i + 3] = v.w;
  }
  __syncthreads();
  const int h = tid;
  float acc[32];
  const float bias = b1[h];
  #pragma unroll
  for (int r = 0; r < 32; ++r) acc[r] = bias;
  const float* wr = w1 + (size_t)h * H;
  for (int k = 0; k < H; k += 4) {
    float4 wv = *(const float4*)(wr + k);
    #pragma unroll
    for (int r = 0; r < 32; ++r) {
      float4 a = *(const float4*)&A[r * 256 + k];
      acc[r] += a.x * wv.x + a.y * wv.y + a.z * wv.z + a.w * wv.w;
    }
  }
  const int b = row0 / TENC, t0 = row0 % TENC;
  #pragma unroll
  for (int r = 0; r < 32; ++r)
    w1eT[((size_t)b * H + h) * TENC + t0 + r] = f2bf(2.8853900817779268f * acc[r]);
}

// ---- pack whh f32[768][256] -> uint4 groups: [3][32][256] of 4 F16-pairs ----
// u32 flat index: ((g*32 + k4)*256 + j)*4 + i   where k2 = 4*k4 + i,
// value = f16(w[g*256+j][2*k2]) | f16(w[g*256+j][2*k2+1]) << 16.
__global__ __launch_bounds__(256) void k_pack(const float* __restrict__ w, u32* __restrict__ o) {
  int idx = blockIdx.x * 256 + threadIdx.x;
  if (idx >= 3 * 32 * 256 * 4) return;
  int i  = idx & 3;
  int j  = (idx >> 2) & 255;
  int k4 = (idx >> 10) & 31;
  int g  = idx >> 15;
  int k2 = 4 * k4 + i;
  union { _Float16 f[2]; u32 u; } c;
  c.f[0] = (_Float16)w[((size_t)g * 256 + j) * 256 + 2 * k2];
  c.f[1] = (_Float16)w[((size_t)g * 256 + j) * 256 + 2 * k2 + 1];
  o[idx] = c.u;
}

// ---- tiled GEMM: C[M][N] = A[M][K] @ W[N][K]^T + bias ----
// if outmap != nullptr: write to mel-output layout instead of C.
__global__ __launch_bounds__(256) void k_gemm(
    const float* __restrict__ A, int lda, const float* __restrict__ W, int K,
    const float* __restrict__ bias, float* __restrict__ C, int ldc, int N,
    float* __restrict__ outmap)
{
  __shared__ float As[64][65];
  __shared__ float Ws[64][65];
  const int m0 = blockIdx.y * 64, n0 = blockIdx.x * 64;
  const int tid = threadIdx.x, tx = tid & 15, ty = tid >> 4;
  float acc[4][4] = {};
  for (int k0 = 0; k0 < K; k0 += 64) {
    #pragma unroll
    for (int it = 0; it < 4; ++it) {
      int flat = tid + it * 256;
      int r = flat >> 4, c4 = (flat & 15) * 4;
      *(float4*)&As[r][c4] = *(const float4*)(A + (size_t)(m0 + r) * lda + k0 + c4);
      float4 wv;
      if (n0 + r < N) wv = *(const float4*)(W + (size_t)(n0 + r) * K + k0 + c4);
      else { wv.x = wv.y = wv.z = wv.w = 0.f; }
      *(float4*)&Ws[r][c4] = wv;
    }
    __syncthreads();
    for (int kk = 0; kk < 64; ++kk) {
      float a0 = As[ty*4+0][kk], a1 = As[ty*4+1][kk], a2 = As[ty*4+2][kk], a3 = As[ty*4+3][kk];
      float b0 = Ws[tx*4+0][kk], b1 = Ws[tx*4+1][kk], b2 = Ws[tx*4+2][kk], b3 = Ws[tx*4+3][kk];
      acc[0][0]+=a0*b0; acc[0][1]+=a0*b1; acc[0][2]+=a0*b2; acc[0][3]+=a0*b3;
      acc[1][0]+=a1*b0; acc[1][1]+=a1*b1; acc[1][2]+=a1*b2; acc[1][3]+=a1*b3;
      acc[2][0]+=a2*b0; acc[2][1]+=a2*b1; acc[2][2]+=a2*b2; acc[2][3]+=a2*b3;
      acc[3][0]+=a3*b0; acc[3][1]+=a3*b1; acc[3][2]+=a3*b2; acc[3][3]+=a3*b3;
    }
    __syncthreads();
  }
  #pragma unroll
  for (int i = 0; i < 4; ++i) {
    const int m = m0 + ty * 4 + i;
    #pragma unroll
    for (int jj = 0; jj < 4; ++jj) {
      const int n = n0 + tx * 4 + jj;
      if (n < N) {
        float v = acc[i][jj] + bias[n];
        if (outmap == nullptr) {
          C[(size_t)m * ldc + n] = v;
        } else {
          int s = m >> 7, b = m & 127;
          int fr = s * RF + n / MELD, mel = n - (n / MELD) * MELD;
          outmap[((size_t)b * TDEC + fr) * MELD + mel] = v;
        }
      }
    }
  }
}

// ---- per-row sequential GRU chain, v3 -------------------------------
// 512 threads: tid = (kh<<8)|j. f16-pair weights consumed by V_DOT2_F32_F16.
// Weight residency: 6 k4-groups/half in LDS, 10 k4-groups/half in VGPRs
// (loaded once before the step loop -> zero global weight traffic in-loop).
// h state: per-thread f32 register (kh==0) + f16 LDS mirror hf[256] read as
// uint4 by the dot loops.
constexpr int KC4H = 6;    // k4-groups per half cached in LDS
constexpr int RG4H = 10;   // k4-groups per half resident in VGPRs (6+10=16)
__global__ __launch_bounds__(512) void k_chain(
    const float* __restrict__ gi,      // [25600][768] includes bih
    const uint4* __restrict__ wpk4,    // [3][32][256] uint4 (f16 pairs)
    const float* __restrict__ bhh,     // [768]
    const float* __restrict__ addsrc,  // nullptr or [25600][astride]
    int astride,
    float* __restrict__ outp, int ostride)
{
  const int b = blockIdx.x, tid = threadIdx.x;
  const int j = tid & 255, kh = tid >> 8;
  __shared__ __align__(16) _Float16 hf[256];
  __shared__ float psum[3][256];
  __shared__ uint4 wl4[3][2 * KC4H][256];
  // fill LDS weight cache: slot s -> k4 = (s>=KC4H ? 16 : 0) + s%KC4H
  for (int i = tid; i < 3 * 2 * KC4H * 256; i += 512) {
    int g = i / (2 * KC4H * 256), rem = i - g * (2 * KC4H * 256);
    int slot = rem >> 8, jj = rem & 255;
    int c = slot < KC4H ? slot : slot - KC4H;
    int k4 = (slot < KC4H ? 0 : 16) + c;
    wl4[g][slot][jj] = wpk4[((size_t)g * 32 + k4) * 256 + jj];
  }
  // VGPR-resident weight groups (k4 = kh*16 + KC4H..15)
  uint4 wreg[3][RG4H];
  #pragma unroll
  for (int g = 0; g < 3; ++g) {
    #pragma unroll
    for (int t = 0; t < RG4H; ++t) {
      const int k4 = kh * 16 + KC4H + t;
      wreg[g][t] = wpk4[((size_t)g * 32 + k4) * 256 + j];
    }
  }
  if (tid < 256) hf[tid] = (_Float16)0.f;
  float hreg = 0.f;                       // kh==0: h state for own j
  const float br = bhh[j], bz = bhh[256 + j], bn = bhh[512 + j];
  __syncthreads();
  for (int s = 0; s < STEPS; ++s) {
    const size_t m = (size_t)s * BS + b;
    float gr = 0.f, gz = 0.f, gn = 0.f, av = 0.f;
    if (kh == 0) {                        // wave-uniform branch
      const float* gim = gi + m * 768;
      gr = gim[j]; gz = gim[256 + j]; gn = gim[512 + j];
      if (addsrc) av = addsrc[m * astride + j];
    }
    float ar = 0.f, az = 0.f, an = 0.f;
    const int k4b = kh * 16;
    #pragma unroll
    for (int t = 0; t < RG4H; ++t) {
      const int k4 = k4b + KC4H + t;
      uint4 hp = *(const uint4*)&hf[8 * k4];
      dot8h(ar, wreg[0][t], hp); dot8h(az, wreg[1][t], hp); dot8h(an, wreg[2][t], hp);
    }
    #pragma unroll
    for (int c = 0; c < KC4H; ++c) {
      const int k4 = k4b + c;
      const int slot = kh * KC4H + c;
      uint4 hp = *(const uint4*)&hf[8 * k4];
      dot8h(ar, wl4[0][slot][j], hp); dot8h(az, wl4[1][slot][j], hp); dot8h(an, wl4[2][slot][j], hp);
    }
    if (kh == 1) { psum[0][j] = ar; psum[1][j] = az; psum[2][j] = an; }
    __syncthreads();                      // dots done (hf reads) + psum visible
    if (kh == 0) {
      ar += psum[0][j]; az += psum[1][j]; an += psum[2][j];
      float r = sigm_f(gr + ar + br);
      float z = sigm_f(gz + az + bz);
      float n = tanh_f(gn + r * (an + bn));
      float hn_ = (1.f - z) * n + z * hreg;
      hreg = hn_;
      hf[j] = (_Float16)hn_;
      outp[m * ostride + j] = hn_ + av;
    }
    __syncthreads();                      // hf update visible for next step
  }
}

// ---- fused scores + softmax + d_dot: block = (b, 10-step tile) ----
constexpr int ATT_ST = 10;
__global__ __launch_bounds__(256) void k_att(
    const u16* __restrict__ w1eT, const float* __restrict__ Q,
    const float* __restrict__ vw_, const float* __restrict__ enc,
    float* __restrict__ DD)
{
  const int b = blockIdx.x, s0 = blockIdx.y * ATT_ST, tid = threadIdx.x;
  __shared__ float qt[ATT_ST][260];
  __shared__ float vws[256];
  __shared__ float us[ATT_ST][516];
  __shared__ float redw[ATT_ST][4];
  vws[tid] = -2.0f * vw_[tid];
  #pragma unroll
  for (int si = 0; si < ATT_ST; ++si)
    qt[si][tid] = 2.8853900817779268f * Q[((size_t)(s0 + si) * BS + b) * H + tid];
  __syncthreads();

  // ---- scores: sc = sum_h (-2 v_h) * rcp(1 + exp2(w_sc + q_sc)) ----
  float sc0[ATT_ST], sc1[ATT_ST];
  #pragma unroll
  for (int si = 0; si < ATT_ST; ++si) { sc0[si] = 0.f; sc1[si] = 0.f; }
  const u32* wrow = (const u32*)w1eT + (size_t)b * H * (TENC / 2);
  for (int h = 0; h < H; h += 2) {
    u32 wa = wrow[(size_t)h * 256 + tid];          // t = 2*tid, 2*tid+1
    u32 wb = wrow[(size_t)(h + 1) * 256 + tid];
    float wa0 = bfu_lo(wa), wa1 = bfu_hi(wa);
    float wb0 = bfu_lo(wb), wb1 = bfu_hi(wb);
    float va = vws[h], vb = vws[h + 1];
    #pragma unroll
    for (int si = 0; si < ATT_ST; ++si) {
      float2 q2 = *(const float2*)&qt[si][h];
      sc0[si] += va * __builtin_amdgcn_rcpf(1.f + __builtin_amdgcn_exp2f(wa0 + q2.x))
               + vb * __builtin_amdgcn_rcpf(1.f + __builtin_amdgcn_exp2f(wb0 + q2.y));
      sc1[si] += va * __builtin_amdgcn_rcpf(1.f + __builtin_amdgcn_exp2f(wa1 + q2.x))
               + vb * __builtin_amdgcn_rcpf(1.f + __builtin_amdgcn_exp2f(wb1 + q2.y));
    }
  }
  // softmax over 512 t (2 per thread x 256 threads, 4 waves)
  const int lane = tid & 63, wvi = tid >> 6;
  #pragma unroll
  for (int si = 0; si < ATT_ST; ++si) {
    float mw = fmaxf(sc0[si], sc1[si]);
    for (int off = 1; off < 64; off <<= 1) mw = fmaxf(mw, __shfl_xor(mw, off));
    if (lane == 0) redw[si][wvi] = mw;
  }
  __syncthreads();
  #pragma unroll
  for (int si = 0; si < ATT_ST; ++si) {
    float mx = fmaxf(fmaxf(redw[si][0], redw[si][1]), fmaxf(redw[si][2], redw[si][3]));
    sc0[si] = fexp(sc0[si] - mx);
    sc1[si] = fexp(sc1[si] - mx);
  }
  __syncthreads();
  #pragma unroll
  for (int si = 0; si < ATT_ST; ++si) {
    float sm = sc0[si] + sc1[si];
    for (int off = 1; off < 64; off <<= 1) sm += __shfl_xor(sm, off);
    if (lane == 0) redw[si][wvi] = sm;
  }
  __syncthreads();
  #pragma unroll
  for (int si = 0; si < ATT_ST; ++si) {
    float tot = redw[si][0] + redw[si][1] + redw[si][2] + redw[si][3];
    float li = __builtin_amdgcn_rcpf(tot);
    float2 uv; uv.x = sc0[si] * li; uv.y = sc1[si] * li;
    *(float2*)&us[si][2 * tid] = uv;
  }
  __syncthreads();
  // ---- d_dot[si][h=tid] = sum_t us[si][t] * enc[b][t][h]  (enc direct) ----
  float dd[ATT_ST];
  #pragma unroll
  for (int si = 0; si < ATT_ST; ++si) dd[si] = 0.f;
  const float* ep = enc + (size_t)b * TENC * H + tid;
  for (int t = 0; t < TENC; t += 4) {
    float e0 = ep[(size_t)(t + 0) * H];
    float e1 = ep[(size_t)(t + 1) * H];
    float e2 = ep[(size_t)(t + 2) * H];
    float e3 = ep[(size_t)(t + 3) * H];
    #pragma unroll
    for (int si = 0; si < ATT_ST; ++si) {
      float4 u4 = *(const float4*)&us[si][t];
      dd[si] += e0 * u4.x + e1 * u4.y + e2 * u4.z + e3 * u4.w;
    }
  }
  #pragma unroll
  for (int si = 0; si < ATT_ST; ++si)
    DD[((size_t)(s0 + si) * BS + b) * 512 + 256 + tid] = dd[si];
}

// =====================================================================
//                      FALLBACK PATH (R4, verified)
// =====================================================================
__global__ __launch_bounds__(256) void fbk_zeroinit(float* __restrict__ fst) {
  int i = blockIdx.x * 256 + threadIdx.x;
  if (i < H * BS)              fst[FBDT_F + i] = 0.f;
  else if (i < 2 * H * BS)     fst[FBO1_F + (i - H * BS)] = 0.f;
  else if (i < 3 * H * BS)     fst[FBO2_F + (i - 2 * H * BS)] = 0.f;
}

__global__ __launch_bounds__(256) void fbk_prenet(
    const float* __restrict__ dec, const float* __restrict__ w1, const float* __restrict__ b1,
    const float* __restrict__ w2, const float* __restrict__ b2, u16* __restrict__ xsT)
{
  const int s = blockIdx.x, tid = threadIdx.x;
  __shared__ float X0[32][80];
  __shared__ float P1t[32][256];
  for (int bt = 0; bt < 4; ++bt) {
    const int b0 = bt * 32;
    __syncthreads();
    for (int i = tid; i < 32 * 80; i += 256) {
      int bb = i / 80, m = i - bb * 80;
      X0[bb][m] = dec[((size_t)(b0 + bb) * TDEC + (size_t)s * RF) * MELD + m];
    }
    __syncthreads();
    {
      const int h = tid;
      float acc[32];
      const float bias = b1[h];
      #pragma unroll
      for (int r = 0; r < 32; ++r) acc[r] = bias;
      const float* wr = w1 + (size_t)h * MELD;
      for (int m = 0; m < 80; m += 4) {
        float4 wv = *(const float4*)(wr + m);
        #pragma unroll
        for (int r = 0; r < 32; ++r) {
          float4 x = *(const float4*)&X0[r][m];
          acc[r] += x.x * wv.x + x.y * wv.y + x.z * wv.z + x.w * wv.w;
        }
      }
      #pragma unroll
      for (int r = 0; r < 32; ++r) P1t[r][h] = fmaxf(acc[r], 0.f);
    }
    __syncthreads();
    {
      const int k = tid & 127, bh = tid >> 7;
      float acc[16];
      const float bias = b2[k];
      #pragma unroll
      for (int r = 0; r < 16; ++r) acc[r] = bias;
      const float* wr = w2 + (size_t)k * H;
      for (int h = 0; h < H; h += 4) {
        float4 wv = *(const float4*)(wr + h);
        #pragma unroll
        for (int r = 0; r < 16; ++r) {
          float4 x = *(const float4*)&P1t[bh * 16 + r][h];
          acc[r] += x.x * wv.x + x.y * wv.y + x.z * wv.z + x.w * wv.w;
        }
      }
      #pragma unroll
      for (int r = 0; r < 16; ++r)
        xsT[((size_t)s * HH + k) * BS + b0 + bh * 16 + r] = f2bf(fmaxf(acc[r], 0.f));
    }
  }
}

__global__ __launch_bounds__(256) void fbk_w1enc(
    const float* __restrict__ enc, const float* __restrict__ w1, const float* __restrict__ b1,
    u16* __restrict__ w1e)
{
  const int row0 = blockIdx.x * 32;
  const int tid = threadIdx.x;
  __shared__ float A[32 * 256];
  for (int i = tid * 4; i < 32 * 256; i += 256 * 4) {
    float4 v = *(const float4*)(enc + (size_t)row0 * H + i);
    A[i] = v.x; A[i + 1] = v.y; A[i + 2] = v.z; A[i + 3] = v.w;
  }
  __syncthreads();
  const int h = tid;
  float acc[32];
  const float bias = b1[h];
  #pragma unroll
  for (int r = 0; r < 32; ++r) acc[r] = bias;
  const float* wr = w1 + (size_t)h * H;
  for (int k = 0; k < H; k += 4) {
    float4 wv = *(const float4*)(wr + k);
    #pragma unroll
    for (int r = 0; r < 32; ++r) {
      float4 a = *(const float4*)&A[r * 256 + k];
      acc[r] += a.x * wv.x + a.y * wv.y + a.z * wv.z + a.w * wv.w;
    }
  }
  #pragma unroll
  for (int r = 0; r < 32; ++r) w1e[((size_t)row0 + r) * H + h] = f2bf(acc[r]);
}

__device__ __forceinline__ void fb_gru_body(
    float (*w6)[260], float (*pA)[128], float (*pB)[128], int j, int tid,
    const float* __restrict__ gi_src, const float* __restrict__ h_src,
    const float* __restrict__ wih, const float* __restrict__ whh,
    const float* __restrict__ bih, const float* __restrict__ bhh,
    float* __restrict__ h_out, float* __restrict__ sum_out)
{
  for (int i = tid; i < 3 * H; i += 256) {
    int gg = i >> 8, k = i & 255;
    w6[gg][k]     = wih[((size_t)gg * H + j) * H + k];
    w6[3 + gg][k] = whh[((size_t)gg * H + j) * H + k];
  }
  __syncthreads();
  const int b = tid & 127, kh = tid >> 7;
  float pr = 0, pz = 0, pn = 0, hr = 0, hz = 0, hn = 0;
  for (int k = kh * 128; k < kh * 128 + 128; k += 4) {
    float4 wia = *(const float4*)&w6[0][k];
    float4 wib = *(const float4*)&w6[1][k];
    float4 wic = *(const float4*)&w6[2][k];
    float4 wha = *(const float4*)&w6[3][k];
    float4 whb = *(const float4*)&w6[4][k];
    float4 whc = *(const float4*)&w6[5][k];
    float x0 = gi_src[(size_t)(k + 0) * BS + b], x1 = gi_src[(size_t)(k + 1) * BS + b];
    float x2 = gi_src[(size_t)(k + 2) * BS + b], x3 = gi_src[(size_t)(k + 3) * BS + b];
    float h0 = h_src[(size_t)(k + 0) * BS + b],  h1 = h_src[(size_t)(k + 1) * BS + b];
    float h2 = h_src[(size_t)(k + 2) * BS + b],  h3 = h_src[(size_t)(k + 3) * BS + b];
    pr += x0 * wia.x + x1 * wia.y + x2 * wia.z + x3 * wia.w;
    pz += x0 * wib.x + x1 * wib.y + x2 * wib.z + x3 * wib.w;
    pn += x0 * wic.x + x1 * wic.y + x2 * wic.z + x3 * wic.w;
    hr += h0 * wha.x + h1 * wha.y + h2 * wha.z + h3 * wha.w;
    hz += h0 * whb.x + h1 * whb.y + h2 * whb.z + h3 * whb.w;
    hn += h0 * whc.x + h1 * whc.y + h2 * whc.z + h3 * whc.w;
  }
  if (kh) {
    pA[0][b] = pr; pA[1][b] = pz; pA[2][b] = pn;
    pB[0][b] = hr; pB[1][b] = hz; pB[2][b] = hn;
  }
  __syncthreads();
  if (!kh) {
    float gir = pr + pA[0][b] + bih[j];
    float giz = pz + pA[1][b] + bih[H + j];
    float gin = pn + pA[2][b] + bih[2 * H + j];
    float ghr = hr + pB[0][b] + bhh[j];
    float ghz = hz + pB[1][b] + bhh[H + j];
    float ghn = hn + pB[2][b] + bhh[2 * H + j];
    float r = sigm_f(gir + ghr);
    float z = sigm_f(giz + ghz);
    float n = tanh_f(gin + r * ghn);
    float hp = h_src[(size_t)j * BS + b];
    float o = (1.f - z) * n + z * hp;
    h_out[(size_t)j * BS + b] = o;
    if (sum_out) sum_out[(size_t)j * BS + b] = o + gi_src[(size_t)j * BS + b];
  }
}

__global__ __launch_bounds__(256) void fbk_attgru(
    const u16* __restrict__ xstu, float* __restrict__ fst,
    const float* __restrict__ awih, const float* __restrict__ awhh,
    const float* __restrict__ abih, const float* __restrict__ abhh, int s)
{
  const int j = blockIdx.x, tid = threadIdx.x;
  __shared__ float w6[6][260];
  __shared__ float pA[3][128];
  __shared__ float pB[3][128];
  const float* dprev = fst + FBDT_F + (size_t)(s & 1) * H * BS;
  float*       dcur  = fst + FBDT_F + (size_t)((s + 1) & 1) * H * BS;
  for (int i = tid; i < 3 * HH; i += 256) {
    int gg = i >> 7, k = i & (HH - 1);
    w6[gg][k] = awih[((size_t)gg * H + j) * HH + k];
  }
  for (int i = tid; i < 3 * H; i += 256) {
    int gg = i >> 8, k = i & (H - 1);
    w6[3 + gg][k] = awhh[((size_t)gg * H + j) * H + k];
  }
  __syncthreads();
  const u16* xcol = xstu + (size_t)s * HH * BS;
  const int b = tid & 127, kh = tid >> 7;
  float pr = 0, pz = 0, pn = 0, hr = 0, hz = 0, hn = 0;
  for (int k = kh * 64; k < kh * 64 + 64; k += 4) {
    float4 wa = *(const float4*)&w6[0][k];
    float4 wb = *(const float4*)&w6[1][k];
    float4 wc = *(const float4*)&w6[2][k];
    float x0 = bf2f(xcol[(size_t)(k + 0) * BS + b]), x1 = bf2f(xcol[(size_t)(k + 1) * BS + b]);
    float x2 = bf2f(xcol[(size_t)(k + 2) * BS + b]), x3 = bf2f(xcol[(size_t)(k + 3) * BS + b]);
    pr += x0 * wa.x + x1 * wa.y + x2 * wa.z + x3 * wa.w;
    pz += x0 * wb.x + x1 * wb.y + x2 * wb.z + x3 * wb.w;
    pn += x0 * wc.x + x1 * wc.y + x2 * wc.z + x3 * wc.w;
  }
  for (int k = kh * 128; k < kh * 128 + 128; k += 4) {
    float4 wa = *(const float4*)&w6[3][k];
    float4 wb = *(const float4*)&w6[4][k];
    float4 wc = *(const float4*)&w6[5][k];
    float h0 = dprev[(size_t)(k + 0) * BS + b], h1 = dprev[(size_t)(k + 1) * BS + b];
    float h2 = dprev[(size_t)(k + 2) * BS + b], h3 = dprev[(size_t)(k + 3) * BS + b];
    hr += h0 * wa.x + h1 * wa.y + h2 * wa.z + h3 * wa.w;
    hz += h0 * wb.x + h1 * wb.y + h2 * wb.z + h3 * wb.w;
    hn += h0 * wc.x + h1 * wc.y + h2 * wc.z + h3 * wc.w;
  }
  if (kh) {
    pA[0][b] = pr; pA[1][b] = pz; pA[2][b] = pn;
    pB[0][b] = hr; pB[1][b] = hz; pB[2][b] = hn;
  }
  __syncthreads();
  if (!kh) {
    float gir = pr + pA[0][b] + abih[j];
    float giz = pz + pA[1][b] + abih[H + j];
    float gin = pn + pA[2][b] + abih[2 * H + j];
    float ghr = hr + pB[0][b] + abhh[j];
    float ghz = hz + pB[1][b] + abhh[H + j];
    float ghn = hn + pB[2][b] + abhh[2 * H + j];
    float r = sigm_f(gir + ghr);
    float z = sigm_f(giz + ghz);
    float n = tanh_f(gin + r * ghn);
    float hp = dprev[(size_t)j * BS + b];
    dcur[(size_t)j * BS + b] = (1.f - z) * n + z * hp;
  }
}

__global__ __launch_bounds__(256) void fbk_attn(
    const float* __restrict__ enc, const u16* __restrict__ w1eu,
    const float* __restrict__ w2w, const float* __restrict__ b2w,
    const float* __restrict__ vww, const float* __restrict__ vbw,
    const float* __restrict__ pjw, const float* __restrict__ pjb,
    float* __restrict__ fst, int s)
{
  const int b3 = blockIdx.x, tid = threadIdx.x;
  __shared__ float dsh[256], qs[256], ddh[256], vwsh[256], ev[512], red[256];
  const float* dcur = fst + FBDT_F + (size_t)((s + 1) & 1) * H * BS;
  float* pT = fst + FBPT_F;
  dsh[tid]  = dcur[(size_t)tid * BS + b3];
  vwsh[tid] = vww[tid];
  __syncthreads();
  {
    const int jj = tid;
    const float* wr = w2w + (size_t)jj * H;
    float acc = b2w[jj];
    for (int k = 0; k < H; k += 8) {
      float4 wA = *(const float4*)(wr + k);
      float4 wB = *(const float4*)(wr + k + 4);
      float4 dA = *(const float4*)&dsh[k];
      float4 dB = *(const float4*)&dsh[k + 4];
      acc += dA.x * wA.x + dA.y * wA.y + dA.z * wA.z + dA.w * wA.w
           + dB.x * wB.x + dB.y * wB.y + dB.z * wB.z + dB.w * wB.w;
    }
    qs[jj] = acc;
  }
  __syncthreads();
  const float vbf = vbw[0];
  const u16* wr0 = w1eu + ((size_t)b3 * TENC + tid) * H;
  const u16* wr1 = wr0 + (size_t)256 * H;
  float sc0 = vbf, sc1 = vbf;
  for (int h = 0; h < H; h += 8) {
    uint4 ua = *(const uint4*)(wr0 + h);
    uint4 uc = *(const uint4*)(wr1 + h);
    float4 qA = *(const float4*)&qs[h];
    float4 qB = *(const float4*)&qs[h + 4];
    float4 vA = *(const float4*)&vwsh[h];
    float4 vB = *(const float4*)&vwsh[h + 4];
    sc0 += vA.x * tanh_f(bfu_lo(ua.x) + qA.x) + vA.y * tanh_f(bfu_hi(ua.x) + qA.y)
         + vA.z * tanh_f(bfu_lo(ua.y) + qA.z) + vA.w * tanh_f(bfu_hi(ua.y) + qA.w)
         + vB.x * tanh_f(bfu_lo(ua.z) + qB.x) + vB.y * tanh_f(bfu_hi(ua.z) + qB.y)
         + vB.z * tanh_f(bfu_lo(ua.w) + qB.z) + vB.w * tanh_f(bfu_hi(ua.w) + qB.w);
    sc1 += vA.x * tanh_f(bfu_lo(uc.x) + qA.x) + vA.y * tanh_f(bfu_hi(uc.x) + qA.y)
         + vA.z * tanh_f(bfu_lo(uc.y) + qA.z) + vA.w * tanh_f(bfu_hi(uc.y) + qA.w)
         + vB.x * tanh_f(bfu_lo(uc.z) + qB.x) + vB.y * tanh_f(bfu_hi(uc.z) + qB.y)
         + vB.z * tanh_f(bfu_lo(uc.w) + qB.z) + vB.w * tanh_f(bfu_hi(uc.w) + qB.w);
  }
  red[tid] = fmaxf(sc0, sc1);
  __syncthreads();
  for (int off = 128; off > 0; off >>= 1) {
    if (tid < off) red[tid] = fmaxf(red[tid], red[tid + off]);
    __syncthreads();
  }
  float mx = red[0];
  __syncthreads();
  float e0 = fexp(sc0 - mx), e1 = fexp(sc1 - mx);
  ev[tid] = e0; ev[256 + tid] = e1;
  red[tid] = e0 + e1;
  __syncthreads();
  for (int off = 128; off > 0; off >>= 1) {
    if (tid < off) red[tid] += red[tid + off];
    __syncthreads();
  }
  float linv = __builtin_amdgcn_rcpf(red[0]);
  __syncthreads();
  {
    float vacc = 0.f;
    const float* ep = enc + (size_t)b3 * TENC * H + tid;
    for (int tt = 0; tt < TENC; tt += 4) {
      float4 e4 = *(const float4*)&ev[tt];
      vacc += e4.x * ep[(size_t)(tt + 0) * H] + e4.y * ep[(size_t)(tt + 1) * H]
            + e4.z * ep[(size_t)(tt + 2) * H] + e4.w * ep[(size_t)(tt + 3) * H];
    }
    ddh[tid] = vacc * linv;
  }
  __syncthreads();
  {
    const int jj = tid;
    const float* wr = pjw + (size_t)jj * (2 * H);
    float acc = pjb[jj];
    for (int k = 0; k < H; k += 8) {
      float4 wA = *(const float4*)(wr + k);
      float4 wB = *(const float4*)(wr + k + 4);
      float4 dA = *(const float4*)&dsh[k];
      float4 dB = *(const float4*)&dsh[k + 4];
      acc += dA.x * wA.x + dA.y * wA.y + dA.z * wA.z + dA.w * wA.w
           + dB.x * wB.x + dB.y * wB.y + dB.z * wB.z + dB.w * wB.w;
    }
    for (int k = 0; k < H; k += 8) {
      float4 wA = *(const float4*)(wr + H + k);
      float4 wB = *(const float4*)(wr + H + k + 4);
      float4 dA = *(const float4*)&ddh[k];
      float4 dB = *(const float4*)&ddh[k + 4];
      acc += dA.x * wA.x + dA.y * wA.y + dA.z * wA.z + dA.w * wA.w
           + dB.x * wB.x + dB.y * wB.y + dB.z * wB.z + dB.w * wB.w;
    }
    pT[(size_t)jj * BS + b3] = acc;
  }
}

__global__ __launch_bounds__(256) void fbk_gru1(
    float* __restrict__ fst,
    const float* __restrict__ wih, const float* __restrict__ whh,
    const float* __restrict__ bih, const float* __restrict__ bhh, int s)
{
  __shared__ float w6[6][260];
  __shared__ float pA[3][128];
  __shared__ float pB[3][128];
  const float* pT     = fst + FBPT_F;
  const float* o1prev = fst + FBO1_F + (size_t)(s & 1) * H * BS;
  float*       o1cur  = fst + FBO1_F + (size_t)((s + 1) & 1) * H * BS;
  float*       in2T   = fst + FBIN2_F;
  fb_gru_body(w6, pA, pB, blockIdx.x, threadIdx.x, pT, o1prev, wih, whh, bih, bhh, o1cur, in2T);
}

__device__ __forceinline__ void fb_out_body(
    float (*pA)[128], int bb, int tid, int s,
    const float* __restrict__ sT, const float* __restrict__ ow,
    const float* __restrict__ ob, float* __restrict__ out)
{
  const int b = tid & 127, kh = tid >> 7;
  for (int r = bb; r < OD; r += 128) {
    const float* wr = ow + (size_t)r * H + kh * 128;
    float acc = 0.f;
    for (int kk = 0; kk < 128; kk += 4) {
      float4 wv = *(const float4*)(wr + kk);
      const float* sp = sT + (size_t)(kh * 128 + kk) * BS + b;
      acc += sp[0] * wv.x + sp[BS] * wv.y + sp[2 * BS] * wv.z + sp[3 * BS] * wv.w;
    }
    __syncthreads();
    if (kh) pA[0][b] = acc;
    __syncthreads();
    if (!kh) {
      float y = acc + pA[0][b] + ob[r];
      int frame = s * RF + r / MELD;
      int m = r - (r / MELD) * MELD;
      out[((size_t)b * TDEC + frame) * MELD + m] = y;
    }
  }
}

__global__ __launch_bounds__(256) void fbk_gru2out(
    float* __restrict__ fst,
    const float* __restrict__ wih, const float* __restrict__ whh,
    const float* __restrict__ bih, const float* __restrict__ bhh,
    const float* __restrict__ ow, const float* __restrict__ ob,
    float* __restrict__ out, int s)
{
  const int bid = blockIdx.x, tid = threadIdx.x;
  __shared__ float w6[6][260];
  __shared__ float pA[3][128];
  __shared__ float pB[3][128];
  if (bid < 256) {
    const float* in2T   = fst + FBIN2_F;
    const float* o2prev = fst + FBO2_F + (size_t)(s & 1) * H * BS;
    float*       o2cur  = fst + FBO2_F + (size_t)((s + 1) & 1) * H * BS;
    float*       stp    = fst + FBST_F + (size_t)(s & 1) * H * BS;
    fb_gru_body(w6, pA, pB, bid, tid, in2T, o2prev, wih, whh, bih, bhh, o2cur, stp);
  } else if (s > 0) {
    const float* sT = fst + FBST_F + (size_t)((s - 1) & 1) * H * BS;
    fb_out_body(pA, bid - 256, tid, s - 1, sT, ow, ob, out);
  }
}

__global__ __launch_bounds__(256) void fbk_outlast(
    const float* __restrict__ fst, const float* __restrict__ ow,
    const float* __restrict__ ob, float* __restrict__ out)
{
  __shared__ float pA[3][128];
  const float* sT = fst + FBST_F + (size_t)((STEPS - 1) & 1) * H * BS;
  fb_out_body(pA, blockIdx.x, threadIdx.x, STEPS - 1, sT, ow, ob, out);
}

// =====================================================================
//                              LAUNCH
// =====================================================================
extern "C" void kernel_launch(void* const* d_in, const int* in_sizes, int n_in,
                              void* d_out, int out_size, void* d_ws, size_t ws_size,
                              hipStream_t stream) {
  const float* enc   = (const float*)d_in[0];
  const float* dec   = (const float*)d_in[1];
  const float* pw1   = (const float*)d_in[2];
  const float* pb1   = (const float*)d_in[3];
  const float* pw2   = (const float*)d_in[4];
  const float* pb2   = (const float*)d_in[5];
  const float* w1w   = (const float*)d_in[6];
  const float* b1w   = (const float*)d_in[7];
  const float* w2w   = (const float*)d_in[8];
  const float* b2w   = (const float*)d_in[9];
  const float* vww   = (const float*)d_in[10];
  const float* vbw   = (const float*)d_in[11];
  const float* pjw   = (const float*)d_in[12];
  const float* pjb   = (const float*)d_in[13];
  const float* ow    = (const float*)d_in[14];
  const float* ob    = (const float*)d_in[15];
  const float* awih  = (const float*)d_in[16];
  const float* awhh  = (const float*)d_in[17];
  const float* abih  = (const float*)d_in[18];
  const float* abhh  = (const float*)d_in[19];
  const float* g1wih = (const float*)d_in[20];
  const float* g1whh = (const float*)d_in[21];
  const float* g1bih = (const float*)d_in[22];
  const float* g1bhh = (const float*)d_in[23];
  const float* g2wih = (const float*)d_in[24];
  const float* g2whh = (const float*)d_in[25];
  const float* g2bih = (const float*)d_in[26];
  const float* g2bhh = (const float*)d_in[27];
  float* out = (float*)d_out;
  char* wsb = (char*)d_ws;

  if (ws_size >= NEED_FAST) {
    float* xs   = (float*)(wsb + XS_B);
    u16*   w1eT = (u16*)(wsb + W1ET_B);
    float* DD   = (float*)(wsb + DD_B);
    float* GI   = (float*)(wsb + GI_B);
    float* P    = (float*)(wsb + P_B);
    u32*   wpkA = (u32*)(wsb + WPK_B);
    u32*   wpk1 = wpkA + 98304;
    u32*   wpk2 = wpk1 + 98304;

    k_prenet_f<<<STEPS, 256, 0, stream>>>(dec, pw1, pb1, pw2, pb2, xs);
    k_w1encT<<<(BS * TENC) / 32, 256, 0, stream>>>(enc, w1w, b1w, w1eT);
    k_pack<<<384, 256, 0, stream>>>(awhh, wpkA);
    k_pack<<<384, 256, 0, stream>>>(g1whh, wpk1);
    k_pack<<<384, 256, 0, stream>>>(g2whh, wpk2);
    // gi_x = xs @ awih^T + abih  -> GI [m][768]
    k_gemm<<<dim3(12, M_ALL / 64), 256, 0, stream>>>(xs, HH, awih, HH, abih, GI, 768, 768, nullptr);
    // attention-GRU chain -> d into DD[m][0:256] (row stride 512)
    k_chain<<<BS, 512, 0, stream>>>(GI, (const uint4*)wpkA, abhh, nullptr, 0, DD, 512);
    // Q = d @ w2^T + b2 -> GI (reused) [m][256]
    k_gemm<<<dim3(4, M_ALL / 64), 256, 0, stream>>>(DD, 512, w2w, H, b2w, GI, 256, 256, nullptr);
    // scores+softmax+d_dot -> DD[m][256:512]
    k_att<<<dim3(BS, STEPS / ATT_ST), 256, 0, stream>>>(w1eT, GI, vww, enc, DD);
    // P = [d|ddot] @ pjw^T + pjb
    k_gemm<<<dim3(4, M_ALL / 64), 256, 0, stream>>>(DD, 512, pjw, 2 * H, pjb, P, 256, 256, nullptr);
    // gi1 = P @ g1wih^T + g1bih -> GI
    k_gemm<<<dim3(12, M_ALL / 64), 256, 0, stream>>>(P, H, g1wih, H, g1bih, GI, 768, 768, nullptr);
    // GRU1 chain; in2 = o1 + P -> DD (reused as [m][256])
    k_chain<<<BS, 512, 0, stream>>>(GI, (const uint4*)wpk1, g1bhh, P, 256, DD, 256);
    // gi2 = in2 @ g2wih^T + g2bih -> GI
    k_gemm<<<dim3(12, M_ALL / 64), 256, 0, stream>>>(DD, H, g2wih, H, g2bih, GI, 768, 768, nullptr);
    // GRU2 chain; st = in2 + o2 -> P (reused)
    k_chain<<<BS, 512, 0, stream>>>(GI, (const uint4*)wpk2, g2bhh, DD, 256, P, 256);
    // out = st @ ow^T + ob, mapped to [b][frame][mel]
    k_gemm<<<dim3(7, M_ALL / 64), 256, 0, stream>>>(P, H, ow, H, ob, nullptr, 0, OD, out);
    return;
  }

  if (ws_size < FB_NEED_B) {
    k_zero<<<(out_size + 255) / 256, 256, 0, stream>>>(out, out_size);
    return;
  }

  // -------- fallback: verified R4 multi-kernel path --------
  u16*  w1eu = (u16*)(wsb + FBW1E_B);
  u16*  xstu = (u16*)(wsb + FBXST_B);
  float* fst = (float*)(wsb + FBF32_B);

  fbk_zeroinit<<<384, 256, 0, stream>>>(fst);
  fbk_prenet<<<STEPS, 256, 0, stream>>>(dec, pw1, pb1, pw2, pb2, xstu);
  fbk_w1enc<<<(BS * TENC) / 32, 256, 0, stream>>>(enc, w1w, b1w, w1eu);
  for (int s = 0; s < STEPS; ++s) {
    fbk_attgru<<<256, 256, 0, stream>>>(xstu, fst, awih, awhh, abih, abhh, s);
    fbk_attn<<<BS, 256, 0, stream>>>(enc, w1eu, w2w, b2w, vww, vbw, pjw, pjb, fst, s);
    fbk_gru1<<<256, 256, 0, stream>>>(fst, g1wih, g1whh, g1bih, g1bhh, s);
    fbk_gru2out<<<384, 256, 0, stream>>>(fst, g2wih, g2whh, g2bih, g2bhh, ow, ob, out, s);
  }
  fbk_outlast<<<BS, 256, 0, stream>>>(fst, ow, ob, out);
}

// Round 4
// 2135.005 us; speedup vs baseline: 3.3704x; 1.3319x over previous
//
#include <hip/hip_runtime.h>
#include <hip/hip_bf16.h>

typedef unsigned short u16;
typedef unsigned int   u32;

constexpr int H     = 256;
constexpr int HH    = 128;
constexpr int MELD  = 80;
constexpr int RF    = 5;
constexpr int BS    = 128;
constexpr int TENC  = 512;
constexpr int TDEC  = 1000;
constexpr int STEPS = 200;
constexpr int OD    = 400;
constexpr int M_ALL = STEPS * BS;   // 25600

// ================= fast-path workspace layout (bytes) =================
// Liveness-overlapped:
//  GI   f32 [25600][768]  (gate pre-acts; also reused as Q [m][256])
//  D16  u16 [25600][512]  (d|ddot f16 for Q/P GEMMs); later IN2 f32 [m][256]
//  W1ET bf16 [b][h][t]    (attn enc proj); later P16 + IN2H (f16 [m][256] each)
//  P    f32 [25600][256]
//  XSH  u16 [25600][128]
//  ST16 u16 [25600][256]
//  WPK  3x whh f16-pair packs; WH*: plain f16 weight copies
constexpr size_t GI_B   = 0;
constexpr size_t D16_B  = GI_B   + (size_t)M_ALL*768*4;        //  78,643,200
constexpr size_t IN2_B  = D16_B;                               //  f32 [m][256] (after D16 dead)
constexpr size_t W1ET_B = D16_B  + (size_t)M_ALL*512*2;        // 104,857,600
constexpr size_t P16_B  = W1ET_B;                              //  f16 [m][256] (after w1eT dead)
constexpr size_t IN2H_B = W1ET_B + (size_t)M_ALL*256*2;        // 117,964,800
constexpr size_t P_B    = W1ET_B + (size_t)BS*H*TENC*2;        // 138,412,032
constexpr size_t XSH_B  = P_B    + (size_t)M_ALL*256*4;        // 164,626,432
constexpr size_t ST16_B = XSH_B  + (size_t)M_ALL*128*2;        // 171,180,032
constexpr size_t WPK_B  = ST16_B + (size_t)M_ALL*256*2;        // 184,287,232
constexpr size_t WH_B   = WPK_B  + 3*(size_t)393216;           // 185,466,880
// f16 weight copies within WH_B:
constexpr size_t WH_AW  = 0;                 // awih 768x128
constexpr size_t WH_W2  = WH_AW + 98304*2;   // w2   256x256
constexpr size_t WH_PJ  = WH_W2 + 65536*2;   // pjw  256x512
constexpr size_t WH_G1  = WH_PJ + 131072*2;  // g1wih 768x256
constexpr size_t WH_G2  = WH_G1 + 196608*2;  // g2wih 768x256
constexpr size_t WH_OW  = WH_G2 + 196608*2;  // ow   400x256
constexpr size_t WH_END = WH_OW + 102400*2;
constexpr size_t NEED_FAST = WH_B + WH_END;  // ~187.0 MB  (< proven 205.1 MB)

// ================= fallback (R4) workspace layout =====================
constexpr size_t FBW1E_B  = 65536;
constexpr size_t FBXST_B  = FBW1E_B + (size_t)BS*TENC*H*2;
constexpr size_t FBF32_B  = FBXST_B + (size_t)STEPS*HH*BS*2;
constexpr size_t FBDT_F   = 0;
constexpr size_t FBO1_F   = FBDT_F + 2*(size_t)H*BS;
constexpr size_t FBO2_F   = FBO1_F + 2*(size_t)H*BS;
constexpr size_t FBPT_F   = FBO2_F + 2*(size_t)H*BS;
constexpr size_t FBIN2_F  = FBPT_F + (size_t)H*BS;
constexpr size_t FBST_F   = FBIN2_F + (size_t)H*BS;
constexpr size_t FB_NEED_B = FBF32_B + (FBST_F + 2*(size_t)H*BS) * 4;

// ================= helpers =================
__device__ __forceinline__ float bf2f(u16 v) {
  union { u32 x; float f; } c; c.x = ((u32)v) << 16; return c.f;
}
__device__ __forceinline__ float bfu_lo(u32 u) { union { u32 x; float f; } c; c.x = u << 16;        return c.f; }
__device__ __forceinline__ float bfu_hi(u32 u) { union { u32 x; float f; } c; c.x = u & 0xffff0000u; return c.f; }
__device__ __forceinline__ u16 f2bf(float f) {
  union { float f; u32 u; } c; c.f = f;
  u32 u = c.u;
  u32 r = (u + 0x7fffu + ((u >> 16) & 1u)) >> 16;  // RNE
  return (u16)r;
}
__device__ __forceinline__ u16 f2h(float f) {
  union { _Float16 h; u16 u; } c; c.h = (_Float16)f; return c.u;
}
__device__ __forceinline__ float fexp(float x) {
  return __builtin_amdgcn_exp2f(1.4426950408889634f * x);
}
__device__ __forceinline__ float sigm_f(float x) {
  return __builtin_amdgcn_rcpf(1.0f + __builtin_amdgcn_exp2f(-1.4426950408889634f * x));
}
__device__ __forceinline__ float tanh_f(float x) {
  x = fminf(fmaxf(x, -15.f), 15.f);
  float e = __builtin_amdgcn_exp2f(2.8853900817779268f * x);   // e^(2x)
  return (e - 1.0f) * __builtin_amdgcn_rcpf(e + 1.0f);
}

// f16 pair dot: acc += w.lo*h.lo + w.hi*h.hi  (V_DOT2_F32_F16 when available)
typedef _Float16 hlf2 __attribute__((ext_vector_type(2)));
typedef _Float16 f16x8 __attribute__((ext_vector_type(8)));
typedef float f32x4 __attribute__((ext_vector_type(4)));
#if __has_builtin(__builtin_amdgcn_fdot2)
__device__ __forceinline__ float dot2h(float acc, u32 w, u32 h) {
  union { u32 u; hlf2 v; } cw, ch; cw.u = w; ch.u = h;
  return __builtin_amdgcn_fdot2(cw.v, ch.v, acc, false);
}
#else
__device__ __forceinline__ float dot2h(float acc, u32 w, u32 h) {
  union { u32 u; _Float16 f[2]; } cw, ch; cw.u = w; ch.u = h;
  return acc + (float)cw.f[0] * (float)ch.f[0] + (float)cw.f[1] * (float)ch.f[1];
}
#endif
__device__ __forceinline__ void dot8h(float& acc, const uint4 w, const uint4 hp) {
  acc = dot2h(acc, w.x, hp.x);
  acc = dot2h(acc, w.y, hp.y);
  acc = dot2h(acc, w.z, hp.z);
  acc = dot2h(acc, w.w, hp.w);
}

__global__ __launch_bounds__(256) void k_zero(float* __restrict__ out, int n) {
  int i = blockIdx.x * 256 + threadIdx.x;
  if (i < n) out[i] = 0.f;
}

// =====================================================================
//                           FAST PATH
// =====================================================================

// ---- prenet (2 fused layers) -> xsh f16 [s][b][128] ----
__global__ __launch_bounds__(256) void k_prenet_f(
    const float* __restrict__ dec, const float* __restrict__ w1, const float* __restrict__ b1,
    const float* __restrict__ w2, const float* __restrict__ b2, u16* __restrict__ xsh)
{
  const int s = blockIdx.x, tid = threadIdx.x;
  __shared__ float X0[32][80];
  __shared__ float P1t[32][256];
  for (int bt = 0; bt < 4; ++bt) {
    const int b0 = bt * 32;
    __syncthreads();
    for (int i = tid; i < 32 * 80; i += 256) {
      int bb = i / 80, m = i - bb * 80;
      X0[bb][m] = dec[((size_t)(b0 + bb) * TDEC + (size_t)s * RF) * MELD + m];
    }
    __syncthreads();
    {
      const int h = tid;
      float acc[32];
      const float bias = b1[h];
      #pragma unroll
      for (int r = 0; r < 32; ++r) acc[r] = bias;
      const float* wr = w1 + (size_t)h * MELD;
      for (int m = 0; m < 80; m += 4) {
        float4 wv = *(const float4*)(wr + m);
        #pragma unroll
        for (int r = 0; r < 32; ++r) {
          float4 x = *(const float4*)&X0[r][m];
          acc[r] += x.x * wv.x + x.y * wv.y + x.z * wv.z + x.w * wv.w;
        }
      }
      #pragma unroll
      for (int r = 0; r < 32; ++r) P1t[r][h] = fmaxf(acc[r], 0.f);
    }
    __syncthreads();
    {
      const int k = tid & 127, bh = tid >> 7;
      float acc[16];
      const float bias = b2[k];
      #pragma unroll
      for (int r = 0; r < 16; ++r) acc[r] = bias;
      const float* wr = w2 + (size_t)k * H;
      for (int h = 0; h < H; h += 4) {
        float4 wv = *(const float4*)(wr + h);
        #pragma unroll
        for (int r = 0; r < 16; ++r) {
          float4 x = *(const float4*)&P1t[bh * 16 + r][h];
          acc[r] += x.x * wv.x + x.y * wv.y + x.z * wv.z + x.w * wv.w;
        }
      }
      #pragma unroll
      for (int r = 0; r < 16; ++r)
        xsh[((size_t)s * BS + b0 + bh * 16 + r) * HH + k] = f2h(fmaxf(acc[r], 0.f));
    }
  }
}

// ---- w1enc transposed: w1eT[b][h][t] bf16, PRE-SCALED by 2/ln2-equivalent ----
__global__ __launch_bounds__(256) void k_w1encT(
    const float* __restrict__ enc, const float* __restrict__ w1, const float* __restrict__ b1,
    u16* __restrict__ w1eT)
{
  const int row0 = blockIdx.x * 32;   // row = b*TENC + t
  const int tid = threadIdx.x;
  __shared__ float A[32 * 256];
  for (int i = tid * 4; i < 32 * 256; i += 256 * 4) {
    float4 v = *(const float4*)(enc + (size_t)row0 * H + i);
    A[i] = v.x; A[i + 1] = v.y; A[i + 2] = v.z; A[i + 3] = v.w;
  }
  __syncthreads();
  const int h = tid;
  float acc[32];
  const float bias = b1[h];
  #pragma unroll
  for (int r = 0; r < 32; ++r) acc[r] = bias;
  const float* wr = w1 + (size_t)h * H;
  for (int k = 0; k < H; k += 4) {
    float4 wv = *(const float4*)(wr + k);
    #pragma unroll
    for (int r = 0; r < 32; ++r) {
      float4 a = *(const float4*)&A[r * 256 + k];
      acc[r] += a.x * wv.x + a.y * wv.y + a.z * wv.z + a.w * wv.w;
    }
  }
  const int b = row0 / TENC, t0 = row0 % TENC;
  #pragma unroll
  for (int r = 0; r < 32; ++r)
    w1eT[((size_t)b * H + h) * TENC + t0 + r] = f2bf(2.8853900817779268f * acc[r]);
}

// ---- pack whh f32[768][256] -> uint4 groups: [3][32][256] of 4 F16-pairs ----
__global__ __launch_bounds__(256) void k_pack(const float* __restrict__ w, u32* __restrict__ o) {
  int idx = blockIdx.x * 256 + threadIdx.x;
  if (idx >= 3 * 32 * 256 * 4) return;
  int i  = idx & 3;
  int j  = (idx >> 2) & 255;
  int k4 = (idx >> 10) & 31;
  int g  = idx >> 15;
  int k2 = 4 * k4 + i;
  union { _Float16 f[2]; u32 u; } c;
  c.f[0] = (_Float16)w[((size_t)g * 256 + j) * 256 + 2 * k2];
  c.f[1] = (_Float16)w[((size_t)g * 256 + j) * 256 + 2 * k2 + 1];
  o[idx] = c.u;
}

// ---- plain f32 -> f16 weight copy ----
__global__ __launch_bounds__(256) void k_packw(const float* __restrict__ w, u16* __restrict__ o, int n) {
  int i = blockIdx.x * 256 + threadIdx.x;
  if (i < n) o[i] = f2h(w[i]);
}

// ---- MFMA f16 GEMM: C[M][N] = A[M][K]f16 @ W[N][K]f16^T + bias ----
// block: 256 thr = 4 waves; tile 128(M)x64(N); wave w: rows [w*32, w*32+32).
// K stepped by 32 (one 16x16x32 mfma per (mi,ni) pair). LDS rows padded to 40 f16.
__global__ __launch_bounds__(256) void k_hgemm(
    const u16* __restrict__ A, int lda,       // f16 [M][lda]
    const u16* __restrict__ W, int K,         // f16 [N][K]
    const float* __restrict__ bias,
    float* __restrict__ C, u16* __restrict__ Ch, int ldc, int N,
    float* __restrict__ outmap)
{
  __shared__ _Float16 As[128 * 40];
  __shared__ _Float16 Ws[64 * 40];
  const int m0 = blockIdx.y * 128, n0 = blockIdx.x * 64;
  const int tid = threadIdx.x;
  const int wv = tid >> 6, lane = tid & 63;
  const int l15 = lane & 15, hi = lane >> 4;
  f32x4 acc[2][4];
  #pragma unroll
  for (int mi = 0; mi < 2; ++mi)
    #pragma unroll
    for (int ni = 0; ni < 4; ++ni) acc[mi][ni] = (f32x4){0.f, 0.f, 0.f, 0.f};

  const int ar = tid >> 1, ac = (tid & 1) * 16;   // A stage: 128 rows x 2 half-rows
  const int wr = tid >> 2, wc = (tid & 3) * 8;    // W stage: 64 rows x 4 chunks
  for (int k0 = 0; k0 < K; k0 += 32) {
    __syncthreads();
    {
      const u16* src = A + (size_t)(m0 + ar) * lda + k0 + ac;
      uint4 v0 = *(const uint4*)(src);
      uint4 v1 = *(const uint4*)(src + 8);
      *(uint4*)&As[ar * 40 + ac] = v0;
      *(uint4*)&As[ar * 40 + ac + 8] = v1;
    }
    {
      uint4 v;
      if (n0 + wr < N) v = *(const uint4*)(W + (size_t)(n0 + wr) * K + k0 + wc);
      else { v.x = v.y = v.z = v.w = 0u; }
      *(uint4*)&Ws[wr * 40 + wc] = v;
    }
    __syncthreads();
    f16x8 af[2], bf[4];
    #pragma unroll
    for (int mi = 0; mi < 2; ++mi)
      af[mi] = *(const f16x8*)&As[(wv * 32 + mi * 16 + l15) * 40 + hi * 8];
    #pragma unroll
    for (int ni = 0; ni < 4; ++ni)
      bf[ni] = *(const f16x8*)&Ws[(ni * 16 + l15) * 40 + hi * 8];
    #pragma unroll
    for (int mi = 0; mi < 2; ++mi)
      #pragma unroll
      for (int ni = 0; ni < 4; ++ni)
        acc[mi][ni] = __builtin_amdgcn_mfma_f32_16x16x32_f16(af[mi], bf[ni], acc[mi][ni], 0, 0, 0);
  }
  // epilogue: D row = (lane>>4)*4 + reg (within 16), col = lane&15  [m89 layout]
  const int gm = m0 + wv * 32;
  #pragma unroll
  for (int ni = 0; ni < 4; ++ni) {
    const int col = n0 + ni * 16 + l15;
    if (col < N) {
      const float bv = bias[col];
      #pragma unroll
      for (int mi = 0; mi < 2; ++mi) {
        #pragma unroll
        for (int r = 0; r < 4; ++r) {
          const int row = gm + mi * 16 + hi * 4 + r;
          float v = acc[mi][ni][r] + bv;
          if (outmap) {
            int s = row >> 7, b = row & 127;
            int fr = s * RF + col / MELD, mel = col - (col / MELD) * MELD;
            outmap[((size_t)b * TDEC + fr) * MELD + mel] = v;
          } else {
            if (C)  C[(size_t)row * ldc + col] = v;
            if (Ch) Ch[(size_t)row * ldc + col] = f2h(v);
          }
        }
      }
    }
  }
}

// ---- per-row sequential GRU chain, v4 -------------------------------
// 512 threads: tid = (kh<<8)|j. f16-pair weights via V_DOT2_F32_F16.
// Weights: 2 k4-groups/half in LDS, 14 in VGPRs (168 VGPR).
// Outputs optional: f32 (outp) and/or f16 (outph).
constexpr int KC4H = 2;    // k4-groups per half cached in LDS
constexpr int RG4H = 14;   // k4-groups per half resident in VGPRs (2+14=16)
__global__ __launch_bounds__(512) void k_chain(
    const float* __restrict__ gi,      // [25600][768] includes bih
    const uint4* __restrict__ wpk4,    // [3][32][256] uint4 (f16 pairs)
    const float* __restrict__ bhh,     // [768]
    const float* __restrict__ addsrc,  // nullptr or [25600][astride]
    int astride,
    float* __restrict__ outp, int ostride,
    u16* __restrict__ outph, int ostrideh)
{
  const int b = blockIdx.x, tid = threadIdx.x;
  const int j = tid & 255, kh = tid >> 8;
  __shared__ __align__(16) _Float16 hf[256];
  __shared__ float psum[3][256];
  __shared__ uint4 wl4[3][2 * KC4H][256];
  for (int i = tid; i < 3 * 2 * KC4H * 256; i += 512) {
    int g = i / (2 * KC4H * 256), rem = i - g * (2 * KC4H * 256);
    int slot = rem >> 8, jj = rem & 255;
    int c = slot < KC4H ? slot : slot - KC4H;
    int k4 = (slot < KC4H ? 0 : 16) + c;
    wl4[g][slot][jj] = wpk4[((size_t)g * 32 + k4) * 256 + jj];
  }
  uint4 wreg[3][RG4H];
  #pragma unroll
  for (int g = 0; g < 3; ++g) {
    #pragma unroll
    for (int t = 0; t < RG4H; ++t) {
      const int k4 = kh * 16 + KC4H + t;
      wreg[g][t] = wpk4[((size_t)g * 32 + k4) * 256 + j];
    }
  }
  if (tid < 256) hf[tid] = (_Float16)0.f;
  float hreg = 0.f;
  const float br = bhh[j], bz = bhh[256 + j], bn = bhh[512 + j];
  __syncthreads();
  for (int s = 0; s < STEPS; ++s) {
    const size_t m = (size_t)s * BS + b;
    float gr = 0.f, gz = 0.f, gn = 0.f, av = 0.f;
    if (kh == 0) {                        // wave-uniform branch
      const float* gim = gi + m * 768;
      gr = gim[j]; gz = gim[256 + j]; gn = gim[512 + j];
      if (addsrc) av = addsrc[m * astride + j];
    }
    float ar = 0.f, az = 0.f, an = 0.f;
    const int k4b = kh * 16;
    #pragma unroll
    for (int t = 0; t < RG4H; ++t) {
      const int k4 = k4b + KC4H + t;
      uint4 hp = *(const uint4*)&hf[8 * k4];
      dot8h(ar, wreg[0][t], hp); dot8h(az, wreg[1][t], hp); dot8h(an, wreg[2][t], hp);
    }
    #pragma unroll
    for (int c = 0; c < KC4H; ++c) {
      const int k4 = k4b + c;
      const int slot = kh * KC4H + c;
      uint4 hp = *(const uint4*)&hf[8 * k4];
      dot8h(ar, wl4[0][slot][j], hp); dot8h(az, wl4[1][slot][j], hp); dot8h(an, wl4[2][slot][j], hp);
    }
    if (kh == 1) { psum[0][j] = ar; psum[1][j] = az; psum[2][j] = an; }
    __syncthreads();
    if (kh == 0) {
      ar += psum[0][j]; az += psum[1][j]; an += psum[2][j];
      float r = sigm_f(gr + ar + br);
      float z = sigm_f(gz + az + bz);
      float n = tanh_f(gn + r * (an + bn));
      float hn_ = (1.f - z) * n + z * hreg;
      hreg = hn_;
      hf[j] = (_Float16)hn_;
      float ov = hn_ + av;
      if (outp)  outp[m * ostride + j] = ov;
      if (outph) outph[m * ostrideh + j] = f2h(ov);
    }
    __syncthreads();
  }
}

// ---- fused scores + softmax + d_dot: block = (b, 10-step tile) ----
constexpr int ATT_ST = 10;
__global__ __launch_bounds__(256) void k_att(
    const u16* __restrict__ w1eT, const float* __restrict__ Q,
    const float* __restrict__ vw_, const float* __restrict__ enc,
    u16* __restrict__ D16)
{
  const int b = blockIdx.x, s0 = blockIdx.y * ATT_ST, tid = threadIdx.x;
  __shared__ float qt[ATT_ST][260];
  __shared__ float vws[256];
  __shared__ float us[ATT_ST][516];
  __shared__ float redw[ATT_ST][4];
  vws[tid] = -2.0f * vw_[tid];
  #pragma unroll
  for (int si = 0; si < ATT_ST; ++si)
    qt[si][tid] = 2.8853900817779268f * Q[((size_t)(s0 + si) * BS + b) * H + tid];
  __syncthreads();

  float sc0[ATT_ST], sc1[ATT_ST];
  #pragma unroll
  for (int si = 0; si < ATT_ST; ++si) { sc0[si] = 0.f; sc1[si] = 0.f; }
  const u32* wrow = (const u32*)w1eT + (size_t)b * H * (TENC / 2);
  for (int h = 0; h < H; h += 2) {
    u32 wa = wrow[(size_t)h * 256 + tid];          // t = 2*tid, 2*tid+1
    u32 wb = wrow[(size_t)(h + 1) * 256 + tid];
    float wa0 = bfu_lo(wa), wa1 = bfu_hi(wa);
    float wb0 = bfu_lo(wb), wb1 = bfu_hi(wb);
    float va = vws[h], vb = vws[h + 1];
    #pragma unroll
    for (int si = 0; si < ATT_ST; ++si) {
      float2 q2 = *(const float2*)&qt[si][h];
      sc0[si] += va * __builtin_amdgcn_rcpf(1.f + __builtin_amdgcn_exp2f(wa0 + q2.x))
               + vb * __builtin_amdgcn_rcpf(1.f + __builtin_amdgcn_exp2f(wb0 + q2.y));
      sc1[si] += va * __builtin_amdgcn_rcpf(1.f + __builtin_amdgcn_exp2f(wa1 + q2.x))
               + vb * __builtin_amdgcn_rcpf(1.f + __builtin_amdgcn_exp2f(wb1 + q2.y));
    }
  }
  const int lane = tid & 63, wvi = tid >> 6;
  #pragma unroll
  for (int si = 0; si < ATT_ST; ++si) {
    float mw = fmaxf(sc0[si], sc1[si]);
    for (int off = 1; off < 64; off <<= 1) mw = fmaxf(mw, __shfl_xor(mw, off));
    if (lane == 0) redw[si][wvi] = mw;
  }
  __syncthreads();
  #pragma unroll
  for (int si = 0; si < ATT_ST; ++si) {
    float mx = fmaxf(fmaxf(redw[si][0], redw[si][1]), fmaxf(redw[si][2], redw[si][3]));
    sc0[si] = fexp(sc0[si] - mx);
    sc1[si] = fexp(sc1[si] - mx);
  }
  __syncthreads();
  #pragma unroll
  for (int si = 0; si < ATT_ST; ++si) {
    float sm = sc0[si] + sc1[si];
    for (int off = 1; off < 64; off <<= 1) sm += __shfl_xor(sm, off);
    if (lane == 0) redw[si][wvi] = sm;
  }
  __syncthreads();
  #pragma unroll
  for (int si = 0; si < ATT_ST; ++si) {
    float tot = redw[si][0] + redw[si][1] + redw[si][2] + redw[si][3];
    float li = __builtin_amdgcn_rcpf(tot);
    float2 uv; uv.x = sc0[si] * li; uv.y = sc1[si] * li;
    *(float2*)&us[si][2 * tid] = uv;
  }
  __syncthreads();
  float dd[ATT_ST];
  #pragma unroll
  for (int si = 0; si < ATT_ST; ++si) dd[si] = 0.f;
  const float* ep = enc + (size_t)b * TENC * H + tid;
  for (int t = 0; t < TENC; t += 4) {
    float e0 = ep[(size_t)(t + 0) * H];
    float e1 = ep[(size_t)(t + 1) * H];
    float e2 = ep[(size_t)(t + 2) * H];
    float e3 = ep[(size_t)(t + 3) * H];
    #pragma unroll
    for (int si = 0; si < ATT_ST; ++si) {
      float4 u4 = *(const float4*)&us[si][t];
      dd[si] += e0 * u4.x + e1 * u4.y + e2 * u4.z + e3 * u4.w;
    }
  }
  #pragma unroll
  for (int si = 0; si < ATT_ST; ++si)
    D16[((size_t)(s0 + si) * BS + b) * 512 + 256 + tid] = f2h(dd[si]);
}

// =====================================================================
//                      FALLBACK PATH (R4, verified)
// =====================================================================
__global__ __launch_bounds__(256) void fbk_zeroinit(float* __restrict__ fst) {
  int i = blockIdx.x * 256 + threadIdx.x;
  if (i < H * BS)              fst[FBDT_F + i] = 0.f;
  else if (i < 2 * H * BS)     fst[FBO1_F + (i - H * BS)] = 0.f;
  else if (i < 3 * H * BS)     fst[FBO2_F + (i - 2 * H * BS)] = 0.f;
}

__global__ __launch_bounds__(256) void fbk_prenet(
    const float* __restrict__ dec, const float* __restrict__ w1, const float* __restrict__ b1,
    const float* __restrict__ w2, const float* __restrict__ b2, u16* __restrict__ xsT)
{
  const int s = blockIdx.x, tid = threadIdx.x;
  __shared__ float X0[32][80];
  __shared__ float P1t[32][256];
  for (int bt = 0; bt < 4; ++bt) {
    const int b0 = bt * 32;
    __syncthreads();
    for (int i = tid; i < 32 * 80; i += 256) {
      int bb = i / 80, m = i - bb * 80;
      X0[bb][m] = dec[((size_t)(b0 + bb) * TDEC + (size_t)s * RF) * MELD + m];
    }
    __syncthreads();
    {
      const int h = tid;
      float acc[32];
      const float bias = b1[h];
      #pragma unroll
      for (int r = 0; r < 32; ++r) acc[r] = bias;
      const float* wr = w1 + (size_t)h * MELD;
      for (int m = 0; m < 80; m += 4) {
        float4 wv = *(const float4*)(wr + m);
        #pragma unroll
        for (int r = 0; r < 32; ++r) {
          float4 x = *(const float4*)&X0[r][m];
          acc[r] += x.x * wv.x + x.y * wv.y + x.z * wv.z + x.w * wv.w;
        }
      }
      #pragma unroll
      for (int r = 0; r < 32; ++r) P1t[r][h] = fmaxf(acc[r], 0.f);
    }
    __syncthreads();
    {
      const int k = tid & 127, bh = tid >> 7;
      float acc[16];
      const float bias = b2[k];
      #pragma unroll
      for (int r = 0; r < 16; ++r) acc[r] = bias;
      const float* wr = w2 + (size_t)k * H;
      for (int h = 0; h < H; h += 4) {
        float4 wv = *(const float4*)(wr + h);
        #pragma unroll
        for (int r = 0; r < 16; ++r) {
          float4 x = *(const float4*)&P1t[bh * 16 + r][h];
          acc[r] += x.x * wv.x + x.y * wv.y + x.z * wv.z + x.w * wv.w;
        }
      }
      #pragma unroll
      for (int r = 0; r < 16; ++r)
        xsT[((size_t)s * HH + k) * BS + b0 + bh * 16 + r] = f2bf(fmaxf(acc[r], 0.f));
    }
  }
}

__global__ __launch_bounds__(256) void fbk_w1enc(
    const float* __restrict__ enc, const float* __restrict__ w1, const float* __restrict__ b1,
    u16* __restrict__ w1e)
{
  const int row0 = blockIdx.x * 32;
  const int tid = threadIdx.x;
  __shared__ float A[32 * 256];
  for (int i = tid * 4; i < 32 * 256; i += 256 * 4) {
    float4 v = *(const float4*)(enc + (size_t)row0 * H + i);
    A[i] = v.x; A[i + 1] = v.y; A[i + 2] = v.z; A[i + 3] = v.w;
  }
  __syncthreads();
  const int h = tid;
  float acc[32];
  const float bias = b1[h];
  #pragma unroll
  for (int r = 0; r < 32; ++r) acc[r] = bias;
  const float* wr = w1 + (size_t)h * H;
  for (int k = 0; k < H; k += 4) {
    float4 wv = *(const float4*)(wr + k);
    #pragma unroll
    for (int r = 0; r < 32; ++r) {
      float4 a = *(const float4*)&A[r * 256 + k];
      acc[r] += a.x * wv.x + a.y * wv.y + a.z * wv.z + a.w * wv.w;
    }
  }
  #pragma unroll
  for (int r = 0; r < 32; ++r) w1e[((size_t)row0 + r) * H + h] = f2bf(acc[r]);
}

__device__ __forceinline__ void fb_gru_body(
    float (*w6)[260], float (*pA)[128], float (*pB)[128], int j, int tid,
    const float* __restrict__ gi_src, const float* __restrict__ h_src,
    const float* __restrict__ wih, const float* __restrict__ whh,
    const float* __restrict__ bih, const float* __restrict__ bhh,
    float* __restrict__ h_out, float* __restrict__ sum_out)
{
  for (int i = tid; i < 3 * H; i += 256) {
    int gg = i >> 8, k = i & 255;
    w6[gg][k]     = wih[((size_t)gg * H + j) * H + k];
    w6[3 + gg][k] = whh[((size_t)gg * H + j) * H + k];
  }
  __syncthreads();
  const int b = tid & 127, kh = tid >> 7;
  float pr = 0, pz = 0, pn = 0, hr = 0, hz = 0, hn = 0;
  for (int k = kh * 128; k < kh * 128 + 128; k += 4) {
    float4 wia = *(const float4*)&w6[0][k];
    float4 wib = *(const float4*)&w6[1][k];
    float4 wic = *(const float4*)&w6[2][k];
    float4 wha = *(const float4*)&w6[3][k];
    float4 whb = *(const float4*)&w6[4][k];
    float4 whc = *(const float4*)&w6[5][k];
    float x0 = gi_src[(size_t)(k + 0) * BS + b], x1 = gi_src[(size_t)(k + 1) * BS + b];
    float x2 = gi_src[(size_t)(k + 2) * BS + b], x3 = gi_src[(size_t)(k + 3) * BS + b];
    float h0 = h_src[(size_t)(k + 0) * BS + b],  h1 = h_src[(size_t)(k + 1) * BS + b];
    float h2 = h_src[(size_t)(k + 2) * BS + b],  h3 = h_src[(size_t)(k + 3) * BS + b];
    pr += x0 * wia.x + x1 * wia.y + x2 * wia.z + x3 * wia.w;
    pz += x0 * wib.x + x1 * wib.y + x2 * wib.z + x3 * wib.w;
    pn += x0 * wic.x + x1 * wic.y + x2 * wic.z + x3 * wic.w;
    hr += h0 * wha.x + h1 * wha.y + h2 * wha.z + h3 * wha.w;
    hz += h0 * whb.x + h1 * whb.y + h2 * whb.z + h3 * whb.w;
    hn += h0 * whc.x + h1 * whc.y + h2 * whc.z + h3 * whc.w;
  }
  if (kh) {
    pA[0][b] = pr; pA[1][b] = pz; pA[2][b] = pn;
    pB[0][b] = hr; pB[1][b] = hz; pB[2][b] = hn;
  }
  __syncthreads();
  if (!kh) {
    float gir = pr + pA[0][b] + bih[j];
    float giz = pz + pA[1][b] + bih[H + j];
    float gin = pn + pA[2][b] + bih[2 * H + j];
    float ghr = hr + pB[0][b] + bhh[j];
    float ghz = hz + pB[1][b] + bhh[H + j];
    float ghn = hn + pB[2][b] + bhh[2 * H + j];
    float r = sigm_f(gir + ghr);
    float z = sigm_f(giz + ghz);
    float n = tanh_f(gin + r * ghn);
    float hp = h_src[(size_t)j * BS + b];
    float o = (1.f - z) * n + z * hp;
    h_out[(size_t)j * BS + b] = o;
    if (sum_out) sum_out[(size_t)j * BS + b] = o + gi_src[(size_t)j * BS + b];
  }
}

__global__ __launch_bounds__(256) void fbk_attgru(
    const u16* __restrict__ xstu, float* __restrict__ fst,
    const float* __restrict__ awih, const float* __restrict__ awhh,
    const float* __restrict__ abih, const float* __restrict__ abhh, int s)
{
  const int j = blockIdx.x, tid = threadIdx.x;
  __shared__ float w6[6][260];
  __shared__ float pA[3][128];
  __shared__ float pB[3][128];
  const float* dprev = fst + FBDT_F + (size_t)(s & 1) * H * BS;
  float*       dcur  = fst + FBDT_F + (size_t)((s + 1) & 1) * H * BS;
  for (int i = tid; i < 3 * HH; i += 256) {
    int gg = i >> 7, k = i & (HH - 1);
    w6[gg][k] = awih[((size_t)gg * H + j) * HH + k];
  }
  for (int i = tid; i < 3 * H; i += 256) {
    int gg = i >> 8, k = i & (H - 1);
    w6[3 + gg][k] = awhh[((size_t)gg * H + j) * H + k];
  }
  __syncthreads();
  const u16* xcol = xstu + (size_t)s * HH * BS;
  const int b = tid & 127, kh = tid >> 7;
  float pr = 0, pz = 0, pn = 0, hr = 0, hz = 0, hn = 0;
  for (int k = kh * 64; k < kh * 64 + 64; k += 4) {
    float4 wa = *(const float4*)&w6[0][k];
    float4 wb = *(const float4*)&w6[1][k];
    float4 wc = *(const float4*)&w6[2][k];
    float x0 = bf2f(xcol[(size_t)(k + 0) * BS + b]), x1 = bf2f(xcol[(size_t)(k + 1) * BS + b]);
    float x2 = bf2f(xcol[(size_t)(k + 2) * BS + b]), x3 = bf2f(xcol[(size_t)(k + 3) * BS + b]);
    pr += x0 * wa.x + x1 * wa.y + x2 * wa.z + x3 * wa.w;
    pz += x0 * wb.x + x1 * wb.y + x2 * wb.z + x3 * wb.w;
    pn += x0 * wc.x + x1 * wc.y + x2 * wc.z + x3 * wc.w;
  }
  for (int k = kh * 128; k < kh * 128 + 128; k += 4) {
    float4 wa = *(const float4*)&w6[3][k];
    float4 wb = *(const float4*)&w6[4][k];
    float4 wc = *(const float4*)&w6[5][k];
    float h0 = dprev[(size_t)(k + 0) * BS + b], h1 = dprev[(size_t)(k + 1) * BS + b];
    float h2 = dprev[(size_t)(k + 2) * BS + b], h3 = dprev[(size_t)(k + 3) * BS + b];
    hr += h0 * wa.x + h1 * wa.y + h2 * wa.z + h3 * wa.w;
    hz += h0 * wb.x + h1 * wb.y + h2 * wb.z + h3 * wb.w;
    hn += h0 * wc.x + h1 * wc.y + h2 * wc.z + h3 * wc.w;
  }
  if (kh) {
    pA[0][b] = pr; pA[1][b] = pz; pA[2][b] = pn;
    pB[0][b] = hr; pB[1][b] = hz; pB[2][b] = hn;
  }
  __syncthreads();
  if (!kh) {
    float gir = pr + pA[0][b] + abih[j];
    float giz = pz + pA[1][b] + abih[H + j];
    float gin = pn + pA[2][b] + abih[2 * H + j];
    float ghr = hr + pB[0][b] + abhh[j];
    float ghz = hz + pB[1][b] + abhh[H + j];
    float ghn = hn + pB[2][b] + abhh[2 * H + j];
    float r = sigm_f(gir + ghr);
    float z = sigm_f(giz + ghz);
    float n = tanh_f(gin + r * ghn);
    float hp = dprev[(size_t)j * BS + b];
    dcur[(size_t)j * BS + b] = (1.f - z) * n + z * hp;
  }
}

__global__ __launch_bounds__(256) void fbk_attn(
    const float* __restrict__ enc, const u16* __restrict__ w1eu,
    const float* __restrict__ w2w, const float* __restrict__ b2w,
    const float* __restrict__ vww, const float* __restrict__ vbw,
    const float* __restrict__ pjw, const float* __restrict__ pjb,
    float* __restrict__ fst, int s)
{
  const int b3 = blockIdx.x, tid = threadIdx.x;
  __shared__ float dsh[256], qs[256], ddh[256], vwsh[256], ev[512], red[256];
  const float* dcur = fst + FBDT_F + (size_t)((s + 1) & 1) * H * BS;
  float* pT = fst + FBPT_F;
  dsh[tid]  = dcur[(size_t)tid * BS + b3];
  vwsh[tid] = vww[tid];
  __syncthreads();
  {
    const int jj = tid;
    const float* wr = w2w + (size_t)jj * H;
    float acc = b2w[jj];
    for (int k = 0; k < H; k += 8) {
      float4 wA = *(const float4*)(wr + k);
      float4 wB = *(const float4*)(wr + k + 4);
      float4 dA = *(const float4*)&dsh[k];
      float4 dB = *(const float4*)&dsh[k + 4];
      acc += dA.x * wA.x + dA.y * wA.y + dA.z * wA.z + dA.w * wA.w
           + dB.x * wB.x + dB.y * wB.y + dB.z * wB.z + dB.w * wB.w;
    }
    qs[jj] = acc;
  }
  __syncthreads();
  const float vbf = vbw[0];
  const u16* wr0 = w1eu + ((size_t)b3 * TENC + tid) * H;
  const u16* wr1 = wr0 + (size_t)256 * H;
  float sc0 = vbf, sc1 = vbf;
  for (int h = 0; h < H; h += 8) {
    uint4 ua = *(const uint4*)(wr0 + h);
    uint4 uc = *(const uint4*)(wr1 + h);
    float4 qA = *(const float4*)&qs[h];
    float4 qB = *(const float4*)&qs[h + 4];
    float4 vA = *(const float4*)&vwsh[h];
    float4 vB = *(const float4*)&vwsh[h + 4];
    sc0 += vA.x * tanh_f(bfu_lo(ua.x) + qA.x) + vA.y * tanh_f(bfu_hi(ua.x) + qA.y)
         + vA.z * tanh_f(bfu_lo(ua.y) + qA.z) + vA.w * tanh_f(bfu_hi(ua.y) + qA.w)
         + vB.x * tanh_f(bfu_lo(ua.z) + qB.x) + vB.y * tanh_f(bfu_hi(ua.z) + qB.y)
         + vB.z * tanh_f(bfu_lo(ua.w) + qB.z) + vB.w * tanh_f(bfu_hi(ua.w) + qB.w);
    sc1 += vA.x * tanh_f(bfu_lo(uc.x) + qA.x) + vA.y * tanh_f(bfu_hi(uc.x) + qA.y)
         + vA.z * tanh_f(bfu_lo(uc.y) + qA.z) + vA.w * tanh_f(bfu_hi(uc.y) + qA.w)
         + vB.x * tanh_f(bfu_lo(uc.z) + qB.x) + vB.y * tanh_f(bfu_hi(uc.z) + qB.y)
         + vB.z * tanh_f(bfu_lo(uc.w) + qB.z) + vB.w * tanh_f(bfu_hi(uc.w) + qB.w);
  }
  red[tid] = fmaxf(sc0, sc1);
  __syncthreads();
  for (int off = 128; off > 0; off >>= 1) {
    if (tid < off) red[tid] = fmaxf(red[tid], red[tid + off]);
    __syncthreads();
  }
  float mx = red[0];
  __syncthreads();
  float e0 = fexp(sc0 - mx), e1 = fexp(sc1 - mx);
  ev[tid] = e0; ev[256 + tid] = e1;
  red[tid] = e0 + e1;
  __syncthreads();
  for (int off = 128; off > 0; off >>= 1) {
    if (tid < off) red[tid] += red[tid + off];
    __syncthreads();
  }
  float linv = __builtin_amdgcn_rcpf(red[0]);
  __syncthreads();
  {
    float vacc = 0.f;
    const float* ep = enc + (size_t)b3 * TENC * H + tid;
    for (int tt = 0; tt < TENC; tt += 4) {
      float4 e4 = *(const float4*)&ev[tt];
      vacc += e4.x * ep[(size_t)(tt + 0) * H] + e4.y * ep[(size_t)(tt + 1) * H]
            + e4.z * ep[(size_t)(tt + 2) * H] + e4.w * ep[(size_t)(tt + 3) * H];
    }
    ddh[tid] = vacc * linv;
  }
  __syncthreads();
  {
    const int jj = tid;
    const float* wr = pjw + (size_t)jj * (2 * H);
    float acc = pjb[jj];
    for (int k = 0; k < H; k += 8) {
      float4 wA = *(const float4*)(wr + k);
      float4 wB = *(const float4*)(wr + k + 4);
      float4 dA = *(const float4*)&dsh[k];
      float4 dB = *(const float4*)&dsh[k + 4];
      acc += dA.x * wA.x + dA.y * wA.y + dA.z * wA.z + dA.w * wA.w
           + dB.x * wB.x + dB.y * wB.y + dB.z * wB.z + dB.w * wB.w;
    }
    for (int k = 0; k < H; k += 8) {
      float4 wA = *(const float4*)(wr + H + k);
      float4 wB = *(const float4*)(wr + H + k + 4);
      float4 dA = *(const float4*)&ddh[k];
      float4 dB = *(const float4*)&ddh[k + 4];
      acc += dA.x * wA.x + dA.y * wA.y + dA.z * wA.z + dA.w * wA.w
           + dB.x * wB.x + dB.y * wB.y + dB.z * wB.z + dB.w * wB.w;
    }
    pT[(size_t)jj * BS + b3] = acc;
  }
}

__global__ __launch_bounds__(256) void fbk_gru1(
    float* __restrict__ fst,
    const float* __restrict__ wih, const float* __restrict__ whh,
    const float* __restrict__ bih, const float* __restrict__ bhh, int s)
{
  __shared__ float w6[6][260];
  __shared__ float pA[3][128];
  __shared__ float pB[3][128];
  const float* pT     = fst + FBPT_F;
  const float* o1prev = fst + FBO1_F + (size_t)(s & 1) * H * BS;
  float*       o1cur  = fst + FBO1_F + (size_t)((s + 1) & 1) * H * BS;
  float*       in2T   = fst + FBIN2_F;
  fb_gru_body(w6, pA, pB, blockIdx.x, threadIdx.x, pT, o1prev, wih, whh, bih, bhh, o1cur, in2T);
}

__device__ __forceinline__ void fb_out_body(
    float (*pA)[128], int bb, int tid, int s,
    const float* __restrict__ sT, const float* __restrict__ ow,
    const float* __restrict__ ob, float* __restrict__ out)
{
  const int b = tid & 127, kh = tid >> 7;
  for (int r = bb; r < OD; r += 128) {
    const float* wr = ow + (size_t)r * H + kh * 128;
    float acc = 0.f;
    for (int kk = 0; kk < 128; kk += 4) {
      float4 wv = *(const float4*)(wr + kk);
      const float* sp = sT + (size_t)(kh * 128 + kk) * BS + b;
      acc += sp[0] * wv.x + sp[BS] * wv.y + sp[2 * BS] * wv.z + sp[3 * BS] * wv.w;
    }
    __syncthreads();
    if (kh) pA[0][b] = acc;
    __syncthreads();
    if (!kh) {
      float y = acc + pA[0][b] + ob[r];
      int frame = s * RF + r / MELD;
      int m = r - (r / MELD) * MELD;
      out[((size_t)b * TDEC + frame) * MELD + m] = y;
    }
  }
}

__global__ __launch_bounds__(256) void fbk_gru2out(
    float* __restrict__ fst,
    const float* __restrict__ wih, const float* __restrict__ whh,
    const float* __restrict__ bih, const float* __restrict__ bhh,
    const float* __restrict__ ow, const float* __restrict__ ob,
    float* __restrict__ out, int s)
{
  const int bid = blockIdx.x, tid = threadIdx.x;
  __shared__ float w6[6][260];
  __shared__ float pA[3][128];
  __shared__ float pB[3][128];
  if (bid < 256) {
    const float* in2T   = fst + FBIN2_F;
    const float* o2prev = fst + FBO2_F + (size_t)(s & 1) * H * BS;
    float*       o2cur  = fst + FBO2_F + (size_t)((s + 1) & 1) * H * BS;
    float*       stp    = fst + FBST_F + (size_t)(s & 1) * H * BS;
    fb_gru_body(w6, pA, pB, bid, tid, in2T, o2prev, wih, whh, bih, bhh, o2cur, stp);
  } else if (s > 0) {
    const float* sT = fst + FBST_F + (size_t)((s - 1) & 1) * H * BS;
    fb_out_body(pA, bid - 256, tid, s - 1, sT, ow, ob, out);
  }
}

__global__ __launch_bounds__(256) void fbk_outlast(
    const float* __restrict__ fst, const float* __restrict__ ow,
    const float* __restrict__ ob, float* __restrict__ out)
{
  __shared__ float pA[3][128];
  const float* sT = fst + FBST_F + (size_t)((STEPS - 1) & 1) * H * BS;
  fb_out_body(pA, blockIdx.x, threadIdx.x, STEPS - 1, sT, ow, ob, out);
}

// =====================================================================
//                              LAUNCH
// =====================================================================
extern "C" void kernel_launch(void* const* d_in, const int* in_sizes, int n_in,
                              void* d_out, int out_size, void* d_ws, size_t ws_size,
                              hipStream_t stream) {
  const float* enc   = (const float*)d_in[0];
  const float* dec   = (const float*)d_in[1];
  const float* pw1   = (const float*)d_in[2];
  const float* pb1   = (const float*)d_in[3];
  const float* pw2   = (const float*)d_in[4];
  const float* pb2   = (const float*)d_in[5];
  const float* w1w   = (const float*)d_in[6];
  const float* b1w   = (const float*)d_in[7];
  const float* w2w   = (const float*)d_in[8];
  const float* b2w   = (const float*)d_in[9];
  const float* vww   = (const float*)d_in[10];
  const float* vbw   = (const float*)d_in[11];
  const float* pjw   = (const float*)d_in[12];
  const float* pjb   = (const float*)d_in[13];
  const float* ow    = (const float*)d_in[14];
  const float* ob    = (const float*)d_in[15];
  const float* awih  = (const float*)d_in[16];
  const float* awhh  = (const float*)d_in[17];
  const float* abih  = (const float*)d_in[18];
  const float* abhh  = (const float*)d_in[19];
  const float* g1wih = (const float*)d_in[20];
  const float* g1whh = (const float*)d_in[21];
  const float* g1bih = (const float*)d_in[22];
  const float* g1bhh = (const float*)d_in[23];
  const float* g2wih = (const float*)d_in[24];
  const float* g2whh = (const float*)d_in[25];
  const float* g2bih = (const float*)d_in[26];
  const float* g2bhh = (const float*)d_in[27];
  float* out = (float*)d_out;
  char* wsb = (char*)d_ws;

  if (ws_size >= NEED_FAST) {
    float* GI   = (float*)(wsb + GI_B);
    u16*   D16  = (u16*)(wsb + D16_B);
    float* IN2  = (float*)(wsb + IN2_B);
    u16*   w1eT = (u16*)(wsb + W1ET_B);
    u16*   P16  = (u16*)(wsb + P16_B);
    u16*   IN2H = (u16*)(wsb + IN2H_B);
    float* P    = (float*)(wsb + P_B);
    u16*   XSH  = (u16*)(wsb + XSH_B);
    u16*   ST16 = (u16*)(wsb + ST16_B);
    u32*   wpkA = (u32*)(wsb + WPK_B);
    u32*   wpk1 = wpkA + 98304;
    u32*   wpk2 = wpk1 + 98304;
    u16*   awih16 = (u16*)(wsb + WH_B + WH_AW);
    u16*   w2w16  = (u16*)(wsb + WH_B + WH_W2);
    u16*   pjw16  = (u16*)(wsb + WH_B + WH_PJ);
    u16*   g1w16  = (u16*)(wsb + WH_B + WH_G1);
    u16*   g2w16  = (u16*)(wsb + WH_B + WH_G2);
    u16*   ow16   = (u16*)(wsb + WH_B + WH_OW);

    k_prenet_f<<<STEPS, 256, 0, stream>>>(dec, pw1, pb1, pw2, pb2, XSH);
    k_w1encT<<<(BS * TENC) / 32, 256, 0, stream>>>(enc, w1w, b1w, w1eT);
    k_pack<<<384, 256, 0, stream>>>(awhh, wpkA);
    k_pack<<<384, 256, 0, stream>>>(g1whh, wpk1);
    k_pack<<<384, 256, 0, stream>>>(g2whh, wpk2);
    k_packw<<<(98304 + 255) / 256, 256, 0, stream>>>(awih, awih16, 98304);
    k_packw<<<(65536 + 255) / 256, 256, 0, stream>>>(w2w, w2w16, 65536);
    k_packw<<<(131072 + 255) / 256, 256, 0, stream>>>(pjw, pjw16, 131072);
    k_packw<<<(196608 + 255) / 256, 256, 0, stream>>>(g1wih, g1w16, 196608);
    k_packw<<<(196608 + 255) / 256, 256, 0, stream>>>(g2wih, g2w16, 196608);
    k_packw<<<(102400 + 255) / 256, 256, 0, stream>>>(ow, ow16, 102400);

    // gi_x = xs @ awih^T + abih -> GI [m][768]
    k_hgemm<<<dim3(12, M_ALL / 128), 256, 0, stream>>>(XSH, HH, awih16, HH, abih, GI, nullptr, 768, 768, nullptr);
    // attention-GRU chain -> d (f16) into D16[m][0:256]
    k_chain<<<BS, 512, 0, stream>>>(GI, (const uint4*)wpkA, abhh, nullptr, 0, nullptr, 0, D16, 512);
    // Q = d @ w2^T + b2 -> GI reused as Q [m][256]
    k_hgemm<<<dim3(4, M_ALL / 128), 256, 0, stream>>>(D16, 512, w2w16, H, b2w, GI, nullptr, 256, 256, nullptr);
    // scores+softmax+d_dot -> D16[m][256:512] (f16)
    k_att<<<dim3(BS, STEPS / ATT_ST), 256, 0, stream>>>(w1eT, GI, vww, enc, D16);
    // P = [d|ddot] @ pjw^T + pjb -> P f32 + P16 f16
    k_hgemm<<<dim3(4, M_ALL / 128), 256, 0, stream>>>(D16, 512, pjw16, 2 * H, pjb, P, P16, 256, 256, nullptr);
    // gi1 = P @ g1wih^T + g1bih -> GI
    k_hgemm<<<dim3(12, M_ALL / 128), 256, 0, stream>>>(P16, H, g1w16, H, g1bih, GI, nullptr, 768, 768, nullptr);
    // GRU1 chain; in2 = o1 + P -> IN2 f32 + IN2H f16
    k_chain<<<BS, 512, 0, stream>>>(GI, (const uint4*)wpk1, g1bhh, P, 256, IN2, 256, IN2H, 256);
    // gi2 = in2 @ g2wih^T + g2bih -> GI
    k_hgemm<<<dim3(12, M_ALL / 128), 256, 0, stream>>>(IN2H, H, g2w16, H, g2bih, GI, nullptr, 768, 768, nullptr);
    // GRU2 chain; st = in2 + o2 -> ST16 f16
    k_chain<<<BS, 512, 0, stream>>>(GI, (const uint4*)wpk2, g2bhh, IN2, 256, nullptr, 0, ST16, 256);
    // out = st @ ow^T + ob, mapped to [b][frame][mel]
    k_hgemm<<<dim3(7, M_ALL / 128), 256, 0, stream>>>(ST16, H, ow16, H, ob, nullptr, nullptr, 0, OD, out);
    return;
  }

  if (ws_size < FB_NEED_B) {
    k_zero<<<(out_size + 255) / 256, 256, 0, stream>>>(out, out_size);
    return;
  }

  // -------- fallback: verified R4 multi-kernel path --------
  u16*  w1eu = (u16*)(wsb + FBW1E_B);
  u16*  xstu = (u16*)(wsb + FBXST_B);
  float* fst = (float*)(wsb + FBF32_B);

  fbk_zeroinit<<<384, 256, 0, stream>>>(fst);
  fbk_prenet<<<STEPS, 256, 0, stream>>>(dec, pw1, pb1, pw2, pb2, xstu);
  fbk_w1enc<<<(BS * TENC) / 32, 256, 0, stream>>>(enc, w1w, b1w, w1eu);
  for (int s = 0; s < STEPS; ++s) {
    fbk_attgru<<<256, 256, 0, stream>>>(xstu, fst, awih, awhh, abih, abhh, s);
    fbk_attn<<<BS, 256, 0, stream>>>(enc, w1eu, w2w, b2w, vww, vbw, pjw, pjb, fst, s);
    fbk_gru1<<<256, 256, 0, stream>>>(fst, g1wih, g1whh, g1bih, g1bhh, s);
    fbk_gru2out<<<384, 256, 0, stream>>>(fst, g2wih, g2whh, g2bih, g2bhh, ow, ob, out, s);
  }
  fbk_outlast<<<BS, 256, 0, stream>>>(fst, ow, ob, out);
}

// Round 5
// 2058.562 us; speedup vs baseline: 3.4955x; 1.0371x over previous
//
#include <hip/hip_runtime.h>
#include <hip/hip_bf16.h>

typedef unsigned short u16;
typedef unsigned int   u32;

constexpr int H     = 256;
constexpr int HH    = 128;
constexpr int MELD  = 80;
constexpr int RF    = 5;
constexpr int BS    = 128;
constexpr int TENC  = 512;
constexpr int TDEC  = 1000;
constexpr int STEPS = 200;
constexpr int OD    = 400;
constexpr int M_ALL = STEPS * BS;   // 25600

// ================= fast-path workspace layout (bytes) =================
// Liveness-overlapped:
//  GI   f32 [25600][768]  (gate pre-acts; reused as Q [m][256]); ENC16 f16
//       [b][t][h] (32MB) lives here BEFORE GI's first write (w1enc hgemm).
//  D16  u16 [25600][512]  (d|ddot f16); later IN2 f32 [m][256]
//  W1ET bf16 [b][h][t]; later P16 + IN2H (f16 [m][256] each)
//  P    f32 [25600][256]
//  XSH  u16 [25600][128]
//  ST16 u16 [25600][256]
//  WPK  3x whh f16-pair packs; WH*: plain f16 weight copies
constexpr size_t GI_B   = 0;
constexpr size_t ENC16_B= GI_B;                                // f16 enc (pre-GI)
constexpr size_t D16_B  = GI_B   + (size_t)M_ALL*768*4;        //  78,643,200
constexpr size_t IN2_B  = D16_B;                               //  f32 [m][256] (after D16 dead)
constexpr size_t W1ET_B = D16_B  + (size_t)M_ALL*512*2;        // 104,857,600
constexpr size_t P16_B  = W1ET_B;                              //  f16 [m][256] (after w1eT dead)
constexpr size_t IN2H_B = W1ET_B + (size_t)M_ALL*256*2;        // 117,964,800
constexpr size_t P_B    = W1ET_B + (size_t)BS*H*TENC*2;        // 138,412,032
constexpr size_t XSH_B  = P_B    + (size_t)M_ALL*256*4;        // 164,626,432
constexpr size_t ST16_B = XSH_B  + (size_t)M_ALL*128*2;        // 171,180,032
constexpr size_t WPK_B  = ST16_B + (size_t)M_ALL*256*2;        // 184,287,232
constexpr size_t WH_B   = WPK_B  + 3*(size_t)393216;           // 185,466,880
// f16 weight copies within WH_B:
constexpr size_t WH_AW  = 0;                 // awih 768x128
constexpr size_t WH_W2  = WH_AW + 98304*2;   // w2   256x256
constexpr size_t WH_PJ  = WH_W2 + 65536*2;   // pjw  256x512
constexpr size_t WH_G1  = WH_PJ + 131072*2;  // g1wih 768x256
constexpr size_t WH_G2  = WH_G1 + 196608*2;  // g2wih 768x256
constexpr size_t WH_OW  = WH_G2 + 196608*2;  // ow   400x256
constexpr size_t WH_W1  = WH_OW + 102400*2;  // w1   256x256
constexpr size_t WH_END = WH_W1 + 65536*2;
constexpr size_t NEED_FAST = WH_B + WH_END;  // ~187.2 MB (< proven 205.1 MB)

// ================= fallback (R4) workspace layout =====================
constexpr size_t FBW1E_B  = 65536;
constexpr size_t FBXST_B  = FBW1E_B + (size_t)BS*TENC*H*2;
constexpr size_t FBF32_B  = FBXST_B + (size_t)STEPS*HH*BS*2;
constexpr size_t FBDT_F   = 0;
constexpr size_t FBO1_F   = FBDT_F + 2*(size_t)H*BS;
constexpr size_t FBO2_F   = FBO1_F + 2*(size_t)H*BS;
constexpr size_t FBPT_F   = FBO2_F + 2*(size_t)H*BS;
constexpr size_t FBIN2_F  = FBPT_F + (size_t)H*BS;
constexpr size_t FBST_F   = FBIN2_F + (size_t)H*BS;
constexpr size_t FB_NEED_B = FBF32_B + (FBST_F + 2*(size_t)H*BS) * 4;

// ================= helpers =================
__device__ __forceinline__ float bf2f(u16 v) {
  union { u32 x; float f; } c; c.x = ((u32)v) << 16; return c.f;
}
__device__ __forceinline__ float bfu_lo(u32 u) { union { u32 x; float f; } c; c.x = u << 16;        return c.f; }
__device__ __forceinline__ float bfu_hi(u32 u) { union { u32 x; float f; } c; c.x = u & 0xffff0000u; return c.f; }
__device__ __forceinline__ u16 f2bf(float f) {
  union { float f; u32 u; } c; c.f = f;
  u32 u = c.u;
  u32 r = (u + 0x7fffu + ((u >> 16) & 1u)) >> 16;  // RNE
  return (u16)r;
}
__device__ __forceinline__ u16 f2h(float f) {
  union { _Float16 h; u16 u; } c; c.h = (_Float16)f; return c.u;
}
__device__ __forceinline__ float fexp(float x) {
  return __builtin_amdgcn_exp2f(1.4426950408889634f * x);
}
__device__ __forceinline__ float sigm_f(float x) {
  return __builtin_amdgcn_rcpf(1.0f + __builtin_amdgcn_exp2f(-1.4426950408889634f * x));
}
__device__ __forceinline__ float tanh_f(float x) {
  x = fminf(fmaxf(x, -15.f), 15.f);
  float e = __builtin_amdgcn_exp2f(2.8853900817779268f * x);   // e^(2x)
  return (e - 1.0f) * __builtin_amdgcn_rcpf(e + 1.0f);
}

// f16 pair dot: acc += w.lo*h.lo + w.hi*h.hi  (V_DOT2_F32_F16 when available)
typedef _Float16 hlf2 __attribute__((ext_vector_type(2)));
typedef _Float16 f16x8 __attribute__((ext_vector_type(8)));
typedef float f32x4 __attribute__((ext_vector_type(4)));
#if __has_builtin(__builtin_amdgcn_fdot2)
__device__ __forceinline__ float dot2h(float acc, u32 w, u32 h) {
  union { u32 u; hlf2 v; } cw, ch; cw.u = w; ch.u = h;
  return __builtin_amdgcn_fdot2(cw.v, ch.v, acc, false);
}
#else
__device__ __forceinline__ float dot2h(float acc, u32 w, u32 h) {
  union { u32 u; _Float16 f[2]; } cw, ch; cw.u = w; ch.u = h;
  return acc + (float)cw.f[0] * (float)ch.f[0] + (float)cw.f[1] * (float)ch.f[1];
}
#endif
__device__ __forceinline__ void dot8h(float& acc, const uint4 w, const uint4 hp) {
  acc = dot2h(acc, w.x, hp.x);
  acc = dot2h(acc, w.y, hp.y);
  acc = dot2h(acc, w.z, hp.z);
  acc = dot2h(acc, w.w, hp.w);
}

__global__ __launch_bounds__(256) void k_zero(float* __restrict__ out, int n) {
  int i = blockIdx.x * 256 + threadIdx.x;
  if (i < n) out[i] = 0.f;
}

// =====================================================================
//                           FAST PATH
// =====================================================================

// ---- prenet (2 fused layers) -> xsh f16 [s][b][128] ----
__global__ __launch_bounds__(256) void k_prenet_f(
    const float* __restrict__ dec, const float* __restrict__ w1, const float* __restrict__ b1,
    const float* __restrict__ w2, const float* __restrict__ b2, u16* __restrict__ xsh)
{
  const int s = blockIdx.x, tid = threadIdx.x;
  __shared__ float X0[32][80];
  __shared__ float P1t[32][256];
  for (int bt = 0; bt < 4; ++bt) {
    const int b0 = bt * 32;
    __syncthreads();
    for (int i = tid; i < 32 * 80; i += 256) {
      int bb = i / 80, m = i - bb * 80;
      X0[bb][m] = dec[((size_t)(b0 + bb) * TDEC + (size_t)s * RF) * MELD + m];
    }
    __syncthreads();
    {
      const int h = tid;
      float acc[32];
      const float bias = b1[h];
      #pragma unroll
      for (int r = 0; r < 32; ++r) acc[r] = bias;
      const float* wr = w1 + (size_t)h * MELD;
      for (int m = 0; m < 80; m += 4) {
        float4 wv = *(const float4*)(wr + m);
        #pragma unroll
        for (int r = 0; r < 32; ++r) {
          float4 x = *(const float4*)&X0[r][m];
          acc[r] += x.x * wv.x + x.y * wv.y + x.z * wv.z + x.w * wv.w;
        }
      }
      #pragma unroll
      for (int r = 0; r < 32; ++r) P1t[r][h] = fmaxf(acc[r], 0.f);
    }
    __syncthreads();
    {
      const int k = tid & 127, bh = tid >> 7;
      float acc[16];
      const float bias = b2[k];
      #pragma unroll
      for (int r = 0; r < 16; ++r) acc[r] = bias;
      const float* wr = w2 + (size_t)k * H;
      for (int h = 0; h < H; h += 4) {
        float4 wv = *(const float4*)(wr + h);
        #pragma unroll
        for (int r = 0; r < 16; ++r) {
          float4 x = *(const float4*)&P1t[bh * 16 + r][h];
          acc[r] += x.x * wv.x + x.y * wv.y + x.z * wv.z + x.w * wv.w;
        }
      }
      #pragma unroll
      for (int r = 0; r < 16; ++r)
        xsh[((size_t)s * BS + b0 + bh * 16 + r) * HH + k] = f2h(fmaxf(acc[r], 0.f));
    }
  }
}

// ---- all packs/copies in one kernel ----
// ranges: enc16 (16.78M) | 3x whh packs (294912) | 7 f16 copies (856064)
__global__ __launch_bounds__(256) void k_packall(
    const float* __restrict__ enc, u16* __restrict__ enc16,
    const float* __restrict__ awhh, const float* __restrict__ g1whh,
    const float* __restrict__ g2whh, u32* __restrict__ wpk,
    const float* __restrict__ awih, u16* __restrict__ awih16,
    const float* __restrict__ w2w,  u16* __restrict__ w2w16,
    const float* __restrict__ pjw,  u16* __restrict__ pjw16,
    const float* __restrict__ g1wih, u16* __restrict__ g1w16,
    const float* __restrict__ g2wih, u16* __restrict__ g2w16,
    const float* __restrict__ ow,   u16* __restrict__ ow16,
    const float* __restrict__ w1w,  u16* __restrict__ w1w16)
{
  int i = blockIdx.x * 256 + threadIdx.x;
  if (i < 16777216) { enc16[i] = f2h(enc[i]); return; }
  i -= 16777216;
  if (i < 294912) {
    int which = i / 98304, idx = i - which * 98304;
    const float* w = which == 0 ? awhh : (which == 1 ? g1whh : g2whh);
    int ii = idx & 3;
    int j  = (idx >> 2) & 255;
    int k4 = (idx >> 10) & 31;
    int g  = idx >> 15;
    int k2 = 4 * k4 + ii;
    union { _Float16 f[2]; u32 u; } c;
    c.f[0] = (_Float16)w[((size_t)g * 256 + j) * 256 + 2 * k2];
    c.f[1] = (_Float16)w[((size_t)g * 256 + j) * 256 + 2 * k2 + 1];
    wpk[which * 98304 + idx] = c.u;
    return;
  }
  i -= 294912;
  if (i < 98304)  { awih16[i] = f2h(awih[i]); return; }  i -= 98304;
  if (i < 65536)  { w2w16[i]  = f2h(w2w[i]);  return; }  i -= 65536;
  if (i < 131072) { pjw16[i]  = f2h(pjw[i]);  return; }  i -= 131072;
  if (i < 196608) { g1w16[i]  = f2h(g1wih[i]); return; } i -= 196608;
  if (i < 196608) { g2w16[i]  = f2h(g2wih[i]); return; } i -= 196608;
  if (i < 102400) { ow16[i]   = f2h(ow[i]);   return; }  i -= 102400;
  if (i < 65536)  { w1w16[i]  = f2h(w1w[i]);  return; }
}
constexpr int PACKALL_N = 16777216 + 294912 + 856064;   // 17,928,192

// ---- MFMA f16 GEMM: C[M][N] = A[M][K]f16 @ W[N][K]f16^T + bias ----
// block: 256 thr = 4 waves; tile 128(M)x64(N); wave w: rows [w*32, w*32+32).
// K stepped by 32. LDS rows padded to 40 f16.
// Output modes: outmap -> mel layout; CbfT -> transposed scaled bf16
// (w1eT[b][col][t], row=b*512+t); else C (f32) and/or Ch (f16).
__global__ __launch_bounds__(256) void k_hgemm(
    const u16* __restrict__ A, int lda,       // f16 [M][lda]
    const u16* __restrict__ W, int K,         // f16 [N][K]
    const float* __restrict__ bias,
    float* __restrict__ C, u16* __restrict__ Ch, int ldc, int N,
    float* __restrict__ outmap, u16* __restrict__ CbfT)
{
  __shared__ _Float16 As[128 * 40];
  __shared__ _Float16 Ws[64 * 40];
  const int m0 = blockIdx.y * 128, n0 = blockIdx.x * 64;
  const int tid = threadIdx.x;
  const int wv = tid >> 6, lane = tid & 63;
  const int l15 = lane & 15, hi = lane >> 4;
  f32x4 acc[2][4];
  #pragma unroll
  for (int mi = 0; mi < 2; ++mi)
    #pragma unroll
    for (int ni = 0; ni < 4; ++ni) acc[mi][ni] = (f32x4){0.f, 0.f, 0.f, 0.f};

  const int ar = tid >> 1, ac = (tid & 1) * 16;   // A stage: 128 rows x 2 half-rows
  const int wr = tid >> 2, wc = (tid & 3) * 8;    // W stage: 64 rows x 4 chunks
  for (int k0 = 0; k0 < K; k0 += 32) {
    __syncthreads();
    {
      const u16* src = A + (size_t)(m0 + ar) * lda + k0 + ac;
      uint4 v0 = *(const uint4*)(src);
      uint4 v1 = *(const uint4*)(src + 8);
      *(uint4*)&As[ar * 40 + ac] = v0;
      *(uint4*)&As[ar * 40 + ac + 8] = v1;
    }
    {
      uint4 v;
      if (n0 + wr < N) v = *(const uint4*)(W + (size_t)(n0 + wr) * K + k0 + wc);
      else { v.x = v.y = v.z = v.w = 0u; }
      *(uint4*)&Ws[wr * 40 + wc] = v;
    }
    __syncthreads();
    f16x8 af[2], bf[4];
    #pragma unroll
    for (int mi = 0; mi < 2; ++mi)
      af[mi] = *(const f16x8*)&As[(wv * 32 + mi * 16 + l15) * 40 + hi * 8];
    #pragma unroll
    for (int ni = 0; ni < 4; ++ni)
      bf[ni] = *(const f16x8*)&Ws[(ni * 16 + l15) * 40 + hi * 8];
    #pragma unroll
    for (int mi = 0; mi < 2; ++mi)
      #pragma unroll
      for (int ni = 0; ni < 4; ++ni)
        acc[mi][ni] = __builtin_amdgcn_mfma_f32_16x16x32_f16(af[mi], bf[ni], acc[mi][ni], 0, 0, 0);
  }
  // epilogue: D row = (lane>>4)*4 + reg (within 16), col = lane&15  [m89 layout]
  const int gm = m0 + wv * 32;
  #pragma unroll
  for (int ni = 0; ni < 4; ++ni) {
    const int col = n0 + ni * 16 + l15;
    if (col < N) {
      const float bv = bias[col];
      #pragma unroll
      for (int mi = 0; mi < 2; ++mi) {
        #pragma unroll
        for (int r = 0; r < 4; ++r) {
          const int row = gm + mi * 16 + hi * 4 + r;
          float v = acc[mi][ni][r] + bv;
          if (outmap) {
            int s = row >> 7, b = row & 127;
            int fr = s * RF + col / MELD, mel = col - (col / MELD) * MELD;
            outmap[((size_t)b * TDEC + fr) * MELD + mel] = v;
          } else if (CbfT) {
            // w1eT[b][col][t], b = row>>9, t = row&511; pre-scale for k_att
            CbfT[(((size_t)(row >> 9) * 256 + col) << 9) + (row & 511)] =
                f2bf(2.8853900817779268f * v);
          } else {
            if (C)  C[(size_t)row * ldc + col] = v;
            if (Ch) Ch[(size_t)row * ldc + col] = f2h(v);
          }
        }
      }
    }
  }
}

// ---- per-row sequential GRU chain, v5 -------------------------------
// 512 threads: tid = (kh<<8)|j. f16-pair weights via V_DOT2_F32_F16.
// Weights: 2 k4-groups/half in LDS, 14 in VGPRs.
// gi/addsrc loads SOFTWARE-PIPELINED: step s+1's loads issue before step s's
// dot loop so their ~500-900cy latency hides under dots+barrier+gate math.
constexpr int KC4H = 2;    // k4-groups per half cached in LDS
constexpr int RG4H = 14;   // k4-groups per half resident in VGPRs (2+14=16)
__global__ __launch_bounds__(512) void k_chain(
    const float* __restrict__ gi,      // [25600][768] includes bih
    const uint4* __restrict__ wpk4,    // [3][32][256] uint4 (f16 pairs)
    const float* __restrict__ bhh,     // [768]
    const float* __restrict__ addsrc,  // nullptr or [25600][astride]
    int astride,
    float* __restrict__ outp, int ostride,
    u16* __restrict__ outph, int ostrideh)
{
  const int b = blockIdx.x, tid = threadIdx.x;
  const int j = tid & 255, kh = tid >> 8;
  __shared__ __align__(16) _Float16 hf[256];
  __shared__ float psum[3][256];
  __shared__ uint4 wl4[3][2 * KC4H][256];
  for (int i = tid; i < 3 * 2 * KC4H * 256; i += 512) {
    int g = i / (2 * KC4H * 256), rem = i - g * (2 * KC4H * 256);
    int slot = rem >> 8, jj = rem & 255;
    int c = slot < KC4H ? slot : slot - KC4H;
    int k4 = (slot < KC4H ? 0 : 16) + c;
    wl4[g][slot][jj] = wpk4[((size_t)g * 32 + k4) * 256 + jj];
  }
  uint4 wreg[3][RG4H];
  #pragma unroll
  for (int g = 0; g < 3; ++g) {
    #pragma unroll
    for (int t = 0; t < RG4H; ++t) {
      const int k4 = kh * 16 + KC4H + t;
      wreg[g][t] = wpk4[((size_t)g * 32 + k4) * 256 + j];
    }
  }
  if (tid < 256) hf[tid] = (_Float16)0.f;
  float hreg = 0.f;
  const float br = bhh[j], bz = bhh[256 + j], bn = bhh[512 + j];
  // prologue loads for step 0
  float gr = 0.f, gz = 0.f, gn = 0.f, av = 0.f;
  if (kh == 0) {
    const float* gim = gi + (size_t)b * 768;
    gr = gim[j]; gz = gim[256 + j]; gn = gim[512 + j];
    if (addsrc) av = addsrc[(size_t)b * astride + j];
  }
  __syncthreads();
  for (int s = 0; s < STEPS; ++s) {
    // issue next-step loads early (latency hidden under dots + barrier)
    float gr_n = 0.f, gz_n = 0.f, gn_n = 0.f, av_n = 0.f;
    if (kh == 0 && s + 1 < STEPS) {
      const size_t mn = (size_t)(s + 1) * BS + b;
      const float* gim = gi + mn * 768;
      gr_n = gim[j]; gz_n = gim[256 + j]; gn_n = gim[512 + j];
      if (addsrc) av_n = addsrc[mn * astride + j];
    }
    float ar = 0.f, az = 0.f, an = 0.f;
    const int k4b = kh * 16;
    #pragma unroll
    for (int t = 0; t < RG4H; ++t) {
      const int k4 = k4b + KC4H + t;
      uint4 hp = *(const uint4*)&hf[8 * k4];
      dot8h(ar, wreg[0][t], hp); dot8h(az, wreg[1][t], hp); dot8h(an, wreg[2][t], hp);
    }
    #pragma unroll
    for (int c = 0; c < KC4H; ++c) {
      const int k4 = k4b + c;
      const int slot = kh * KC4H + c;
      uint4 hp = *(const uint4*)&hf[8 * k4];
      dot8h(ar, wl4[0][slot][j], hp); dot8h(az, wl4[1][slot][j], hp); dot8h(an, wl4[2][slot][j], hp);
    }
    if (kh == 1) { psum[0][j] = ar; psum[1][j] = az; psum[2][j] = an; }
    __syncthreads();
    if (kh == 0) {
      const size_t m = (size_t)s * BS + b;
      ar += psum[0][j]; az += psum[1][j]; an += psum[2][j];
      float r = sigm_f(gr + ar + br);
      float z = sigm_f(gz + az + bz);
      float n = tanh_f(gn + r * (an + bn));
      float hn_ = (1.f - z) * n + z * hreg;
      hreg = hn_;
      hf[j] = (_Float16)hn_;
      float ov = hn_ + av;
      if (outp)  outp[m * ostride + j] = ov;
      if (outph) outph[m * ostrideh + j] = f2h(ov);
    }
    __syncthreads();
    gr = gr_n; gz = gz_n; gn = gn_n; av = av_n;
  }
}

// ---- fused scores + softmax + d_dot: block = (b, 10-step tile) ----
constexpr int ATT_ST = 10;
__global__ __launch_bounds__(256) void k_att(
    const u16* __restrict__ w1eT, const float* __restrict__ Q,
    const float* __restrict__ vw_, const float* __restrict__ enc,
    u16* __restrict__ D16)
{
  const int b = blockIdx.x, s0 = blockIdx.y * ATT_ST, tid = threadIdx.x;
  __shared__ float qt[ATT_ST][260];
  __shared__ float vws[256];
  __shared__ float us[ATT_ST][516];
  __shared__ float redw[ATT_ST][4];
  vws[tid] = -2.0f * vw_[tid];
  #pragma unroll
  for (int si = 0; si < ATT_ST; ++si)
    qt[si][tid] = 2.8853900817779268f * Q[((size_t)(s0 + si) * BS + b) * H + tid];
  __syncthreads();

  float sc0[ATT_ST], sc1[ATT_ST];
  #pragma unroll
  for (int si = 0; si < ATT_ST; ++si) { sc0[si] = 0.f; sc1[si] = 0.f; }
  const u32* wrow = (const u32*)w1eT + (size_t)b * H * (TENC / 2);
  for (int h = 0; h < H; h += 2) {
    u32 wa = wrow[(size_t)h * 256 + tid];          // t = 2*tid, 2*tid+1
    u32 wb = wrow[(size_t)(h + 1) * 256 + tid];
    float wa0 = bfu_lo(wa), wa1 = bfu_hi(wa);
    float wb0 = bfu_lo(wb), wb1 = bfu_hi(wb);
    float va = vws[h], vb = vws[h + 1];
    #pragma unroll
    for (int si = 0; si < ATT_ST; ++si) {
      float2 q2 = *(const float2*)&qt[si][h];
      sc0[si] += va * __builtin_amdgcn_rcpf(1.f + __builtin_amdgcn_exp2f(wa0 + q2.x))
               + vb * __builtin_amdgcn_rcpf(1.f + __builtin_amdgcn_exp2f(wb0 + q2.y));
      sc1[si] += va * __builtin_amdgcn_rcpf(1.f + __builtin_amdgcn_exp2f(wa1 + q2.x))
               + vb * __builtin_amdgcn_rcpf(1.f + __builtin_amdgcn_exp2f(wb1 + q2.y));
    }
  }
  const int lane = tid & 63, wvi = tid >> 6;
  #pragma unroll
  for (int si = 0; si < ATT_ST; ++si) {
    float mw = fmaxf(sc0[si], sc1[si]);
    for (int off = 1; off < 64; off <<= 1) mw = fmaxf(mw, __shfl_xor(mw, off));
    if (lane == 0) redw[si][wvi] = mw;
  }
  __syncthreads();
  #pragma unroll
  for (int si = 0; si < ATT_ST; ++si) {
    float mx = fmaxf(fmaxf(redw[si][0], redw[si][1]), fmaxf(redw[si][2], redw[si][3]));
    sc0[si] = fexp(sc0[si] - mx);
    sc1[si] = fexp(sc1[si] - mx);
  }
  __syncthreads();
  #pragma unroll
  for (int si = 0; si < ATT_ST; ++si) {
    float sm = sc0[si] + sc1[si];
    for (int off = 1; off < 64; off <<= 1) sm += __shfl_xor(sm, off);
    if (lane == 0) redw[si][wvi] = sm;
  }
  __syncthreads();
  #pragma unroll
  for (int si = 0; si < ATT_ST; ++si) {
    float tot = redw[si][0] + redw[si][1] + redw[si][2] + redw[si][3];
    float li = __builtin_amdgcn_rcpf(tot);
    float2 uv; uv.x = sc0[si] * li; uv.y = sc1[si] * li;
    *(float2*)&us[si][2 * tid] = uv;
  }
  __syncthreads();
  float dd[ATT_ST];
  #pragma unroll
  for (int si = 0; si < ATT_ST; ++si) dd[si] = 0.f;
  const float* ep = enc + (size_t)b * TENC * H + tid;
  for (int t = 0; t < TENC; t += 4) {
    float e0 = ep[(size_t)(t + 0) * H];
    float e1 = ep[(size_t)(t + 1) * H];
    float e2 = ep[(size_t)(t + 2) * H];
    float e3 = ep[(size_t)(t + 3) * H];
    #pragma unroll
    for (int si = 0; si < ATT_ST; ++si) {
      float4 u4 = *(const float4*)&us[si][t];
      dd[si] += e0 * u4.x + e1 * u4.y + e2 * u4.z + e3 * u4.w;
    }
  }
  #pragma unroll
  for (int si = 0; si < ATT_ST; ++si)
    D16[((size_t)(s0 + si) * BS + b) * 512 + 256 + tid] = f2h(dd[si]);
}

// =====================================================================
//                      FALLBACK PATH (R4, verified)
// =====================================================================
__global__ __launch_bounds__(256) void fbk_zeroinit(float* __restrict__ fst) {
  int i = blockIdx.x * 256 + threadIdx.x;
  if (i < H * BS)              fst[FBDT_F + i] = 0.f;
  else if (i < 2 * H * BS)     fst[FBO1_F + (i - H * BS)] = 0.f;
  else if (i < 3 * H * BS)     fst[FBO2_F + (i - 2 * H * BS)] = 0.f;
}

__global__ __launch_bounds__(256) void fbk_prenet(
    const float* __restrict__ dec, const float* __restrict__ w1, const float* __restrict__ b1,
    const float* __restrict__ w2, const float* __restrict__ b2, u16* __restrict__ xsT)
{
  const int s = blockIdx.x, tid = threadIdx.x;
  __shared__ float X0[32][80];
  __shared__ float P1t[32][256];
  for (int bt = 0; bt < 4; ++bt) {
    const int b0 = bt * 32;
    __syncthreads();
    for (int i = tid; i < 32 * 80; i += 256) {
      int bb = i / 80, m = i - bb * 80;
      X0[bb][m] = dec[((size_t)(b0 + bb) * TDEC + (size_t)s * RF) * MELD + m];
    }
    __syncthreads();
    {
      const int h = tid;
      float acc[32];
      const float bias = b1[h];
      #pragma unroll
      for (int r = 0; r < 32; ++r) acc[r] = bias;
      const float* wr = w1 + (size_t)h * MELD;
      for (int m = 0; m < 80; m += 4) {
        float4 wv = *(const float4*)(wr + m);
        #pragma unroll
        for (int r = 0; r < 32; ++r) {
          float4 x = *(const float4*)&X0[r][m];
          acc[r] += x.x * wv.x + x.y * wv.y + x.z * wv.z + x.w * wv.w;
        }
      }
      #pragma unroll
      for (int r = 0; r < 32; ++r) P1t[r][h] = fmaxf(acc[r], 0.f);
    }
    __syncthreads();
    {
      const int k = tid & 127, bh = tid >> 7;
      float acc[16];
      const float bias = b2[k];
      #pragma unroll
      for (int r = 0; r < 16; ++r) acc[r] = bias;
      const float* wr = w2 + (size_t)k * H;
      for (int h = 0; h < H; h += 4) {
        float4 wv = *(const float4*)(wr + h);
        #pragma unroll
        for (int r = 0; r < 16; ++r) {
          float4 x = *(const float4*)&P1t[bh * 16 + r][h];
          acc[r] += x.x * wv.x + x.y * wv.y + x.z * wv.z + x.w * wv.w;
        }
      }
      #pragma unroll
      for (int r = 0; r < 16; ++r)
        xsT[((size_t)s * HH + k) * BS + b0 + bh * 16 + r] = f2bf(fmaxf(acc[r], 0.f));
    }
  }
}

__global__ __launch_bounds__(256) void fbk_w1enc(
    const float* __restrict__ enc, const float* __restrict__ w1, const float* __restrict__ b1,
    u16* __restrict__ w1e)
{
  const int row0 = blockIdx.x * 32;
  const int tid = threadIdx.x;
  __shared__ float A[32 * 256];
  for (int i = tid * 4; i < 32 * 256; i += 256 * 4) {
    float4 v = *(const float4*)(enc + (size_t)row0 * H + i);
    A[i] = v.x; A[i + 1] = v.y; A[i + 2] = v.z; A[i + 3] = v.w;
  }
  __syncthreads();
  const int h = tid;
  float acc[32];
  const float bias = b1[h];
  #pragma unroll
  for (int r = 0; r < 32; ++r) acc[r] = bias;
  const float* wr = w1 + (size_t)h * H;
  for (int k = 0; k < H; k += 4) {
    float4 wv = *(const float4*)(wr + k);
    #pragma unroll
    for (int r = 0; r < 32; ++r) {
      float4 a = *(const float4*)&A[r * 256 + k];
      acc[r] += a.x * wv.x + a.y * wv.y + a.z * wv.z + a.w * wv.w;
    }
  }
  #pragma unroll
  for (int r = 0; r < 32; ++r) w1e[((size_t)row0 + r) * H + h] = f2bf(acc[r]);
}

__device__ __forceinline__ void fb_gru_body(
    float (*w6)[260], float (*pA)[128], float (*pB)[128], int j, int tid,
    const float* __restrict__ gi_src, const float* __restrict__ h_src,
    const float* __restrict__ wih, const float* __restrict__ whh,
    const float* __restrict__ bih, const float* __restrict__ bhh,
    float* __restrict__ h_out, float* __restrict__ sum_out)
{
  for (int i = tid; i < 3 * H; i += 256) {
    int gg = i >> 8, k = i & 255;
    w6[gg][k]     = wih[((size_t)gg * H + j) * H + k];
    w6[3 + gg][k] = whh[((size_t)gg * H + j) * H + k];
  }
  __syncthreads();
  const int b = tid & 127, kh = tid >> 7;
  float pr = 0, pz = 0, pn = 0, hr = 0, hz = 0, hn = 0;
  for (int k = kh * 128; k < kh * 128 + 128; k += 4) {
    float4 wia = *(const float4*)&w6[0][k];
    float4 wib = *(const float4*)&w6[1][k];
    float4 wic = *(const float4*)&w6[2][k];
    float4 wha = *(const float4*)&w6[3][k];
    float4 whb = *(const float4*)&w6[4][k];
    float4 whc = *(const float4*)&w6[5][k];
    float x0 = gi_src[(size_t)(k + 0) * BS + b], x1 = gi_src[(size_t)(k + 1) * BS + b];
    float x2 = gi_src[(size_t)(k + 2) * BS + b], x3 = gi_src[(size_t)(k + 3) * BS + b];
    float h0 = h_src[(size_t)(k + 0) * BS + b],  h1 = h_src[(size_t)(k + 1) * BS + b];
    float h2 = h_src[(size_t)(k + 2) * BS + b],  h3 = h_src[(size_t)(k + 3) * BS + b];
    pr += x0 * wia.x + x1 * wia.y + x2 * wia.z + x3 * wia.w;
    pz += x0 * wib.x + x1 * wib.y + x2 * wib.z + x3 * wib.w;
    pn += x0 * wic.x + x1 * wic.y + x2 * wic.z + x3 * wic.w;
    hr += h0 * wha.x + h1 * wha.y + h2 * wha.z + h3 * wha.w;
    hz += h0 * whb.x + h1 * whb.y + h2 * whb.z + h3 * whb.w;
    hn += h0 * whc.x + h1 * whc.y + h2 * whc.z + h3 * whc.w;
  }
  if (kh) {
    pA[0][b] = pr; pA[1][b] = pz; pA[2][b] = pn;
    pB[0][b] = hr; pB[1][b] = hz; pB[2][b] = hn;
  }
  __syncthreads();
  if (!kh) {
    float gir = pr + pA[0][b] + bih[j];
    float giz = pz + pA[1][b] + bih[H + j];
    float gin = pn + pA[2][b] + bih[2 * H + j];
    float ghr = hr + pB[0][b] + bhh[j];
    float ghz = hz + pB[1][b] + bhh[H + j];
    float ghn = hn + pB[2][b] + bhh[2 * H + j];
    float r = sigm_f(gir + ghr);
    float z = sigm_f(giz + ghz);
    float n = tanh_f(gin + r * ghn);
    float hp = h_src[(size_t)j * BS + b];
    float o = (1.f - z) * n + z * hp;
    h_out[(size_t)j * BS + b] = o;
    if (sum_out) sum_out[(size_t)j * BS + b] = o + gi_src[(size_t)j * BS + b];
  }
}

__global__ __launch_bounds__(256) void fbk_attgru(
    const u16* __restrict__ xstu, float* __restrict__ fst,
    const float* __restrict__ awih, const float* __restrict__ awhh,
    const float* __restrict__ abih, const float* __restrict__ abhh, int s)
{
  const int j = blockIdx.x, tid = threadIdx.x;
  __shared__ float w6[6][260];
  __shared__ float pA[3][128];
  __shared__ float pB[3][128];
  const float* dprev = fst + FBDT_F + (size_t)(s & 1) * H * BS;
  float*       dcur  = fst + FBDT_F + (size_t)((s + 1) & 1) * H * BS;
  for (int i = tid; i < 3 * HH; i += 256) {
    int gg = i >> 7, k = i & (HH - 1);
    w6[gg][k] = awih[((size_t)gg * H + j) * HH + k];
  }
  for (int i = tid; i < 3 * H; i += 256) {
    int gg = i >> 8, k = i & (H - 1);
    w6[3 + gg][k] = awhh[((size_t)gg * H + j) * H + k];
  }
  __syncthreads();
  const u16* xcol = xstu + (size_t)s * HH * BS;
  const int b = tid & 127, kh = tid >> 7;
  float pr = 0, pz = 0, pn = 0, hr = 0, hz = 0, hn = 0;
  for (int k = kh * 64; k < kh * 64 + 64; k += 4) {
    float4 wa = *(const float4*)&w6[0][k];
    float4 wb = *(const float4*)&w6[1][k];
    float4 wc = *(const float4*)&w6[2][k];
    float x0 = bf2f(xcol[(size_t)(k + 0) * BS + b]), x1 = bf2f(xcol[(size_t)(k + 1) * BS + b]);
    float x2 = bf2f(xcol[(size_t)(k + 2) * BS + b]), x3 = bf2f(xcol[(size_t)(k + 3) * BS + b]);
    pr += x0 * wa.x + x1 * wa.y + x2 * wa.z + x3 * wa.w;
    pz += x0 * wb.x + x1 * wb.y + x2 * wb.z + x3 * wb.w;
    pn += x0 * wc.x + x1 * wc.y + x2 * wc.z + x3 * wc.w;
  }
  for (int k = kh * 128; k < kh * 128 + 128; k += 4) {
    float4 wa = *(const float4*)&w6[3][k];
    float4 wb = *(const float4*)&w6[4][k];
    float4 wc = *(const float4*)&w6[5][k];
    float h0 = dprev[(size_t)(k + 0) * BS + b], h1 = dprev[(size_t)(k + 1) * BS + b];
    float h2 = dprev[(size_t)(k + 2) * BS + b], h3 = dprev[(size_t)(k + 3) * BS + b];
    hr += h0 * wa.x + h1 * wa.y + h2 * wa.z + h3 * wa.w;
    hz += h0 * wb.x + h1 * wb.y + h2 * wb.z + h3 * wb.w;
    hn += h0 * wc.x + h1 * wc.y + h2 * wc.z + h3 * wc.w;
  }
  if (kh) {
    pA[0][b] = pr; pA[1][b] = pz; pA[2][b] = pn;
    pB[0][b] = hr; pB[1][b] = hz; pB[2][b] = hn;
  }
  __syncthreads();
  if (!kh) {
    float gir = pr + pA[0][b] + abih[j];
    float giz = pz + pA[1][b] + abih[H + j];
    float gin = pn + pA[2][b] + abih[2 * H + j];
    float ghr = hr + pB[0][b] + abhh[j];
    float ghz = hz + pB[1][b] + abhh[H + j];
    float ghn = hn + pB[2][b] + abhh[2 * H + j];
    float r = sigm_f(gir + ghr);
    float z = sigm_f(giz + ghz);
    float n = tanh_f(gin + r * ghn);
    float hp = dprev[(size_t)j * BS + b];
    dcur[(size_t)j * BS + b] = (1.f - z) * n + z * hp;
  }
}

__global__ __launch_bounds__(256) void fbk_attn(
    const float* __restrict__ enc, const u16* __restrict__ w1eu,
    const float* __restrict__ w2w, const float* __restrict__ b2w,
    const float* __restrict__ vww, const float* __restrict__ vbw,
    const float* __restrict__ pjw, const float* __restrict__ pjb,
    float* __restrict__ fst, int s)
{
  const int b3 = blockIdx.x, tid = threadIdx.x;
  __shared__ float dsh[256], qs[256], ddh[256], vwsh[256], ev[512], red[256];
  const float* dcur = fst + FBDT_F + (size_t)((s + 1) & 1) * H * BS;
  float* pT = fst + FBPT_F;
  dsh[tid]  = dcur[(size_t)tid * BS + b3];
  vwsh[tid] = vww[tid];
  __syncthreads();
  {
    const int jj = tid;
    const float* wr = w2w + (size_t)jj * H;
    float acc = b2w[jj];
    for (int k = 0; k < H; k += 8) {
      float4 wA = *(const float4*)(wr + k);
      float4 wB = *(const float4*)(wr + k + 4);
      float4 dA = *(const float4*)&dsh[k];
      float4 dB = *(const float4*)&dsh[k + 4];
      acc += dA.x * wA.x + dA.y * wA.y + dA.z * wA.z + dA.w * wA.w
           + dB.x * wB.x + dB.y * wB.y + dB.z * wB.z + dB.w * wB.w;
    }
    qs[jj] = acc;
  }
  __syncthreads();
  const float vbf = vbw[0];
  const u16* wr0 = w1eu + ((size_t)b3 * TENC + tid) * H;
  const u16* wr1 = wr0 + (size_t)256 * H;
  float sc0 = vbf, sc1 = vbf;
  for (int h = 0; h < H; h += 8) {
    uint4 ua = *(const uint4*)(wr0 + h);
    uint4 uc = *(const uint4*)(wr1 + h);
    float4 qA = *(const float4*)&qs[h];
    float4 qB = *(const float4*)&qs[h + 4];
    float4 vA = *(const float4*)&vwsh[h];
    float4 vB = *(const float4*)&vwsh[h + 4];
    sc0 += vA.x * tanh_f(bfu_lo(ua.x) + qA.x) + vA.y * tanh_f(bfu_hi(ua.x) + qA.y)
         + vA.z * tanh_f(bfu_lo(ua.y) + qA.z) + vA.w * tanh_f(bfu_hi(ua.y) + qA.w)
         + vB.x * tanh_f(bfu_lo(ua.z) + qB.x) + vB.y * tanh_f(bfu_hi(ua.z) + qB.y)
         + vB.z * tanh_f(bfu_lo(ua.w) + qB.z) + vB.w * tanh_f(bfu_hi(ua.w) + qB.w);
    sc1 += vA.x * tanh_f(bfu_lo(uc.x) + qA.x) + vA.y * tanh_f(bfu_hi(uc.x) + qA.y)
         + vA.z * tanh_f(bfu_lo(uc.y) + qA.z) + vA.w * tanh_f(bfu_hi(uc.y) + qA.w)
         + vB.x * tanh_f(bfu_lo(uc.z) + qB.x) + vB.y * tanh_f(bfu_hi(uc.z) + qB.y)
         + vB.z * tanh_f(bfu_lo(uc.w) + qB.z) + vB.w * tanh_f(bfu_hi(uc.w) + qB.w);
  }
  red[tid] = fmaxf(sc0, sc1);
  __syncthreads();
  for (int off = 128; off > 0; off >>= 1) {
    if (tid < off) red[tid] = fmaxf(red[tid], red[tid + off]);
    __syncthreads();
  }
  float mx = red[0];
  __syncthreads();
  float e0 = fexp(sc0 - mx), e1 = fexp(sc1 - mx);
  ev[tid] = e0; ev[256 + tid] = e1;
  red[tid] = e0 + e1;
  __syncthreads();
  for (int off = 128; off > 0; off >>= 1) {
    if (tid < off) red[tid] += red[tid + off];
    __syncthreads();
  }
  float linv = __builtin_amdgcn_rcpf(red[0]);
  __syncthreads();
  {
    float vacc = 0.f;
    const float* ep = enc + (size_t)b3 * TENC * H + tid;
    for (int tt = 0; tt < TENC; tt += 4) {
      float4 e4 = *(const float4*)&ev[tt];
      vacc += e4.x * ep[(size_t)(tt + 0) * H] + e4.y * ep[(size_t)(tt + 1) * H]
            + e4.z * ep[(size_t)(tt + 2) * H] + e4.w * ep[(size_t)(tt + 3) * H];
    }
    ddh[tid] = vacc * linv;
  }
  __syncthreads();
  {
    const int jj = tid;
    const float* wr = pjw + (size_t)jj * (2 * H);
    float acc = pjb[jj];
    for (int k = 0; k < H; k += 8) {
      float4 wA = *(const float4*)(wr + k);
      float4 wB = *(const float4*)(wr + k + 4);
      float4 dA = *(const float4*)&dsh[k];
      float4 dB = *(const float4*)&dsh[k + 4];
      acc += dA.x * wA.x + dA.y * wA.y + dA.z * wA.z + dA.w * wA.w
           + dB.x * wB.x + dB.y * wB.y + dB.z * wB.z + dB.w * wB.w;
    }
    for (int k = 0; k < H; k += 8) {
      float4 wA = *(const float4*)(wr + H + k);
      float4 wB = *(const float4*)(wr + H + k + 4);
      float4 dA = *(const float4*)&ddh[k];
      float4 dB = *(const float4*)&ddh[k + 4];
      acc += dA.x * wA.x + dA.y * wA.y + dA.z * wA.z + dA.w * wA.w
           + dB.x * wB.x + dB.y * wB.y + dB.z * wB.z + dB.w * wB.w;
    }
    pT[(size_t)jj * BS + b3] = acc;
  }
}

__global__ __launch_bounds__(256) void fbk_gru1(
    float* __restrict__ fst,
    const float* __restrict__ wih, const float* __restrict__ whh,
    const float* __restrict__ bih, const float* __restrict__ bhh, int s)
{
  __shared__ float w6[6][260];
  __shared__ float pA[3][128];
  __shared__ float pB[3][128];
  const float* pT     = fst + FBPT_F;
  const float* o1prev = fst + FBO1_F + (size_t)(s & 1) * H * BS;
  float*       o1cur  = fst + FBO1_F + (size_t)((s + 1) & 1) * H * BS;
  float*       in2T   = fst + FBIN2_F;
  fb_gru_body(w6, pA, pB, blockIdx.x, threadIdx.x, pT, o1prev, wih, whh, bih, bhh, o1cur, in2T);
}

__device__ __forceinline__ void fb_out_body(
    float (*pA)[128], int bb, int tid, int s,
    const float* __restrict__ sT, const float* __restrict__ ow,
    const float* __restrict__ ob, float* __restrict__ out)
{
  const int b = tid & 127, kh = tid >> 7;
  for (int r = bb; r < OD; r += 128) {
    const float* wr = ow + (size_t)r * H + kh * 128;
    float acc = 0.f;
    for (int kk = 0; kk < 128; kk += 4) {
      float4 wv = *(const float4*)(wr + kk);
      const float* sp = sT + (size_t)(kh * 128 + kk) * BS + b;
      acc += sp[0] * wv.x + sp[BS] * wv.y + sp[2 * BS] * wv.z + sp[3 * BS] * wv.w;
    }
    __syncthreads();
    if (kh) pA[0][b] = acc;
    __syncthreads();
    if (!kh) {
      float y = acc + pA[0][b] + ob[r];
      int frame = s * RF + r / MELD;
      int m = r - (r / MELD) * MELD;
      out[((size_t)b * TDEC + frame) * MELD + m] = y;
    }
  }
}

__global__ __launch_bounds__(256) void fbk_gru2out(
    float* __restrict__ fst,
    const float* __restrict__ wih, const float* __restrict__ whh,
    const float* __restrict__ bih, const float* __restrict__ bhh,
    const float* __restrict__ ow, const float* __restrict__ ob,
    float* __restrict__ out, int s)
{
  const int bid = blockIdx.x, tid = threadIdx.x;
  __shared__ float w6[6][260];
  __shared__ float pA[3][128];
  __shared__ float pB[3][128];
  if (bid < 256) {
    const float* in2T   = fst + FBIN2_F;
    const float* o2prev = fst + FBO2_F + (size_t)(s & 1) * H * BS;
    float*       o2cur  = fst + FBO2_F + (size_t)((s + 1) & 1) * H * BS;
    float*       stp    = fst + FBST_F + (size_t)(s & 1) * H * BS;
    fb_gru_body(w6, pA, pB, bid, tid, in2T, o2prev, wih, whh, bih, bhh, o2cur, stp);
  } else if (s > 0) {
    const float* sT = fst + FBST_F + (size_t)((s - 1) & 1) * H * BS;
    fb_out_body(pA, bid - 256, tid, s - 1, sT, ow, ob, out);
  }
}

__global__ __launch_bounds__(256) void fbk_outlast(
    const float* __restrict__ fst, const float* __restrict__ ow,
    const float* __restrict__ ob, float* __restrict__ out)
{
  __shared__ float pA[3][128];
  const float* sT = fst + FBST_F + (size_t)((STEPS - 1) & 1) * H * BS;
  fb_out_body(pA, blockIdx.x, threadIdx.x, STEPS - 1, sT, ow, ob, out);
}

// =====================================================================
//                              LAUNCH
// =====================================================================
extern "C" void kernel_launch(void* const* d_in, const int* in_sizes, int n_in,
                              void* d_out, int out_size, void* d_ws, size_t ws_size,
                              hipStream_t stream) {
  const float* enc   = (const float*)d_in[0];
  const float* dec   = (const float*)d_in[1];
  const float* pw1   = (const float*)d_in[2];
  const float* pb1   = (const float*)d_in[3];
  const float* pw2   = (const float*)d_in[4];
  const float* pb2   = (const float*)d_in[5];
  const float* w1w   = (const float*)d_in[6];
  const float* b1w   = (const float*)d_in[7];
  const float* w2w   = (const float*)d_in[8];
  const float* b2w   = (const float*)d_in[9];
  const float* vww   = (const float*)d_in[10];
  const float* vbw   = (const float*)d_in[11];
  const float* pjw   = (const float*)d_in[12];
  const float* pjb   = (const float*)d_in[13];
  const float* ow    = (const float*)d_in[14];
  const float* ob    = (const float*)d_in[15];
  const float* awih  = (const float*)d_in[16];
  const float* awhh  = (const float*)d_in[17];
  const float* abih  = (const float*)d_in[18];
  const float* abhh  = (const float*)d_in[19];
  const float* g1wih = (const float*)d_in[20];
  const float* g1whh = (const float*)d_in[21];
  const float* g1bih = (const float*)d_in[22];
  const float* g1bhh = (const float*)d_in[23];
  const float* g2wih = (const float*)d_in[24];
  const float* g2whh = (const float*)d_in[25];
  const float* g2bih = (const float*)d_in[26];
  const float* g2bhh = (const float*)d_in[27];
  float* out = (float*)d_out;
  char* wsb = (char*)d_ws;

  if (ws_size >= NEED_FAST) {
    float* GI   = (float*)(wsb + GI_B);
    u16*   ENC16= (u16*)(wsb + ENC16_B);   // aliases GI, used before GI's first write
    u16*   D16  = (u16*)(wsb + D16_B);
    float* IN2  = (float*)(wsb + IN2_B);
    u16*   w1eT = (u16*)(wsb + W1ET_B);
    u16*   P16  = (u16*)(wsb + P16_B);
    u16*   IN2H = (u16*)(wsb + IN2H_B);
    float* P    = (float*)(wsb + P_B);
    u16*   XSH  = (u16*)(wsb + XSH_B);
    u16*   ST16 = (u16*)(wsb + ST16_B);
    u32*   wpkA = (u32*)(wsb + WPK_B);
    u32*   wpk1 = wpkA + 98304;
    u32*   wpk2 = wpk1 + 98304;
    u16*   awih16 = (u16*)(wsb + WH_B + WH_AW);
    u16*   w2w16  = (u16*)(wsb + WH_B + WH_W2);
    u16*   pjw16  = (u16*)(wsb + WH_B + WH_PJ);
    u16*   g1w16  = (u16*)(wsb + WH_B + WH_G1);
    u16*   g2w16  = (u16*)(wsb + WH_B + WH_G2);
    u16*   ow16   = (u16*)(wsb + WH_B + WH_OW);
    u16*   w1w16  = (u16*)(wsb + WH_B + WH_W1);

    // all packs + enc16 in one kernel
    k_packall<<<PACKALL_N / 256, 256, 0, stream>>>(
        enc, ENC16, awhh, g1whh, g2whh, wpkA,
        awih, awih16, w2w, w2w16, pjw, pjw16, g1wih, g1w16,
        g2wih, g2w16, ow, ow16, w1w, w1w16);
    // w1eT = f2bf(2.885*(enc @ w1^T + b1)), transposed — MFMA path
    k_hgemm<<<dim3(4, (BS * TENC) / 128), 256, 0, stream>>>(
        ENC16, H, w1w16, H, b1w, nullptr, nullptr, 0, 256, nullptr, w1eT);
    k_prenet_f<<<STEPS, 256, 0, stream>>>(dec, pw1, pb1, pw2, pb2, XSH);
    // gi_x = xs @ awih^T + abih -> GI [m][768]
    k_hgemm<<<dim3(12, M_ALL / 128), 256, 0, stream>>>(XSH, HH, awih16, HH, abih, GI, nullptr, 768, 768, nullptr, nullptr);
    // attention-GRU chain -> d (f16) into D16[m][0:256]
    k_chain<<<BS, 512, 0, stream>>>(GI, (const uint4*)wpkA, abhh, nullptr, 0, nullptr, 0, D16, 512);
    // Q = d @ w2^T + b2 -> GI reused as Q [m][256]
    k_hgemm<<<dim3(4, M_ALL / 128), 256, 0, stream>>>(D16, 512, w2w16, H, b2w, GI, nullptr, 256, 256, nullptr, nullptr);
    // scores+softmax+d_dot -> D16[m][256:512] (f16)
    k_att<<<dim3(BS, STEPS / ATT_ST), 256, 0, stream>>>(w1eT, GI, vww, enc, D16);
    // P = [d|ddot] @ pjw^T + pjb -> P f32 + P16 f16
    k_hgemm<<<dim3(4, M_ALL / 128), 256, 0, stream>>>(D16, 512, pjw16, 2 * H, pjb, P, P16, 256, 256, nullptr, nullptr);
    // gi1 = P @ g1wih^T + g1bih -> GI
    k_hgemm<<<dim3(12, M_ALL / 128), 256, 0, stream>>>(P16, H, g1w16, H, g1bih, GI, nullptr, 768, 768, nullptr, nullptr);
    // GRU1 chain; in2 = o1 + P -> IN2 f32 + IN2H f16
    k_chain<<<BS, 512, 0, stream>>>(GI, (const uint4*)wpk1, g1bhh, P, 256, IN2, 256, IN2H, 256);
    // gi2 = in2 @ g2wih^T + g2bih -> GI
    k_hgemm<<<dim3(12, M_ALL / 128), 256, 0, stream>>>(IN2H, H, g2w16, H, g2bih, GI, nullptr, 768, 768, nullptr, nullptr);
    // GRU2 chain; st = in2 + o2 -> ST16 f16
    k_chain<<<BS, 512, 0, stream>>>(GI, (const uint4*)wpk2, g2bhh, IN2, 256, nullptr, 0, ST16, 256);
    // out = st @ ow^T + ob, mapped to [b][frame][mel]
    k_hgemm<<<dim3(7, M_ALL / 128), 256, 0, stream>>>(ST16, H, ow16, H, ob, nullptr, nullptr, 0, OD, out, nullptr);
    return;
  }

  if (ws_size < FB_NEED_B) {
    k_zero<<<(out_size + 255) / 256, 256, 0, stream>>>(out, out_size);
    return;
  }

  // -------- fallback: verified R4 multi-kernel path --------
  u16*  w1eu = (u16*)(wsb + FBW1E_B);
  u16*  xstu = (u16*)(wsb + FBXST_B);
  float* fst = (float*)(wsb + FBF32_B);

  fbk_zeroinit<<<384, 256, 0, stream>>>(fst);
  fbk_prenet<<<STEPS, 256, 0, stream>>>(dec, pw1, pb1, pw2, pb2, xstu);
  fbk_w1enc<<<(BS * TENC) / 32, 256, 0, stream>>>(enc, w1w, b1w, w1eu);
  for (int s = 0; s < STEPS; ++s) {
    fbk_attgru<<<256, 256, 0, stream>>>(xstu, fst, awih, awhh, abih, abhh, s);
    fbk_attn<<<BS, 256, 0, stream>>>(enc, w1eu, w2w, b2w, vww, vbw, pjw, pjb, fst, s);
    fbk_gru1<<<256, 256, 0, stream>>>(fst, g1wih, g1whh, g1bih, g1bhh, s);
    fbk_gru2out<<<384, 256, 0, stream>>>(fst, g2wih, g2whh, g2bih, g2bhh, ow, ob, out, s);
  }
  fbk_outlast<<<BS, 256, 0, stream>>>(fst, ow, ob, out);
}

// Round 6
// 1787.498 us; speedup vs baseline: 4.0256x; 1.1516x over previous
//
#include <hip/hip_runtime.h>
#include <hip/hip_bf16.h>

typedef unsigned short u16;
typedef unsigned int   u32;

constexpr int H     = 256;
constexpr int HH    = 128;
constexpr int MELD  = 80;
constexpr int RF    = 5;
constexpr int BS    = 128;
constexpr int TENC  = 512;
constexpr int TDEC  = 1000;
constexpr int STEPS = 200;
constexpr int OD    = 400;
constexpr int M_ALL = STEPS * BS;   // 25600

// ================= fast-path workspace layout (bytes) =================
// Liveness-overlapped:
//  GI   f32 [25600][768]  (gate pre-acts; reused as Q [m][256]); ENC16 f16
//       [b][t][h] (32MB) lives here BEFORE GI's first write (w1enc hgemm).
//  D16  u16 [25600][512]  (d|ddot f16); later IN2 f32 [m][256]
//  W1ET bf16 [b][h][t] (stores exp2 of scaled proj — see k_hgemm CbfT);
//       later P16 + IN2H (f16 [m][256] each)
//  P    f32 [25600][256]
//  XSH  u16 [25600][128]
//  ST16 u16 [25600][256]
//  WPK  3x whh f16-pair packs; WH*: plain f16 weight copies
constexpr size_t GI_B   = 0;
constexpr size_t ENC16_B= GI_B;                                // f16 enc (pre-GI)
constexpr size_t D16_B  = GI_B   + (size_t)M_ALL*768*4;        //  78,643,200
constexpr size_t IN2_B  = D16_B;                               //  f32 [m][256] (after D16 dead)
constexpr size_t W1ET_B = D16_B  + (size_t)M_ALL*512*2;        // 104,857,600
constexpr size_t P16_B  = W1ET_B;                              //  f16 [m][256] (after w1eT dead)
constexpr size_t IN2H_B = W1ET_B + (size_t)M_ALL*256*2;        // 117,964,800
constexpr size_t P_B    = W1ET_B + (size_t)BS*H*TENC*2;        // 138,412,032
constexpr size_t XSH_B  = P_B    + (size_t)M_ALL*256*4;        // 164,626,432
constexpr size_t ST16_B = XSH_B  + (size_t)M_ALL*128*2;        // 171,180,032
constexpr size_t WPK_B  = ST16_B + (size_t)M_ALL*256*2;        // 184,287,232
constexpr size_t WH_B   = WPK_B  + 3*(size_t)393216;           // 185,466,880
// f16 weight copies within WH_B:
constexpr size_t WH_AW  = 0;                 // awih 768x128
constexpr size_t WH_W2  = WH_AW + 98304*2;   // w2   256x256
constexpr size_t WH_PJ  = WH_W2 + 65536*2;   // pjw  256x512
constexpr size_t WH_G1  = WH_PJ + 131072*2;  // g1wih 768x256
constexpr size_t WH_G2  = WH_G1 + 196608*2;  // g2wih 768x256
constexpr size_t WH_OW  = WH_G2 + 196608*2;  // ow   400x256
constexpr size_t WH_W1  = WH_OW + 102400*2;  // w1   256x256
constexpr size_t WH_END = WH_W1 + 65536*2;
constexpr size_t NEED_FAST = WH_B + WH_END;  // ~187.2 MB (< proven 205.1 MB)

// ================= fallback (R4) workspace layout =====================
constexpr size_t FBW1E_B  = 65536;
constexpr size_t FBXST_B  = FBW1E_B + (size_t)BS*TENC*H*2;
constexpr size_t FBF32_B  = FBXST_B + (size_t)STEPS*HH*BS*2;
constexpr size_t FBDT_F   = 0;
constexpr size_t FBO1_F   = FBDT_F + 2*(size_t)H*BS;
constexpr size_t FBO2_F   = FBO1_F + 2*(size_t)H*BS;
constexpr size_t FBPT_F   = FBO2_F + 2*(size_t)H*BS;
constexpr size_t FBIN2_F  = FBPT_F + (size_t)H*BS;
constexpr size_t FBST_F   = FBIN2_F + (size_t)H*BS;
constexpr size_t FB_NEED_B = FBF32_B + (FBST_F + 2*(size_t)H*BS) * 4;

// ================= helpers =================
__device__ __forceinline__ float bf2f(u16 v) {
  union { u32 x; float f; } c; c.x = ((u32)v) << 16; return c.f;
}
__device__ __forceinline__ float bfu_lo(u32 u) { union { u32 x; float f; } c; c.x = u << 16;        return c.f; }
__device__ __forceinline__ float bfu_hi(u32 u) { union { u32 x; float f; } c; c.x = u & 0xffff0000u; return c.f; }
__device__ __forceinline__ u16 f2bf(float f) {
  union { float f; u32 u; } c; c.f = f;
  u32 u = c.u;
  u32 r = (u + 0x7fffu + ((u >> 16) & 1u)) >> 16;  // RNE
  return (u16)r;
}
__device__ __forceinline__ u16 f2h(float f) {
  union { _Float16 h; u16 u; } c; c.h = (_Float16)f; return c.u;
}
__device__ __forceinline__ float fexp(float x) {
  return __builtin_amdgcn_exp2f(1.4426950408889634f * x);
}
__device__ __forceinline__ float sigm_f(float x) {
  return __builtin_amdgcn_rcpf(1.0f + __builtin_amdgcn_exp2f(-1.4426950408889634f * x));
}
__device__ __forceinline__ float tanh_f(float x) {
  x = fminf(fmaxf(x, -15.f), 15.f);
  float e = __builtin_amdgcn_exp2f(2.8853900817779268f * x);   // e^(2x)
  return (e - 1.0f) * __builtin_amdgcn_rcpf(e + 1.0f);
}

// f16 pair dot: acc += w.lo*h.lo + w.hi*h.hi  (V_DOT2_F32_F16 when available)
typedef _Float16 hlf2 __attribute__((ext_vector_type(2)));
typedef _Float16 f16x8 __attribute__((ext_vector_type(8)));
typedef float f32x4 __attribute__((ext_vector_type(4)));
#if __has_builtin(__builtin_amdgcn_fdot2)
__device__ __forceinline__ float dot2h(float acc, u32 w, u32 h) {
  union { u32 u; hlf2 v; } cw, ch; cw.u = w; ch.u = h;
  return __builtin_amdgcn_fdot2(cw.v, ch.v, acc, false);
}
#else
__device__ __forceinline__ float dot2h(float acc, u32 w, u32 h) {
  union { u32 u; _Float16 f[2]; } cw, ch; cw.u = w; ch.u = h;
  return acc + (float)cw.f[0] * (float)ch.f[0] + (float)cw.f[1] * (float)ch.f[1];
}
#endif
__device__ __forceinline__ void dot8h(float& acc, const uint4 w, const uint4 hp) {
  acc = dot2h(acc, w.x, hp.x);
  acc = dot2h(acc, w.y, hp.y);
  acc = dot2h(acc, w.z, hp.z);
  acc = dot2h(acc, w.w, hp.w);
}

__global__ __launch_bounds__(256) void k_zero(float* __restrict__ out, int n) {
  int i = blockIdx.x * 256 + threadIdx.x;
  if (i < n) out[i] = 0.f;
}

// =====================================================================
//                           FAST PATH
// =====================================================================

// ---- prenet (2 fused layers) -> xsh f16 [s][b][128] ----
__global__ __launch_bounds__(256) void k_prenet_f(
    const float* __restrict__ dec, const float* __restrict__ w1, const float* __restrict__ b1,
    const float* __restrict__ w2, const float* __restrict__ b2, u16* __restrict__ xsh)
{
  const int s = blockIdx.x, tid = threadIdx.x;
  __shared__ float X0[32][80];
  __shared__ float P1t[32][256];
  for (int bt = 0; bt < 4; ++bt) {
    const int b0 = bt * 32;
    __syncthreads();
    for (int i = tid; i < 32 * 80; i += 256) {
      int bb = i / 80, m = i - bb * 80;
      X0[bb][m] = dec[((size_t)(b0 + bb) * TDEC + (size_t)s * RF) * MELD + m];
    }
    __syncthreads();
    {
      const int h = tid;
      float acc[32];
      const float bias = b1[h];
      #pragma unroll
      for (int r = 0; r < 32; ++r) acc[r] = bias;
      const float* wr = w1 + (size_t)h * MELD;
      for (int m = 0; m < 80; m += 4) {
        float4 wv = *(const float4*)(wr + m);
        #pragma unroll
        for (int r = 0; r < 32; ++r) {
          float4 x = *(const float4*)&X0[r][m];
          acc[r] += x.x * wv.x + x.y * wv.y + x.z * wv.z + x.w * wv.w;
        }
      }
      #pragma unroll
      for (int r = 0; r < 32; ++r) P1t[r][h] = fmaxf(acc[r], 0.f);
    }
    __syncthreads();
    {
      const int k = tid & 127, bh = tid >> 7;
      float acc[16];
      const float bias = b2[k];
      #pragma unroll
      for (int r = 0; r < 16; ++r) acc[r] = bias;
      const float* wr = w2 + (size_t)k * H;
      for (int h = 0; h < H; h += 4) {
        float4 wv = *(const float4*)(wr + h);
        #pragma unroll
        for (int r = 0; r < 16; ++r) {
          float4 x = *(const float4*)&P1t[bh * 16 + r][h];
          acc[r] += x.x * wv.x + x.y * wv.y + x.z * wv.z + x.w * wv.w;
        }
      }
      #pragma unroll
      for (int r = 0; r < 16; ++r)
        xsh[((size_t)s * BS + b0 + bh * 16 + r) * HH + k] = f2h(fmaxf(acc[r], 0.f));
    }
  }
}

// ---- all packs/copies in one kernel ----
// ranges: enc16 (16.78M) | 3x whh packs (294912) | 7 f16 copies (856064)
__global__ __launch_bounds__(256) void k_packall(
    const float* __restrict__ enc, u16* __restrict__ enc16,
    const float* __restrict__ awhh, const float* __restrict__ g1whh,
    const float* __restrict__ g2whh, u32* __restrict__ wpk,
    const float* __restrict__ awih, u16* __restrict__ awih16,
    const float* __restrict__ w2w,  u16* __restrict__ w2w16,
    const float* __restrict__ pjw,  u16* __restrict__ pjw16,
    const float* __restrict__ g1wih, u16* __restrict__ g1w16,
    const float* __restrict__ g2wih, u16* __restrict__ g2w16,
    const float* __restrict__ ow,   u16* __restrict__ ow16,
    const float* __restrict__ w1w,  u16* __restrict__ w1w16)
{
  int i = blockIdx.x * 256 + threadIdx.x;
  if (i < 16777216) { enc16[i] = f2h(enc[i]); return; }
  i -= 16777216;
  if (i < 294912) {
    int which = i / 98304, idx = i - which * 98304;
    const float* w = which == 0 ? awhh : (which == 1 ? g1whh : g2whh);
    int ii = idx & 3;
    int j  = (idx >> 2) & 255;
    int k4 = (idx >> 10) & 31;
    int g  = idx >> 15;
    int k2 = 4 * k4 + ii;
    union { _Float16 f[2]; u32 u; } c;
    c.f[0] = (_Float16)w[((size_t)g * 256 + j) * 256 + 2 * k2];
    c.f[1] = (_Float16)w[((size_t)g * 256 + j) * 256 + 2 * k2 + 1];
    wpk[which * 98304 + idx] = c.u;
    return;
  }
  i -= 294912;
  if (i < 98304)  { awih16[i] = f2h(awih[i]); return; }  i -= 98304;
  if (i < 65536)  { w2w16[i]  = f2h(w2w[i]);  return; }  i -= 65536;
  if (i < 131072) { pjw16[i]  = f2h(pjw[i]);  return; }  i -= 131072;
  if (i < 196608) { g1w16[i]  = f2h(g1wih[i]); return; } i -= 196608;
  if (i < 196608) { g2w16[i]  = f2h(g2wih[i]); return; } i -= 196608;
  if (i < 102400) { ow16[i]   = f2h(ow[i]);   return; }  i -= 102400;
  if (i < 65536)  { w1w16[i]  = f2h(w1w[i]);  return; }
}
constexpr int PACKALL_N = 16777216 + 294912 + 856064;   // 17,928,192

// ---- MFMA f16 GEMM: C[M][N] = A[M][K]f16 @ W[N][K]f16^T + bias ----
// block: 256 thr = 4 waves; tile 128(M)x64(N); wave w: rows [w*32, w*32+32).
// K stepped by 32. LDS rows padded to 40 f16.
// Output modes: outmap -> mel layout; CbfT -> transposed EXP-domain bf16
// w1eT[b][col][t] = bf16(exp2(clamp(2.885*v, ±60))) (factorized-sigmoid
// trick: k_att computes rcp(fma(Ew, Eq, 1)) — one transcendental saved per
// element; clamp keeps Ew*Eq finite, so no inf*0 NaN);
// else C (f32) and/or Ch (f16).
__global__ __launch_bounds__(256) void k_hgemm(
    const u16* __restrict__ A, int lda,       // f16 [M][lda]
    const u16* __restrict__ W, int K,         // f16 [N][K]
    const float* __restrict__ bias,
    float* __restrict__ C, u16* __restrict__ Ch, int ldc, int N,
    float* __restrict__ outmap, u16* __restrict__ CbfT)
{
  __shared__ _Float16 As[128 * 40];
  __shared__ _Float16 Ws[64 * 40];
  const int m0 = blockIdx.y * 128, n0 = blockIdx.x * 64;
  const int tid = threadIdx.x;
  const int wv = tid >> 6, lane = tid & 63;
  const int l15 = lane & 15, hi = lane >> 4;
  f32x4 acc[2][4];
  #pragma unroll
  for (int mi = 0; mi < 2; ++mi)
    #pragma unroll
    for (int ni = 0; ni < 4; ++ni) acc[mi][ni] = (f32x4){0.f, 0.f, 0.f, 0.f};

  const int ar = tid >> 1, ac = (tid & 1) * 16;   // A stage: 128 rows x 2 half-rows
  const int wr = tid >> 2, wc = (tid & 3) * 8;    // W stage: 64 rows x 4 chunks
  for (int k0 = 0; k0 < K; k0 += 32) {
    __syncthreads();
    {
      const u16* src = A + (size_t)(m0 + ar) * lda + k0 + ac;
      uint4 v0 = *(const uint4*)(src);
      uint4 v1 = *(const uint4*)(src + 8);
      *(uint4*)&As[ar * 40 + ac] = v0;
      *(uint4*)&As[ar * 40 + ac + 8] = v1;
    }
    {
      uint4 v;
      if (n0 + wr < N) v = *(const uint4*)(W + (size_t)(n0 + wr) * K + k0 + wc);
      else { v.x = v.y = v.z = v.w = 0u; }
      *(uint4*)&Ws[wr * 40 + wc] = v;
    }
    __syncthreads();
    f16x8 af[2], bf[4];
    #pragma unroll
    for (int mi = 0; mi < 2; ++mi)
      af[mi] = *(const f16x8*)&As[(wv * 32 + mi * 16 + l15) * 40 + hi * 8];
    #pragma unroll
    for (int ni = 0; ni < 4; ++ni)
      bf[ni] = *(const f16x8*)&Ws[(ni * 16 + l15) * 40 + hi * 8];
    #pragma unroll
    for (int mi = 0; mi < 2; ++mi)
      #pragma unroll
      for (int ni = 0; ni < 4; ++ni)
        acc[mi][ni] = __builtin_amdgcn_mfma_f32_16x16x32_f16(af[mi], bf[ni], acc[mi][ni], 0, 0, 0);
  }
  // epilogue: D row = (lane>>4)*4 + reg (within 16), col = lane&15  [m89 layout]
  const int gm = m0 + wv * 32;
  #pragma unroll
  for (int ni = 0; ni < 4; ++ni) {
    const int col = n0 + ni * 16 + l15;
    if (col < N) {
      const float bv = bias[col];
      #pragma unroll
      for (int mi = 0; mi < 2; ++mi) {
        #pragma unroll
        for (int r = 0; r < 4; ++r) {
          const int row = gm + mi * 16 + hi * 4 + r;
          float v = acc[mi][ni][r] + bv;
          if (outmap) {
            int s = row >> 7, b = row & 127;
            int fr = s * RF + col / MELD, mel = col - (col / MELD) * MELD;
            outmap[((size_t)b * TDEC + fr) * MELD + mel] = v;
          } else if (CbfT) {
            // w1eT[b][col][t], b = row>>9, t = row&511; EXP-domain for k_att
            float a = fminf(fmaxf(2.8853900817779268f * v, -60.f), 60.f);
            CbfT[(((size_t)(row >> 9) * 256 + col) << 9) + (row & 511)] =
                f2bf(__builtin_amdgcn_exp2f(a));
          } else {
            if (C)  C[(size_t)row * ldc + col] = v;
            if (Ch) Ch[(size_t)row * ldc + col] = f2h(v);
          }
        }
      }
    }
  }
}

// ---- per-row sequential GRU chain, v5 -------------------------------
// 512 threads: tid = (kh<<8)|j. f16-pair weights via V_DOT2_F32_F16.
// Weights: 2 k4-groups/half in LDS, 14 in VGPRs.
// gi/addsrc loads SOFTWARE-PIPELINED: step s+1's loads issue before step s's
// dot loop so their ~500-900cy latency hides under dots+barrier+gate math.
constexpr int KC4H = 2;    // k4-groups per half cached in LDS
constexpr int RG4H = 14;   // k4-groups per half resident in VGPRs (2+14=16)
__global__ __launch_bounds__(512) void k_chain(
    const float* __restrict__ gi,      // [25600][768] includes bih
    const uint4* __restrict__ wpk4,    // [3][32][256] uint4 (f16 pairs)
    const float* __restrict__ bhh,     // [768]
    const float* __restrict__ addsrc,  // nullptr or [25600][astride]
    int astride,
    float* __restrict__ outp, int ostride,
    u16* __restrict__ outph, int ostrideh)
{
  const int b = blockIdx.x, tid = threadIdx.x;
  const int j = tid & 255, kh = tid >> 8;
  __shared__ __align__(16) _Float16 hf[256];
  __shared__ float psum[3][256];
  __shared__ uint4 wl4[3][2 * KC4H][256];
  for (int i = tid; i < 3 * 2 * KC4H * 256; i += 512) {
    int g = i / (2 * KC4H * 256), rem = i - g * (2 * KC4H * 256);
    int slot = rem >> 8, jj = rem & 255;
    int c = slot < KC4H ? slot : slot - KC4H;
    int k4 = (slot < KC4H ? 0 : 16) + c;
    wl4[g][slot][jj] = wpk4[((size_t)g * 32 + k4) * 256 + jj];
  }
  uint4 wreg[3][RG4H];
  #pragma unroll
  for (int g = 0; g < 3; ++g) {
    #pragma unroll
    for (int t = 0; t < RG4H; ++t) {
      const int k4 = kh * 16 + KC4H + t;
      wreg[g][t] = wpk4[((size_t)g * 32 + k4) * 256 + j];
    }
  }
  if (tid < 256) hf[tid] = (_Float16)0.f;
  float hreg = 0.f;
  const float br = bhh[j], bz = bhh[256 + j], bn = bhh[512 + j];
  // prologue loads for step 0
  float gr = 0.f, gz = 0.f, gn = 0.f, av = 0.f;
  if (kh == 0) {
    const float* gim = gi + (size_t)b * 768;
    gr = gim[j]; gz = gim[256 + j]; gn = gim[512 + j];
    if (addsrc) av = addsrc[(size_t)b * astride + j];
  }
  __syncthreads();
  for (int s = 0; s < STEPS; ++s) {
    // issue next-step loads early (latency hidden under dots + barrier)
    float gr_n = 0.f, gz_n = 0.f, gn_n = 0.f, av_n = 0.f;
    if (kh == 0 && s + 1 < STEPS) {
      const size_t mn = (size_t)(s + 1) * BS + b;
      const float* gim = gi + mn * 768;
      gr_n = gim[j]; gz_n = gim[256 + j]; gn_n = gim[512 + j];
      if (addsrc) av_n = addsrc[mn * astride + j];
    }
    float ar = 0.f, az = 0.f, an = 0.f;
    const int k4b = kh * 16;
    #pragma unroll
    for (int t = 0; t < RG4H; ++t) {
      const int k4 = k4b + KC4H + t;
      uint4 hp = *(const uint4*)&hf[8 * k4];
      dot8h(ar, wreg[0][t], hp); dot8h(az, wreg[1][t], hp); dot8h(an, wreg[2][t], hp);
    }
    #pragma unroll
    for (int c = 0; c < KC4H; ++c) {
      const int k4 = k4b + c;
      const int slot = kh * KC4H + c;
      uint4 hp = *(const uint4*)&hf[8 * k4];
      dot8h(ar, wl4[0][slot][j], hp); dot8h(az, wl4[1][slot][j], hp); dot8h(an, wl4[2][slot][j], hp);
    }
    if (kh == 1) { psum[0][j] = ar; psum[1][j] = az; psum[2][j] = an; }
    __syncthreads();
    if (kh == 0) {
      const size_t m = (size_t)s * BS + b;
      ar += psum[0][j]; az += psum[1][j]; an += psum[2][j];
      float r = sigm_f(gr + ar + br);
      float z = sigm_f(gz + az + bz);
      float n = tanh_f(gn + r * (an + bn));
      float hn_ = (1.f - z) * n + z * hreg;
      hreg = hn_;
      hf[j] = (_Float16)hn_;
      float ov = hn_ + av;
      if (outp)  outp[m * ostride + j] = ov;
      if (outph) outph[m * ostrideh + j] = f2h(ov);
    }
    __syncthreads();
    gr = gr_n; gz = gz_n; gn = gn_n; av = av_n;
  }
}

// ---- fused scores + softmax + d_dot: block = (b, 10-step tile) ----
// Factorized sigmoid: w1eT holds Ew = exp2(clamp(2.885*w)), qt holds
// Eq = exp2(clamp(2.885*q)); per element sigma = rcp(fma(Ew, Eq, 1)).
// 12 cyc/wave-elem vs 22 for the joint-exp form.
constexpr int ATT_ST = 10;
__global__ __launch_bounds__(256) void k_att(
    const u16* __restrict__ w1eT, const float* __restrict__ Q,
    const float* __restrict__ vw_, const float* __restrict__ enc,
    u16* __restrict__ D16)
{
  const int b = blockIdx.x, s0 = blockIdx.y * ATT_ST, tid = threadIdx.x;
  __shared__ float qt[ATT_ST][260];
  __shared__ float vws[256];
  __shared__ float us[ATT_ST][516];
  __shared__ float redw[ATT_ST][4];
  vws[tid] = -2.0f * vw_[tid];
  #pragma unroll
  for (int si = 0; si < ATT_ST; ++si) {
    float q = 2.8853900817779268f * Q[((size_t)(s0 + si) * BS + b) * H + tid];
    qt[si][tid] = __builtin_amdgcn_exp2f(fminf(fmaxf(q, -60.f), 60.f));
  }
  __syncthreads();

  float sc0[ATT_ST], sc1[ATT_ST];
  #pragma unroll
  for (int si = 0; si < ATT_ST; ++si) { sc0[si] = 0.f; sc1[si] = 0.f; }
  const u32* wrow = (const u32*)w1eT + (size_t)b * H * (TENC / 2);
  for (int h = 0; h < H; h += 2) {
    u32 wa = wrow[(size_t)h * 256 + tid];          // t = 2*tid, 2*tid+1
    u32 wb = wrow[(size_t)(h + 1) * 256 + tid];
    float Ea0 = bfu_lo(wa), Ea1 = bfu_hi(wa);
    float Eb0 = bfu_lo(wb), Eb1 = bfu_hi(wb);
    float va = vws[h], vb = vws[h + 1];
    #pragma unroll
    for (int si = 0; si < ATT_ST; ++si) {
      float2 Eq = *(const float2*)&qt[si][h];
      sc0[si] += va * __builtin_amdgcn_rcpf(__builtin_fmaf(Ea0, Eq.x, 1.f))
               + vb * __builtin_amdgcn_rcpf(__builtin_fmaf(Eb0, Eq.y, 1.f));
      sc1[si] += va * __builtin_amdgcn_rcpf(__builtin_fmaf(Ea1, Eq.x, 1.f))
               + vb * __builtin_amdgcn_rcpf(__builtin_fmaf(Eb1, Eq.y, 1.f));
    }
  }
  const int lane = tid & 63, wvi = tid >> 6;
  #pragma unroll
  for (int si = 0; si < ATT_ST; ++si) {
    float mw = fmaxf(sc0[si], sc1[si]);
    for (int off = 1; off < 64; off <<= 1) mw = fmaxf(mw, __shfl_xor(mw, off));
    if (lane == 0) redw[si][wvi] = mw;
  }
  __syncthreads();
  #pragma unroll
  for (int si = 0; si < ATT_ST; ++si) {
    float mx = fmaxf(fmaxf(redw[si][0], redw[si][1]), fmaxf(redw[si][2], redw[si][3]));
    sc0[si] = fexp(sc0[si] - mx);
    sc1[si] = fexp(sc1[si] - mx);
  }
  __syncthreads();
  #pragma unroll
  for (int si = 0; si < ATT_ST; ++si) {
    float sm = sc0[si] + sc1[si];
    for (int off = 1; off < 64; off <<= 1) sm += __shfl_xor(sm, off);
    if (lane == 0) redw[si][wvi] = sm;
  }
  __syncthreads();
  #pragma unroll
  for (int si = 0; si < ATT_ST; ++si) {
    float tot = redw[si][0] + redw[si][1] + redw[si][2] + redw[si][3];
    float li = __builtin_amdgcn_rcpf(tot);
    float2 uv; uv.x = sc0[si] * li; uv.y = sc1[si] * li;
    *(float2*)&us[si][2 * tid] = uv;
  }
  __syncthreads();
  float dd[ATT_ST];
  #pragma unroll
  for (int si = 0; si < ATT_ST; ++si) dd[si] = 0.f;
  const float* ep = enc + (size_t)b * TENC * H + tid;
  for (int t = 0; t < TENC; t += 4) {
    float e0 = ep[(size_t)(t + 0) * H];
    float e1 = ep[(size_t)(t + 1) * H];
    float e2 = ep[(size_t)(t + 2) * H];
    float e3 = ep[(size_t)(t + 3) * H];
    #pragma unroll
    for (int si = 0; si < ATT_ST; ++si) {
      float4 u4 = *(const float4*)&us[si][t];
      dd[si] += e0 * u4.x + e1 * u4.y + e2 * u4.z + e3 * u4.w;
    }
  }
  #pragma unroll
  for (int si = 0; si < ATT_ST; ++si)
    D16[((size_t)(s0 + si) * BS + b) * 512 + 256 + tid] = f2h(dd[si]);
}

// =====================================================================
//                      FALLBACK PATH (R4, verified)
// =====================================================================
__global__ __launch_bounds__(256) void fbk_zeroinit(float* __restrict__ fst) {
  int i = blockIdx.x * 256 + threadIdx.x;
  if (i < H * BS)              fst[FBDT_F + i] = 0.f;
  else if (i < 2 * H * BS)     fst[FBO1_F + (i - H * BS)] = 0.f;
  else if (i < 3 * H * BS)     fst[FBO2_F + (i - 2 * H * BS)] = 0.f;
}

__global__ __launch_bounds__(256) void fbk_prenet(
    const float* __restrict__ dec, const float* __restrict__ w1, const float* __restrict__ b1,
    const float* __restrict__ w2, const float* __restrict__ b2, u16* __restrict__ xsT)
{
  const int s = blockIdx.x, tid = threadIdx.x;
  __shared__ float X0[32][80];
  __shared__ float P1t[32][256];
  for (int bt = 0; bt < 4; ++bt) {
    const int b0 = bt * 32;
    __syncthreads();
    for (int i = tid; i < 32 * 80; i += 256) {
      int bb = i / 80, m = i - bb * 80;
      X0[bb][m] = dec[((size_t)(b0 + bb) * TDEC + (size_t)s * RF) * MELD + m];
    }
    __syncthreads();
    {
      const int h = tid;
      float acc[32];
      const float bias = b1[h];
      #pragma unroll
      for (int r = 0; r < 32; ++r) acc[r] = bias;
      const float* wr = w1 + (size_t)h * MELD;
      for (int m = 0; m < 80; m += 4) {
        float4 wv = *(const float4*)(wr + m);
        #pragma unroll
        for (int r = 0; r < 32; ++r) {
          float4 x = *(const float4*)&X0[r][m];
          acc[r] += x.x * wv.x + x.y * wv.y + x.z * wv.z + x.w * wv.w;
        }
      }
      #pragma unroll
      for (int r = 0; r < 32; ++r) P1t[r][h] = fmaxf(acc[r], 0.f);
    }
    __syncthreads();
    {
      const int k = tid & 127, bh = tid >> 7;
      float acc[16];
      const float bias = b2[k];
      #pragma unroll
      for (int r = 0; r < 16; ++r) acc[r] = bias;
      const float* wr = w2 + (size_t)k * H;
      for (int h = 0; h < H; h += 4) {
        float4 wv = *(const float4*)(wr + h);
        #pragma unroll
        for (int r = 0; r < 16; ++r) {
          float4 x = *(const float4*)&P1t[bh * 16 + r][h];
          acc[r] += x.x * wv.x + x.y * wv.y + x.z * wv.z + x.w * wv.w;
        }
      }
      #pragma unroll
      for (int r = 0; r < 16; ++r)
        xsT[((size_t)s * HH + k) * BS + b0 + bh * 16 + r] = f2bf(fmaxf(acc[r], 0.f));
    }
  }
}

__global__ __launch_bounds__(256) void fbk_w1enc(
    const float* __restrict__ enc, const float* __restrict__ w1, const float* __restrict__ b1,
    u16* __restrict__ w1e)
{
  const int row0 = blockIdx.x * 32;
  const int tid = threadIdx.x;
  __shared__ float A[32 * 256];
  for (int i = tid * 4; i < 32 * 256; i += 256 * 4) {
    float4 v = *(const float4*)(enc + (size_t)row0 * H + i);
    A[i] = v.x; A[i + 1] = v.y; A[i + 2] = v.z; A[i + 3] = v.w;
  }
  __syncthreads();
  const int h = tid;
  float acc[32];
  const float bias = b1[h];
  #pragma unroll
  for (int r = 0; r < 32; ++r) acc[r] = bias;
  const float* wr = w1 + (size_t)h * H;
  for (int k = 0; k < H; k += 4) {
    float4 wv = *(const float4*)(wr + k);
    #pragma unroll
    for (int r = 0; r < 32; ++r) {
      float4 a = *(const float4*)&A[r * 256 + k];
      acc[r] += a.x * wv.x + a.y * wv.y + a.z * wv.z + a.w * wv.w;
    }
  }
  #pragma unroll
  for (int r = 0; r < 32; ++r) w1e[((size_t)row0 + r) * H + h] = f2bf(acc[r]);
}

__device__ __forceinline__ void fb_gru_body(
    float (*w6)[260], float (*pA)[128], float (*pB)[128], int j, int tid,
    const float* __restrict__ gi_src, const float* __restrict__ h_src,
    const float* __restrict__ wih, const float* __restrict__ whh,
    const float* __restrict__ bih, const float* __restrict__ bhh,
    float* __restrict__ h_out, float* __restrict__ sum_out)
{
  for (int i = tid; i < 3 * H; i += 256) {
    int gg = i >> 8, k = i & 255;
    w6[gg][k]     = wih[((size_t)gg * H + j) * H + k];
    w6[3 + gg][k] = whh[((size_t)gg * H + j) * H + k];
  }
  __syncthreads();
  const int b = tid & 127, kh = tid >> 7;
  float pr = 0, pz = 0, pn = 0, hr = 0, hz = 0, hn = 0;
  for (int k = kh * 128; k < kh * 128 + 128; k += 4) {
    float4 wia = *(const float4*)&w6[0][k];
    float4 wib = *(const float4*)&w6[1][k];
    float4 wic = *(const float4*)&w6[2][k];
    float4 wha = *(const float4*)&w6[3][k];
    float4 whb = *(const float4*)&w6[4][k];
    float4 whc = *(const float4*)&w6[5][k];
    float x0 = gi_src[(size_t)(k + 0) * BS + b], x1 = gi_src[(size_t)(k + 1) * BS + b];
    float x2 = gi_src[(size_t)(k + 2) * BS + b], x3 = gi_src[(size_t)(k + 3) * BS + b];
    float h0 = h_src[(size_t)(k + 0) * BS + b],  h1 = h_src[(size_t)(k + 1) * BS + b];
    float h2 = h_src[(size_t)(k + 2) * BS + b],  h3 = h_src[(size_t)(k + 3) * BS + b];
    pr += x0 * wia.x + x1 * wia.y + x2 * wia.z + x3 * wia.w;
    pz += x0 * wib.x + x1 * wib.y + x2 * wib.z + x3 * wib.w;
    pn += x0 * wic.x + x1 * wic.y + x2 * wic.z + x3 * wic.w;
    hr += h0 * wha.x + h1 * wha.y + h2 * wha.z + h3 * wha.w;
    hz += h0 * whb.x + h1 * whb.y + h2 * whb.z + h3 * whb.w;
    hn += h0 * whc.x + h1 * whc.y + h2 * whc.z + h3 * whc.w;
  }
  if (kh) {
    pA[0][b] = pr; pA[1][b] = pz; pA[2][b] = pn;
    pB[0][b] = hr; pB[1][b] = hz; pB[2][b] = hn;
  }
  __syncthreads();
  if (!kh) {
    float gir = pr + pA[0][b] + bih[j];
    float giz = pz + pA[1][b] + bih[H + j];
    float gin = pn + pA[2][b] + bih[2 * H + j];
    float ghr = hr + pB[0][b] + bhh[j];
    float ghz = hz + pB[1][b] + bhh[H + j];
    float ghn = hn + pB[2][b] + bhh[2 * H + j];
    float r = sigm_f(gir + ghr);
    float z = sigm_f(giz + ghz);
    float n = tanh_f(gin + r * ghn);
    float hp = h_src[(size_t)j * BS + b];
    float o = (1.f - z) * n + z * hp;
    h_out[(size_t)j * BS + b] = o;
    if (sum_out) sum_out[(size_t)j * BS + b] = o + gi_src[(size_t)j * BS + b];
  }
}

__global__ __launch_bounds__(256) void fbk_attgru(
    const u16* __restrict__ xstu, float* __restrict__ fst,
    const float* __restrict__ awih, const float* __restrict__ awhh,
    const float* __restrict__ abih, const float* __restrict__ abhh, int s)
{
  const int j = blockIdx.x, tid = threadIdx.x;
  __shared__ float w6[6][260];
  __shared__ float pA[3][128];
  __shared__ float pB[3][128];
  const float* dprev = fst + FBDT_F + (size_t)(s & 1) * H * BS;
  float*       dcur  = fst + FBDT_F + (size_t)((s + 1) & 1) * H * BS;
  for (int i = tid; i < 3 * HH; i += 256) {
    int gg = i >> 7, k = i & (HH - 1);
    w6[gg][k] = awih[((size_t)gg * H + j) * HH + k];
  }
  for (int i = tid; i < 3 * H; i += 256) {
    int gg = i >> 8, k = i & (H - 1);
    w6[3 + gg][k] = awhh[((size_t)gg * H + j) * H + k];
  }
  __syncthreads();
  const u16* xcol = xstu + (size_t)s * HH * BS;
  const int b = tid & 127, kh = tid >> 7;
  float pr = 0, pz = 0, pn = 0, hr = 0, hz = 0, hn = 0;
  for (int k = kh * 64; k < kh * 64 + 64; k += 4) {
    float4 wa = *(const float4*)&w6[0][k];
    float4 wb = *(const float4*)&w6[1][k];
    float4 wc = *(const float4*)&w6[2][k];
    float x0 = bf2f(xcol[(size_t)(k + 0) * BS + b]), x1 = bf2f(xcol[(size_t)(k + 1) * BS + b]);
    float x2 = bf2f(xcol[(size_t)(k + 2) * BS + b]), x3 = bf2f(xcol[(size_t)(k + 3) * BS + b]);
    pr += x0 * wa.x + x1 * wa.y + x2 * wa.z + x3 * wa.w;
    pz += x0 * wb.x + x1 * wb.y + x2 * wb.z + x3 * wb.w;
    pn += x0 * wc.x + x1 * wc.y + x2 * wc.z + x3 * wc.w;
  }
  for (int k = kh * 128; k < kh * 128 + 128; k += 4) {
    float4 wa = *(const float4*)&w6[3][k];
    float4 wb = *(const float4*)&w6[4][k];
    float4 wc = *(const float4*)&w6[5][k];
    float h0 = dprev[(size_t)(k + 0) * BS + b], h1 = dprev[(size_t)(k + 1) * BS + b];
    float h2 = dprev[(size_t)(k + 2) * BS + b], h3 = dprev[(size_t)(k + 3) * BS + b];
    hr += h0 * wa.x + h1 * wa.y + h2 * wa.z + h3 * wa.w;
    hz += h0 * wb.x + h1 * wb.y + h2 * wb.z + h3 * wb.w;
    hn += h0 * wc.x + h1 * wc.y + h2 * wc.z + h3 * wc.w;
  }
  if (kh) {
    pA[0][b] = pr; pA[1][b] = pz; pA[2][b] = pn;
    pB[0][b] = hr; pB[1][b] = hz; pB[2][b] = hn;
  }
  __syncthreads();
  if (!kh) {
    float gir = pr + pA[0][b] + abih[j];
    float giz = pz + pA[1][b] + abih[H + j];
    float gin = pn + pA[2][b] + abih[2 * H + j];
    float ghr = hr + pB[0][b] + abhh[j];
    float ghz = hz + pB[1][b] + abhh[H + j];
    float ghn = hn + pB[2][b] + abhh[2 * H + j];
    float r = sigm_f(gir + ghr);
    float z = sigm_f(giz + ghz);
    float n = tanh_f(gin + r * ghn);
    float hp = dprev[(size_t)j * BS + b];
    dcur[(size_t)j * BS + b] = (1.f - z) * n + z * hp;
  }
}

__global__ __launch_bounds__(256) void fbk_attn(
    const float* __restrict__ enc, const u16* __restrict__ w1eu,
    const float* __restrict__ w2w, const float* __restrict__ b2w,
    const float* __restrict__ vww, const float* __restrict__ vbw,
    const float* __restrict__ pjw, const float* __restrict__ pjb,
    float* __restrict__ fst, int s)
{
  const int b3 = blockIdx.x, tid = threadIdx.x;
  __shared__ float dsh[256], qs[256], ddh[256], vwsh[256], ev[512], red[256];
  const float* dcur = fst + FBDT_F + (size_t)((s + 1) & 1) * H * BS;
  float* pT = fst + FBPT_F;
  dsh[tid]  = dcur[(size_t)tid * BS + b3];
  vwsh[tid] = vww[tid];
  __syncthreads();
  {
    const int jj = tid;
    const float* wr = w2w + (size_t)jj * H;
    float acc = b2w[jj];
    for (int k = 0; k < H; k += 8) {
      float4 wA = *(const float4*)(wr + k);
      float4 wB = *(const float4*)(wr + k + 4);
      float4 dA = *(const float4*)&dsh[k];
      float4 dB = *(const float4*)&dsh[k + 4];
      acc += dA.x * wA.x + dA.y * wA.y + dA.z * wA.z + dA.w * wA.w
           + dB.x * wB.x + dB.y * wB.y + dB.z * wB.z + dB.w * wB.w;
    }
    qs[jj] = acc;
  }
  __syncthreads();
  const float vbf = vbw[0];
  const u16* wr0 = w1eu + ((size_t)b3 * TENC + tid) * H;
  const u16* wr1 = wr0 + (size_t)256 * H;
  float sc0 = vbf, sc1 = vbf;
  for (int h = 0; h < H; h += 8) {
    uint4 ua = *(const uint4*)(wr0 + h);
    uint4 uc = *(const uint4*)(wr1 + h);
    float4 qA = *(const float4*)&qs[h];
    float4 qB = *(const float4*)&qs[h + 4];
    float4 vA = *(const float4*)&vwsh[h];
    float4 vB = *(const float4*)&vwsh[h + 4];
    sc0 += vA.x * tanh_f(bfu_lo(ua.x) + qA.x) + vA.y * tanh_f(bfu_hi(ua.x) + qA.y)
         + vA.z * tanh_f(bfu_lo(ua.y) + qA.z) + vA.w * tanh_f(bfu_hi(ua.y) + qA.w)
         + vB.x * tanh_f(bfu_lo(ua.z) + qB.x) + vB.y * tanh_f(bfu_hi(ua.z) + qB.y)
         + vB.z * tanh_f(bfu_lo(ua.w) + qB.z) + vB.w * tanh_f(bfu_hi(ua.w) + qB.w);
    sc1 += vA.x * tanh_f(bfu_lo(uc.x) + qA.x) + vA.y * tanh_f(bfu_hi(uc.x) + qA.y)
         + vA.z * tanh_f(bfu_lo(uc.y) + qA.z) + vA.w * tanh_f(bfu_hi(uc.y) + qA.w)
         + vB.x * tanh_f(bfu_lo(uc.z) + qB.x) + vB.y * tanh_f(bfu_hi(uc.z) + qB.y)
         + vB.z * tanh_f(bfu_lo(uc.w) + qB.z) + vB.w * tanh_f(bfu_hi(uc.w) + qB.w);
  }
  red[tid] = fmaxf(sc0, sc1);
  __syncthreads();
  for (int off = 128; off > 0; off >>= 1) {
    if (tid < off) red[tid] = fmaxf(red[tid], red[tid + off]);
    __syncthreads();
  }
  float mx = red[0];
  __syncthreads();
  float e0 = fexp(sc0 - mx), e1 = fexp(sc1 - mx);
  ev[tid] = e0; ev[256 + tid] = e1;
  red[tid] = e0 + e1;
  __syncthreads();
  for (int off = 128; off > 0; off >>= 1) {
    if (tid < off) red[tid] += red[tid + off];
    __syncthreads();
  }
  float linv = __builtin_amdgcn_rcpf(red[0]);
  __syncthreads();
  {
    float vacc = 0.f;
    const float* ep = enc + (size_t)b3 * TENC * H + tid;
    for (int tt = 0; tt < TENC; tt += 4) {
      float4 e4 = *(const float4*)&ev[tt];
      vacc += e4.x * ep[(size_t)(tt + 0) * H] + e4.y * ep[(size_t)(tt + 1) * H]
            + e4.z * ep[(size_t)(tt + 2) * H] + e4.w * ep[(size_t)(tt + 3) * H];
    }
    ddh[tid] = vacc * linv;
  }
  __syncthreads();
  {
    const int jj = tid;
    const float* wr = pjw + (size_t)jj * (2 * H);
    float acc = pjb[jj];
    for (int k = 0; k < H; k += 8) {
      float4 wA = *(const float4*)(wr + k);
      float4 wB = *(const float4*)(wr + k + 4);
      float4 dA = *(const float4*)&dsh[k];
      float4 dB = *(const float4*)&dsh[k + 4];
      acc += dA.x * wA.x + dA.y * wA.y + dA.z * wA.z + dA.w * wA.w
           + dB.x * wB.x + dB.y * wB.y + dB.z * wB.z + dB.w * wB.w;
    }
    for (int k = 0; k < H; k += 8) {
      float4 wA = *(const float4*)(wr + H + k);
      float4 wB = *(const float4*)(wr + H + k + 4);
      float4 dA = *(const float4*)&ddh[k];
      float4 dB = *(const float4*)&ddh[k + 4];
      acc += dA.x * wA.x + dA.y * wA.y + dA.z * wA.z + dA.w * wA.w
           + dB.x * wB.x + dB.y * wB.y + dB.z * wB.z + dB.w * wB.w;
    }
    pT[(size_t)jj * BS + b3] = acc;
  }
}

__global__ __launch_bounds__(256) void fbk_gru1(
    float* __restrict__ fst,
    const float* __restrict__ wih, const float* __restrict__ whh,
    const float* __restrict__ bih, const float* __restrict__ bhh, int s)
{
  __shared__ float w6[6][260];
  __shared__ float pA[3][128];
  __shared__ float pB[3][128];
  const float* pT     = fst + FBPT_F;
  const float* o1prev = fst + FBO1_F + (size_t)(s & 1) * H * BS;
  float*       o1cur  = fst + FBO1_F + (size_t)((s + 1) & 1) * H * BS;
  float*       in2T   = fst + FBIN2_F;
  fb_gru_body(w6, pA, pB, blockIdx.x, threadIdx.x, pT, o1prev, wih, whh, bih, bhh, o1cur, in2T);
}

__device__ __forceinline__ void fb_out_body(
    float (*pA)[128], int bb, int tid, int s,
    const float* __restrict__ sT, const float* __restrict__ ow,
    const float* __restrict__ ob, float* __restrict__ out)
{
  const int b = tid & 127, kh = tid >> 7;
  for (int r = bb; r < OD; r += 128) {
    const float* wr = ow + (size_t)r * H + kh * 128;
    float acc = 0.f;
    for (int kk = 0; kk < 128; kk += 4) {
      float4 wv = *(const float4*)(wr + kk);
      const float* sp = sT + (size_t)(kh * 128 + kk) * BS + b;
      acc += sp[0] * wv.x + sp[BS] * wv.y + sp[2 * BS] * wv.z + sp[3 * BS] * wv.w;
    }
    __syncthreads();
    if (kh) pA[0][b] = acc;
    __syncthreads();
    if (!kh) {
      float y = acc + pA[0][b] + ob[r];
      int frame = s * RF + r / MELD;
      int m = r - (r / MELD) * MELD;
      out[((size_t)b * TDEC + frame) * MELD + m] = y;
    }
  }
}

__global__ __launch_bounds__(256) void fbk_gru2out(
    float* __restrict__ fst,
    const float* __restrict__ wih, const float* __restrict__ whh,
    const float* __restrict__ bih, const float* __restrict__ bhh,
    const float* __restrict__ ow, const float* __restrict__ ob,
    float* __restrict__ out, int s)
{
  const int bid = blockIdx.x, tid = threadIdx.x;
  __shared__ float w6[6][260];
  __shared__ float pA[3][128];
  __shared__ float pB[3][128];
  if (bid < 256) {
    const float* in2T   = fst + FBIN2_F;
    const float* o2prev = fst + FBO2_F + (size_t)(s & 1) * H * BS;
    float*       o2cur  = fst + FBO2_F + (size_t)((s + 1) & 1) * H * BS;
    float*       stp    = fst + FBST_F + (size_t)(s & 1) * H * BS;
    fb_gru_body(w6, pA, pB, bid, tid, in2T, o2prev, wih, whh, bih, bhh, o2cur, stp);
  } else if (s > 0) {
    const float* sT = fst + FBST_F + (size_t)((s - 1) & 1) * H * BS;
    fb_out_body(pA, bid - 256, tid, s - 1, sT, ow, ob, out);
  }
}

__global__ __launch_bounds__(256) void fbk_outlast(
    const float* __restrict__ fst, const float* __restrict__ ow,
    const float* __restrict__ ob, float* __restrict__ out)
{
  __shared__ float pA[3][128];
  const float* sT = fst + FBST_F + (size_t)((STEPS - 1) & 1) * H * BS;
  fb_out_body(pA, blockIdx.x, threadIdx.x, STEPS - 1, sT, ow, ob, out);
}

// =====================================================================
//                              LAUNCH
// =====================================================================
extern "C" void kernel_launch(void* const* d_in, const int* in_sizes, int n_in,
                              void* d_out, int out_size, void* d_ws, size_t ws_size,
                              hipStream_t stream) {
  const float* enc   = (const float*)d_in[0];
  const float* dec   = (const float*)d_in[1];
  const float* pw1   = (const float*)d_in[2];
  const float* pb1   = (const float*)d_in[3];
  const float* pw2   = (const float*)d_in[4];
  const float* pb2   = (const float*)d_in[5];
  const float* w1w   = (const float*)d_in[6];
  const float* b1w   = (const float*)d_in[7];
  const float* w2w   = (const float*)d_in[8];
  const float* b2w   = (const float*)d_in[9];
  const float* vww   = (const float*)d_in[10];
  const float* vbw   = (const float*)d_in[11];
  const float* pjw   = (const float*)d_in[12];
  const float* pjb   = (const float*)d_in[13];
  const float* ow    = (const float*)d_in[14];
  const float* ob    = (const float*)d_in[15];
  const float* awih  = (const float*)d_in[16];
  const float* awhh  = (const float*)d_in[17];
  const float* abih  = (const float*)d_in[18];
  const float* abhh  = (const float*)d_in[19];
  const float* g1wih = (const float*)d_in[20];
  const float* g1whh = (const float*)d_in[21];
  const float* g1bih = (const float*)d_in[22];
  const float* g1bhh = (const float*)d_in[23];
  const float* g2wih = (const float*)d_in[24];
  const float* g2whh = (const float*)d_in[25];
  const float* g2bih = (const float*)d_in[26];
  const float* g2bhh = (const float*)d_in[27];
  float* out = (float*)d_out;
  char* wsb = (char*)d_ws;

  if (ws_size >= NEED_FAST) {
    float* GI   = (float*)(wsb + GI_B);
    u16*   ENC16= (u16*)(wsb + ENC16_B);   // aliases GI, used before GI's first write
    u16*   D16  = (u16*)(wsb + D16_B);
    float* IN2  = (float*)(wsb + IN2_B);
    u16*   w1eT = (u16*)(wsb + W1ET_B);
    u16*   P16  = (u16*)(wsb + P16_B);
    u16*   IN2H = (u16*)(wsb + IN2H_B);
    float* P    = (float*)(wsb + P_B);
    u16*   XSH  = (u16*)(wsb + XSH_B);
    u16*   ST16 = (u16*)(wsb + ST16_B);
    u32*   wpkA = (u32*)(wsb + WPK_B);
    u32*   wpk1 = wpkA + 98304;
    u32*   wpk2 = wpk1 + 98304;
    u16*   awih16 = (u16*)(wsb + WH_B + WH_AW);
    u16*   w2w16  = (u16*)(wsb + WH_B + WH_W2);
    u16*   pjw16  = (u16*)(wsb + WH_B + WH_PJ);
    u16*   g1w16  = (u16*)(wsb + WH_B + WH_G1);
    u16*   g2w16  = (u16*)(wsb + WH_B + WH_G2);
    u16*   ow16   = (u16*)(wsb + WH_B + WH_OW);
    u16*   w1w16  = (u16*)(wsb + WH_B + WH_W1);

    // all packs + enc16 in one kernel
    k_packall<<<PACKALL_N / 256, 256, 0, stream>>>(
        enc, ENC16, awhh, g1whh, g2whh, wpkA,
        awih, awih16, w2w, w2w16, pjw, pjw16, g1wih, g1w16,
        g2wih, g2w16, ow, ow16, w1w, w1w16);
    // w1eT = bf16(exp2(clamp(2.885*(enc @ w1^T + b1)))), transposed — MFMA path
    k_hgemm<<<dim3(4, (BS * TENC) / 128), 256, 0, stream>>>(
        ENC16, H, w1w16, H, b1w, nullptr, nullptr, 0, 256, nullptr, w1eT);
    k_prenet_f<<<STEPS, 256, 0, stream>>>(dec, pw1, pb1, pw2, pb2, XSH);
    // gi_x = xs @ awih^T + abih -> GI [m][768]
    k_hgemm<<<dim3(12, M_ALL / 128), 256, 0, stream>>>(XSH, HH, awih16, HH, abih, GI, nullptr, 768, 768, nullptr, nullptr);
    // attention-GRU chain -> d (f16) into D16[m][0:256]
    k_chain<<<BS, 512, 0, stream>>>(GI, (const uint4*)wpkA, abhh, nullptr, 0, nullptr, 0, D16, 512);
    // Q = d @ w2^T + b2 -> GI reused as Q [m][256]
    k_hgemm<<<dim3(4, M_ALL / 128), 256, 0, stream>>>(D16, 512, w2w16, H, b2w, GI, nullptr, 256, 256, nullptr, nullptr);
    // scores+softmax+d_dot -> D16[m][256:512] (f16)
    k_att<<<dim3(BS, STEPS / ATT_ST), 256, 0, stream>>>(w1eT, GI, vww, enc, D16);
    // P = [d|ddot] @ pjw^T + pjb -> P f32 + P16 f16
    k_hgemm<<<dim3(4, M_ALL / 128), 256, 0, stream>>>(D16, 512, pjw16, 2 * H, pjb, P, P16, 256, 256, nullptr, nullptr);
    // gi1 = P @ g1wih^T + g1bih -> GI
    k_hgemm<<<dim3(12, M_ALL / 128), 256, 0, stream>>>(P16, H, g1w16, H, g1bih, GI, nullptr, 768, 768, nullptr, nullptr);
    // GRU1 chain; in2 = o1 + P -> IN2 f32 + IN2H f16
    k_chain<<<BS, 512, 0, stream>>>(GI, (const uint4*)wpk1, g1bhh, P, 256, IN2, 256, IN2H, 256);
    // gi2 = in2 @ g2wih^T + g2bih -> GI
    k_hgemm<<<dim3(12, M_ALL / 128), 256, 0, stream>>>(IN2H, H, g2w16, H, g2bih, GI, nullptr, 768, 768, nullptr, nullptr);
    // GRU2 chain; st = in2 + o2 -> ST16 f16
    k_chain<<<BS, 512, 0, stream>>>(GI, (const uint4*)wpk2, g2bhh, IN2, 256, nullptr, 0, ST16, 256);
    // out = st @ ow^T + ob, mapped to [b][frame][mel]
    k_hgemm<<<dim3(7, M_ALL / 128), 256, 0, stream>>>(ST16, H, ow16, H, ob, nullptr, nullptr, 0, OD, out, nullptr);
    return;
  }

  if (ws_size < FB_NEED_B) {
    k_zero<<<(out_size + 255) / 256, 256, 0, stream>>>(out, out_size);
    return;
  }

  // -------- fallback: verified R4 multi-kernel path --------
  u16*  w1eu = (u16*)(wsb + FBW1E_B);
  u16*  xstu = (u16*)(wsb + FBXST_B);
  float* fst = (float*)(wsb + FBF32_B);

  fbk_zeroinit<<<384, 256, 0, stream>>>(fst);
  fbk_prenet<<<STEPS, 256, 0, stream>>>(dec, pw1, pb1, pw2, pb2, xstu);
  fbk_w1enc<<<(BS * TENC) / 32, 256, 0, stream>>>(enc, w1w, b1w, w1eu);
  for (int s = 0; s < STEPS; ++s) {
    fbk_attgru<<<256, 256, 0, stream>>>(xstu, fst, awih, awhh, abih, abhh, s);
    fbk_attn<<<BS, 256, 0, stream>>>(enc, w1eu, w2w, b2w, vww, vbw, pjw, pjb, fst, s);
    fbk_gru1<<<256, 256, 0, stream>>>(fst, g1wih, g1whh, g1bih, g1bhh, s);
    fbk_gru2out<<<384, 256, 0, stream>>>(fst, g2wih, g2whh, g2bih, g2bhh, ow, ob, out, s);
  }
  fbk_outlast<<<BS, 256, 0, stream>>>(fst, ow, ob, out);
}

// Round 7
// 1754.258 us; speedup vs baseline: 4.1019x; 1.0189x over previous
//
#include <hip/hip_runtime.h>
#include <hip/hip_bf16.h>

typedef unsigned short u16;
typedef unsigned int   u32;

constexpr int H     = 256;
constexpr int HH    = 128;
constexpr int MELD  = 80;
constexpr int RF    = 5;
constexpr int BS    = 128;
constexpr int TENC  = 512;
constexpr int TDEC  = 1000;
constexpr int STEPS = 200;
constexpr int OD    = 400;
constexpr int M_ALL = STEPS * BS;   // 25600

// ================= fast-path workspace layout (bytes) =================
// Liveness-overlapped:
//  GI   f32 [25600][768]  (gate pre-acts; reused as Q [m][256]); ENC16 f16
//       [b][t][h] (32MB) lives here BEFORE GI's first write (w1enc hgemm).
//  D16  u16 [25600][512]  (d|ddot f16); later IN2 f32 [m][256]
//  W1ET bf16 [b][h][t] (stores exp2 of scaled proj — see k_hgemm CbfT);
//       later P16 + IN2H (f16 [m][256] each)
//  P    f32 [25600][256]
//  XSH  u16 [25600][128]
//  ST16 u16 [25600][256]
//  WPK  3x whh f16-pair packs; WH*: plain f16 weight copies
constexpr size_t GI_B   = 0;
constexpr size_t ENC16_B= GI_B;                                // f16 enc (pre-GI)
constexpr size_t D16_B  = GI_B   + (size_t)M_ALL*768*4;        //  78,643,200
constexpr size_t IN2_B  = D16_B;                               //  f32 [m][256] (after D16 dead)
constexpr size_t W1ET_B = D16_B  + (size_t)M_ALL*512*2;        // 104,857,600
constexpr size_t P16_B  = W1ET_B;                              //  f16 [m][256] (after w1eT dead)
constexpr size_t IN2H_B = W1ET_B + (size_t)M_ALL*256*2;        // 117,964,800
constexpr size_t P_B    = W1ET_B + (size_t)BS*H*TENC*2;        // 138,412,032
constexpr size_t XSH_B  = P_B    + (size_t)M_ALL*256*4;        // 164,626,432
constexpr size_t ST16_B = XSH_B  + (size_t)M_ALL*128*2;        // 171,180,032
constexpr size_t WPK_B  = ST16_B + (size_t)M_ALL*256*2;        // 184,287,232
constexpr size_t WH_B   = WPK_B  + 3*(size_t)393216;           // 185,466,880
// f16 weight copies within WH_B:
constexpr size_t WH_AW  = 0;                 // awih 768x128
constexpr size_t WH_W2  = WH_AW + 98304*2;   // w2   256x256
constexpr size_t WH_PJ  = WH_W2 + 65536*2;   // pjw  256x512
constexpr size_t WH_G1  = WH_PJ + 131072*2;  // g1wih 768x256
constexpr size_t WH_G2  = WH_G1 + 196608*2;  // g2wih 768x256
constexpr size_t WH_OW  = WH_G2 + 196608*2;  // ow   400x256
constexpr size_t WH_W1  = WH_OW + 102400*2;  // w1   256x256
constexpr size_t WH_END = WH_W1 + 65536*2;
constexpr size_t NEED_FAST = WH_B + WH_END;  // ~187.2 MB (< proven 205.1 MB)

// ================= fallback (R4) workspace layout =====================
constexpr size_t FBW1E_B  = 65536;
constexpr size_t FBXST_B  = FBW1E_B + (size_t)BS*TENC*H*2;
constexpr size_t FBF32_B  = FBXST_B + (size_t)STEPS*HH*BS*2;
constexpr size_t FBDT_F   = 0;
constexpr size_t FBO1_F   = FBDT_F + 2*(size_t)H*BS;
constexpr size_t FBO2_F   = FBO1_F + 2*(size_t)H*BS;
constexpr size_t FBPT_F   = FBO2_F + 2*(size_t)H*BS;
constexpr size_t FBIN2_F  = FBPT_F + (size_t)H*BS;
constexpr size_t FBST_F   = FBIN2_F + (size_t)H*BS;
constexpr size_t FB_NEED_B = FBF32_B + (FBST_F + 2*(size_t)H*BS) * 4;

// ================= helpers =================
__device__ __forceinline__ float bf2f(u16 v) {
  union { u32 x; float f; } c; c.x = ((u32)v) << 16; return c.f;
}
__device__ __forceinline__ float bfu_lo(u32 u) { union { u32 x; float f; } c; c.x = u << 16;        return c.f; }
__device__ __forceinline__ float bfu_hi(u32 u) { union { u32 x; float f; } c; c.x = u & 0xffff0000u; return c.f; }
__device__ __forceinline__ u16 f2bf(float f) {
  union { float f; u32 u; } c; c.f = f;
  u32 u = c.u;
  u32 r = (u + 0x7fffu + ((u >> 16) & 1u)) >> 16;  // RNE
  return (u16)r;
}
__device__ __forceinline__ u16 f2h(float f) {
  union { _Float16 h; u16 u; } c; c.h = (_Float16)f; return c.u;
}
__device__ __forceinline__ float fexp(float x) {
  return __builtin_amdgcn_exp2f(1.4426950408889634f * x);
}
__device__ __forceinline__ float sigm_f(float x) {
  return __builtin_amdgcn_rcpf(1.0f + __builtin_amdgcn_exp2f(-1.4426950408889634f * x));
}
__device__ __forceinline__ float tanh_f(float x) {
  x = fminf(fmaxf(x, -15.f), 15.f);
  float e = __builtin_amdgcn_exp2f(2.8853900817779268f * x);   // e^(2x)
  return (e - 1.0f) * __builtin_amdgcn_rcpf(e + 1.0f);
}

// f16 pair dot: acc += w.lo*h.lo + w.hi*h.hi  (V_DOT2_F32_F16 when available)
typedef _Float16 hlf2 __attribute__((ext_vector_type(2)));
typedef _Float16 f16x8 __attribute__((ext_vector_type(8)));
typedef float f32x4 __attribute__((ext_vector_type(4)));
#if __has_builtin(__builtin_amdgcn_fdot2)
__device__ __forceinline__ float dot2h(float acc, u32 w, u32 h) {
  union { u32 u; hlf2 v; } cw, ch; cw.u = w; ch.u = h;
  return __builtin_amdgcn_fdot2(cw.v, ch.v, acc, false);
}
#else
__device__ __forceinline__ float dot2h(float acc, u32 w, u32 h) {
  union { u32 u; _Float16 f[2]; } cw, ch; cw.u = w; ch.u = h;
  return acc + (float)cw.f[0] * (float)ch.f[0] + (float)cw.f[1] * (float)ch.f[1];
}
#endif
__device__ __forceinline__ void dot8h(float& acc, const uint4 w, const uint4 hp) {
  acc = dot2h(acc, w.x, hp.x);
  acc = dot2h(acc, w.y, hp.y);
  acc = dot2h(acc, w.z, hp.z);
  acc = dot2h(acc, w.w, hp.w);
}

__global__ __launch_bounds__(256) void k_zero(float* __restrict__ out, int n) {
  int i = blockIdx.x * 256 + threadIdx.x;
  if (i < n) out[i] = 0.f;
}

// =====================================================================
//                           FAST PATH
// =====================================================================

// ---- prenet (2 fused layers) -> xsh f16 [s][b][128] ----
__global__ __launch_bounds__(256) void k_prenet_f(
    const float* __restrict__ dec, const float* __restrict__ w1, const float* __restrict__ b1,
    const float* __restrict__ w2, const float* __restrict__ b2, u16* __restrict__ xsh)
{
  const int s = blockIdx.x, tid = threadIdx.x;
  __shared__ float X0[32][80];
  __shared__ float P1t[32][256];
  for (int bt = 0; bt < 4; ++bt) {
    const int b0 = bt * 32;
    __syncthreads();
    for (int i = tid; i < 32 * 80; i += 256) {
      int bb = i / 80, m = i - bb * 80;
      X0[bb][m] = dec[((size_t)(b0 + bb) * TDEC + (size_t)s * RF) * MELD + m];
    }
    __syncthreads();
    {
      const int h = tid;
      float acc[32];
      const float bias = b1[h];
      #pragma unroll
      for (int r = 0; r < 32; ++r) acc[r] = bias;
      const float* wr = w1 + (size_t)h * MELD;
      for (int m = 0; m < 80; m += 4) {
        float4 wv = *(const float4*)(wr + m);
        #pragma unroll
        for (int r = 0; r < 32; ++r) {
          float4 x = *(const float4*)&X0[r][m];
          acc[r] += x.x * wv.x + x.y * wv.y + x.z * wv.z + x.w * wv.w;
        }
      }
      #pragma unroll
      for (int r = 0; r < 32; ++r) P1t[r][h] = fmaxf(acc[r], 0.f);
    }
    __syncthreads();
    {
      const int k = tid & 127, bh = tid >> 7;
      float acc[16];
      const float bias = b2[k];
      #pragma unroll
      for (int r = 0; r < 16; ++r) acc[r] = bias;
      const float* wr = w2 + (size_t)k * H;
      for (int h = 0; h < H; h += 4) {
        float4 wv = *(const float4*)(wr + h);
        #pragma unroll
        for (int r = 0; r < 16; ++r) {
          float4 x = *(const float4*)&P1t[bh * 16 + r][h];
          acc[r] += x.x * wv.x + x.y * wv.y + x.z * wv.z + x.w * wv.w;
        }
      }
      #pragma unroll
      for (int r = 0; r < 16; ++r)
        xsh[((size_t)s * BS + b0 + bh * 16 + r) * HH + k] = f2h(fmaxf(acc[r], 0.f));
    }
  }
}

// ---- all packs/copies in one kernel ----
// ranges: enc16 (16.78M) | 3x whh packs (294912) | 7 f16 copies (856064)
__global__ __launch_bounds__(256) void k_packall(
    const float* __restrict__ enc, u16* __restrict__ enc16,
    const float* __restrict__ awhh, const float* __restrict__ g1whh,
    const float* __restrict__ g2whh, u32* __restrict__ wpk,
    const float* __restrict__ awih, u16* __restrict__ awih16,
    const float* __restrict__ w2w,  u16* __restrict__ w2w16,
    const float* __restrict__ pjw,  u16* __restrict__ pjw16,
    const float* __restrict__ g1wih, u16* __restrict__ g1w16,
    const float* __restrict__ g2wih, u16* __restrict__ g2w16,
    const float* __restrict__ ow,   u16* __restrict__ ow16,
    const float* __restrict__ w1w,  u16* __restrict__ w1w16)
{
  int i = blockIdx.x * 256 + threadIdx.x;
  if (i < 16777216) { enc16[i] = f2h(enc[i]); return; }
  i -= 16777216;
  if (i < 294912) {
    int which = i / 98304, idx = i - which * 98304;
    const float* w = which == 0 ? awhh : (which == 1 ? g1whh : g2whh);
    int ii = idx & 3;
    int j  = (idx >> 2) & 255;
    int k4 = (idx >> 10) & 31;
    int g  = idx >> 15;
    int k2 = 4 * k4 + ii;
    union { _Float16 f[2]; u32 u; } c;
    c.f[0] = (_Float16)w[((size_t)g * 256 + j) * 256 + 2 * k2];
    c.f[1] = (_Float16)w[((size_t)g * 256 + j) * 256 + 2 * k2 + 1];
    wpk[which * 98304 + idx] = c.u;
    return;
  }
  i -= 294912;
  if (i < 98304)  { awih16[i] = f2h(awih[i]); return; }  i -= 98304;
  if (i < 65536)  { w2w16[i]  = f2h(w2w[i]);  return; }  i -= 65536;
  if (i < 131072) { pjw16[i]  = f2h(pjw[i]);  return; }  i -= 131072;
  if (i < 196608) { g1w16[i]  = f2h(g1wih[i]); return; } i -= 196608;
  if (i < 196608) { g2w16[i]  = f2h(g2wih[i]); return; } i -= 196608;
  if (i < 102400) { ow16[i]   = f2h(ow[i]);   return; }  i -= 102400;
  if (i < 65536)  { w1w16[i]  = f2h(w1w[i]);  return; }
}
constexpr int PACKALL_N = 16777216 + 294912 + 856064;   // 17,928,192

// ---- MFMA f16 GEMM: C[M][N] = A[M][K]f16 @ W[N][K]f16^T + bias ----
// block: 256 thr = 4 waves; tile 128(M)x64(N); wave w: rows [w*32, w*32+32).
// K stepped by 32. LDS rows padded to 40 f16.
// Output modes: outmap -> mel layout; CbfT -> transposed EXP-domain bf16
// w1eT[b][col][t] = bf16(exp2(clamp(2.885*v, ±15))) (factorized-sigmoid;
// k_att combines 4 sigmoid terms over a common denominator, so per-factor
// magnitude must satisfy (2^15·2^15)^4 = 2^120 < f32 max — hence ±15;
// |tanh arg| ≤ 5.2 saturation error ≤ 6e-5);
// else C (f32) and/or Ch (f16).
__global__ __launch_bounds__(256) void k_hgemm(
    const u16* __restrict__ A, int lda,       // f16 [M][lda]
    const u16* __restrict__ W, int K,         // f16 [N][K]
    const float* __restrict__ bias,
    float* __restrict__ C, u16* __restrict__ Ch, int ldc, int N,
    float* __restrict__ outmap, u16* __restrict__ CbfT)
{
  __shared__ _Float16 As[128 * 40];
  __shared__ _Float16 Ws[64 * 40];
  const int m0 = blockIdx.y * 128, n0 = blockIdx.x * 64;
  const int tid = threadIdx.x;
  const int wv = tid >> 6, lane = tid & 63;
  const int l15 = lane & 15, hi = lane >> 4;
  f32x4 acc[2][4];
  #pragma unroll
  for (int mi = 0; mi < 2; ++mi)
    #pragma unroll
    for (int ni = 0; ni < 4; ++ni) acc[mi][ni] = (f32x4){0.f, 0.f, 0.f, 0.f};

  const int ar = tid >> 1, ac = (tid & 1) * 16;   // A stage: 128 rows x 2 half-rows
  const int wr = tid >> 2, wc = (tid & 3) * 8;    // W stage: 64 rows x 4 chunks
  for (int k0 = 0; k0 < K; k0 += 32) {
    __syncthreads();
    {
      const u16* src = A + (size_t)(m0 + ar) * lda + k0 + ac;
      uint4 v0 = *(const uint4*)(src);
      uint4 v1 = *(const uint4*)(src + 8);
      *(uint4*)&As[ar * 40 + ac] = v0;
      *(uint4*)&As[ar * 40 + ac + 8] = v1;
    }
    {
      uint4 v;
      if (n0 + wr < N) v = *(const uint4*)(W + (size_t)(n0 + wr) * K + k0 + wc);
      else { v.x = v.y = v.z = v.w = 0u; }
      *(uint4*)&Ws[wr * 40 + wc] = v;
    }
    __syncthreads();
    f16x8 af[2], bf[4];
    #pragma unroll
    for (int mi = 0; mi < 2; ++mi)
      af[mi] = *(const f16x8*)&As[(wv * 32 + mi * 16 + l15) * 40 + hi * 8];
    #pragma unroll
    for (int ni = 0; ni < 4; ++ni)
      bf[ni] = *(const f16x8*)&Ws[(ni * 16 + l15) * 40 + hi * 8];
    #pragma unroll
    for (int mi = 0; mi < 2; ++mi)
      #pragma unroll
      for (int ni = 0; ni < 4; ++ni)
        acc[mi][ni] = __builtin_amdgcn_mfma_f32_16x16x32_f16(af[mi], bf[ni], acc[mi][ni], 0, 0, 0);
  }
  // epilogue: D row = (lane>>4)*4 + reg (within 16), col = lane&15  [m89 layout]
  const int gm = m0 + wv * 32;
  #pragma unroll
  for (int ni = 0; ni < 4; ++ni) {
    const int col = n0 + ni * 16 + l15;
    if (col < N) {
      const float bv = bias[col];
      #pragma unroll
      for (int mi = 0; mi < 2; ++mi) {
        #pragma unroll
        for (int r = 0; r < 4; ++r) {
          const int row = gm + mi * 16 + hi * 4 + r;
          float v = acc[mi][ni][r] + bv;
          if (outmap) {
            int s = row >> 7, b = row & 127;
            int fr = s * RF + col / MELD, mel = col - (col / MELD) * MELD;
            outmap[((size_t)b * TDEC + fr) * MELD + mel] = v;
          } else if (CbfT) {
            // w1eT[b][col][t], b = row>>9, t = row&511; EXP-domain for k_att
            float a = fminf(fmaxf(2.8853900817779268f * v, -15.f), 15.f);
            CbfT[(((size_t)(row >> 9) * 256 + col) << 9) + (row & 511)] =
                f2bf(__builtin_amdgcn_exp2f(a));
          } else {
            if (C)  C[(size_t)row * ldc + col] = v;
            if (Ch) Ch[(size_t)row * ldc + col] = f2h(v);
          }
        }
      }
    }
  }
}

// ---- per-row sequential GRU chain, v5 -------------------------------
// 512 threads: tid = (kh<<8)|j. f16-pair weights via V_DOT2_F32_F16.
// Weights: 2 k4-groups/half in LDS, 14 in VGPRs.
// gi/addsrc loads SOFTWARE-PIPELINED: step s+1's loads issue before step s's
// dot loop so their ~500-900cy latency hides under dots+barrier+gate math.
constexpr int KC4H = 2;    // k4-groups per half cached in LDS
constexpr int RG4H = 14;   // k4-groups per half resident in VGPRs (2+14=16)
__global__ __launch_bounds__(512) void k_chain(
    const float* __restrict__ gi,      // [25600][768] includes bih
    const uint4* __restrict__ wpk4,    // [3][32][256] uint4 (f16 pairs)
    const float* __restrict__ bhh,     // [768]
    const float* __restrict__ addsrc,  // nullptr or [25600][astride]
    int astride,
    float* __restrict__ outp, int ostride,
    u16* __restrict__ outph, int ostrideh)
{
  const int b = blockIdx.x, tid = threadIdx.x;
  const int j = tid & 255, kh = tid >> 8;
  __shared__ __align__(16) _Float16 hf[256];
  __shared__ float psum[3][256];
  __shared__ uint4 wl4[3][2 * KC4H][256];
  for (int i = tid; i < 3 * 2 * KC4H * 256; i += 512) {
    int g = i / (2 * KC4H * 256), rem = i - g * (2 * KC4H * 256);
    int slot = rem >> 8, jj = rem & 255;
    int c = slot < KC4H ? slot : slot - KC4H;
    int k4 = (slot < KC4H ? 0 : 16) + c;
    wl4[g][slot][jj] = wpk4[((size_t)g * 32 + k4) * 256 + jj];
  }
  uint4 wreg[3][RG4H];
  #pragma unroll
  for (int g = 0; g < 3; ++g) {
    #pragma unroll
    for (int t = 0; t < RG4H; ++t) {
      const int k4 = kh * 16 + KC4H + t;
      wreg[g][t] = wpk4[((size_t)g * 32 + k4) * 256 + j];
    }
  }
  if (tid < 256) hf[tid] = (_Float16)0.f;
  float hreg = 0.f;
  const float br = bhh[j], bz = bhh[256 + j], bn = bhh[512 + j];
  // prologue loads for step 0
  float gr = 0.f, gz = 0.f, gn = 0.f, av = 0.f;
  if (kh == 0) {
    const float* gim = gi + (size_t)b * 768;
    gr = gim[j]; gz = gim[256 + j]; gn = gim[512 + j];
    if (addsrc) av = addsrc[(size_t)b * astride + j];
  }
  __syncthreads();
  for (int s = 0; s < STEPS; ++s) {
    // issue next-step loads early (latency hidden under dots + barrier)
    float gr_n = 0.f, gz_n = 0.f, gn_n = 0.f, av_n = 0.f;
    if (kh == 0 && s + 1 < STEPS) {
      const size_t mn = (size_t)(s + 1) * BS + b;
      const float* gim = gi + mn * 768;
      gr_n = gim[j]; gz_n = gim[256 + j]; gn_n = gim[512 + j];
      if (addsrc) av_n = addsrc[mn * astride + j];
    }
    float ar = 0.f, az = 0.f, an = 0.f;
    const int k4b = kh * 16;
    #pragma unroll
    for (int t = 0; t < RG4H; ++t) {
      const int k4 = k4b + KC4H + t;
      uint4 hp = *(const uint4*)&hf[8 * k4];
      dot8h(ar, wreg[0][t], hp); dot8h(az, wreg[1][t], hp); dot8h(an, wreg[2][t], hp);
    }
    #pragma unroll
    for (int c = 0; c < KC4H; ++c) {
      const int k4 = k4b + c;
      const int slot = kh * KC4H + c;
      uint4 hp = *(const uint4*)&hf[8 * k4];
      dot8h(ar, wl4[0][slot][j], hp); dot8h(az, wl4[1][slot][j], hp); dot8h(an, wl4[2][slot][j], hp);
    }
    if (kh == 1) { psum[0][j] = ar; psum[1][j] = az; psum[2][j] = an; }
    __syncthreads();
    if (kh == 0) {
      const size_t m = (size_t)s * BS + b;
      ar += psum[0][j]; az += psum[1][j]; an += psum[2][j];
      float r = sigm_f(gr + ar + br);
      float z = sigm_f(gz + az + bz);
      float n = tanh_f(gn + r * (an + bn));
      float hn_ = (1.f - z) * n + z * hreg;
      hreg = hn_;
      hf[j] = (_Float16)hn_;
      float ov = hn_ + av;
      if (outp)  outp[m * ostride + j] = ov;
      if (outph) outph[m * ostrideh + j] = f2h(ov);
    }
    __syncthreads();
    gr = gr_n; gz = gz_n; gn = gn_n; av = av_n;
  }
}

// ---- fused scores + softmax + d_dot: block = (b, 10-step tile) ----
// Factorized sigmoid + 4-way common denominator:
//   Σ_{i=1..4} v_i/F_i = [P34(v1F2+v2F1) + P12(v3F4+v4F3)] / (P12·P34)
// with F_i = fma(Ew_i, Eq_i, 1), P12 = F1F2, P34 = F3F4.
// ONE v_rcp per 4 elements (rcp is ~16cy quarter-rate — the k_att cost).
// Clamps ±15 on both exp args keep den = ΠF ≤ 2^120 < f32 max.
constexpr int ATT_ST = 10;
__global__ __launch_bounds__(256) void k_att(
    const u16* __restrict__ w1eT, const float* __restrict__ Q,
    const float* __restrict__ vw_, const float* __restrict__ enc,
    u16* __restrict__ D16)
{
  const int b = blockIdx.x, s0 = blockIdx.y * ATT_ST, tid = threadIdx.x;
  __shared__ float qt[ATT_ST][260];
  __shared__ float vws[256];
  __shared__ float us[ATT_ST][516];
  __shared__ float redw[ATT_ST][4];
  vws[tid] = -2.0f * vw_[tid];
  #pragma unroll
  for (int si = 0; si < ATT_ST; ++si) {
    float q = 2.8853900817779268f * Q[((size_t)(s0 + si) * BS + b) * H + tid];
    qt[si][tid] = __builtin_amdgcn_exp2f(fminf(fmaxf(q, -15.f), 15.f));
  }
  __syncthreads();

  float sc0[ATT_ST], sc1[ATT_ST];
  #pragma unroll
  for (int si = 0; si < ATT_ST; ++si) { sc0[si] = 0.f; sc1[si] = 0.f; }
  const u32* wrow = (const u32*)w1eT + (size_t)b * H * (TENC / 2);
  for (int h = 0; h < H; h += 4) {
    u32 wa = wrow[(size_t)(h + 0) * 256 + tid];    // t = 2*tid, 2*tid+1
    u32 wb = wrow[(size_t)(h + 1) * 256 + tid];
    u32 wc = wrow[(size_t)(h + 2) * 256 + tid];
    u32 wd = wrow[(size_t)(h + 3) * 256 + tid];
    float Ea0 = bfu_lo(wa), Ea1 = bfu_hi(wa);
    float Eb0 = bfu_lo(wb), Eb1 = bfu_hi(wb);
    float Ec0 = bfu_lo(wc), Ec1 = bfu_hi(wc);
    float Ed0 = bfu_lo(wd), Ed1 = bfu_hi(wd);
    float4 vv = *(const float4*)&vws[h];
    #pragma unroll
    for (int si = 0; si < ATT_ST; ++si) {
      float4 Eq = *(const float4*)&qt[si][h];
      {  // t even
        float F1 = __builtin_fmaf(Ea0, Eq.x, 1.f);
        float F2 = __builtin_fmaf(Eb0, Eq.y, 1.f);
        float F3 = __builtin_fmaf(Ec0, Eq.z, 1.f);
        float F4 = __builtin_fmaf(Ed0, Eq.w, 1.f);
        float P12 = F1 * F2, P34 = F3 * F4;
        float u12 = __builtin_fmaf(vv.y, F1, vv.x * F2);
        float u34 = __builtin_fmaf(vv.w, F3, vv.z * F4);
        float num = __builtin_fmaf(P12, u34, P34 * u12);
        sc0[si] = __builtin_fmaf(num, __builtin_amdgcn_rcpf(P12 * P34), sc0[si]);
      }
      {  // t odd
        float F1 = __builtin_fmaf(Ea1, Eq.x, 1.f);
        float F2 = __builtin_fmaf(Eb1, Eq.y, 1.f);
        float F3 = __builtin_fmaf(Ec1, Eq.z, 1.f);
        float F4 = __builtin_fmaf(Ed1, Eq.w, 1.f);
        float P12 = F1 * F2, P34 = F3 * F4;
        float u12 = __builtin_fmaf(vv.y, F1, vv.x * F2);
        float u34 = __builtin_fmaf(vv.w, F3, vv.z * F4);
        float num = __builtin_fmaf(P12, u34, P34 * u12);
        sc1[si] = __builtin_fmaf(num, __builtin_amdgcn_rcpf(P12 * P34), sc1[si]);
      }
    }
  }
  const int lane = tid & 63, wvi = tid >> 6;
  #pragma unroll
  for (int si = 0; si < ATT_ST; ++si) {
    float mw = fmaxf(sc0[si], sc1[si]);
    for (int off = 1; off < 64; off <<= 1) mw = fmaxf(mw, __shfl_xor(mw, off));
    if (lane == 0) redw[si][wvi] = mw;
  }
  __syncthreads();
  #pragma unroll
  for (int si = 0; si < ATT_ST; ++si) {
    float mx = fmaxf(fmaxf(redw[si][0], redw[si][1]), fmaxf(redw[si][2], redw[si][3]));
    sc0[si] = fexp(sc0[si] - mx);
    sc1[si] = fexp(sc1[si] - mx);
  }
  __syncthreads();
  #pragma unroll
  for (int si = 0; si < ATT_ST; ++si) {
    float sm = sc0[si] + sc1[si];
    for (int off = 1; off < 64; off <<= 1) sm += __shfl_xor(sm, off);
    if (lane == 0) redw[si][wvi] = sm;
  }
  __syncthreads();
  #pragma unroll
  for (int si = 0; si < ATT_ST; ++si) {
    float tot = redw[si][0] + redw[si][1] + redw[si][2] + redw[si][3];
    float li = __builtin_amdgcn_rcpf(tot);
    float2 uv; uv.x = sc0[si] * li; uv.y = sc1[si] * li;
    *(float2*)&us[si][2 * tid] = uv;
  }
  __syncthreads();
  float dd[ATT_ST];
  #pragma unroll
  for (int si = 0; si < ATT_ST; ++si) dd[si] = 0.f;
  const float* ep = enc + (size_t)b * TENC * H + tid;
  for (int t = 0; t < TENC; t += 4) {
    float e0 = ep[(size_t)(t + 0) * H];
    float e1 = ep[(size_t)(t + 1) * H];
    float e2 = ep[(size_t)(t + 2) * H];
    float e3 = ep[(size_t)(t + 3) * H];
    #pragma unroll
    for (int si = 0; si < ATT_ST; ++si) {
      float4 u4 = *(const float4*)&us[si][t];
      dd[si] += e0 * u4.x + e1 * u4.y + e2 * u4.z + e3 * u4.w;
    }
  }
  #pragma unroll
  for (int si = 0; si < ATT_ST; ++si)
    D16[((size_t)(s0 + si) * BS + b) * 512 + 256 + tid] = f2h(dd[si]);
}

// =====================================================================
//                      FALLBACK PATH (R4, verified)
// =====================================================================
__global__ __launch_bounds__(256) void fbk_zeroinit(float* __restrict__ fst) {
  int i = blockIdx.x * 256 + threadIdx.x;
  if (i < H * BS)              fst[FBDT_F + i] = 0.f;
  else if (i < 2 * H * BS)     fst[FBO1_F + (i - H * BS)] = 0.f;
  else if (i < 3 * H * BS)     fst[FBO2_F + (i - 2 * H * BS)] = 0.f;
}

__global__ __launch_bounds__(256) void fbk_prenet(
    const float* __restrict__ dec, const float* __restrict__ w1, const float* __restrict__ b1,
    const float* __restrict__ w2, const float* __restrict__ b2, u16* __restrict__ xsT)
{
  const int s = blockIdx.x, tid = threadIdx.x;
  __shared__ float X0[32][80];
  __shared__ float P1t[32][256];
  for (int bt = 0; bt < 4; ++bt) {
    const int b0 = bt * 32;
    __syncthreads();
    for (int i = tid; i < 32 * 80; i += 256) {
      int bb = i / 80, m = i - bb * 80;
      X0[bb][m] = dec[((size_t)(b0 + bb) * TDEC + (size_t)s * RF) * MELD + m];
    }
    __syncthreads();
    {
      const int h = tid;
      float acc[32];
      const float bias = b1[h];
      #pragma unroll
      for (int r = 0; r < 32; ++r) acc[r] = bias;
      const float* wr = w1 + (size_t)h * MELD;
      for (int m = 0; m < 80; m += 4) {
        float4 wv = *(const float4*)(wr + m);
        #pragma unroll
        for (int r = 0; r < 32; ++r) {
          float4 x = *(const float4*)&X0[r][m];
          acc[r] += x.x * wv.x + x.y * wv.y + x.z * wv.z + x.w * wv.w;
        }
      }
      #pragma unroll
      for (int r = 0; r < 32; ++r) P1t[r][h] = fmaxf(acc[r], 0.f);
    }
    __syncthreads();
    {
      const int k = tid & 127, bh = tid >> 7;
      float acc[16];
      const float bias = b2[k];
      #pragma unroll
      for (int r = 0; r < 16; ++r) acc[r] = bias;
      const float* wr = w2 + (size_t)k * H;
      for (int h = 0; h < H; h += 4) {
        float4 wv = *(const float4*)(wr + h);
        #pragma unroll
        for (int r = 0; r < 16; ++r) {
          float4 x = *(const float4*)&P1t[bh * 16 + r][h];
          acc[r] += x.x * wv.x + x.y * wv.y + x.z * wv.z + x.w * wv.w;
        }
      }
      #pragma unroll
      for (int r = 0; r < 16; ++r)
        xsT[((size_t)s * HH + k) * BS + b0 + bh * 16 + r] = f2bf(fmaxf(acc[r], 0.f));
    }
  }
}

__global__ __launch_bounds__(256) void fbk_w1enc(
    const float* __restrict__ enc, const float* __restrict__ w1, const float* __restrict__ b1,
    u16* __restrict__ w1e)
{
  const int row0 = blockIdx.x * 32;
  const int tid = threadIdx.x;
  __shared__ float A[32 * 256];
  for (int i = tid * 4; i < 32 * 256; i += 256 * 4) {
    float4 v = *(const float4*)(enc + (size_t)row0 * H + i);
    A[i] = v.x; A[i + 1] = v.y; A[i + 2] = v.z; A[i + 3] = v.w;
  }
  __syncthreads();
  const int h = tid;
  float acc[32];
  const float bias = b1[h];
  #pragma unroll
  for (int r = 0; r < 32; ++r) acc[r] = bias;
  const float* wr = w1 + (size_t)h * H;
  for (int k = 0; k < H; k += 4) {
    float4 wv = *(const float4*)(wr + k);
    #pragma unroll
    for (int r = 0; r < 32; ++r) {
      float4 a = *(const float4*)&A[r * 256 + k];
      acc[r] += a.x * wv.x + a.y * wv.y + a.z * wv.z + a.w * wv.w;
    }
  }
  #pragma unroll
  for (int r = 0; r < 32; ++r) w1e[((size_t)row0 + r) * H + h] = f2bf(acc[r]);
}

__device__ __forceinline__ void fb_gru_body(
    float (*w6)[260], float (*pA)[128], float (*pB)[128], int j, int tid,
    const float* __restrict__ gi_src, const float* __restrict__ h_src,
    const float* __restrict__ wih, const float* __restrict__ whh,
    const float* __restrict__ bih, const float* __restrict__ bhh,
    float* __restrict__ h_out, float* __restrict__ sum_out)
{
  for (int i = tid; i < 3 * H; i += 256) {
    int gg = i >> 8, k = i & 255;
    w6[gg][k]     = wih[((size_t)gg * H + j) * H + k];
    w6[3 + gg][k] = whh[((size_t)gg * H + j) * H + k];
  }
  __syncthreads();
  const int b = tid & 127, kh = tid >> 7;
  float pr = 0, pz = 0, pn = 0, hr = 0, hz = 0, hn = 0;
  for (int k = kh * 128; k < kh * 128 + 128; k += 4) {
    float4 wia = *(const float4*)&w6[0][k];
    float4 wib = *(const float4*)&w6[1][k];
    float4 wic = *(const float4*)&w6[2][k];
    float4 wha = *(const float4*)&w6[3][k];
    float4 whb = *(const float4*)&w6[4][k];
    float4 whc = *(const float4*)&w6[5][k];
    float x0 = gi_src[(size_t)(k + 0) * BS + b], x1 = gi_src[(size_t)(k + 1) * BS + b];
    float x2 = gi_src[(size_t)(k + 2) * BS + b], x3 = gi_src[(size_t)(k + 3) * BS + b];
    float h0 = h_src[(size_t)(k + 0) * BS + b],  h1 = h_src[(size_t)(k + 1) * BS + b];
    float h2 = h_src[(size_t)(k + 2) * BS + b],  h3 = h_src[(size_t)(k + 3) * BS + b];
    pr += x0 * wia.x + x1 * wia.y + x2 * wia.z + x3 * wia.w;
    pz += x0 * wib.x + x1 * wib.y + x2 * wib.z + x3 * wib.w;
    pn += x0 * wic.x + x1 * wic.y + x2 * wic.z + x3 * wic.w;
    hr += h0 * wha.x + h1 * wha.y + h2 * wha.z + h3 * wha.w;
    hz += h0 * whb.x + h1 * whb.y + h2 * whb.z + h3 * whb.w;
    hn += h0 * whc.x + h1 * whc.y + h2 * whc.z + h3 * whc.w;
  }
  if (kh) {
    pA[0][b] = pr; pA[1][b] = pz; pA[2][b] = pn;
    pB[0][b] = hr; pB[1][b] = hz; pB[2][b] = hn;
  }
  __syncthreads();
  if (!kh) {
    float gir = pr + pA[0][b] + bih[j];
    float giz = pz + pA[1][b] + bih[H + j];
    float gin = pn + pA[2][b] + bih[2 * H + j];
    float ghr = hr + pB[0][b] + bhh[j];
    float ghz = hz + pB[1][b] + bhh[H + j];
    float ghn = hn + pB[2][b] + bhh[2 * H + j];
    float r = sigm_f(gir + ghr);
    float z = sigm_f(giz + ghz);
    float n = tanh_f(gin + r * ghn);
    float hp = h_src[(size_t)j * BS + b];
    float o = (1.f - z) * n + z * hp;
    h_out[(size_t)j * BS + b] = o;
    if (sum_out) sum_out[(size_t)j * BS + b] = o + gi_src[(size_t)j * BS + b];
  }
}

__global__ __launch_bounds__(256) void fbk_attgru(
    const u16* __restrict__ xstu, float* __restrict__ fst,
    const float* __restrict__ awih, const float* __restrict__ awhh,
    const float* __restrict__ abih, const float* __restrict__ abhh, int s)
{
  const int j = blockIdx.x, tid = threadIdx.x;
  __shared__ float w6[6][260];
  __shared__ float pA[3][128];
  __shared__ float pB[3][128];
  const float* dprev = fst + FBDT_F + (size_t)(s & 1) * H * BS;
  float*       dcur  = fst + FBDT_F + (size_t)((s + 1) & 1) * H * BS;
  for (int i = tid; i < 3 * HH; i += 256) {
    int gg = i >> 7, k = i & (HH - 1);
    w6[gg][k] = awih[((size_t)gg * H + j) * HH + k];
  }
  for (int i = tid; i < 3 * H; i += 256) {
    int gg = i >> 8, k = i & (H - 1);
    w6[3 + gg][k] = awhh[((size_t)gg * H + j) * H + k];
  }
  __syncthreads();
  const u16* xcol = xstu + (size_t)s * HH * BS;
  const int b = tid & 127, kh = tid >> 7;
  float pr = 0, pz = 0, pn = 0, hr = 0, hz = 0, hn = 0;
  for (int k = kh * 64; k < kh * 64 + 64; k += 4) {
    float4 wa = *(const float4*)&w6[0][k];
    float4 wb = *(const float4*)&w6[1][k];
    float4 wc = *(const float4*)&w6[2][k];
    float x0 = bf2f(xcol[(size_t)(k + 0) * BS + b]), x1 = bf2f(xcol[(size_t)(k + 1) * BS + b]);
    float x2 = bf2f(xcol[(size_t)(k + 2) * BS + b]), x3 = bf2f(xcol[(size_t)(k + 3) * BS + b]);
    pr += x0 * wa.x + x1 * wa.y + x2 * wa.z + x3 * wa.w;
    pz += x0 * wb.x + x1 * wb.y + x2 * wb.z + x3 * wb.w;
    pn += x0 * wc.x + x1 * wc.y + x2 * wc.z + x3 * wc.w;
  }
  for (int k = kh * 128; k < kh * 128 + 128; k += 4) {
    float4 wa = *(const float4*)&w6[3][k];
    float4 wb = *(const float4*)&w6[4][k];
    float4 wc = *(const float4*)&w6[5][k];
    float h0 = dprev[(size_t)(k + 0) * BS + b], h1 = dprev[(size_t)(k + 1) * BS + b];
    float h2 = dprev[(size_t)(k + 2) * BS + b], h3 = dprev[(size_t)(k + 3) * BS + b];
    hr += h0 * wa.x + h1 * wa.y + h2 * wa.z + h3 * wa.w;
    hz += h0 * wb.x + h1 * wb.y + h2 * wb.z + h3 * wb.w;
    hn += h0 * wc.x + h1 * wc.y + h2 * wc.z + h3 * wc.w;
  }
  if (kh) {
    pA[0][b] = pr; pA[1][b] = pz; pA[2][b] = pn;
    pB[0][b] = hr; pB[1][b] = hz; pB[2][b] = hn;
  }
  __syncthreads();
  if (!kh) {
    float gir = pr + pA[0][b] + abih[j];
    float giz = pz + pA[1][b] + abih[H + j];
    float gin = pn + pA[2][b] + abih[2 * H + j];
    float ghr = hr + pB[0][b] + abhh[j];
    float ghz = hz + pB[1][b] + abhh[H + j];
    float ghn = hn + pB[2][b] + abhh[2 * H + j];
    float r = sigm_f(gir + ghr);
    float z = sigm_f(giz + ghz);
    float n = tanh_f(gin + r * ghn);
    float hp = dprev[(size_t)j * BS + b];
    dcur[(size_t)j * BS + b] = (1.f - z) * n + z * hp;
  }
}

__global__ __launch_bounds__(256) void fbk_attn(
    const float* __restrict__ enc, const u16* __restrict__ w1eu,
    const float* __restrict__ w2w, const float* __restrict__ b2w,
    const float* __restrict__ vww, const float* __restrict__ vbw,
    const float* __restrict__ pjw, const float* __restrict__ pjb,
    float* __restrict__ fst, int s)
{
  const int b3 = blockIdx.x, tid = threadIdx.x;
  __shared__ float dsh[256], qs[256], ddh[256], vwsh[256], ev[512], red[256];
  const float* dcur = fst + FBDT_F + (size_t)((s + 1) & 1) * H * BS;
  float* pT = fst + FBPT_F;
  dsh[tid]  = dcur[(size_t)tid * BS + b3];
  vwsh[tid] = vww[tid];
  __syncthreads();
  {
    const int jj = tid;
    const float* wr = w2w + (size_t)jj * H;
    float acc = b2w[jj];
    for (int k = 0; k < H; k += 8) {
      float4 wA = *(const float4*)(wr + k);
      float4 wB = *(const float4*)(wr + k + 4);
      float4 dA = *(const float4*)&dsh[k];
      float4 dB = *(const float4*)&dsh[k + 4];
      acc += dA.x * wA.x + dA.y * wA.y + dA.z * wA.z + dA.w * wA.w
           + dB.x * wB.x + dB.y * wB.y + dB.z * wB.z + dB.w * wB.w;
    }
    qs[jj] = acc;
  }
  __syncthreads();
  const float vbf = vbw[0];
  const u16* wr0 = w1eu + ((size_t)b3 * TENC + tid) * H;
  const u16* wr1 = wr0 + (size_t)256 * H;
  float sc0 = vbf, sc1 = vbf;
  for (int h = 0; h < H; h += 8) {
    uint4 ua = *(const uint4*)(wr0 + h);
    uint4 uc = *(const uint4*)(wr1 + h);
    float4 qA = *(const float4*)&qs[h];
    float4 qB = *(const float4*)&qs[h + 4];
    float4 vA = *(const float4*)&vwsh[h];
    float4 vB = *(const float4*)&vwsh[h + 4];
    sc0 += vA.x * tanh_f(bfu_lo(ua.x) + qA.x) + vA.y * tanh_f(bfu_hi(ua.x) + qA.y)
         + vA.z * tanh_f(bfu_lo(ua.y) + qA.z) + vA.w * tanh_f(bfu_hi(ua.y) + qA.w)
         + vB.x * tanh_f(bfu_lo(ua.z) + qB.x) + vB.y * tanh_f(bfu_hi(ua.z) + qB.y)
         + vB.z * tanh_f(bfu_lo(ua.w) + qB.z) + vB.w * tanh_f(bfu_hi(ua.w) + qB.w);
    sc1 += vA.x * tanh_f(bfu_lo(uc.x) + qA.x) + vA.y * tanh_f(bfu_hi(uc.x) + qA.y)
         + vA.z * tanh_f(bfu_lo(uc.y) + qA.z) + vA.w * tanh_f(bfu_hi(uc.y) + qA.w)
         + vB.x * tanh_f(bfu_lo(uc.z) + qB.x) + vB.y * tanh_f(bfu_hi(uc.z) + qB.y)
         + vB.z * tanh_f(bfu_lo(uc.w) + qB.z) + vB.w * tanh_f(bfu_hi(uc.w) + qB.w);
  }
  red[tid] = fmaxf(sc0, sc1);
  __syncthreads();
  for (int off = 128; off > 0; off >>= 1) {
    if (tid < off) red[tid] = fmaxf(red[tid], red[tid + off]);
    __syncthreads();
  }
  float mx = red[0];
  __syncthreads();
  float e0 = fexp(sc0 - mx), e1 = fexp(sc1 - mx);
  ev[tid] = e0; ev[256 + tid] = e1;
  red[tid] = e0 + e1;
  __syncthreads();
  for (int off = 128; off > 0; off >>= 1) {
    if (tid < off) red[tid] += red[tid + off];
    __syncthreads();
  }
  float linv = __builtin_amdgcn_rcpf(red[0]);
  __syncthreads();
  {
    float vacc = 0.f;
    const float* ep = enc + (size_t)b3 * TENC * H + tid;
    for (int tt = 0; tt < TENC; tt += 4) {
      float4 e4 = *(const float4*)&ev[tt];
      vacc += e4.x * ep[(size_t)(tt + 0) * H] + e4.y * ep[(size_t)(tt + 1) * H]
            + e4.z * ep[(size_t)(tt + 2) * H] + e4.w * ep[(size_t)(tt + 3) * H];
    }
    ddh[tid] = vacc * linv;
  }
  __syncthreads();
  {
    const int jj = tid;
    const float* wr = pjw + (size_t)jj * (2 * H);
    float acc = pjb[jj];
    for (int k = 0; k < H; k += 8) {
      float4 wA = *(const float4*)(wr + k);
      float4 wB = *(const float4*)(wr + k + 4);
      float4 dA = *(const float4*)&dsh[k];
      float4 dB = *(const float4*)&dsh[k + 4];
      acc += dA.x * wA.x + dA.y * wA.y + dA.z * wA.z + dA.w * wA.w
           + dB.x * wB.x + dB.y * wB.y + dB.z * wB.z + dB.w * wB.w;
    }
    for (int k = 0; k < H; k += 8) {
      float4 wA = *(const float4*)(wr + H + k);
      float4 wB = *(const float4*)(wr + H + k + 4);
      float4 dA = *(const float4*)&ddh[k];
      float4 dB = *(const float4*)&ddh[k + 4];
      acc += dA.x * wA.x + dA.y * wA.y + dA.z * wA.z + dA.w * wA.w
           + dB.x * wB.x + dB.y * wB.y + dB.z * wB.z + dB.w * wB.w;
    }
    pT[(size_t)jj * BS + b3] = acc;
  }
}

__global__ __launch_bounds__(256) void fbk_gru1(
    float* __restrict__ fst,
    const float* __restrict__ wih, const float* __restrict__ whh,
    const float* __restrict__ bih, const float* __restrict__ bhh, int s)
{
  __shared__ float w6[6][260];
  __shared__ float pA[3][128];
  __shared__ float pB[3][128];
  const float* pT     = fst + FBPT_F;
  const float* o1prev = fst + FBO1_F + (size_t)(s & 1) * H * BS;
  float*       o1cur  = fst + FBO1_F + (size_t)((s + 1) & 1) * H * BS;
  float*       in2T   = fst + FBIN2_F;
  fb_gru_body(w6, pA, pB, blockIdx.x, threadIdx.x, pT, o1prev, wih, whh, bih, bhh, o1cur, in2T);
}

__device__ __forceinline__ void fb_out_body(
    float (*pA)[128], int bb, int tid, int s,
    const float* __restrict__ sT, const float* __restrict__ ow,
    const float* __restrict__ ob, float* __restrict__ out)
{
  const int b = tid & 127, kh = tid >> 7;
  for (int r = bb; r < OD; r += 128) {
    const float* wr = ow + (size_t)r * H + kh * 128;
    float acc = 0.f;
    for (int kk = 0; kk < 128; kk += 4) {
      float4 wv = *(const float4*)(wr + kk);
      const float* sp = sT + (size_t)(kh * 128 + kk) * BS + b;
      acc += sp[0] * wv.x + sp[BS] * wv.y + sp[2 * BS] * wv.z + sp[3 * BS] * wv.w;
    }
    __syncthreads();
    if (kh) pA[0][b] = acc;
    __syncthreads();
    if (!kh) {
      float y = acc + pA[0][b] + ob[r];
      int frame = s * RF + r / MELD;
      int m = r - (r / MELD) * MELD;
      out[((size_t)b * TDEC + frame) * MELD + m] = y;
    }
  }
}

__global__ __launch_bounds__(256) void fbk_gru2out(
    float* __restrict__ fst,
    const float* __restrict__ wih, const float* __restrict__ whh,
    const float* __restrict__ bih, const float* __restrict__ bhh,
    const float* __restrict__ ow, const float* __restrict__ ob,
    float* __restrict__ out, int s)
{
  const int bid = blockIdx.x, tid = threadIdx.x;
  __shared__ float w6[6][260];
  __shared__ float pA[3][128];
  __shared__ float pB[3][128];
  if (bid < 256) {
    const float* in2T   = fst + FBIN2_F;
    const float* o2prev = fst + FBO2_F + (size_t)(s & 1) * H * BS;
    float*       o2cur  = fst + FBO2_F + (size_t)((s + 1) & 1) * H * BS;
    float*       stp    = fst + FBST_F + (size_t)(s & 1) * H * BS;
    fb_gru_body(w6, pA, pB, bid, tid, in2T, o2prev, wih, whh, bih, bhh, o2cur, stp);
  } else if (s > 0) {
    const float* sT = fst + FBST_F + (size_t)((s - 1) & 1) * H * BS;
    fb_out_body(pA, bid - 256, tid, s - 1, sT, ow, ob, out);
  }
}

__global__ __launch_bounds__(256) void fbk_outlast(
    const float* __restrict__ fst, const float* __restrict__ ow,
    const float* __restrict__ ob, float* __restrict__ out)
{
  __shared__ float pA[3][128];
  const float* sT = fst + FBST_F + (size_t)((STEPS - 1) & 1) * H * BS;
  fb_out_body(pA, blockIdx.x, threadIdx.x, STEPS - 1, sT, ow, ob, out);
}

// =====================================================================
//                              LAUNCH
// =====================================================================
extern "C" void kernel_launch(void* const* d_in, const int* in_sizes, int n_in,
                              void* d_out, int out_size, void* d_ws, size_t ws_size,
                              hipStream_t stream) {
  const float* enc   = (const float*)d_in[0];
  const float* dec   = (const float*)d_in[1];
  const float* pw1   = (const float*)d_in[2];
  const float* pb1   = (const float*)d_in[3];
  const float* pw2   = (const float*)d_in[4];
  const float* pb2   = (const float*)d_in[5];
  const float* w1w   = (const float*)d_in[6];
  const float* b1w   = (const float*)d_in[7];
  const float* w2w   = (const float*)d_in[8];
  const float* b2w   = (const float*)d_in[9];
  const float* vww   = (const float*)d_in[10];
  const float* vbw   = (const float*)d_in[11];
  const float* pjw   = (const float*)d_in[12];
  const float* pjb   = (const float*)d_in[13];
  const float* ow    = (const float*)d_in[14];
  const float* ob    = (const float*)d_in[15];
  const float* awih  = (const float*)d_in[16];
  const float* awhh  = (const float*)d_in[17];
  const float* abih  = (const float*)d_in[18];
  const float* abhh  = (const float*)d_in[19];
  const float* g1wih = (const float*)d_in[20];
  const float* g1whh = (const float*)d_in[21];
  const float* g1bih = (const float*)d_in[22];
  const float* g1bhh = (const float*)d_in[23];
  const float* g2wih = (const float*)d_in[24];
  const float* g2whh = (const float*)d_in[25];
  const float* g2bih = (const float*)d_in[26];
  const float* g2bhh = (const float*)d_in[27];
  float* out = (float*)d_out;
  char* wsb = (char*)d_ws;

  if (ws_size >= NEED_FAST) {
    float* GI   = (float*)(wsb + GI_B);
    u16*   ENC16= (u16*)(wsb + ENC16_B);   // aliases GI, used before GI's first write
    u16*   D16  = (u16*)(wsb + D16_B);
    float* IN2  = (float*)(wsb + IN2_B);
    u16*   w1eT = (u16*)(wsb + W1ET_B);
    u16*   P16  = (u16*)(wsb + P16_B);
    u16*   IN2H = (u16*)(wsb + IN2H_B);
    float* P    = (float*)(wsb + P_B);
    u16*   XSH  = (u16*)(wsb + XSH_B);
    u16*   ST16 = (u16*)(wsb + ST16_B);
    u32*   wpkA = (u32*)(wsb + WPK_B);
    u32*   wpk1 = wpkA + 98304;
    u32*   wpk2 = wpk1 + 98304;
    u16*   awih16 = (u16*)(wsb + WH_B + WH_AW);
    u16*   w2w16  = (u16*)(wsb + WH_B + WH_W2);
    u16*   pjw16  = (u16*)(wsb + WH_B + WH_PJ);
    u16*   g1w16  = (u16*)(wsb + WH_B + WH_G1);
    u16*   g2w16  = (u16*)(wsb + WH_B + WH_G2);
    u16*   ow16   = (u16*)(wsb + WH_B + WH_OW);
    u16*   w1w16  = (u16*)(wsb + WH_B + WH_W1);

    // all packs + enc16 in one kernel
    k_packall<<<PACKALL_N / 256, 256, 0, stream>>>(
        enc, ENC16, awhh, g1whh, g2whh, wpkA,
        awih, awih16, w2w, w2w16, pjw, pjw16, g1wih, g1w16,
        g2wih, g2w16, ow, ow16, w1w, w1w16);
    // w1eT = bf16(exp2(clamp(2.885*(enc @ w1^T + b1), ±15))), transposed — MFMA
    k_hgemm<<<dim3(4, (BS * TENC) / 128), 256, 0, stream>>>(
        ENC16, H, w1w16, H, b1w, nullptr, nullptr, 0, 256, nullptr, w1eT);
    k_prenet_f<<<STEPS, 256, 0, stream>>>(dec, pw1, pb1, pw2, pb2, XSH);
    // gi_x = xs @ awih^T + abih -> GI [m][768]
    k_hgemm<<<dim3(12, M_ALL / 128), 256, 0, stream>>>(XSH, HH, awih16, HH, abih, GI, nullptr, 768, 768, nullptr, nullptr);
    // attention-GRU chain -> d (f16) into D16[m][0:256]
    k_chain<<<BS, 512, 0, stream>>>(GI, (const uint4*)wpkA, abhh, nullptr, 0, nullptr, 0, D16, 512);
    // Q = d @ w2^T + b2 -> GI reused as Q [m][256]
    k_hgemm<<<dim3(4, M_ALL / 128), 256, 0, stream>>>(D16, 512, w2w16, H, b2w, GI, nullptr, 256, 256, nullptr, nullptr);
    // scores+softmax+d_dot -> D16[m][256:512] (f16)
    k_att<<<dim3(BS, STEPS / ATT_ST), 256, 0, stream>>>(w1eT, GI, vww, enc, D16);
    // P = [d|ddot] @ pjw^T + pjb -> P f32 + P16 f16
    k_hgemm<<<dim3(4, M_ALL / 128), 256, 0, stream>>>(D16, 512, pjw16, 2 * H, pjb, P, P16, 256, 256, nullptr, nullptr);
    // gi1 = P @ g1wih^T + g1bih -> GI
    k_hgemm<<<dim3(12, M_ALL / 128), 256, 0, stream>>>(P16, H, g1w16, H, g1bih, GI, nullptr, 768, 768, nullptr, nullptr);
    // GRU1 chain; in2 = o1 + P -> IN2 f32 + IN2H f16
    k_chain<<<BS, 512, 0, stream>>>(GI, (const uint4*)wpk1, g1bhh, P, 256, IN2, 256, IN2H, 256);
    // gi2 = in2 @ g2wih^T + g2bih -> GI
    k_hgemm<<<dim3(12, M_ALL / 128), 256, 0, stream>>>(IN2H, H, g2w16, H, g2bih, GI, nullptr, 768, 768, nullptr, nullptr);
    // GRU2 chain; st = in2 + o2 -> ST16 f16
    k_chain<<<BS, 512, 0, stream>>>(GI, (const uint4*)wpk2, g2bhh, IN2, 256, nullptr, 0, ST16, 256);
    // out = st @ ow^T + ob, mapped to [b][frame][mel]
    k_hgemm<<<dim3(7, M_ALL / 128), 256, 0, stream>>>(ST16, H, ow16, H, ob, nullptr, nullptr, 0, OD, out, nullptr);
    return;
  }

  if (ws_size < FB_NEED_B) {
    k_zero<<<(out_size + 255) / 256, 256, 0, stream>>>(out, out_size);
    return;
  }

  // -------- fallback: verified R4 multi-kernel path --------
  u16*  w1eu = (u16*)(wsb + FBW1E_B);
  u16*  xstu = (u16*)(wsb + FBXST_B);
  float* fst = (float*)(wsb + FBF32_B);

  fbk_zeroinit<<<384, 256, 0, stream>>>(fst);
  fbk_prenet<<<STEPS, 256, 0, stream>>>(dec, pw1, pb1, pw2, pb2, xstu);
  fbk_w1enc<<<(BS * TENC) / 32, 256, 0, stream>>>(enc, w1w, b1w, w1eu);
  for (int s = 0; s < STEPS; ++s) {
    fbk_attgru<<<256, 256, 0, stream>>>(xstu, fst, awih, awhh, abih, abhh, s);
    fbk_attn<<<BS, 256, 0, stream>>>(enc, w1eu, w2w, b2w, vww, vbw, pjw, pjb, fst, s);
    fbk_gru1<<<256, 256, 0, stream>>>(fst, g1wih, g1whh, g1bih, g1bhh, s);
    fbk_gru2out<<<384, 256, 0, stream>>>(fst, g2wih, g2whh, g2bih, g2bhh, ow, ob, out, s);
  }
  fbk_outlast<<<BS, 256, 0, stream>>>(fst, ow, ob, out);
}

// Round 8
// 1614.725 us; speedup vs baseline: 4.4563x; 1.0864x over previous
//
#include <hip/hip_runtime.h>
#include <hip/hip_bf16.h>

typedef unsigned short u16;
typedef unsigned int   u32;

constexpr int H     = 256;
constexpr int HH    = 128;
constexpr int MELD  = 80;
constexpr int RF    = 5;
constexpr int BS    = 128;
constexpr int TENC  = 512;
constexpr int TDEC  = 1000;
constexpr int STEPS = 200;
constexpr int OD    = 400;
constexpr int M_ALL = STEPS * BS;   // 25600

// ================= fast-path workspace layout (bytes) =================
// Liveness-overlapped:
//  GI   f32 [25600][768]  (gate pre-acts; reused as Q [m][256]); ENC16 f16
//       [b][t][h] (32MB) lives here BEFORE GI's first write (w1enc hgemm).
//  D16  u16 [25600][512]  (d|ddot f16); later IN2 f32 [m][256]
//  W1ET bf16 [b][h][t] (stores exp2 of scaled proj — see k_hgemm CbfT);
//       later P16 + IN2H (f16 [m][256] each)
//  P    f32 [25600][256]; U16 f16 [128][200][512] lives here BEFORE P's write
//  XSH  u16 [25600][128]
//  ST16 u16 [25600][256]
//  WPK  3x whh f16-pair packs; WH*: plain f16 weight copies
constexpr size_t GI_B   = 0;
constexpr size_t ENC16_B= GI_B;                                // f16 enc (pre-GI)
constexpr size_t D16_B  = GI_B   + (size_t)M_ALL*768*4;        //  78,643,200
constexpr size_t IN2_B  = D16_B;                               //  f32 [m][256] (after D16 dead)
constexpr size_t W1ET_B = D16_B  + (size_t)M_ALL*512*2;        // 104,857,600
constexpr size_t P16_B  = W1ET_B;                              //  f16 [m][256] (after w1eT dead)
constexpr size_t IN2H_B = W1ET_B + (size_t)M_ALL*256*2;        // 117,964,800
constexpr size_t P_B    = W1ET_B + (size_t)BS*H*TENC*2;        // 138,412,032
constexpr size_t U16_B  = P_B;                                 //  f16 u-weights (pre-P)
constexpr size_t XSH_B  = P_B    + (size_t)M_ALL*256*4;        // 164,626,432
constexpr size_t ST16_B = XSH_B  + (size_t)M_ALL*128*2;        // 171,180,032
constexpr size_t WPK_B  = ST16_B + (size_t)M_ALL*256*2;        // 184,287,232
constexpr size_t WH_B   = WPK_B  + 3*(size_t)393216;           // 185,466,880
// f16 weight copies within WH_B:
constexpr size_t WH_AW  = 0;                 // awih 768x128
constexpr size_t WH_W2  = WH_AW + 98304*2;   // w2   256x256
constexpr size_t WH_PJ  = WH_W2 + 65536*2;   // pjw  256x512
constexpr size_t WH_G1  = WH_PJ + 131072*2;  // g1wih 768x256
constexpr size_t WH_G2  = WH_G1 + 196608*2;  // g2wih 768x256
constexpr size_t WH_OW  = WH_G2 + 196608*2;  // ow   400x256
constexpr size_t WH_W1  = WH_OW + 102400*2;  // w1   256x256
constexpr size_t WH_END = WH_W1 + 65536*2;
constexpr size_t NEED_FAST = WH_B + WH_END;  // ~187.2 MB (< proven 205.1 MB)

// ================= fallback (R4) workspace layout =====================
constexpr size_t FBW1E_B  = 65536;
constexpr size_t FBXST_B  = FBW1E_B + (size_t)BS*TENC*H*2;
constexpr size_t FBF32_B  = FBXST_B + (size_t)STEPS*HH*BS*2;
constexpr size_t FBDT_F   = 0;
constexpr size_t FBO1_F   = FBDT_F + 2*(size_t)H*BS;
constexpr size_t FBO2_F   = FBO1_F + 2*(size_t)H*BS;
constexpr size_t FBPT_F   = FBO2_F + 2*(size_t)H*BS;
constexpr size_t FBIN2_F  = FBPT_F + (size_t)H*BS;
constexpr size_t FBST_F   = FBIN2_F + (size_t)H*BS;
constexpr size_t FB_NEED_B = FBF32_B + (FBST_F + 2*(size_t)H*BS) * 4;

// ================= helpers =================
__device__ __forceinline__ float bf2f(u16 v) {
  union { u32 x; float f; } c; c.x = ((u32)v) << 16; return c.f;
}
__device__ __forceinline__ float bfu_lo(u32 u) { union { u32 x; float f; } c; c.x = u << 16;        return c.f; }
__device__ __forceinline__ float bfu_hi(u32 u) { union { u32 x; float f; } c; c.x = u & 0xffff0000u; return c.f; }
__device__ __forceinline__ u16 f2bf(float f) {
  union { float f; u32 u; } c; c.f = f;
  u32 u = c.u;
  u32 r = (u + 0x7fffu + ((u >> 16) & 1u)) >> 16;  // RNE
  return (u16)r;
}
__device__ __forceinline__ u16 f2h(float f) {
  union { _Float16 h; u16 u; } c; c.h = (_Float16)f; return c.u;
}
__device__ __forceinline__ float fexp(float x) {
  return __builtin_amdgcn_exp2f(1.4426950408889634f * x);
}
__device__ __forceinline__ float sigm_f(float x) {
  return __builtin_amdgcn_rcpf(1.0f + __builtin_amdgcn_exp2f(-1.4426950408889634f * x));
}
__device__ __forceinline__ float tanh_f(float x) {
  x = fminf(fmaxf(x, -15.f), 15.f);
  float e = __builtin_amdgcn_exp2f(2.8853900817779268f * x);   // e^(2x)
  return (e - 1.0f) * __builtin_amdgcn_rcpf(e + 1.0f);
}

// f16 pair dot: acc += w.lo*h.lo + w.hi*h.hi  (V_DOT2_F32_F16 when available)
typedef _Float16 hlf2 __attribute__((ext_vector_type(2)));
typedef _Float16 f16x8 __attribute__((ext_vector_type(8)));
typedef float f32x4 __attribute__((ext_vector_type(4)));
#if __has_builtin(__builtin_amdgcn_fdot2)
__device__ __forceinline__ float dot2h(float acc, u32 w, u32 h) {
  union { u32 u; hlf2 v; } cw, ch; cw.u = w; ch.u = h;
  return __builtin_amdgcn_fdot2(cw.v, ch.v, acc, false);
}
#else
__device__ __forceinline__ float dot2h(float acc, u32 w, u32 h) {
  union { u32 u; _Float16 f[2]; } cw, ch; cw.u = w; ch.u = h;
  return acc + (float)cw.f[0] * (float)ch.f[0] + (float)cw.f[1] * (float)ch.f[1];
}
#endif
__device__ __forceinline__ void dot8h(float& acc, const uint4 w, const uint4 hp) {
  acc = dot2h(acc, w.x, hp.x);
  acc = dot2h(acc, w.y, hp.y);
  acc = dot2h(acc, w.z, hp.z);
  acc = dot2h(acc, w.w, hp.w);
}

__global__ __launch_bounds__(256) void k_zero(float* __restrict__ out, int n) {
  int i = blockIdx.x * 256 + threadIdx.x;
  if (i < n) out[i] = 0.f;
}

// =====================================================================
//                           FAST PATH
// =====================================================================

// ---- prenet (2 fused layers) -> xsh f16 [s][b][128] ----
__global__ __launch_bounds__(256) void k_prenet_f(
    const float* __restrict__ dec, const float* __restrict__ w1, const float* __restrict__ b1,
    const float* __restrict__ w2, const float* __restrict__ b2, u16* __restrict__ xsh)
{
  const int s = blockIdx.x, tid = threadIdx.x;
  __shared__ float X0[32][80];
  __shared__ float P1t[32][256];
  for (int bt = 0; bt < 4; ++bt) {
    const int b0 = bt * 32;
    __syncthreads();
    for (int i = tid; i < 32 * 80; i += 256) {
      int bb = i / 80, m = i - bb * 80;
      X0[bb][m] = dec[((size_t)(b0 + bb) * TDEC + (size_t)s * RF) * MELD + m];
    }
    __syncthreads();
    {
      const int h = tid;
      float acc[32];
      const float bias = b1[h];
      #pragma unroll
      for (int r = 0; r < 32; ++r) acc[r] = bias;
      const float* wr = w1 + (size_t)h * MELD;
      for (int m = 0; m < 80; m += 4) {
        float4 wv = *(const float4*)(wr + m);
        #pragma unroll
        for (int r = 0; r < 32; ++r) {
          float4 x = *(const float4*)&X0[r][m];
          acc[r] += x.x * wv.x + x.y * wv.y + x.z * wv.z + x.w * wv.w;
        }
      }
      #pragma unroll
      for (int r = 0; r < 32; ++r) P1t[r][h] = fmaxf(acc[r], 0.f);
    }
    __syncthreads();
    {
      const int k = tid & 127, bh = tid >> 7;
      float acc[16];
      const float bias = b2[k];
      #pragma unroll
      for (int r = 0; r < 16; ++r) acc[r] = bias;
      const float* wr = w2 + (size_t)k * H;
      for (int h = 0; h < H; h += 4) {
        float4 wv = *(const float4*)(wr + h);
        #pragma unroll
        for (int r = 0; r < 16; ++r) {
          float4 x = *(const float4*)&P1t[bh * 16 + r][h];
          acc[r] += x.x * wv.x + x.y * wv.y + x.z * wv.z + x.w * wv.w;
        }
      }
      #pragma unroll
      for (int r = 0; r < 16; ++r)
        xsh[((size_t)s * BS + b0 + bh * 16 + r) * HH + k] = f2h(fmaxf(acc[r], 0.f));
    }
  }
}

// ---- all packs/copies in one kernel ----
__global__ __launch_bounds__(256) void k_packall(
    const float* __restrict__ enc, u16* __restrict__ enc16,
    const float* __restrict__ awhh, const float* __restrict__ g1whh,
    const float* __restrict__ g2whh, u32* __restrict__ wpk,
    const float* __restrict__ awih, u16* __restrict__ awih16,
    const float* __restrict__ w2w,  u16* __restrict__ w2w16,
    const float* __restrict__ pjw,  u16* __restrict__ pjw16,
    const float* __restrict__ g1wih, u16* __restrict__ g1w16,
    const float* __restrict__ g2wih, u16* __restrict__ g2w16,
    const float* __restrict__ ow,   u16* __restrict__ ow16,
    const float* __restrict__ w1w,  u16* __restrict__ w1w16)
{
  int i = blockIdx.x * 256 + threadIdx.x;
  if (i < 16777216) { enc16[i] = f2h(enc[i]); return; }
  i -= 16777216;
  if (i < 294912) {
    int which = i / 98304, idx = i - which * 98304;
    const float* w = which == 0 ? awhh : (which == 1 ? g1whh : g2whh);
    int ii = idx & 3;
    int j  = (idx >> 2) & 255;
    int k4 = (idx >> 10) & 31;
    int g  = idx >> 15;
    int k2 = 4 * k4 + ii;
    union { _Float16 f[2]; u32 u; } c;
    c.f[0] = (_Float16)w[((size_t)g * 256 + j) * 256 + 2 * k2];
    c.f[1] = (_Float16)w[((size_t)g * 256 + j) * 256 + 2 * k2 + 1];
    wpk[which * 98304 + idx] = c.u;
    return;
  }
  i -= 294912;
  if (i < 98304)  { awih16[i] = f2h(awih[i]); return; }  i -= 98304;
  if (i < 65536)  { w2w16[i]  = f2h(w2w[i]);  return; }  i -= 65536;
  if (i < 131072) { pjw16[i]  = f2h(pjw[i]);  return; }  i -= 131072;
  if (i < 196608) { g1w16[i]  = f2h(g1wih[i]); return; } i -= 196608;
  if (i < 196608) { g2w16[i]  = f2h(g2wih[i]); return; } i -= 196608;
  if (i < 102400) { ow16[i]   = f2h(ow[i]);   return; }  i -= 102400;
  if (i < 65536)  { w1w16[i]  = f2h(w1w[i]);  return; }
}
constexpr int PACKALL_N = 16777216 + 294912 + 856064;   // 17,928,192

// ---- MFMA f16 GEMM: C[M][N] = A[M][K]f16 @ W[N][K]f16^T + bias ----
__global__ __launch_bounds__(256) void k_hgemm(
    const u16* __restrict__ A, int lda,       // f16 [M][lda]
    const u16* __restrict__ W, int K,         // f16 [N][K]
    const float* __restrict__ bias,
    float* __restrict__ C, u16* __restrict__ Ch, int ldc, int N,
    float* __restrict__ outmap, u16* __restrict__ CbfT)
{
  __shared__ _Float16 As[128 * 40];
  __shared__ _Float16 Ws[64 * 40];
  const int m0 = blockIdx.y * 128, n0 = blockIdx.x * 64;
  const int tid = threadIdx.x;
  const int wv = tid >> 6, lane = tid & 63;
  const int l15 = lane & 15, hi = lane >> 4;
  f32x4 acc[2][4];
  #pragma unroll
  for (int mi = 0; mi < 2; ++mi)
    #pragma unroll
    for (int ni = 0; ni < 4; ++ni) acc[mi][ni] = (f32x4){0.f, 0.f, 0.f, 0.f};

  const int ar = tid >> 1, ac = (tid & 1) * 16;   // A stage: 128 rows x 2 half-rows
  const int wr = tid >> 2, wc = (tid & 3) * 8;    // W stage: 64 rows x 4 chunks
  for (int k0 = 0; k0 < K; k0 += 32) {
    __syncthreads();
    {
      const u16* src = A + (size_t)(m0 + ar) * lda + k0 + ac;
      uint4 v0 = *(const uint4*)(src);
      uint4 v1 = *(const uint4*)(src + 8);
      *(uint4*)&As[ar * 40 + ac] = v0;
      *(uint4*)&As[ar * 40 + ac + 8] = v1;
    }
    {
      uint4 v;
      if (n0 + wr < N) v = *(const uint4*)(W + (size_t)(n0 + wr) * K + k0 + wc);
      else { v.x = v.y = v.z = v.w = 0u; }
      *(uint4*)&Ws[wr * 40 + wc] = v;
    }
    __syncthreads();
    f16x8 af[2], bf[4];
    #pragma unroll
    for (int mi = 0; mi < 2; ++mi)
      af[mi] = *(const f16x8*)&As[(wv * 32 + mi * 16 + l15) * 40 + hi * 8];
    #pragma unroll
    for (int ni = 0; ni < 4; ++ni)
      bf[ni] = *(const f16x8*)&Ws[(ni * 16 + l15) * 40 + hi * 8];
    #pragma unroll
    for (int mi = 0; mi < 2; ++mi)
      #pragma unroll
      for (int ni = 0; ni < 4; ++ni)
        acc[mi][ni] = __builtin_amdgcn_mfma_f32_16x16x32_f16(af[mi], bf[ni], acc[mi][ni], 0, 0, 0);
  }
  // epilogue: D row = (lane>>4)*4 + reg (within 16), col = lane&15  [m89 layout]
  const int gm = m0 + wv * 32;
  #pragma unroll
  for (int ni = 0; ni < 4; ++ni) {
    const int col = n0 + ni * 16 + l15;
    if (col < N) {
      const float bv = bias[col];
      #pragma unroll
      for (int mi = 0; mi < 2; ++mi) {
        #pragma unroll
        for (int r = 0; r < 4; ++r) {
          const int row = gm + mi * 16 + hi * 4 + r;
          float v = acc[mi][ni][r] + bv;
          if (outmap) {
            int s = row >> 7, b = row & 127;
            int fr = s * RF + col / MELD, mel = col - (col / MELD) * MELD;
            outmap[((size_t)b * TDEC + fr) * MELD + mel] = v;
          } else if (CbfT) {
            // w1eT[b][col][t], b = row>>9, t = row&511; EXP-domain for k_att
            float a = fminf(fmaxf(2.8853900817779268f * v, -15.f), 15.f);
            CbfT[(((size_t)(row >> 9) * 256 + col) << 9) + (row & 511)] =
                f2bf(__builtin_amdgcn_exp2f(a));
          } else {
            if (C)  C[(size_t)row * ldc + col] = v;
            if (Ch) Ch[(size_t)row * ldc + col] = f2h(v);
          }
        }
      }
    }
  }
}

// ---- batched d_dot MFMA GEMM: dd[b][s][h] = sum_t u[b][s][t]*enc[b][t][h] --
// A = U16 [128][200][512] f16 (per-b contiguous; over-reads into the padded
// tail / adjacent workspace for s>=200 are discarded by the write guard).
// B staged from f32 enc[b][t][h] with transpose+f16 convert in LDS.
// grid = (4 n-tiles, 2 m-tiles, 128 batches). Writes D16[m][256+h].
__global__ __launch_bounds__(256) void k_ddgemm(
    const u16* __restrict__ U, const float* __restrict__ enc,
    u16* __restrict__ D16)
{
  __shared__ _Float16 As[128 * 40];
  __shared__ _Float16 Ws[64 * 40];
  const int b = blockIdx.z;
  const int m0 = blockIdx.y * 128, n0 = blockIdx.x * 64;
  const int tid = threadIdx.x;
  const int wv = tid >> 6, lane = tid & 63;
  const int l15 = lane & 15, hi = lane >> 4;
  f32x4 acc[2][4];
  #pragma unroll
  for (int mi = 0; mi < 2; ++mi)
    #pragma unroll
    for (int ni = 0; ni < 4; ++ni) acc[mi][ni] = (f32x4){0.f, 0.f, 0.f, 0.f};

  const u16* A = U + (size_t)b * STEPS * TENC;
  const float* E = enc + (size_t)b * TENC * H;
  const int ar = tid >> 1, ac = (tid & 1) * 16;
  for (int k0 = 0; k0 < TENC; k0 += 32) {
    __syncthreads();
    {
      const u16* src = A + (size_t)(m0 + ar) * TENC + k0 + ac;
      uint4 v0 = *(const uint4*)(src);
      uint4 v1 = *(const uint4*)(src + 8);
      *(uint4*)&As[ar * 40 + ac] = v0;
      *(uint4*)&As[ar * 40 + ac + 8] = v1;
    }
    {
      // stage B^T: Ws[h - n0][t - k0] from enc[b][t][h] (f32 -> f16)
      #pragma unroll
      for (int it = 0; it < 2; ++it) {
        int flat = tid + it * 256;
        int kk = flat >> 4, hc4 = (flat & 15) * 4;
        float4 v = *(const float4*)(E + (size_t)(k0 + kk) * H + n0 + hc4);
        Ws[(hc4 + 0) * 40 + kk] = (_Float16)v.x;
        Ws[(hc4 + 1) * 40 + kk] = (_Float16)v.y;
        Ws[(hc4 + 2) * 40 + kk] = (_Float16)v.z;
        Ws[(hc4 + 3) * 40 + kk] = (_Float16)v.w;
      }
    }
    __syncthreads();
    f16x8 af[2], bf[4];
    #pragma unroll
    for (int mi = 0; mi < 2; ++mi)
      af[mi] = *(const f16x8*)&As[(wv * 32 + mi * 16 + l15) * 40 + hi * 8];
    #pragma unroll
    for (int ni = 0; ni < 4; ++ni)
      bf[ni] = *(const f16x8*)&Ws[(ni * 16 + l15) * 40 + hi * 8];
    #pragma unroll
    for (int mi = 0; mi < 2; ++mi)
      #pragma unroll
      for (int ni = 0; ni < 4; ++ni)
        acc[mi][ni] = __builtin_amdgcn_mfma_f32_16x16x32_f16(af[mi], bf[ni], acc[mi][ni], 0, 0, 0);
  }
  const int gm = m0 + wv * 32;
  #pragma unroll
  for (int ni = 0; ni < 4; ++ni) {
    const int col = n0 + ni * 16 + l15;
    #pragma unroll
    for (int mi = 0; mi < 2; ++mi) {
      #pragma unroll
      for (int r = 0; r < 4; ++r) {
        const int row = gm + mi * 16 + hi * 4 + r;   // within-batch step s
        if (row < STEPS)
          D16[((size_t)(row * BS + b)) * 512 + 256 + col] = f2h(acc[mi][ni][r]);
      }
    }
  }
}

// ---- per-row sequential GRU chain, v5 -------------------------------
constexpr int KC4H = 2;    // k4-groups per half cached in LDS
constexpr int RG4H = 14;   // k4-groups per half resident in VGPRs (2+14=16)
__global__ __launch_bounds__(512) void k_chain(
    const float* __restrict__ gi,      // [25600][768] includes bih
    const uint4* __restrict__ wpk4,    // [3][32][256] uint4 (f16 pairs)
    const float* __restrict__ bhh,     // [768]
    const float* __restrict__ addsrc,  // nullptr or [25600][astride]
    int astride,
    float* __restrict__ outp, int ostride,
    u16* __restrict__ outph, int ostrideh)
{
  const int b = blockIdx.x, tid = threadIdx.x;
  const int j = tid & 255, kh = tid >> 8;
  __shared__ __align__(16) _Float16 hf[256];
  __shared__ float psum[3][256];
  __shared__ uint4 wl4[3][2 * KC4H][256];
  for (int i = tid; i < 3 * 2 * KC4H * 256; i += 512) {
    int g = i / (2 * KC4H * 256), rem = i - g * (2 * KC4H * 256);
    int slot = rem >> 8, jj = rem & 255;
    int c = slot < KC4H ? slot : slot - KC4H;
    int k4 = (slot < KC4H ? 0 : 16) + c;
    wl4[g][slot][jj] = wpk4[((size_t)g * 32 + k4) * 256 + jj];
  }
  uint4 wreg[3][RG4H];
  #pragma unroll
  for (int g = 0; g < 3; ++g) {
    #pragma unroll
    for (int t = 0; t < RG4H; ++t) {
      const int k4 = kh * 16 + KC4H + t;
      wreg[g][t] = wpk4[((size_t)g * 32 + k4) * 256 + j];
    }
  }
  if (tid < 256) hf[tid] = (_Float16)0.f;
  float hreg = 0.f;
  const float br = bhh[j], bz = bhh[256 + j], bn = bhh[512 + j];
  float gr = 0.f, gz = 0.f, gn = 0.f, av = 0.f;
  if (kh == 0) {
    const float* gim = gi + (size_t)b * 768;
    gr = gim[j]; gz = gim[256 + j]; gn = gim[512 + j];
    if (addsrc) av = addsrc[(size_t)b * astride + j];
  }
  __syncthreads();
  for (int s = 0; s < STEPS; ++s) {
    float gr_n = 0.f, gz_n = 0.f, gn_n = 0.f, av_n = 0.f;
    if (kh == 0 && s + 1 < STEPS) {
      const size_t mn = (size_t)(s + 1) * BS + b;
      const float* gim = gi + mn * 768;
      gr_n = gim[j]; gz_n = gim[256 + j]; gn_n = gim[512 + j];
      if (addsrc) av_n = addsrc[mn * astride + j];
    }
    float ar = 0.f, az = 0.f, an = 0.f;
    const int k4b = kh * 16;
    #pragma unroll
    for (int t = 0; t < RG4H; ++t) {
      const int k4 = k4b + KC4H + t;
      uint4 hp = *(const uint4*)&hf[8 * k4];
      dot8h(ar, wreg[0][t], hp); dot8h(az, wreg[1][t], hp); dot8h(an, wreg[2][t], hp);
    }
    #pragma unroll
    for (int c = 0; c < KC4H; ++c) {
      const int k4 = k4b + c;
      const int slot = kh * KC4H + c;
      uint4 hp = *(const uint4*)&hf[8 * k4];
      dot8h(ar, wl4[0][slot][j], hp); dot8h(az, wl4[1][slot][j], hp); dot8h(an, wl4[2][slot][j], hp);
    }
    if (kh == 1) { psum[0][j] = ar; psum[1][j] = az; psum[2][j] = an; }
    __syncthreads();
    if (kh == 0) {
      const size_t m = (size_t)s * BS + b;
      ar += psum[0][j]; az += psum[1][j]; an += psum[2][j];
      float r = sigm_f(gr + ar + br);
      float z = sigm_f(gz + az + bz);
      float n = tanh_f(gn + r * (an + bn));
      float hn_ = (1.f - z) * n + z * hreg;
      hreg = hn_;
      hf[j] = (_Float16)hn_;
      float ov = hn_ + av;
      if (outp)  outp[m * ostride + j] = ov;
      if (outph) outph[m * ostrideh + j] = f2h(ov);
    }
    __syncthreads();
    gr = gr_n; gz = gz_n; gn = gn_n; av = av_n;
  }
}

// ---- fused scores + softmax: block = (b, 10-step tile) ----
// Factorized sigmoid + 4-way common denominator (one rcp / 4 elems).
// Writes normalized softmax weights u as f16 to U16[b][s][t] (d_dot is a
// separate MFMA GEMM — k_ddgemm).  LDS ~11.6KB (no us/esh) -> high occupancy.
constexpr int ATT_ST = 10;
__global__ __launch_bounds__(256) void k_att(
    const u16* __restrict__ w1eT, const float* __restrict__ Q,
    const float* __restrict__ vw_, u16* __restrict__ U16)
{
  const int b = blockIdx.x, s0 = blockIdx.y * ATT_ST, tid = threadIdx.x;
  __shared__ float qt[ATT_ST][260];
  __shared__ float vws[256];
  __shared__ float redw[ATT_ST][4];
  vws[tid] = -2.0f * vw_[tid];
  #pragma unroll
  for (int si = 0; si < ATT_ST; ++si) {
    float q = 2.8853900817779268f * Q[((size_t)(s0 + si) * BS + b) * H + tid];
    qt[si][tid] = __builtin_amdgcn_exp2f(fminf(fmaxf(q, -15.f), 15.f));
  }
  __syncthreads();

  float sc0[ATT_ST], sc1[ATT_ST];
  #pragma unroll
  for (int si = 0; si < ATT_ST; ++si) { sc0[si] = 0.f; sc1[si] = 0.f; }
  const u32* wrow = (const u32*)w1eT + (size_t)b * H * (TENC / 2);
  for (int h = 0; h < H; h += 4) {
    u32 wa = wrow[(size_t)(h + 0) * 256 + tid];    // t = 2*tid, 2*tid+1
    u32 wb = wrow[(size_t)(h + 1) * 256 + tid];
    u32 wc = wrow[(size_t)(h + 2) * 256 + tid];
    u32 wd = wrow[(size_t)(h + 3) * 256 + tid];
    float Ea0 = bfu_lo(wa), Ea1 = bfu_hi(wa);
    float Eb0 = bfu_lo(wb), Eb1 = bfu_hi(wb);
    float Ec0 = bfu_lo(wc), Ec1 = bfu_hi(wc);
    float Ed0 = bfu_lo(wd), Ed1 = bfu_hi(wd);
    float4 vv = *(const float4*)&vws[h];
    #pragma unroll
    for (int si = 0; si < ATT_ST; ++si) {
      float4 Eq = *(const float4*)&qt[si][h];
      {  // t even
        float F1 = __builtin_fmaf(Ea0, Eq.x, 1.f);
        float F2 = __builtin_fmaf(Eb0, Eq.y, 1.f);
        float F3 = __builtin_fmaf(Ec0, Eq.z, 1.f);
        float F4 = __builtin_fmaf(Ed0, Eq.w, 1.f);
        float P12 = F1 * F2, P34 = F3 * F4;
        float u12 = __builtin_fmaf(vv.y, F1, vv.x * F2);
        float u34 = __builtin_fmaf(vv.w, F3, vv.z * F4);
        float num = __builtin_fmaf(P12, u34, P34 * u12);
        sc0[si] = __builtin_fmaf(num, __builtin_amdgcn_rcpf(P12 * P34), sc0[si]);
      }
      {  // t odd
        float F1 = __builtin_fmaf(Ea1, Eq.x, 1.f);
        float F2 = __builtin_fmaf(Eb1, Eq.y, 1.f);
        float F3 = __builtin_fmaf(Ec1, Eq.z, 1.f);
        float F4 = __builtin_fmaf(Ed1, Eq.w, 1.f);
        float P12 = F1 * F2, P34 = F3 * F4;
        float u12 = __builtin_fmaf(vv.y, F1, vv.x * F2);
        float u34 = __builtin_fmaf(vv.w, F3, vv.z * F4);
        float num = __builtin_fmaf(P12, u34, P34 * u12);
        sc1[si] = __builtin_fmaf(num, __builtin_amdgcn_rcpf(P12 * P34), sc1[si]);
      }
    }
  }
  const int lane = tid & 63, wvi = tid >> 6;
  #pragma unroll
  for (int si = 0; si < ATT_ST; ++si) {
    float mw = fmaxf(sc0[si], sc1[si]);
    for (int off = 1; off < 64; off <<= 1) mw = fmaxf(mw, __shfl_xor(mw, off));
    if (lane == 0) redw[si][wvi] = mw;
  }
  __syncthreads();
  #pragma unroll
  for (int si = 0; si < ATT_ST; ++si) {
    float mx = fmaxf(fmaxf(redw[si][0], redw[si][1]), fmaxf(redw[si][2], redw[si][3]));
    sc0[si] = fexp(sc0[si] - mx);
    sc1[si] = fexp(sc1[si] - mx);
  }
  __syncthreads();
  #pragma unroll
  for (int si = 0; si < ATT_ST; ++si) {
    float sm = sc0[si] + sc1[si];
    for (int off = 1; off < 64; off <<= 1) sm += __shfl_xor(sm, off);
    if (lane == 0) redw[si][wvi] = sm;
  }
  __syncthreads();
  #pragma unroll
  for (int si = 0; si < ATT_ST; ++si) {
    float tot = redw[si][0] + redw[si][1] + redw[si][2] + redw[si][3];
    float li = __builtin_amdgcn_rcpf(tot);
    u32 pk = (u32)f2h(sc0[si] * li) | ((u32)f2h(sc1[si] * li) << 16);
    *(u32*)&U16[((size_t)b * STEPS + s0 + si) * TENC + 2 * tid] = pk;
  }
}

// =====================================================================
//                      FALLBACK PATH (R4, verified)
// =====================================================================
__global__ __launch_bounds__(256) void fbk_zeroinit(float* __restrict__ fst) {
  int i = blockIdx.x * 256 + threadIdx.x;
  if (i < H * BS)              fst[FBDT_F + i] = 0.f;
  else if (i < 2 * H * BS)     fst[FBO1_F + (i - H * BS)] = 0.f;
  else if (i < 3 * H * BS)     fst[FBO2_F + (i - 2 * H * BS)] = 0.f;
}

__global__ __launch_bounds__(256) void fbk_prenet(
    const float* __restrict__ dec, const float* __restrict__ w1, const float* __restrict__ b1,
    const float* __restrict__ w2, const float* __restrict__ b2, u16* __restrict__ xsT)
{
  const int s = blockIdx.x, tid = threadIdx.x;
  __shared__ float X0[32][80];
  __shared__ float P1t[32][256];
  for (int bt = 0; bt < 4; ++bt) {
    const int b0 = bt * 32;
    __syncthreads();
    for (int i = tid; i < 32 * 80; i += 256) {
      int bb = i / 80, m = i - bb * 80;
      X0[bb][m] = dec[((size_t)(b0 + bb) * TDEC + (size_t)s * RF) * MELD + m];
    }
    __syncthreads();
    {
      const int h = tid;
      float acc[32];
      const float bias = b1[h];
      #pragma unroll
      for (int r = 0; r < 32; ++r) acc[r] = bias;
      const float* wr = w1 + (size_t)h * MELD;
      for (int m = 0; m < 80; m += 4) {
        float4 wv = *(const float4*)(wr + m);
        #pragma unroll
        for (int r = 0; r < 32; ++r) {
          float4 x = *(const float4*)&X0[r][m];
          acc[r] += x.x * wv.x + x.y * wv.y + x.z * wv.z + x.w * wv.w;
        }
      }
      #pragma unroll
      for (int r = 0; r < 32; ++r) P1t[r][h] = fmaxf(acc[r], 0.f);
    }
    __syncthreads();
    {
      const int k = tid & 127, bh = tid >> 7;
      float acc[16];
      const float bias = b2[k];
      #pragma unroll
      for (int r = 0; r < 16; ++r) acc[r] = bias;
      const float* wr = w2 + (size_t)k * H;
      for (int h = 0; h < H; h += 4) {
        float4 wv = *(const float4*)(wr + h);
        #pragma unroll
        for (int r = 0; r < 16; ++r) {
          float4 x = *(const float4*)&P1t[bh * 16 + r][h];
          acc[r] += x.x * wv.x + x.y * wv.y + x.z * wv.z + x.w * wv.w;
        }
      }
      #pragma unroll
      for (int r = 0; r < 16; ++r)
        xsT[((size_t)s * HH + k) * BS + b0 + bh * 16 + r] = f2bf(fmaxf(acc[r], 0.f));
    }
  }
}

__global__ __launch_bounds__(256) void fbk_w1enc(
    const float* __restrict__ enc, const float* __restrict__ w1, const float* __restrict__ b1,
    u16* __restrict__ w1e)
{
  const int row0 = blockIdx.x * 32;
  const int tid = threadIdx.x;
  __shared__ float A[32 * 256];
  for (int i = tid * 4; i < 32 * 256; i += 256 * 4) {
    float4 v = *(const float4*)(enc + (size_t)row0 * H + i);
    A[i] = v.x; A[i + 1] = v.y; A[i + 2] = v.z; A[i + 3] = v.w;
  }
  __syncthreads();
  const int h = tid;
  float acc[32];
  const float bias = b1[h];
  #pragma unroll
  for (int r = 0; r < 32; ++r) acc[r] = bias;
  const float* wr = w1 + (size_t)h * H;
  for (int k = 0; k < H; k += 4) {
    float4 wv = *(const float4*)(wr + k);
    #pragma unroll
    for (int r = 0; r < 32; ++r) {
      float4 a = *(const float4*)&A[r * 256 + k];
      acc[r] += a.x * wv.x + a.y * wv.y + a.z * wv.z + a.w * wv.w;
    }
  }
  #pragma unroll
  for (int r = 0; r < 32; ++r) w1e[((size_t)row0 + r) * H + h] = f2bf(acc[r]);
}

__device__ __forceinline__ void fb_gru_body(
    float (*w6)[260], float (*pA)[128], float (*pB)[128], int j, int tid,
    const float* __restrict__ gi_src, const float* __restrict__ h_src,
    const float* __restrict__ wih, const float* __restrict__ whh,
    const float* __restrict__ bih, const float* __restrict__ bhh,
    float* __restrict__ h_out, float* __restrict__ sum_out)
{
  for (int i = tid; i < 3 * H; i += 256) {
    int gg = i >> 8, k = i & 255;
    w6[gg][k]     = wih[((size_t)gg * H + j) * H + k];
    w6[3 + gg][k] = whh[((size_t)gg * H + j) * H + k];
  }
  __syncthreads();
  const int b = tid & 127, kh = tid >> 7;
  float pr = 0, pz = 0, pn = 0, hr = 0, hz = 0, hn = 0;
  for (int k = kh * 128; k < kh * 128 + 128; k += 4) {
    float4 wia = *(const float4*)&w6[0][k];
    float4 wib = *(const float4*)&w6[1][k];
    float4 wic = *(const float4*)&w6[2][k];
    float4 wha = *(const float4*)&w6[3][k];
    float4 whb = *(const float4*)&w6[4][k];
    float4 whc = *(const float4*)&w6[5][k];
    float x0 = gi_src[(size_t)(k + 0) * BS + b], x1 = gi_src[(size_t)(k + 1) * BS + b];
    float x2 = gi_src[(size_t)(k + 2) * BS + b], x3 = gi_src[(size_t)(k + 3) * BS + b];
    float h0 = h_src[(size_t)(k + 0) * BS + b],  h1 = h_src[(size_t)(k + 1) * BS + b];
    float h2 = h_src[(size_t)(k + 2) * BS + b],  h3 = h_src[(size_t)(k + 3) * BS + b];
    pr += x0 * wia.x + x1 * wia.y + x2 * wia.z + x3 * wia.w;
    pz += x0 * wib.x + x1 * wib.y + x2 * wib.z + x3 * wib.w;
    pn += x0 * wic.x + x1 * wic.y + x2 * wic.z + x3 * wic.w;
    hr += h0 * wha.x + h1 * wha.y + h2 * wha.z + h3 * wha.w;
    hz += h0 * whb.x + h1 * whb.y + h2 * whb.z + h3 * whb.w;
    hn += h0 * whc.x + h1 * whc.y + h2 * whc.z + h3 * whc.w;
  }
  if (kh) {
    pA[0][b] = pr; pA[1][b] = pz; pA[2][b] = pn;
    pB[0][b] = hr; pB[1][b] = hz; pB[2][b] = hn;
  }
  __syncthreads();
  if (!kh) {
    float gir = pr + pA[0][b] + bih[j];
    float giz = pz + pA[1][b] + bih[H + j];
    float gin = pn + pA[2][b] + bih[2 * H + j];
    float ghr = hr + pB[0][b] + bhh[j];
    float ghz = hz + pB[1][b] + bhh[H + j];
    float ghn = hn + pB[2][b] + bhh[2 * H + j];
    float r = sigm_f(gir + ghr);
    float z = sigm_f(giz + ghz);
    float n = tanh_f(gin + r * ghn);
    float hp = h_src[(size_t)j * BS + b];
    float o = (1.f - z) * n + z * hp;
    h_out[(size_t)j * BS + b] = o;
    if (sum_out) sum_out[(size_t)j * BS + b] = o + gi_src[(size_t)j * BS + b];
  }
}

__global__ __launch_bounds__(256) void fbk_attgru(
    const u16* __restrict__ xstu, float* __restrict__ fst,
    const float* __restrict__ awih, const float* __restrict__ awhh,
    const float* __restrict__ abih, const float* __restrict__ abhh, int s)
{
  const int j = blockIdx.x, tid = threadIdx.x;
  __shared__ float w6[6][260];
  __shared__ float pA[3][128];
  __shared__ float pB[3][128];
  const float* dprev = fst + FBDT_F + (size_t)(s & 1) * H * BS;
  float*       dcur  = fst + FBDT_F + (size_t)((s + 1) & 1) * H * BS;
  for (int i = tid; i < 3 * HH; i += 256) {
    int gg = i >> 7, k = i & (HH - 1);
    w6[gg][k] = awih[((size_t)gg * H + j) * HH + k];
  }
  for (int i = tid; i < 3 * H; i += 256) {
    int gg = i >> 8, k = i & (H - 1);
    w6[3 + gg][k] = awhh[((size_t)gg * H + j) * H + k];
  }
  __syncthreads();
  const u16* xcol = xstu + (size_t)s * HH * BS;
  const int b = tid & 127, kh = tid >> 7;
  float pr = 0, pz = 0, pn = 0, hr = 0, hz = 0, hn = 0;
  for (int k = kh * 64; k < kh * 64 + 64; k += 4) {
    float4 wa = *(const float4*)&w6[0][k];
    float4 wb = *(const float4*)&w6[1][k];
    float4 wc = *(const float4*)&w6[2][k];
    float x0 = bf2f(xcol[(size_t)(k + 0) * BS + b]), x1 = bf2f(xcol[(size_t)(k + 1) * BS + b]);
    float x2 = bf2f(xcol[(size_t)(k + 2) * BS + b]), x3 = bf2f(xcol[(size_t)(k + 3) * BS + b]);
    pr += x0 * wa.x + x1 * wa.y + x2 * wa.z + x3 * wa.w;
    pz += x0 * wb.x + x1 * wb.y + x2 * wb.z + x3 * wb.w;
    pn += x0 * wc.x + x1 * wc.y + x2 * wc.z + x3 * wc.w;
  }
  for (int k = kh * 128; k < kh * 128 + 128; k += 4) {
    float4 wa = *(const float4*)&w6[3][k];
    float4 wb = *(const float4*)&w6[4][k];
    float4 wc = *(const float4*)&w6[5][k];
    float h0 = dprev[(size_t)(k + 0) * BS + b], h1 = dprev[(size_t)(k + 1) * BS + b];
    float h2 = dprev[(size_t)(k + 2) * BS + b], h3 = dprev[(size_t)(k + 3) * BS + b];
    hr += h0 * wa.x + h1 * wa.y + h2 * wa.z + h3 * wa.w;
    hz += h0 * wb.x + h1 * wb.y + h2 * wb.z + h3 * wb.w;
    hn += h0 * wc.x + h1 * wc.y + h2 * wc.z + h3 * wc.w;
  }
  if (kh) {
    pA[0][b] = pr; pA[1][b] = pz; pA[2][b] = pn;
    pB[0][b] = hr; pB[1][b] = hz; pB[2][b] = hn;
  }
  __syncthreads();
  if (!kh) {
    float gir = pr + pA[0][b] + abih[j];
    float giz = pz + pA[1][b] + abih[H + j];
    float gin = pn + pA[2][b] + abih[2 * H + j];
    float ghr = hr + pB[0][b] + abhh[j];
    float ghz = hz + pB[1][b] + abhh[H + j];
    float ghn = hn + pB[2][b] + abhh[2 * H + j];
    float r = sigm_f(gir + ghr);
    float z = sigm_f(giz + ghz);
    float n = tanh_f(gin + r * ghn);
    float hp = dprev[(size_t)j * BS + b];
    dcur[(size_t)j * BS + b] = (1.f - z) * n + z * hp;
  }
}

__global__ __launch_bounds__(256) void fbk_attn(
    const float* __restrict__ enc, const u16* __restrict__ w1eu,
    const float* __restrict__ w2w, const float* __restrict__ b2w,
    const float* __restrict__ vww, const float* __restrict__ vbw,
    const float* __restrict__ pjw, const float* __restrict__ pjb,
    float* __restrict__ fst, int s)
{
  const int b3 = blockIdx.x, tid = threadIdx.x;
  __shared__ float dsh[256], qs[256], ddh[256], vwsh[256], ev[512], red[256];
  const float* dcur = fst + FBDT_F + (size_t)((s + 1) & 1) * H * BS;
  float* pT = fst + FBPT_F;
  dsh[tid]  = dcur[(size_t)tid * BS + b3];
  vwsh[tid] = vww[tid];
  __syncthreads();
  {
    const int jj = tid;
    const float* wr = w2w + (size_t)jj * H;
    float acc = b2w[jj];
    for (int k = 0; k < H; k += 8) {
      float4 wA = *(const float4*)(wr + k);
      float4 wB = *(const float4*)(wr + k + 4);
      float4 dA = *(const float4*)&dsh[k];
      float4 dB = *(const float4*)&dsh[k + 4];
      acc += dA.x * wA.x + dA.y * wA.y + dA.z * wA.z + dA.w * wA.w
           + dB.x * wB.x + dB.y * wB.y + dB.z * wB.z + dB.w * wB.w;
    }
    qs[jj] = acc;
  }
  __syncthreads();
  const float vbf = vbw[0];
  const u16* wr0 = w1eu + ((size_t)b3 * TENC + tid) * H;
  const u16* wr1 = wr0 + (size_t)256 * H;
  float sc0 = vbf, sc1 = vbf;
  for (int h = 0; h < H; h += 8) {
    uint4 ua = *(const uint4*)(wr0 + h);
    uint4 uc = *(const uint4*)(wr1 + h);
    float4 qA = *(const float4*)&qs[h];
    float4 qB = *(const float4*)&qs[h + 4];
    float4 vA = *(const float4*)&vwsh[h];
    float4 vB = *(const float4*)&vwsh[h + 4];
    sc0 += vA.x * tanh_f(bfu_lo(ua.x) + qA.x) + vA.y * tanh_f(bfu_hi(ua.x) + qA.y)
         + vA.z * tanh_f(bfu_lo(ua.y) + qA.z) + vA.w * tanh_f(bfu_hi(ua.y) + qA.w)
         + vB.x * tanh_f(bfu_lo(ua.z) + qB.x) + vB.y * tanh_f(bfu_hi(ua.z) + qB.y)
         + vB.z * tanh_f(bfu_lo(ua.w) + qB.z) + vB.w * tanh_f(bfu_hi(ua.w) + qB.w);
    sc1 += vA.x * tanh_f(bfu_lo(uc.x) + qA.x) + vA.y * tanh_f(bfu_hi(uc.x) + qA.y)
         + vA.z * tanh_f(bfu_lo(uc.y) + qA.z) + vA.w * tanh_f(bfu_hi(uc.y) + qA.w)
         + vB.x * tanh_f(bfu_lo(uc.z) + qB.x) + vB.y * tanh_f(bfu_hi(uc.z) + qB.y)
         + vB.z * tanh_f(bfu_lo(uc.w) + qB.z) + vB.w * tanh_f(bfu_hi(uc.w) + qB.w);
  }
  red[tid] = fmaxf(sc0, sc1);
  __syncthreads();
  for (int off = 128; off > 0; off >>= 1) {
    if (tid < off) red[tid] = fmaxf(red[tid], red[tid + off]);
    __syncthreads();
  }
  float mx = red[0];
  __syncthreads();
  float e0 = fexp(sc0 - mx), e1 = fexp(sc1 - mx);
  ev[tid] = e0; ev[256 + tid] = e1;
  red[tid] = e0 + e1;
  __syncthreads();
  for (int off = 128; off > 0; off >>= 1) {
    if (tid < off) red[tid] += red[tid + off];
    __syncthreads();
  }
  float linv = __builtin_amdgcn_rcpf(red[0]);
  __syncthreads();
  {
    float vacc = 0.f;
    const float* ep = enc + (size_t)b3 * TENC * H + tid;
    for (int tt = 0; tt < TENC; tt += 4) {
      float4 e4 = *(const float4*)&ev[tt];
      vacc += e4.x * ep[(size_t)(tt + 0) * H] + e4.y * ep[(size_t)(tt + 1) * H]
            + e4.z * ep[(size_t)(tt + 2) * H] + e4.w * ep[(size_t)(tt + 3) * H];
    }
    ddh[tid] = vacc * linv;
  }
  __syncthreads();
  {
    const int jj = tid;
    const float* wr = pjw + (size_t)jj * (2 * H);
    float acc = pjb[jj];
    for (int k = 0; k < H; k += 8) {
      float4 wA = *(const float4*)(wr + k);
      float4 wB = *(const float4*)(wr + k + 4);
      float4 dA = *(const float4*)&dsh[k];
      float4 dB = *(const float4*)&dsh[k + 4];
      acc += dA.x * wA.x + dA.y * wA.y + dA.z * wA.z + dA.w * wA.w
           + dB.x * wB.x + dB.y * wB.y + dB.z * wB.z + dB.w * wB.w;
    }
    for (int k = 0; k < H; k += 8) {
      float4 wA = *(const float4*)(wr + H + k);
      float4 wB = *(const float4*)(wr + H + k + 4);
      float4 dA = *(const float4*)&ddh[k];
      float4 dB = *(const float4*)&ddh[k + 4];
      acc += dA.x * wA.x + dA.y * wA.y + dA.z * wA.z + dA.w * wA.w
           + dB.x * wB.x + dB.y * wB.y + dB.z * wB.z + dB.w * wB.w;
    }
    pT[(size_t)jj * BS + b3] = acc;
  }
}

__global__ __launch_bounds__(256) void fbk_gru1(
    float* __restrict__ fst,
    const float* __restrict__ wih, const float* __restrict__ whh,
    const float* __restrict__ bih, const float* __restrict__ bhh, int s)
{
  __shared__ float w6[6][260];
  __shared__ float pA[3][128];
  __shared__ float pB[3][128];
  const float* pT     = fst + FBPT_F;
  const float* o1prev = fst + FBO1_F + (size_t)(s & 1) * H * BS;
  float*       o1cur  = fst + FBO1_F + (size_t)((s + 1) & 1) * H * BS;
  float*       in2T   = fst + FBIN2_F;
  fb_gru_body(w6, pA, pB, blockIdx.x, threadIdx.x, pT, o1prev, wih, whh, bih, bhh, o1cur, in2T);
}

__device__ __forceinline__ void fb_out_body(
    float (*pA)[128], int bb, int tid, int s,
    const float* __restrict__ sT, const float* __restrict__ ow,
    const float* __restrict__ ob, float* __restrict__ out)
{
  const int b = tid & 127, kh = tid >> 7;
  for (int r = bb; r < OD; r += 128) {
    const float* wr = ow + (size_t)r * H + kh * 128;
    float acc = 0.f;
    for (int kk = 0; kk < 128; kk += 4) {
      float4 wv = *(const float4*)(wr + kk);
      const float* sp = sT + (size_t)(kh * 128 + kk) * BS + b;
      acc += sp[0] * wv.x + sp[BS] * wv.y + sp[2 * BS] * wv.z + sp[3 * BS] * wv.w;
    }
    __syncthreads();
    if (kh) pA[0][b] = acc;
    __syncthreads();
    if (!kh) {
      float y = acc + pA[0][b] + ob[r];
      int frame = s * RF + r / MELD;
      int m = r - (r / MELD) * MELD;
      out[((size_t)b * TDEC + frame) * MELD + m] = y;
    }
  }
}

__global__ __launch_bounds__(256) void fbk_gru2out(
    float* __restrict__ fst,
    const float* __restrict__ wih, const float* __restrict__ whh,
    const float* __restrict__ bih, const float* __restrict__ bhh,
    const float* __restrict__ ow, const float* __restrict__ ob,
    float* __restrict__ out, int s)
{
  const int bid = blockIdx.x, tid = threadIdx.x;
  __shared__ float w6[6][260];
  __shared__ float pA[3][128];
  __shared__ float pB[3][128];
  if (bid < 256) {
    const float* in2T   = fst + FBIN2_F;
    const float* o2prev = fst + FBO2_F + (size_t)(s & 1) * H * BS;
    float*       o2cur  = fst + FBO2_F + (size_t)((s + 1) & 1) * H * BS;
    float*       stp    = fst + FBST_F + (size_t)(s & 1) * H * BS;
    fb_gru_body(w6, pA, pB, bid, tid, in2T, o2prev, wih, whh, bih, bhh, o2cur, stp);
  } else if (s > 0) {
    const float* sT = fst + FBST_F + (size_t)((s - 1) & 1) * H * BS;
    fb_out_body(pA, bid - 256, tid, s - 1, sT, ow, ob, out);
  }
}

__global__ __launch_bounds__(256) void fbk_outlast(
    const float* __restrict__ fst, const float* __restrict__ ow,
    const float* __restrict__ ob, float* __restrict__ out)
{
  __shared__ float pA[3][128];
  const float* sT = fst + FBST_F + (size_t)((STEPS - 1) & 1) * H * BS;
  fb_out_body(pA, blockIdx.x, threadIdx.x, STEPS - 1, sT, ow, ob, out);
}

// =====================================================================
//                              LAUNCH
// =====================================================================
extern "C" void kernel_launch(void* const* d_in, const int* in_sizes, int n_in,
                              void* d_out, int out_size, void* d_ws, size_t ws_size,
                              hipStream_t stream) {
  const float* enc   = (const float*)d_in[0];
  const float* dec   = (const float*)d_in[1];
  const float* pw1   = (const float*)d_in[2];
  const float* pb1   = (const float*)d_in[3];
  const float* pw2   = (const float*)d_in[4];
  const float* pb2   = (const float*)d_in[5];
  const float* w1w   = (const float*)d_in[6];
  const float* b1w   = (const float*)d_in[7];
  const float* w2w   = (const float*)d_in[8];
  const float* b2w   = (const float*)d_in[9];
  const float* vww   = (const float*)d_in[10];
  const float* vbw   = (const float*)d_in[11];
  const float* pjw   = (const float*)d_in[12];
  const float* pjb   = (const float*)d_in[13];
  const float* ow    = (const float*)d_in[14];
  const float* ob    = (const float*)d_in[15];
  const float* awih  = (const float*)d_in[16];
  const float* awhh  = (const float*)d_in[17];
  const float* abih  = (const float*)d_in[18];
  const float* abhh  = (const float*)d_in[19];
  const float* g1wih = (const float*)d_in[20];
  const float* g1whh = (const float*)d_in[21];
  const float* g1bih = (const float*)d_in[22];
  const float* g1bhh = (const float*)d_in[23];
  const float* g2wih = (const float*)d_in[24];
  const float* g2whh = (const float*)d_in[25];
  const float* g2bih = (const float*)d_in[26];
  const float* g2bhh = (const float*)d_in[27];
  float* out = (float*)d_out;
  char* wsb = (char*)d_ws;

  if (ws_size >= NEED_FAST) {
    float* GI   = (float*)(wsb + GI_B);
    u16*   ENC16= (u16*)(wsb + ENC16_B);   // aliases GI, used before GI's first write
    u16*   D16  = (u16*)(wsb + D16_B);
    float* IN2  = (float*)(wsb + IN2_B);
    u16*   w1eT = (u16*)(wsb + W1ET_B);
    u16*   P16  = (u16*)(wsb + P16_B);
    u16*   IN2H = (u16*)(wsb + IN2H_B);
    float* P    = (float*)(wsb + P_B);
    u16*   U16  = (u16*)(wsb + U16_B);     // aliases P, used before P's write
    u16*   XSH  = (u16*)(wsb + XSH_B);
    u16*   ST16 = (u16*)(wsb + ST16_B);
    u32*   wpkA = (u32*)(wsb + WPK_B);
    u32*   wpk1 = wpkA + 98304;
    u32*   wpk2 = wpk1 + 98304;
    u16*   awih16 = (u16*)(wsb + WH_B + WH_AW);
    u16*   w2w16  = (u16*)(wsb + WH_B + WH_W2);
    u16*   pjw16  = (u16*)(wsb + WH_B + WH_PJ);
    u16*   g1w16  = (u16*)(wsb + WH_B + WH_G1);
    u16*   g2w16  = (u16*)(wsb + WH_B + WH_G2);
    u16*   ow16   = (u16*)(wsb + WH_B + WH_OW);
    u16*   w1w16  = (u16*)(wsb + WH_B + WH_W1);

    // all packs + enc16 in one kernel
    k_packall<<<PACKALL_N / 256, 256, 0, stream>>>(
        enc, ENC16, awhh, g1whh, g2whh, wpkA,
        awih, awih16, w2w, w2w16, pjw, pjw16, g1wih, g1w16,
        g2wih, g2w16, ow, ow16, w1w, w1w16);
    // w1eT = bf16(exp2(clamp(2.885*(enc @ w1^T + b1), ±15))), transposed — MFMA
    k_hgemm<<<dim3(4, (BS * TENC) / 128), 256, 0, stream>>>(
        ENC16, H, w1w16, H, b1w, nullptr, nullptr, 0, 256, nullptr, w1eT);
    k_prenet_f<<<STEPS, 256, 0, stream>>>(dec, pw1, pb1, pw2, pb2, XSH);
    // gi_x = xs @ awih^T + abih -> GI [m][768]
    k_hgemm<<<dim3(12, M_ALL / 128), 256, 0, stream>>>(XSH, HH, awih16, HH, abih, GI, nullptr, 768, 768, nullptr, nullptr);
    // attention-GRU chain -> d (f16) into D16[m][0:256]
    k_chain<<<BS, 512, 0, stream>>>(GI, (const uint4*)wpkA, abhh, nullptr, 0, nullptr, 0, D16, 512);
    // Q = d @ w2^T + b2 -> GI reused as Q [m][256]
    k_hgemm<<<dim3(4, M_ALL / 128), 256, 0, stream>>>(D16, 512, w2w16, H, b2w, GI, nullptr, 256, 256, nullptr, nullptr);
    // scores+softmax -> u f16 [b][s][t]
    k_att<<<dim3(BS, STEPS / ATT_ST), 256, 0, stream>>>(w1eT, GI, vww, U16);
    // d_dot via batched MFMA GEMM -> D16[m][256:512]
    k_ddgemm<<<dim3(4, 2, BS), 256, 0, stream>>>(U16, enc, D16);
    // P = [d|ddot] @ pjw^T + pjb -> P f32 + P16 f16  (overwrites U16)
    k_hgemm<<<dim3(4, M_ALL / 128), 256, 0, stream>>>(D16, 512, pjw16, 2 * H, pjb, P, P16, 256, 256, nullptr, nullptr);
    // gi1 = P @ g1wih^T + g1bih -> GI
    k_hgemm<<<dim3(12, M_ALL / 128), 256, 0, stream>>>(P16, H, g1w16, H, g1bih, GI, nullptr, 768, 768, nullptr, nullptr);
    // GRU1 chain; in2 = o1 + P -> IN2 f32 + IN2H f16
    k_chain<<<BS, 512, 0, stream>>>(GI, (const uint4*)wpk1, g1bhh, P, 256, IN2, 256, IN2H, 256);
    // gi2 = in2 @ g2wih^T + g2bih -> GI
    k_hgemm<<<dim3(12, M_ALL / 128), 256, 0, stream>>>(IN2H, H, g2w16, H, g2bih, GI, nullptr, 768, 768, nullptr, nullptr);
    // GRU2 chain; st = in2 + o2 -> ST16 f16
    k_chain<<<BS, 512, 0, stream>>>(GI, (const uint4*)wpk2, g2bhh, IN2, 256, nullptr, 0, ST16, 256);
    // out = st @ ow^T + ob, mapped to [b][frame][mel]
    k_hgemm<<<dim3(7, M_ALL / 128), 256, 0, stream>>>(ST16, H, ow16, H, ob, nullptr, nullptr, 0, OD, out, nullptr);
    return;
  }

  if (ws_size < FB_NEED_B) {
    k_zero<<<(out_size + 255) / 256, 256, 0, stream>>>(out, out_size);
    return;
  }

  // -------- fallback: verified R4 multi-kernel path --------
  u16*  w1eu = (u16*)(wsb + FBW1E_B);
  u16*  xstu = (u16*)(wsb + FBXST_B);
  float* fst = (float*)(wsb + FBF32_B);

  fbk_zeroinit<<<384, 256, 0, stream>>>(fst);
  fbk_prenet<<<STEPS, 256, 0, stream>>>(dec, pw1, pb1, pw2, pb2, xstu);
  fbk_w1enc<<<(BS * TENC) / 32, 256, 0, stream>>>(enc, w1w, b1w, w1eu);
  for (int s = 0; s < STEPS; ++s) {
    fbk_attgru<<<256, 256, 0, stream>>>(xstu, fst, awih, awhh, abih, abhh, s);
    fbk_attn<<<BS, 256, 0, stream>>>(enc, w1eu, w2w, b2w, vww, vbw, pjw, pjb, fst, s);
    fbk_gru1<<<256, 256, 0, stream>>>(fst, g1wih, g1whh, g1bih, g1bhh, s);
    fbk_gru2out<<<384, 256, 0, stream>>>(fst, g2wih, g2whh, g2bih, g2bhh, ow, ob, out, s);
  }
  fbk_outlast<<<BS, 256, 0, stream>>>(fst, ow, ob, out);
}

// Round 9
// 1567.555 us; speedup vs baseline: 4.5904x; 1.0301x over previous
//
#include <hip/hip_runtime.h>
#include <hip/hip_bf16.h>

typedef unsigned short u16;
typedef unsigned int   u32;

constexpr int H     = 256;
constexpr int HH    = 128;
constexpr int MELD  = 80;
constexpr int RF    = 5;
constexpr int BS    = 128;
constexpr int TENC  = 512;
constexpr int TDEC  = 1000;
constexpr int STEPS = 200;
constexpr int OD    = 400;
constexpr int M_ALL = STEPS * BS;   // 25600

// ================= fast-path workspace layout (bytes) =================
constexpr size_t GI_B   = 0;
constexpr size_t ENC16_B= GI_B;                                // f16 enc (pre-GI)
constexpr size_t D16_B  = GI_B   + (size_t)M_ALL*768*4;        //  78,643,200
constexpr size_t IN2_B  = D16_B;                               //  f32 [m][256] (after D16 dead)
constexpr size_t W1ET_B = D16_B  + (size_t)M_ALL*512*2;        // 104,857,600
constexpr size_t P16_B  = W1ET_B;                              //  f16 [m][256] (after w1eT dead)
constexpr size_t IN2H_B = W1ET_B + (size_t)M_ALL*256*2;        // 117,964,800
constexpr size_t P_B    = W1ET_B + (size_t)BS*H*TENC*2;        // 138,412,032
constexpr size_t U16_B  = P_B;                                 //  f16 u-weights (pre-P)
constexpr size_t XSH_B  = P_B    + (size_t)M_ALL*256*4;        // 164,626,432
constexpr size_t ST16_B = XSH_B  + (size_t)M_ALL*128*2;        // 171,180,032
constexpr size_t WPK_B  = ST16_B + (size_t)M_ALL*256*2;        // 184,287,232
constexpr size_t WH_B   = WPK_B  + 3*(size_t)393216;           // 185,466,880
// f16 weight copies within WH_B:
constexpr size_t WH_AW  = 0;                 // awih 768x128
constexpr size_t WH_W2  = WH_AW + 98304*2;   // w2   256x256
constexpr size_t WH_PJ  = WH_W2 + 65536*2;   // pjw  256x512
constexpr size_t WH_G1  = WH_PJ + 131072*2;  // g1wih 768x256
constexpr size_t WH_G2  = WH_G1 + 196608*2;  // g2wih 768x256
constexpr size_t WH_OW  = WH_G2 + 196608*2;  // ow   400x256
constexpr size_t WH_W1  = WH_OW + 102400*2;  // w1   256x256
constexpr size_t WH_END = WH_W1 + 65536*2;
constexpr size_t NEED_FAST = WH_B + WH_END;  // ~187.2 MB (< proven 205.1 MB)

// ================= fallback (R4) workspace layout =====================
constexpr size_t FBW1E_B  = 65536;
constexpr size_t FBXST_B  = FBW1E_B + (size_t)BS*TENC*H*2;
constexpr size_t FBF32_B  = FBXST_B + (size_t)STEPS*HH*BS*2;
constexpr size_t FBDT_F   = 0;
constexpr size_t FBO1_F   = FBDT_F + 2*(size_t)H*BS;
constexpr size_t FBO2_F   = FBO1_F + 2*(size_t)H*BS;
constexpr size_t FBPT_F   = FBO2_F + 2*(size_t)H*BS;
constexpr size_t FBIN2_F  = FBPT_F + (size_t)H*BS;
constexpr size_t FBST_F   = FBIN2_F + (size_t)H*BS;
constexpr size_t FB_NEED_B = FBF32_B + (FBST_F + 2*(size_t)H*BS) * 4;

// ================= helpers =================
__device__ __forceinline__ float bf2f(u16 v) {
  union { u32 x; float f; } c; c.x = ((u32)v) << 16; return c.f;
}
__device__ __forceinline__ float bfu_lo(u32 u) { union { u32 x; float f; } c; c.x = u << 16;        return c.f; }
__device__ __forceinline__ float bfu_hi(u32 u) { union { u32 x; float f; } c; c.x = u & 0xffff0000u; return c.f; }
__device__ __forceinline__ u16 f2bf(float f) {
  union { float f; u32 u; } c; c.f = f;
  u32 u = c.u;
  u32 r = (u + 0x7fffu + ((u >> 16) & 1u)) >> 16;  // RNE
  return (u16)r;
}
__device__ __forceinline__ u16 f2h(float f) {
  union { _Float16 h; u16 u; } c; c.h = (_Float16)f; return c.u;
}
__device__ __forceinline__ float fexp(float x) {
  return __builtin_amdgcn_exp2f(1.4426950408889634f * x);
}
__device__ __forceinline__ float sigm_f(float x) {
  return __builtin_amdgcn_rcpf(1.0f + __builtin_amdgcn_exp2f(-1.4426950408889634f * x));
}
__device__ __forceinline__ float tanh_f(float x) {
  x = fminf(fmaxf(x, -15.f), 15.f);
  float e = __builtin_amdgcn_exp2f(2.8853900817779268f * x);   // e^(2x)
  return (e - 1.0f) * __builtin_amdgcn_rcpf(e + 1.0f);
}

typedef _Float16 hlf2 __attribute__((ext_vector_type(2)));
typedef _Float16 f16x8 __attribute__((ext_vector_type(8)));
typedef float f32x4 __attribute__((ext_vector_type(4)));

__global__ __launch_bounds__(256) void k_zero(float* __restrict__ out, int n) {
  int i = blockIdx.x * 256 + threadIdx.x;
  if (i < n) out[i] = 0.f;
}

// =====================================================================
//                           FAST PATH
// =====================================================================

// ---- prenet (2 fused layers) -> xsh f16 [s][b][128] ----
__global__ __launch_bounds__(256) void k_prenet_f(
    const float* __restrict__ dec, const float* __restrict__ w1, const float* __restrict__ b1,
    const float* __restrict__ w2, const float* __restrict__ b2, u16* __restrict__ xsh)
{
  const int s = blockIdx.x, tid = threadIdx.x;
  __shared__ float X0[32][80];
  __shared__ float P1t[32][256];
  for (int bt = 0; bt < 4; ++bt) {
    const int b0 = bt * 32;
    __syncthreads();
    for (int i = tid; i < 32 * 80; i += 256) {
      int bb = i / 80, m = i - bb * 80;
      X0[bb][m] = dec[((size_t)(b0 + bb) * TDEC + (size_t)s * RF) * MELD + m];
    }
    __syncthreads();
    {
      const int h = tid;
      float acc[32];
      const float bias = b1[h];
      #pragma unroll
      for (int r = 0; r < 32; ++r) acc[r] = bias;
      const float* wr = w1 + (size_t)h * MELD;
      for (int m = 0; m < 80; m += 4) {
        float4 wv = *(const float4*)(wr + m);
        #pragma unroll
        for (int r = 0; r < 32; ++r) {
          float4 x = *(const float4*)&X0[r][m];
          acc[r] += x.x * wv.x + x.y * wv.y + x.z * wv.z + x.w * wv.w;
        }
      }
      #pragma unroll
      for (int r = 0; r < 32; ++r) P1t[r][h] = fmaxf(acc[r], 0.f);
    }
    __syncthreads();
    {
      const int k = tid & 127, bh = tid >> 7;
      float acc[16];
      const float bias = b2[k];
      #pragma unroll
      for (int r = 0; r < 16; ++r) acc[r] = bias;
      const float* wr = w2 + (size_t)k * H;
      for (int h = 0; h < H; h += 4) {
        float4 wv = *(const float4*)(wr + h);
        #pragma unroll
        for (int r = 0; r < 16; ++r) {
          float4 x = *(const float4*)&P1t[bh * 16 + r][h];
          acc[r] += x.x * wv.x + x.y * wv.y + x.z * wv.z + x.w * wv.w;
        }
      }
      #pragma unroll
      for (int r = 0; r < 16; ++r)
        xsh[((size_t)s * BS + b0 + bh * 16 + r) * HH + k] = f2h(fmaxf(acc[r], 0.f));
    }
  }
}

// ---- all packs/copies in one kernel ----
// whh packs now use the MFMA B-fragment layout consumed by k_chain:
//   idx: q = i&3, l = (i>>2)&63, kt = (i>>8)&7, nt = i>>11  (nt<48)
//   col = nt*16 + (l&15); k = kt*32 + (l>>4)*8 + 2q
//   value = f16(w[col][k]) | f16(w[col][k+1])<<16
__global__ __launch_bounds__(256) void k_packall(
    const float* __restrict__ enc, u16* __restrict__ enc16,
    const float* __restrict__ awhh, const float* __restrict__ g1whh,
    const float* __restrict__ g2whh, u32* __restrict__ wpk,
    const float* __restrict__ awih, u16* __restrict__ awih16,
    const float* __restrict__ w2w,  u16* __restrict__ w2w16,
    const float* __restrict__ pjw,  u16* __restrict__ pjw16,
    const float* __restrict__ g1wih, u16* __restrict__ g1w16,
    const float* __restrict__ g2wih, u16* __restrict__ g2w16,
    const float* __restrict__ ow,   u16* __restrict__ ow16,
    const float* __restrict__ w1w,  u16* __restrict__ w1w16)
{
  int i = blockIdx.x * 256 + threadIdx.x;
  if (i < 16777216) { enc16[i] = f2h(enc[i]); return; }
  i -= 16777216;
  if (i < 294912) {
    int which = i / 98304, idx = i - which * 98304;
    const float* w = which == 0 ? awhh : (which == 1 ? g1whh : g2whh);
    int q  = idx & 3;
    int l  = (idx >> 2) & 63;
    int kt = (idx >> 8) & 7;
    int nt = idx >> 11;
    int col = nt * 16 + (l & 15);
    int k   = kt * 32 + (l >> 4) * 8 + 2 * q;
    union { _Float16 f[2]; u32 u; } c;
    c.f[0] = (_Float16)w[(size_t)col * 256 + k];
    c.f[1] = (_Float16)w[(size_t)col * 256 + k + 1];
    wpk[which * 98304 + idx] = c.u;
    return;
  }
  i -= 294912;
  if (i < 98304)  { awih16[i] = f2h(awih[i]); return; }  i -= 98304;
  if (i < 65536)  { w2w16[i]  = f2h(w2w[i]);  return; }  i -= 65536;
  if (i < 131072) { pjw16[i]  = f2h(pjw[i]);  return; }  i -= 131072;
  if (i < 196608) { g1w16[i]  = f2h(g1wih[i]); return; } i -= 196608;
  if (i < 196608) { g2w16[i]  = f2h(g2wih[i]); return; } i -= 196608;
  if (i < 102400) { ow16[i]   = f2h(ow[i]);   return; }  i -= 102400;
  if (i < 65536)  { w1w16[i]  = f2h(w1w[i]);  return; }
}
constexpr int PACKALL_N = 16777216 + 294912 + 856064;   // 17,928,192

// ---- MFMA f16 GEMM: C[M][N] = A[M][K]f16 @ W[N][K]f16^T + bias ----
__global__ __launch_bounds__(256) void k_hgemm(
    const u16* __restrict__ A, int lda,       // f16 [M][lda]
    const u16* __restrict__ W, int K,         // f16 [N][K]
    const float* __restrict__ bias,
    float* __restrict__ C, u16* __restrict__ Ch, int ldc, int N,
    float* __restrict__ outmap, u16* __restrict__ CbfT)
{
  __shared__ _Float16 As[128 * 40];
  __shared__ _Float16 Ws[64 * 40];
  const int m0 = blockIdx.y * 128, n0 = blockIdx.x * 64;
  const int tid = threadIdx.x;
  const int wv = tid >> 6, lane = tid & 63;
  const int l15 = lane & 15, hi = lane >> 4;
  f32x4 acc[2][4];
  #pragma unroll
  for (int mi = 0; mi < 2; ++mi)
    #pragma unroll
    for (int ni = 0; ni < 4; ++ni) acc[mi][ni] = (f32x4){0.f, 0.f, 0.f, 0.f};

  const int ar = tid >> 1, ac = (tid & 1) * 16;   // A stage: 128 rows x 2 half-rows
  const int wr = tid >> 2, wc = (tid & 3) * 8;    // W stage: 64 rows x 4 chunks
  for (int k0 = 0; k0 < K; k0 += 32) {
    __syncthreads();
    {
      const u16* src = A + (size_t)(m0 + ar) * lda + k0 + ac;
      uint4 v0 = *(const uint4*)(src);
      uint4 v1 = *(const uint4*)(src + 8);
      *(uint4*)&As[ar * 40 + ac] = v0;
      *(uint4*)&As[ar * 40 + ac + 8] = v1;
    }
    {
      uint4 v;
      if (n0 + wr < N) v = *(const uint4*)(W + (size_t)(n0 + wr) * K + k0 + wc);
      else { v.x = v.y = v.z = v.w = 0u; }
      *(uint4*)&Ws[wr * 40 + wc] = v;
    }
    __syncthreads();
    f16x8 af[2], bf[4];
    #pragma unroll
    for (int mi = 0; mi < 2; ++mi)
      af[mi] = *(const f16x8*)&As[(wv * 32 + mi * 16 + l15) * 40 + hi * 8];
    #pragma unroll
    for (int ni = 0; ni < 4; ++ni)
      bf[ni] = *(const f16x8*)&Ws[(ni * 16 + l15) * 40 + hi * 8];
    #pragma unroll
    for (int mi = 0; mi < 2; ++mi)
      #pragma unroll
      for (int ni = 0; ni < 4; ++ni)
        acc[mi][ni] = __builtin_amdgcn_mfma_f32_16x16x32_f16(af[mi], bf[ni], acc[mi][ni], 0, 0, 0);
  }
  // epilogue: D row = (lane>>4)*4 + reg (within 16), col = lane&15  [m89 layout]
  const int gm = m0 + wv * 32;
  #pragma unroll
  for (int ni = 0; ni < 4; ++ni) {
    const int col = n0 + ni * 16 + l15;
    if (col < N) {
      const float bv = bias[col];
      #pragma unroll
      for (int mi = 0; mi < 2; ++mi) {
        #pragma unroll
        for (int r = 0; r < 4; ++r) {
          const int row = gm + mi * 16 + hi * 4 + r;
          float v = acc[mi][ni][r] + bv;
          if (outmap) {
            int s = row >> 7, b = row & 127;
            int fr = s * RF + col / MELD, mel = col - (col / MELD) * MELD;
            outmap[((size_t)b * TDEC + fr) * MELD + mel] = v;
          } else if (CbfT) {
            // w1eT[b][col][t], b = row>>9, t = row&511; EXP-domain for k_att
            float a = fminf(fmaxf(2.8853900817779268f * v, -15.f), 15.f);
            CbfT[(((size_t)(row >> 9) * 256 + col) << 9) + (row & 511)] =
                f2bf(__builtin_amdgcn_exp2f(a));
          } else {
            if (C)  C[(size_t)row * ldc + col] = v;
            if (Ch) Ch[(size_t)row * ldc + col] = f2h(v);
          }
        }
      }
    }
  }
}

// ---- batched d_dot MFMA GEMM: dd[b][s][h] = sum_t u[b][s][t]*enc[b][t][h] --
__global__ __launch_bounds__(256) void k_ddgemm(
    const u16* __restrict__ U, const float* __restrict__ enc,
    u16* __restrict__ D16)
{
  __shared__ _Float16 As[128 * 40];
  __shared__ _Float16 Ws[64 * 40];
  const int b = blockIdx.z;
  const int m0 = blockIdx.y * 128, n0 = blockIdx.x * 64;
  const int tid = threadIdx.x;
  const int wv = tid >> 6, lane = tid & 63;
  const int l15 = lane & 15, hi = lane >> 4;
  f32x4 acc[2][4];
  #pragma unroll
  for (int mi = 0; mi < 2; ++mi)
    #pragma unroll
    for (int ni = 0; ni < 4; ++ni) acc[mi][ni] = (f32x4){0.f, 0.f, 0.f, 0.f};

  const u16* A = U + (size_t)b * STEPS * TENC;
  const float* E = enc + (size_t)b * TENC * H;
  const int ar = tid >> 1, ac = (tid & 1) * 16;
  for (int k0 = 0; k0 < TENC; k0 += 32) {
    __syncthreads();
    {
      const u16* src = A + (size_t)(m0 + ar) * TENC + k0 + ac;
      uint4 v0 = *(const uint4*)(src);
      uint4 v1 = *(const uint4*)(src + 8);
      *(uint4*)&As[ar * 40 + ac] = v0;
      *(uint4*)&As[ar * 40 + ac + 8] = v1;
    }
    {
      #pragma unroll
      for (int it = 0; it < 2; ++it) {
        int flat = tid + it * 256;
        int kk = flat >> 4, hc4 = (flat & 15) * 4;
        float4 v = *(const float4*)(E + (size_t)(k0 + kk) * H + n0 + hc4);
        Ws[(hc4 + 0) * 40 + kk] = (_Float16)v.x;
        Ws[(hc4 + 1) * 40 + kk] = (_Float16)v.y;
        Ws[(hc4 + 2) * 40 + kk] = (_Float16)v.z;
        Ws[(hc4 + 3) * 40 + kk] = (_Float16)v.w;
      }
    }
    __syncthreads();
    f16x8 af[2], bf[4];
    #pragma unroll
    for (int mi = 0; mi < 2; ++mi)
      af[mi] = *(const f16x8*)&As[(wv * 32 + mi * 16 + l15) * 40 + hi * 8];
    #pragma unroll
    for (int ni = 0; ni < 4; ++ni)
      bf[ni] = *(const f16x8*)&Ws[(ni * 16 + l15) * 40 + hi * 8];
    #pragma unroll
    for (int mi = 0; mi < 2; ++mi)
      #pragma unroll
      for (int ni = 0; ni < 4; ++ni)
        acc[mi][ni] = __builtin_amdgcn_mfma_f32_16x16x32_f16(af[mi], bf[ni], acc[mi][ni], 0, 0, 0);
  }
  const int gm = m0 + wv * 32;
  #pragma unroll
  for (int ni = 0; ni < 4; ++ni) {
    const int col = n0 + ni * 16 + l15;
    #pragma unroll
    for (int mi = 0; mi < 2; ++mi) {
      #pragma unroll
      for (int r = 0; r < 4; ++r) {
        const int row = gm + mi * 16 + hi * 4 + r;   // within-batch step s
        if (row < STEPS)
          D16[((size_t)(row * BS + b)) * 512 + 256 + col] = f2h(acc[mi][ni][r]);
      }
    }
  }
}

// ---- per-row sequential GRU chain, v6: MFMA matvec -------------------
// 512 threads = 8 waves; one batch per block.  gates = h @ whh^T via
// mfma_f32_16x16x32_f16: h replicated into all 16 A-rows (every lane's
// A-frag reads the same hf span, so all C rows carry the valid dot).
// Weights live as per-wave B-fragments in VGPRs (wave wv owns output
// cols [wv*96, wv*96+96): 6 n-tiles x 8 k-tiles x uint4 = 192 VGPR),
// loaded once from the B-fragment pack (see k_packall).  Gates exchanged
// via 3KB LDS; gate math + h update on tid<256.
__global__ __launch_bounds__(512) void k_chain(
    const float* __restrict__ gi,      // [25600][768] includes bih
    const uint4* __restrict__ wpkB,    // B-fragment pack [48nt][8kt][64lane]
    const float* __restrict__ bhh,     // [768]
    const float* __restrict__ addsrc,  // nullptr or [25600][astride]
    int astride,
    float* __restrict__ outp, int ostride,
    u16* __restrict__ outph, int ostrideh)
{
  const int b = blockIdx.x, tid = threadIdx.x;
  const int wv = tid >> 6, lane = tid & 63;
  const int l15 = lane & 15, hi = lane >> 4;
  __shared__ __align__(16) _Float16 hf[256];
  __shared__ float gsh[768];
  // B fragments: wave wv owns nt = wv*6 .. wv*6+5
  f16x8 bfrag[6][8];
  #pragma unroll
  for (int nti = 0; nti < 6; ++nti)
    #pragma unroll
    for (int kt = 0; kt < 8; ++kt)
      bfrag[nti][kt] = *(const f16x8*)&wpkB[(((size_t)(wv * 6 + nti) * 8 + kt) * 64 + lane)];
  if (tid < 256) hf[tid] = (_Float16)0.f;
  const int j = tid;
  float br = 0.f, bz = 0.f, bn = 0.f, hreg = 0.f;
  float gr = 0.f, gz = 0.f, gn = 0.f, av = 0.f;
  if (tid < 256) {
    br = bhh[j]; bz = bhh[256 + j]; bn = bhh[512 + j];
    const float* gim = gi + (size_t)b * 768;
    gr = gim[j]; gz = gim[256 + j]; gn = gim[512 + j];
    if (addsrc) av = addsrc[(size_t)b * astride + j];
  }
  __syncthreads();
  for (int s = 0; s < STEPS; ++s) {
    // phase 1: MFMA gates = h @ whh^T  (A rows all replicate h)
    f32x4 acc[6];
    #pragma unroll
    for (int nti = 0; nti < 6; ++nti) acc[nti] = (f32x4){0.f, 0.f, 0.f, 0.f};
    #pragma unroll
    for (int kt = 0; kt < 8; ++kt) {
      f16x8 af = *(const f16x8*)&hf[kt * 32 + hi * 8];
      #pragma unroll
      for (int nti = 0; nti < 6; ++nti)
        acc[nti] = __builtin_amdgcn_mfma_f32_16x16x32_f16(af, bfrag[nti][kt], acc[nti], 0, 0, 0);
    }
    // prefetch next-step gi/addsrc (consumed next step, latency hidden)
    float gr_n = 0.f, gz_n = 0.f, gn_n = 0.f, av_n = 0.f;
    if (tid < 256 && s + 1 < STEPS) {
      const size_t mn = (size_t)(s + 1) * BS + b;
      const float* gim = gi + mn * 768;
      gr_n = gim[j]; gz_n = gim[256 + j]; gn_n = gim[512 + j];
      if (addsrc) av_n = addsrc[mn * astride + j];
    }
    if (hi == 0) {
      #pragma unroll
      for (int nti = 0; nti < 6; ++nti)
        gsh[(wv * 6 + nti) * 16 + l15] = acc[nti][0];
    }
    __syncthreads();
    // phase 2: gate math + h update on tid<256
    if (tid < 256) {
      const size_t m = (size_t)s * BS + b;
      float ar = gsh[j], az = gsh[256 + j], an = gsh[512 + j];
      float r = sigm_f(gr + ar + br);
      float z = sigm_f(gz + az + bz);
      float n = tanh_f(gn + r * (an + bn));
      float hn_ = (1.f - z) * n + z * hreg;
      hreg = hn_;
      hf[j] = (_Float16)hn_;
      float ov = hn_ + av;
      if (outp)  outp[m * ostride + j] = ov;
      if (outph) outph[m * ostrideh + j] = f2h(ov);
    }
    __syncthreads();
    gr = gr_n; gz = gz_n; gn = gn_n; av = av_n;
  }
}

// ---- fused scores + softmax: block = (b, 10-step tile) ----
constexpr int ATT_ST = 10;
__global__ __launch_bounds__(256) void k_att(
    const u16* __restrict__ w1eT, const float* __restrict__ Q,
    const float* __restrict__ vw_, u16* __restrict__ U16)
{
  const int b = blockIdx.x, s0 = blockIdx.y * ATT_ST, tid = threadIdx.x;
  __shared__ float qt[ATT_ST][260];
  __shared__ float vws[256];
  __shared__ float redw[ATT_ST][4];
  vws[tid] = -2.0f * vw_[tid];
  #pragma unroll
  for (int si = 0; si < ATT_ST; ++si) {
    float q = 2.8853900817779268f * Q[((size_t)(s0 + si) * BS + b) * H + tid];
    qt[si][tid] = __builtin_amdgcn_exp2f(fminf(fmaxf(q, -15.f), 15.f));
  }
  __syncthreads();

  float sc0[ATT_ST], sc1[ATT_ST];
  #pragma unroll
  for (int si = 0; si < ATT_ST; ++si) { sc0[si] = 0.f; sc1[si] = 0.f; }
  const u32* wrow = (const u32*)w1eT + (size_t)b * H * (TENC / 2);
  for (int h = 0; h < H; h += 4) {
    u32 wa = wrow[(size_t)(h + 0) * 256 + tid];    // t = 2*tid, 2*tid+1
    u32 wb = wrow[(size_t)(h + 1) * 256 + tid];
    u32 wc = wrow[(size_t)(h + 2) * 256 + tid];
    u32 wd = wrow[(size_t)(h + 3) * 256 + tid];
    float Ea0 = bfu_lo(wa), Ea1 = bfu_hi(wa);
    float Eb0 = bfu_lo(wb), Eb1 = bfu_hi(wb);
    float Ec0 = bfu_lo(wc), Ec1 = bfu_hi(wc);
    float Ed0 = bfu_lo(wd), Ed1 = bfu_hi(wd);
    float4 vv = *(const float4*)&vws[h];
    #pragma unroll
    for (int si = 0; si < ATT_ST; ++si) {
      float4 Eq = *(const float4*)&qt[si][h];
      {  // t even
        float F1 = __builtin_fmaf(Ea0, Eq.x, 1.f);
        float F2 = __builtin_fmaf(Eb0, Eq.y, 1.f);
        float F3 = __builtin_fmaf(Ec0, Eq.z, 1.f);
        float F4 = __builtin_fmaf(Ed0, Eq.w, 1.f);
        float P12 = F1 * F2, P34 = F3 * F4;
        float u12 = __builtin_fmaf(vv.y, F1, vv.x * F2);
        float u34 = __builtin_fmaf(vv.w, F3, vv.z * F4);
        float num = __builtin_fmaf(P12, u34, P34 * u12);
        sc0[si] = __builtin_fmaf(num, __builtin_amdgcn_rcpf(P12 * P34), sc0[si]);
      }
      {  // t odd
        float F1 = __builtin_fmaf(Ea1, Eq.x, 1.f);
        float F2 = __builtin_fmaf(Eb1, Eq.y, 1.f);
        float F3 = __builtin_fmaf(Ec1, Eq.z, 1.f);
        float F4 = __builtin_fmaf(Ed1, Eq.w, 1.f);
        float P12 = F1 * F2, P34 = F3 * F4;
        float u12 = __builtin_fmaf(vv.y, F1, vv.x * F2);
        float u34 = __builtin_fmaf(vv.w, F3, vv.z * F4);
        float num = __builtin_fmaf(P12, u34, P34 * u12);
        sc1[si] = __builtin_fmaf(num, __builtin_amdgcn_rcpf(P12 * P34), sc1[si]);
      }
    }
  }
  const int lane = tid & 63, wvi = tid >> 6;
  #pragma unroll
  for (int si = 0; si < ATT_ST; ++si) {
    float mw = fmaxf(sc0[si], sc1[si]);
    for (int off = 1; off < 64; off <<= 1) mw = fmaxf(mw, __shfl_xor(mw, off));
    if (lane == 0) redw[si][wvi] = mw;
  }
  __syncthreads();
  #pragma unroll
  for (int si = 0; si < ATT_ST; ++si) {
    float mx = fmaxf(fmaxf(redw[si][0], redw[si][1]), fmaxf(redw[si][2], redw[si][3]));
    sc0[si] = fexp(sc0[si] - mx);
    sc1[si] = fexp(sc1[si] - mx);
  }
  __syncthreads();
  #pragma unroll
  for (int si = 0; si < ATT_ST; ++si) {
    float sm = sc0[si] + sc1[si];
    for (int off = 1; off < 64; off <<= 1) sm += __shfl_xor(sm, off);
    if (lane == 0) redw[si][wvi] = sm;
  }
  __syncthreads();
  #pragma unroll
  for (int si = 0; si < ATT_ST; ++si) {
    float tot = redw[si][0] + redw[si][1] + redw[si][2] + redw[si][3];
    float li = __builtin_amdgcn_rcpf(tot);
    u32 pk = (u32)f2h(sc0[si] * li) | ((u32)f2h(sc1[si] * li) << 16);
    *(u32*)&U16[((size_t)b * STEPS + s0 + si) * TENC + 2 * tid] = pk;
  }
}

// =====================================================================
//                      FALLBACK PATH (R4, verified)
// =====================================================================
__global__ __launch_bounds__(256) void fbk_zeroinit(float* __restrict__ fst) {
  int i = blockIdx.x * 256 + threadIdx.x;
  if (i < H * BS)              fst[FBDT_F + i] = 0.f;
  else if (i < 2 * H * BS)     fst[FBO1_F + (i - H * BS)] = 0.f;
  else if (i < 3 * H * BS)     fst[FBO2_F + (i - 2 * H * BS)] = 0.f;
}

__global__ __launch_bounds__(256) void fbk_prenet(
    const float* __restrict__ dec, const float* __restrict__ w1, const float* __restrict__ b1,
    const float* __restrict__ w2, const float* __restrict__ b2, u16* __restrict__ xsT)
{
  const int s = blockIdx.x, tid = threadIdx.x;
  __shared__ float X0[32][80];
  __shared__ float P1t[32][256];
  for (int bt = 0; bt < 4; ++bt) {
    const int b0 = bt * 32;
    __syncthreads();
    for (int i = tid; i < 32 * 80; i += 256) {
      int bb = i / 80, m = i - bb * 80;
      X0[bb][m] = dec[((size_t)(b0 + bb) * TDEC + (size_t)s * RF) * MELD + m];
    }
    __syncthreads();
    {
      const int h = tid;
      float acc[32];
      const float bias = b1[h];
      #pragma unroll
      for (int r = 0; r < 32; ++r) acc[r] = bias;
      const float* wr = w1 + (size_t)h * MELD;
      for (int m = 0; m < 80; m += 4) {
        float4 wv = *(const float4*)(wr + m);
        #pragma unroll
        for (int r = 0; r < 32; ++r) {
          float4 x = *(const float4*)&X0[r][m];
          acc[r] += x.x * wv.x + x.y * wv.y + x.z * wv.z + x.w * wv.w;
        }
      }
      #pragma unroll
      for (int r = 0; r < 32; ++r) P1t[r][h] = fmaxf(acc[r], 0.f);
    }
    __syncthreads();
    {
      const int k = tid & 127, bh = tid >> 7;
      float acc[16];
      const float bias = b2[k];
      #pragma unroll
      for (int r = 0; r < 16; ++r) acc[r] = bias;
      const float* wr = w2 + (size_t)k * H;
      for (int h = 0; h < H; h += 4) {
        float4 wv = *(const float4*)(wr + h);
        #pragma unroll
        for (int r = 0; r < 16; ++r) {
          float4 x = *(const float4*)&P1t[bh * 16 + r][h];
          acc[r] += x.x * wv.x + x.y * wv.y + x.z * wv.z + x.w * wv.w;
        }
      }
      #pragma unroll
      for (int r = 0; r < 16; ++r)
        xsT[((size_t)s * HH + k) * BS + b0 + bh * 16 + r] = f2bf(fmaxf(acc[r], 0.f));
    }
  }
}

__global__ __launch_bounds__(256) void fbk_w1enc(
    const float* __restrict__ enc, const float* __restrict__ w1, const float* __restrict__ b1,
    u16* __restrict__ w1e)
{
  const int row0 = blockIdx.x * 32;
  const int tid = threadIdx.x;
  __shared__ float A[32 * 256];
  for (int i = tid * 4; i < 32 * 256; i += 256 * 4) {
    float4 v = *(const float4*)(enc + (size_t)row0 * H + i);
    A[i] = v.x; A[i + 1] = v.y; A[i + 2] = v.z; A[i + 3] = v.w;
  }
  __syncthreads();
  const int h = tid;
  float acc[32];
  const float bias = b1[h];
  #pragma unroll
  for (int r = 0; r < 32; ++r) acc[r] = bias;
  const float* wr = w1 + (size_t)h * H;
  for (int k = 0; k < H; k += 4) {
    float4 wv = *(const float4*)(wr + k);
    #pragma unroll
    for (int r = 0; r < 32; ++r) {
      float4 a = *(const float4*)&A[r * 256 + k];
      acc[r] += a.x * wv.x + a.y * wv.y + a.z * wv.z + a.w * wv.w;
    }
  }
  #pragma unroll
  for (int r = 0; r < 32; ++r) w1e[((size_t)row0 + r) * H + h] = f2bf(acc[r]);
}

__device__ __forceinline__ void fb_gru_body(
    float (*w6)[260], float (*pA)[128], float (*pB)[128], int j, int tid,
    const float* __restrict__ gi_src, const float* __restrict__ h_src,
    const float* __restrict__ wih, const float* __restrict__ whh,
    const float* __restrict__ bih, const float* __restrict__ bhh,
    float* __restrict__ h_out, float* __restrict__ sum_out)
{
  for (int i = tid; i < 3 * H; i += 256) {
    int gg = i >> 8, k = i & 255;
    w6[gg][k]     = wih[((size_t)gg * H + j) * H + k];
    w6[3 + gg][k] = whh[((size_t)gg * H + j) * H + k];
  }
  __syncthreads();
  const int b = tid & 127, kh = tid >> 7;
  float pr = 0, pz = 0, pn = 0, hr = 0, hz = 0, hn = 0;
  for (int k = kh * 128; k < kh * 128 + 128; k += 4) {
    float4 wia = *(const float4*)&w6[0][k];
    float4 wib = *(const float4*)&w6[1][k];
    float4 wic = *(const float4*)&w6[2][k];
    float4 wha = *(const float4*)&w6[3][k];
    float4 whb = *(const float4*)&w6[4][k];
    float4 whc = *(const float4*)&w6[5][k];
    float x0 = gi_src[(size_t)(k + 0) * BS + b], x1 = gi_src[(size_t)(k + 1) * BS + b];
    float x2 = gi_src[(size_t)(k + 2) * BS + b], x3 = gi_src[(size_t)(k + 3) * BS + b];
    float h0 = h_src[(size_t)(k + 0) * BS + b],  h1 = h_src[(size_t)(k + 1) * BS + b];
    float h2 = h_src[(size_t)(k + 2) * BS + b],  h3 = h_src[(size_t)(k + 3) * BS + b];
    pr += x0 * wia.x + x1 * wia.y + x2 * wia.z + x3 * wia.w;
    pz += x0 * wib.x + x1 * wib.y + x2 * wib.z + x3 * wib.w;
    pn += x0 * wic.x + x1 * wic.y + x2 * wic.z + x3 * wic.w;
    hr += h0 * wha.x + h1 * wha.y + h2 * wha.z + h3 * wha.w;
    hz += h0 * whb.x + h1 * whb.y + h2 * whb.z + h3 * whb.w;
    hn += h0 * whc.x + h1 * whc.y + h2 * whc.z + h3 * whc.w;
  }
  if (kh) {
    pA[0][b] = pr; pA[1][b] = pz; pA[2][b] = pn;
    pB[0][b] = hr; pB[1][b] = hz; pB[2][b] = hn;
  }
  __syncthreads();
  if (!kh) {
    float gir = pr + pA[0][b] + bih[j];
    float giz = pz + pA[1][b] + bih[H + j];
    float gin = pn + pA[2][b] + bih[2 * H + j];
    float ghr = hr + pB[0][b] + bhh[j];
    float ghz = hz + pB[1][b] + bhh[H + j];
    float ghn = hn + pB[2][b] + bhh[2 * H + j];
    float r = sigm_f(gir + ghr);
    float z = sigm_f(giz + ghz);
    float n = tanh_f(gin + r * ghn);
    float hp = h_src[(size_t)j * BS + b];
    float o = (1.f - z) * n + z * hp;
    h_out[(size_t)j * BS + b] = o;
    if (sum_out) sum_out[(size_t)j * BS + b] = o + gi_src[(size_t)j * BS + b];
  }
}

__global__ __launch_bounds__(256) void fbk_attgru(
    const u16* __restrict__ xstu, float* __restrict__ fst,
    const float* __restrict__ awih, const float* __restrict__ awhh,
    const float* __restrict__ abih, const float* __restrict__ abhh, int s)
{
  const int j = blockIdx.x, tid = threadIdx.x;
  __shared__ float w6[6][260];
  __shared__ float pA[3][128];
  __shared__ float pB[3][128];
  const float* dprev = fst + FBDT_F + (size_t)(s & 1) * H * BS;
  float*       dcur  = fst + FBDT_F + (size_t)((s + 1) & 1) * H * BS;
  for (int i = tid; i < 3 * HH; i += 256) {
    int gg = i >> 7, k = i & (HH - 1);
    w6[gg][k] = awih[((size_t)gg * H + j) * HH + k];
  }
  for (int i = tid; i < 3 * H; i += 256) {
    int gg = i >> 8, k = i & (H - 1);
    w6[3 + gg][k] = awhh[((size_t)gg * H + j) * H + k];
  }
  __syncthreads();
  const u16* xcol = xstu + (size_t)s * HH * BS;
  const int b = tid & 127, kh = tid >> 7;
  float pr = 0, pz = 0, pn = 0, hr = 0, hz = 0, hn = 0;
  for (int k = kh * 64; k < kh * 64 + 64; k += 4) {
    float4 wa = *(const float4*)&w6[0][k];
    float4 wb = *(const float4*)&w6[1][k];
    float4 wc = *(const float4*)&w6[2][k];
    float x0 = bf2f(xcol[(size_t)(k + 0) * BS + b]), x1 = bf2f(xcol[(size_t)(k + 1) * BS + b]);
    float x2 = bf2f(xcol[(size_t)(k + 2) * BS + b]), x3 = bf2f(xcol[(size_t)(k + 3) * BS + b]);
    pr += x0 * wa.x + x1 * wa.y + x2 * wa.z + x3 * wa.w;
    pz += x0 * wb.x + x1 * wb.y + x2 * wb.z + x3 * wb.w;
    pn += x0 * wc.x + x1 * wc.y + x2 * wc.z + x3 * wc.w;
  }
  for (int k = kh * 128; k < kh * 128 + 128; k += 4) {
    float4 wa = *(const float4*)&w6[3][k];
    float4 wb = *(const float4*)&w6[4][k];
    float4 wc = *(const float4*)&w6[5][k];
    float h0 = dprev[(size_t)(k + 0) * BS + b], h1 = dprev[(size_t)(k + 1) * BS + b];
    float h2 = dprev[(size_t)(k + 2) * BS + b], h3 = dprev[(size_t)(k + 3) * BS + b];
    hr += h0 * wa.x + h1 * wa.y + h2 * wa.z + h3 * wa.w;
    hz += h0 * wb.x + h1 * wb.y + h2 * wb.z + h3 * wb.w;
    hn += h0 * wc.x + h1 * wc.y + h2 * wc.z + h3 * wc.w;
  }
  if (kh) {
    pA[0][b] = pr; pA[1][b] = pz; pA[2][b] = pn;
    pB[0][b] = hr; pB[1][b] = hz; pB[2][b] = hn;
  }
  __syncthreads();
  if (!kh) {
    float gir = pr + pA[0][b] + abih[j];
    float giz = pz + pA[1][b] + abih[H + j];
    float gin = pn + pA[2][b] + abih[2 * H + j];
    float ghr = hr + pB[0][b] + abhh[j];
    float ghz = hz + pB[1][b] + abhh[H + j];
    float ghn = hn + pB[2][b] + abhh[2 * H + j];
    float r = sigm_f(gir + ghr);
    float z = sigm_f(giz + ghz);
    float n = tanh_f(gin + r * ghn);
    float hp = dprev[(size_t)j * BS + b];
    dcur[(size_t)j * BS + b] = (1.f - z) * n + z * hp;
  }
}

__global__ __launch_bounds__(256) void fbk_attn(
    const float* __restrict__ enc, const u16* __restrict__ w1eu,
    const float* __restrict__ w2w, const float* __restrict__ b2w,
    const float* __restrict__ vww, const float* __restrict__ vbw,
    const float* __restrict__ pjw, const float* __restrict__ pjb,
    float* __restrict__ fst, int s)
{
  const int b3 = blockIdx.x, tid = threadIdx.x;
  __shared__ float dsh[256], qs[256], ddh[256], vwsh[256], ev[512], red[256];
  const float* dcur = fst + FBDT_F + (size_t)((s + 1) & 1) * H * BS;
  float* pT = fst + FBPT_F;
  dsh[tid]  = dcur[(size_t)tid * BS + b3];
  vwsh[tid] = vww[tid];
  __syncthreads();
  {
    const int jj = tid;
    const float* wr = w2w + (size_t)jj * H;
    float acc = b2w[jj];
    for (int k = 0; k < H; k += 8) {
      float4 wA = *(const float4*)(wr + k);
      float4 wB = *(const float4*)(wr + k + 4);
      float4 dA = *(const float4*)&dsh[k];
      float4 dB = *(const float4*)&dsh[k + 4];
      acc += dA.x * wA.x + dA.y * wA.y + dA.z * wA.z + dA.w * wA.w
           + dB.x * wB.x + dB.y * wB.y + dB.z * wB.z + dB.w * wB.w;
    }
    qs[jj] = acc;
  }
  __syncthreads();
  const float vbf = vbw[0];
  const u16* wr0 = w1eu + ((size_t)b3 * TENC + tid) * H;
  const u16* wr1 = wr0 + (size_t)256 * H;
  float sc0 = vbf, sc1 = vbf;
  for (int h = 0; h < H; h += 8) {
    uint4 ua = *(const uint4*)(wr0 + h);
    uint4 uc = *(const uint4*)(wr1 + h);
    float4 qA = *(const float4*)&qs[h];
    float4 qB = *(const float4*)&qs[h + 4];
    float4 vA = *(const float4*)&vwsh[h];
    float4 vB = *(const float4*)&vwsh[h + 4];
    sc0 += vA.x * tanh_f(bfu_lo(ua.x) + qA.x) + vA.y * tanh_f(bfu_hi(ua.x) + qA.y)
         + vA.z * tanh_f(bfu_lo(ua.y) + qA.z) + vA.w * tanh_f(bfu_hi(ua.y) + qA.w)
         + vB.x * tanh_f(bfu_lo(ua.z) + qB.x) + vB.y * tanh_f(bfu_hi(ua.z) + qB.y)
         + vB.z * tanh_f(bfu_lo(ua.w) + qB.z) + vB.w * tanh_f(bfu_hi(ua.w) + qB.w);
    sc1 += vA.x * tanh_f(bfu_lo(uc.x) + qA.x) + vA.y * tanh_f(bfu_hi(uc.x) + qA.y)
         + vA.z * tanh_f(bfu_lo(uc.y) + qA.z) + vA.w * tanh_f(bfu_hi(uc.y) + qA.w)
         + vB.x * tanh_f(bfu_lo(uc.z) + qB.x) + vB.y * tanh_f(bfu_hi(uc.z) + qB.y)
         + vB.z * tanh_f(bfu_lo(uc.w) + qB.z) + vB.w * tanh_f(bfu_hi(uc.w) + qB.w);
  }
  red[tid] = fmaxf(sc0, sc1);
  __syncthreads();
  for (int off = 128; off > 0; off >>= 1) {
    if (tid < off) red[tid] = fmaxf(red[tid], red[tid + off]);
    __syncthreads();
  }
  float mx = red[0];
  __syncthreads();
  float e0 = fexp(sc0 - mx), e1 = fexp(sc1 - mx);
  ev[tid] = e0; ev[256 + tid] = e1;
  red[tid] = e0 + e1;
  __syncthreads();
  for (int off = 128; off > 0; off >>= 1) {
    if (tid < off) red[tid] += red[tid + off];
    __syncthreads();
  }
  float linv = __builtin_amdgcn_rcpf(red[0]);
  __syncthreads();
  {
    float vacc = 0.f;
    const float* ep = enc + (size_t)b3 * TENC * H + tid;
    for (int tt = 0; tt < TENC; tt += 4) {
      float4 e4 = *(const float4*)&ev[tt];
      vacc += e4.x * ep[(size_t)(tt + 0) * H] + e4.y * ep[(size_t)(tt + 1) * H]
            + e4.z * ep[(size_t)(tt + 2) * H] + e4.w * ep[(size_t)(tt + 3) * H];
    }
    ddh[tid] = vacc * linv;
  }
  __syncthreads();
  {
    const int jj = tid;
    const float* wr = pjw + (size_t)jj * (2 * H);
    float acc = pjb[jj];
    for (int k = 0; k < H; k += 8) {
      float4 wA = *(const float4*)(wr + k);
      float4 wB = *(const float4*)(wr + k + 4);
      float4 dA = *(const float4*)&dsh[k];
      float4 dB = *(const float4*)&dsh[k + 4];
      acc += dA.x * wA.x + dA.y * wA.y + dA.z * wA.z + dA.w * wA.w
           + dB.x * wB.x + dB.y * wB.y + dB.z * wB.z + dB.w * wB.w;
    }
    for (int k = 0; k < H; k += 8) {
      float4 wA = *(const float4*)(wr + H + k);
      float4 wB = *(const float4*)(wr + H + k + 4);
      float4 dA = *(const float4*)&ddh[k];
      float4 dB = *(const float4*)&ddh[k + 4];
      acc += dA.x * wA.x + dA.y * wA.y + dA.z * wA.z + dA.w * wA.w
           + dB.x * wB.x + dB.y * wB.y + dB.z * wB.z + dB.w * wB.w;
    }
    pT[(size_t)jj * BS + b3] = acc;
  }
}

__global__ __launch_bounds__(256) void fbk_gru1(
    float* __restrict__ fst,
    const float* __restrict__ wih, const float* __restrict__ whh,
    const float* __restrict__ bih, const float* __restrict__ bhh, int s)
{
  __shared__ float w6[6][260];
  __shared__ float pA[3][128];
  __shared__ float pB[3][128];
  const float* pT     = fst + FBPT_F;
  const float* o1prev = fst + FBO1_F + (size_t)(s & 1) * H * BS;
  float*       o1cur  = fst + FBO1_F + (size_t)((s + 1) & 1) * H * BS;
  float*       in2T   = fst + FBIN2_F;
  fb_gru_body(w6, pA, pB, blockIdx.x, threadIdx.x, pT, o1prev, wih, whh, bih, bhh, o1cur, in2T);
}

__device__ __forceinline__ void fb_out_body(
    float (*pA)[128], int bb, int tid, int s,
    const float* __restrict__ sT, const float* __restrict__ ow,
    const float* __restrict__ ob, float* __restrict__ out)
{
  const int b = tid & 127, kh = tid >> 7;
  for (int r = bb; r < OD; r += 128) {
    const float* wr = ow + (size_t)r * H + kh * 128;
    float acc = 0.f;
    for (int kk = 0; kk < 128; kk += 4) {
      float4 wv = *(const float4*)(wr + kk);
      const float* sp = sT + (size_t)(kh * 128 + kk) * BS + b;
      acc += sp[0] * wv.x + sp[BS] * wv.y + sp[2 * BS] * wv.z + sp[3 * BS] * wv.w;
    }
    __syncthreads();
    if (kh) pA[0][b] = acc;
    __syncthreads();
    if (!kh) {
      float y = acc + pA[0][b] + ob[r];
      int frame = s * RF + r / MELD;
      int m = r - (r / MELD) * MELD;
      out[((size_t)b * TDEC + frame) * MELD + m] = y;
    }
  }
}

__global__ __launch_bounds__(256) void fbk_gru2out(
    float* __restrict__ fst,
    const float* __restrict__ wih, const float* __restrict__ whh,
    const float* __restrict__ bih, const float* __restrict__ bhh,
    const float* __restrict__ ow, const float* __restrict__ ob,
    float* __restrict__ out, int s)
{
  const int bid = blockIdx.x, tid = threadIdx.x;
  __shared__ float w6[6][260];
  __shared__ float pA[3][128];
  __shared__ float pB[3][128];
  if (bid < 256) {
    const float* in2T   = fst + FBIN2_F;
    const float* o2prev = fst + FBO2_F + (size_t)(s & 1) * H * BS;
    float*       o2cur  = fst + FBO2_F + (size_t)((s + 1) & 1) * H * BS;
    float*       stp    = fst + FBST_F + (size_t)(s & 1) * H * BS;
    fb_gru_body(w6, pA, pB, bid, tid, in2T, o2prev, wih, whh, bih, bhh, o2cur, stp);
  } else if (s > 0) {
    const float* sT = fst + FBST_F + (size_t)((s - 1) & 1) * H * BS;
    fb_out_body(pA, bid - 256, tid, s - 1, sT, ow, ob, out);
  }
}

__global__ __launch_bounds__(256) void fbk_outlast(
    const float* __restrict__ fst, const float* __restrict__ ow,
    const float* __restrict__ ob, float* __restrict__ out)
{
  __shared__ float pA[3][128];
  const float* sT = fst + FBST_F + (size_t)((STEPS - 1) & 1) * H * BS;
  fb_out_body(pA, blockIdx.x, threadIdx.x, STEPS - 1, sT, ow, ob, out);
}

// =====================================================================
//                              LAUNCH
// =====================================================================
extern "C" void kernel_launch(void* const* d_in, const int* in_sizes, int n_in,
                              void* d_out, int out_size, void* d_ws, size_t ws_size,
                              hipStream_t stream) {
  const float* enc   = (const float*)d_in[0];
  const float* dec   = (const float*)d_in[1];
  const float* pw1   = (const float*)d_in[2];
  const float* pb1   = (const float*)d_in[3];
  const float* pw2   = (const float*)d_in[4];
  const float* pb2   = (const float*)d_in[5];
  const float* w1w   = (const float*)d_in[6];
  const float* b1w   = (const float*)d_in[7];
  const float* w2w   = (const float*)d_in[8];
  const float* b2w   = (const float*)d_in[9];
  const float* vww   = (const float*)d_in[10];
  const float* vbw   = (const float*)d_in[11];
  const float* pjw   = (const float*)d_in[12];
  const float* pjb   = (const float*)d_in[13];
  const float* ow    = (const float*)d_in[14];
  const float* ob    = (const float*)d_in[15];
  const float* awih  = (const float*)d_in[16];
  const float* awhh  = (const float*)d_in[17];
  const float* abih  = (const float*)d_in[18];
  const float* abhh  = (const float*)d_in[19];
  const float* g1wih = (const float*)d_in[20];
  const float* g1whh = (const float*)d_in[21];
  const float* g1bih = (const float*)d_in[22];
  const float* g1bhh = (const float*)d_in[23];
  const float* g2wih = (const float*)d_in[24];
  const float* g2whh = (const float*)d_in[25];
  const float* g2bih = (const float*)d_in[26];
  const float* g2bhh = (const float*)d_in[27];
  float* out = (float*)d_out;
  char* wsb = (char*)d_ws;

  if (ws_size >= NEED_FAST) {
    float* GI   = (float*)(wsb + GI_B);
    u16*   ENC16= (u16*)(wsb + ENC16_B);   // aliases GI, used before GI's first write
    u16*   D16  = (u16*)(wsb + D16_B);
    float* IN2  = (float*)(wsb + IN2_B);
    u16*   w1eT = (u16*)(wsb + W1ET_B);
    u16*   P16  = (u16*)(wsb + P16_B);
    u16*   IN2H = (u16*)(wsb + IN2H_B);
    float* P    = (float*)(wsb + P_B);
    u16*   U16  = (u16*)(wsb + U16_B);     // aliases P, used before P's write
    u16*   XSH  = (u16*)(wsb + XSH_B);
    u16*   ST16 = (u16*)(wsb + ST16_B);
    u32*   wpkA = (u32*)(wsb + WPK_B);
    u32*   wpk1 = wpkA + 98304;
    u32*   wpk2 = wpk1 + 98304;
    u16*   awih16 = (u16*)(wsb + WH_B + WH_AW);
    u16*   w2w16  = (u16*)(wsb + WH_B + WH_W2);
    u16*   pjw16  = (u16*)(wsb + WH_B + WH_PJ);
    u16*   g1w16  = (u16*)(wsb + WH_B + WH_G1);
    u16*   g2w16  = (u16*)(wsb + WH_B + WH_G2);
    u16*   ow16   = (u16*)(wsb + WH_B + WH_OW);
    u16*   w1w16  = (u16*)(wsb + WH_B + WH_W1);

    // all packs + enc16 in one kernel
    k_packall<<<PACKALL_N / 256, 256, 0, stream>>>(
        enc, ENC16, awhh, g1whh, g2whh, wpkA,
        awih, awih16, w2w, w2w16, pjw, pjw16, g1wih, g1w16,
        g2wih, g2w16, ow, ow16, w1w, w1w16);
    // w1eT = bf16(exp2(clamp(2.885*(enc @ w1^T + b1), ±15))), transposed — MFMA
    k_hgemm<<<dim3(4, (BS * TENC) / 128), 256, 0, stream>>>(
        ENC16, H, w1w16, H, b1w, nullptr, nullptr, 0, 256, nullptr, w1eT);
    k_prenet_f<<<STEPS, 256, 0, stream>>>(dec, pw1, pb1, pw2, pb2, XSH);
    // gi_x = xs @ awih^T + abih -> GI [m][768]
    k_hgemm<<<dim3(12, M_ALL / 128), 256, 0, stream>>>(XSH, HH, awih16, HH, abih, GI, nullptr, 768, 768, nullptr, nullptr);
    // attention-GRU chain (MFMA matvec) -> d (f16) into D16[m][0:256]
    k_chain<<<BS, 512, 0, stream>>>(GI, (const uint4*)wpkA, abhh, nullptr, 0, nullptr, 0, D16, 512);
    // Q = d @ w2^T + b2 -> GI reused as Q [m][256]
    k_hgemm<<<dim3(4, M_ALL / 128), 256, 0, stream>>>(D16, 512, w2w16, H, b2w, GI, nullptr, 256, 256, nullptr, nullptr);
    // scores+softmax -> u f16 [b][s][t]
    k_att<<<dim3(BS, STEPS / ATT_ST), 256, 0, stream>>>(w1eT, GI, vww, U16);
    // d_dot via batched MFMA GEMM -> D16[m][256:512]
    k_ddgemm<<<dim3(4, 2, BS), 256, 0, stream>>>(U16, enc, D16);
    // P = [d|ddot] @ pjw^T + pjb -> P f32 + P16 f16  (overwrites U16)
    k_hgemm<<<dim3(4, M_ALL / 128), 256, 0, stream>>>(D16, 512, pjw16, 2 * H, pjb, P, P16, 256, 256, nullptr, nullptr);
    // gi1 = P @ g1wih^T + g1bih -> GI
    k_hgemm<<<dim3(12, M_ALL / 128), 256, 0, stream>>>(P16, H, g1w16, H, g1bih, GI, nullptr, 768, 768, nullptr, nullptr);
    // GRU1 chain; in2 = o1 + P -> IN2 f32 + IN2H f16
    k_chain<<<BS, 512, 0, stream>>>(GI, (const uint4*)wpk1, g1bhh, P, 256, IN2, 256, IN2H, 256);
    // gi2 = in2 @ g2wih^T + g2bih -> GI
    k_hgemm<<<dim3(12, M_ALL / 128), 256, 0, stream>>>(IN2H, H, g2w16, H, g2bih, GI, nullptr, 768, 768, nullptr, nullptr);
    // GRU2 chain; st = in2 + o2 -> ST16 f16
    k_chain<<<BS, 512, 0, stream>>>(GI, (const uint4*)wpk2, g2bhh, IN2, 256, nullptr, 0, ST16, 256);
    // out = st @ ow^T + ob, mapped to [b][frame][mel]
    k_hgemm<<<dim3(7, M_ALL / 128), 256, 0, stream>>>(ST16, H, ow16, H, ob, nullptr, nullptr, 0, OD, out, nullptr);
    return;
  }

  if (ws_size < FB_NEED_B) {
    k_zero<<<(out_size + 255) / 256, 256, 0, stream>>>(out, out_size);
    return;
  }

  // -------- fallback: verified R4 multi-kernel path --------
  u16*  w1eu = (u16*)(wsb + FBW1E_B);
  u16*  xstu = (u16*)(wsb + FBXST_B);
  float* fst = (float*)(wsb + FBF32_B);

  fbk_zeroinit<<<384, 256, 0, stream>>>(fst);
  fbk_prenet<<<STEPS, 256, 0, stream>>>(dec, pw1, pb1, pw2, pb2, xstu);
  fbk_w1enc<<<(BS * TENC) / 32, 256, 0, stream>>>(enc, w1w, b1w, w1eu);
  for (int s = 0; s < STEPS; ++s) {
    fbk_attgru<<<256, 256, 0, stream>>>(xstu, fst, awih, awhh, abih, abhh, s);
    fbk_attn<<<BS, 256, 0, stream>>>(enc, w1eu, w2w, b2w, vww, vbw, pjw, pjb, fst, s);
    fbk_gru1<<<256, 256, 0, stream>>>(fst, g1wih, g1whh, g1bih, g1bhh, s);
    fbk_gru2out<<<384, 256, 0, stream>>>(fst, g2wih, g2whh, g2bih, g2bhh, ow, ob, out, s);
  }
  fbk_outlast<<<BS, 256, 0, stream>>>(fst, ow, ob, out);
}